// Round 7
// baseline (2231.280 us; speedup 1.0000x reference)
//
#include <hip/hip_runtime.h>
#include <hip/hip_bf16.h>
#include <math.h>

typedef unsigned short ushort_t;
typedef __attribute__((ext_vector_type(8))) __bf16 bf16x8;
typedef __attribute__((ext_vector_type(4))) float f32x4;
typedef __attribute__((ext_vector_type(8))) short s8v;
typedef __attribute__((ext_vector_type(4))) short s4v;

#define SQ 2048
#define DM 1024
#define NH 16
#define HDIM 64
#define FFD 4096
#define NVOC 32000

__device__ inline float b2f(unsigned short u) {
  union { unsigned int i; float f; } x; x.i = ((unsigned int)u) << 16; return x.f;
}
__device__ inline unsigned short f2b(float f) {
  __hip_bfloat16 h = __float2bfloat16(f);
  return *reinterpret_cast<unsigned short*>(&h);
}
__device__ inline void split2(float x, ushort_t& h, ushort_t& l) {
  h = f2b(x);
  l = f2b(x - b2f(h));
}
__device__ inline float geluf(float v) {
  return 0.5f * v * (1.0f + erff(v * 0.70710678118654752f));
}
__device__ __forceinline__ void gld16(const void* g, void* l) {
  __builtin_amdgcn_global_load_lds(
      (const __attribute__((address_space(1))) void*)g,
      (__attribute__((address_space(3))) void*)l, 16, 0, 0);
}

// ---------------------------------------------------------------------------
// Split GEMM engine: C = epi((AH+AL)[M,K] * (BH+BL)[N,K]^T), all planes bf16,
// staged via global_load_lds; 3 MFMA per 32-K step: hh + lh + hl (~2^-17 rel).
// EPI: 0 split-store+bias, 1 split-store*alpha (+h*bC), 2 f32 partial store
//      (kc*pC + h*bC), 3 f32 += v+bias, 4 gelu+bias split-store.
// ---------------------------------------------------------------------------
template<int EPI, int NT, int KS>
__device__ __forceinline__ void gemmsp_body(
    const ushort_t* __restrict__ AH, const ushort_t* __restrict__ AL,
    int lda, long long bA,
    const ushort_t* __restrict__ BH, const ushort_t* __restrict__ BL,
    int ldb, long long bB,
    float* __restrict__ C, ushort_t* __restrict__ CH, ushort_t* __restrict__ CL,
    int ldc, long long bC, long long pC,
    int M, int N, int K, const float* __restrict__ bias, float alpha)
{
  int z = blockIdx.z, h = z / KS, kc = z % KS;
  const ushort_t* AHp = AH + (long long)h * bA + (long long)kc * K;
  const ushort_t* ALp = AL + (long long)h * bA + (long long)kc * K;
  const ushort_t* BHp = BH + (long long)h * bB + (long long)kc * K;
  const ushort_t* BLp = BL + (long long)h * bB + (long long)kc * K;
  int m0 = blockIdx.x * 128, n0 = blockIdx.y * NT;
  const int NF = NT / 32;

  __shared__ __align__(16) ushort_t sAH[128 * 32], sAL[128 * 32];
  __shared__ __align__(16) ushort_t sBH[NT * 32],  sBL[NT * 32];

  int tid = threadIdx.x, lane = tid & 63, wave = tid >> 6;
  int wr = (wave >> 1) * 64, wc = (wave & 1) * (NT >> 1);
  int l15 = lane & 15, l4 = lane >> 4;

  f32x4 acc[4][NF];
#pragma unroll
  for (int m = 0; m < 4; ++m)
#pragma unroll
    for (int n = 0; n < NF; ++n) acc[m][n] = (f32x4){0.f, 0.f, 0.f, 0.f};

  for (int k0 = 0; k0 < K; k0 += 32) {
#pragma unroll
    for (int i = 0; i < 2; ++i) {           // A planes: 128x32 each
      int fi = i * 2048 + tid * 8;
      int r = fi >> 5, c = fi & 31;
      int ra = m0 + r; if (ra > M - 1) ra = M - 1;
      long long go = (long long)ra * lda + k0 + c;
      gld16(AHp + go, &sAH[fi]);
      gld16(ALp + go, &sAL[fi]);
    }
#pragma unroll
    for (int i = 0; i < NT / 64; ++i) {     // B planes: NTx32 each
      int fi = i * 2048 + tid * 8;
      int r = fi >> 5, c = fi & 31;
      int rb = n0 + r; if (rb > N - 1) rb = N - 1;
      long long go = (long long)rb * ldb + k0 + c;
      gld16(BHp + go, &sBH[fi]);
      gld16(BLp + go, &sBL[fi]);
    }
    __syncthreads();
    bf16x8 ah[4], al[4], bh[NF], bl[NF];
#pragma unroll
    for (int m = 0; m < 4; ++m) {
      ah[m] = *(const bf16x8*)&sAH[(wr + m * 16 + l15) * 32 + l4 * 8];
      al[m] = *(const bf16x8*)&sAL[(wr + m * 16 + l15) * 32 + l4 * 8];
    }
#pragma unroll
    for (int n = 0; n < NF; ++n) {
      bh[n] = *(const bf16x8*)&sBH[(wc + n * 16 + l15) * 32 + l4 * 8];
      bl[n] = *(const bf16x8*)&sBL[(wc + n * 16 + l15) * 32 + l4 * 8];
    }
#pragma unroll
    for (int m = 0; m < 4; ++m)
#pragma unroll
      for (int n = 0; n < NF; ++n) {
        acc[m][n] = __builtin_amdgcn_mfma_f32_16x16x32_bf16(ah[m], bh[n], acc[m][n], 0, 0, 0);
        acc[m][n] = __builtin_amdgcn_mfma_f32_16x16x32_bf16(al[m], bh[n], acc[m][n], 0, 0, 0);
        acc[m][n] = __builtin_amdgcn_mfma_f32_16x16x32_bf16(ah[m], bl[n], acc[m][n], 0, 0, 0);
      }
    __syncthreads();
  }

#pragma unroll
  for (int m = 0; m < 4; ++m) {
#pragma unroll
    for (int n = 0; n < NF; ++n) {
      int c = n0 + wc + n * 16 + l15;
      if (c >= N) continue;
      float bv = (EPI == 0 || EPI == 3 || EPI == 4) ? bias[c] : 0.f;
#pragma unroll
      for (int q = 0; q < 4; ++q) {
        int rr = m0 + wr + m * 16 + l4 * 4 + q;
        if (rr >= M) continue;
        float v = acc[m][n][q];
        if (EPI == 0) {
          ushort_t hh, ll; split2(v + bv, hh, ll);
          long long o = (long long)rr * ldc + c; CH[o] = hh; CL[o] = ll;
        } else if (EPI == 1) {
          ushort_t hh, ll; split2(v * alpha, hh, ll);
          long long o = (long long)h * bC + (long long)rr * ldc + c;
          CH[o] = hh; CL[o] = ll;
        } else if (EPI == 2) {
          C[(long long)kc * pC + (long long)rr * ldc + (long long)h * bC + c] = v;
        } else if (EPI == 3) {
          C[(long long)rr * ldc + c] += v + bv;
        } else if (EPI == 4) {
          ushort_t hh, ll; split2(geluf(v + bv), hh, ll);
          long long o = (long long)rr * ldc + c; CH[o] = hh; CL[o] = ll;
        }
      }
    }
  }
}

#define SP_ARGS const ushort_t* AH, const ushort_t* AL, int lda, long long bA, \
    const ushort_t* BH, const ushort_t* BL, int ldb, long long bB, \
    float* C, ushort_t* CH, ushort_t* CL, int ldc, long long bC, long long pC, \
    int M, int N, int K, const float* bias, float alpha
#define SP_PASS AH, AL, lda, bA, BH, BL, ldb, bB, C, CH, CL, ldc, bC, pC, M, N, K, bias, alpha

__global__ __launch_bounds__(256) void k_qkv (SP_ARGS) { gemmsp_body<0,128,1>(SP_PASS); }
__global__ __launch_bounds__(256) void k_qkt (SP_ARGS) { gemmsp_body<1,128,1>(SP_PASS); }
__global__ __launch_bounds__(256) void k_pv  (SP_ARGS) { gemmsp_body<2, 64,4>(SP_PASS); }
__global__ __launch_bounds__(256) void k_outp(SP_ARGS) { gemmsp_body<3, 64,1>(SP_PASS); }
__global__ __launch_bounds__(256) void k_ffn1(SP_ARGS) { gemmsp_body<4,128,1>(SP_PASS); }
__global__ __launch_bounds__(256) void k_ffn2(SP_ARGS) { gemmsp_body<3, 64,1>(SP_PASS); }

// ---------------------------------------------------------------------------
// bf16 GEMM engine (post-gate). EPI: 2 gelu(+bias) bf16 store, 6 f32 store.
// BSRC=1: B bf16 gld16; BSRC=0: B f32 reg-staged+rounded.
// ---------------------------------------------------------------------------
template<int EPI, int BSRC>
__device__ __forceinline__ void gemm16_body(
    const ushort_t* __restrict__ A, int lda, long long bA,
    const void* __restrict__ Bv, int ldb, long long bB,
    void* __restrict__ Cv, int ldc, long long bC,
    int M, int N, int K, const float* __restrict__ bias, int bBias,
    const int* __restrict__ offs)
{
  int z = blockIdx.z;
  const ushort_t* Ap = A + (long long)z * bA;
  int rowStart = 0, Meff = M;
  if (offs) { rowStart = offs[z]; Meff = offs[z + 1] - rowStart; }
  int m0 = blockIdx.x * 128;
  if (m0 >= Meff) return;
  int n0 = blockIdx.y * 128;

  __shared__ __align__(16) ushort_t As[128 * 64];
  __shared__ __align__(16) ushort_t Bs[128 * 64];

  int tid = threadIdx.x, lane = tid & 63, wave = tid >> 6;
  int wr = (wave >> 1) * 64, wc = (wave & 1) * 64;
  int l15 = lane & 15, l4 = lane >> 4;

  f32x4 acc[4][4];
#pragma unroll
  for (int m = 0; m < 4; ++m)
#pragma unroll
    for (int n = 0; n < 4; ++n) acc[m][n] = (f32x4){0.f, 0.f, 0.f, 0.f};

  for (int k0 = 0; k0 < K; k0 += 64) {
#pragma unroll
    for (int i = 0; i < 4; ++i) {
      int idx = i * 2048 + tid * 8;
      int row = idx >> 6, col = idx & 63;
      int ra = m0 + row; if (ra > Meff - 1) ra = Meff - 1;
      gld16(Ap + (long long)(rowStart + ra) * lda + k0 + col, &As[idx]);
    }
    if (BSRC == 1) {
      const ushort_t* Bp = (const ushort_t*)Bv + (long long)z * bB;
#pragma unroll
      for (int i = 0; i < 4; ++i) {
        int idx = i * 2048 + tid * 8;
        int row = idx >> 6, col = idx & 63;
        int rb = n0 + row; if (rb > N - 1) rb = N - 1;
        gld16(Bp + (long long)rb * ldb + k0 + col, &Bs[idx]);
      }
    } else {
      const float* Bf = (const float*)Bv + (long long)z * bB;
#pragma unroll
      for (int i = 0; i < 8; ++i) {
        int g = tid + i * 256;
        int r = g >> 4, c4 = (g & 15) * 4;
        int rb = n0 + r; if (rb > N - 1) rb = N - 1;
        float4 f = *(const float4*)(Bf + (long long)rb * ldb + k0 + c4);
        s4v o; o[0] = (short)f2b(f.x); o[1] = (short)f2b(f.y);
        o[2] = (short)f2b(f.z); o[3] = (short)f2b(f.w);
        *(s4v*)&Bs[r * 64 + c4] = o;
      }
    }
    __syncthreads();
#pragma unroll
    for (int kk = 0; kk < 64; kk += 32) {
      bf16x8 af[4], bfr[4];
#pragma unroll
      for (int m = 0; m < 4; ++m)
        af[m] = *(const bf16x8*)&As[(wr + m * 16 + l15) * 64 + kk + l4 * 8];
#pragma unroll
      for (int n = 0; n < 4; ++n)
        bfr[n] = *(const bf16x8*)&Bs[(wc + n * 16 + l15) * 64 + kk + l4 * 8];
#pragma unroll
      for (int m = 0; m < 4; ++m)
#pragma unroll
        for (int n = 0; n < 4; ++n)
          acc[m][n] = __builtin_amdgcn_mfma_f32_16x16x32_bf16(af[m], bfr[n], acc[m][n], 0, 0, 0);
    }
    __syncthreads();
  }

#pragma unroll
  for (int m = 0; m < 4; ++m) {
#pragma unroll
    for (int n = 0; n < 4; ++n) {
      int c = n0 + wc + n * 16 + l15;
      if (c >= N) continue;
      float bv = (EPI == 2) ? bias[(long long)z * bBias + c] : 0.f;
#pragma unroll
      for (int q = 0; q < 4; ++q) {
        int rr = m0 + wr + m * 16 + l4 * 4 + q;
        if (rr >= Meff) continue;
        float v = acc[m][n][q];
        long long crow = rowStart + rr;
        if (EPI == 2)
          ((ushort_t*)Cv)[crow * ldc + (long long)z * bC + c] = f2b(geluf(v + bv));
        else if (EPI == 6)
          ((float*)Cv)[crow * ldc + c] = v;
      }
    }
  }
}

#define G16_ARGS const ushort_t* A, int lda, long long bA, const void* Bv, \
    int ldb, long long bB, void* Cv, int ldc, long long bC, \
    int M, int N, int K, const float* bias, int bBias, const int* offs
#define G16_PASS A, lda, bA, Bv, ldb, bB, Cv, ldc, bC, M, N, K, bias, bBias, offs

__global__ __launch_bounds__(256) void k_moe1   (G16_ARGS) { gemm16_body<2,1>(G16_PASS); }
__global__ __launch_bounds__(256) void k_moe2   (G16_ARGS) { gemm16_body<6,1>(G16_PASS); }
__global__ __launch_bounds__(256) void k_head_bf(G16_ARGS) { gemm16_body<6,1>(G16_PASS); }
__global__ __launch_bounds__(256) void k_head_f (G16_ARGS) { gemm16_body<6,0>(G16_PASS); }

// ---------------------------------------------------------------------------
__global__ __launch_bounds__(256)
void cvt_split(const float* __restrict__ s, ushort_t* __restrict__ dh,
               ushort_t* __restrict__ dl, int n4)
{
  int i = blockIdx.x * blockDim.x + threadIdx.x;
  int stride = gridDim.x * blockDim.x;
  for (; i < n4; i += stride) {
    float4 f = ((const float4*)s)[i];
    s4v h, l; ushort_t hh, ll;
    split2(f.x, hh, ll); h[0] = (short)hh; l[0] = (short)ll;
    split2(f.y, hh, ll); h[1] = (short)hh; l[1] = (short)ll;
    split2(f.z, hh, ll); h[2] = (short)hh; l[2] = (short)ll;
    split2(f.w, hh, ll); h[3] = (short)hh; l[3] = (short)ll;
    ((s4v*)dh)[i] = h; ((s4v*)dl)[i] = l;
  }
}

__global__ __launch_bounds__(256)
void cvt_bf16(const float* __restrict__ s, ushort_t* __restrict__ d, int n4)
{
  int i = blockIdx.x * blockDim.x + threadIdx.x;
  int stride = gridDim.x * blockDim.x;
  for (; i < n4; i += stride) {
    float4 f = ((const float4*)s)[i];
    s4v o; o[0] = (short)f2b(f.x); o[1] = (short)f2b(f.y);
    o[2] = (short)f2b(f.z); o[3] = (short)f2b(f.w);
    ((s4v*)d)[i] = o;
  }
}

__global__ __launch_bounds__(256)
void embed_kernel(const int* __restrict__ ids, const float* __restrict__ ew,
                  const float* __restrict__ pw, float* __restrict__ x)
{
  int srow = blockIdx.x, tid = threadIdx.x;
  int id = ids[srow];
  const float4 e = *(const float4*)(ew + (long long)id * DM + tid * 4);
  const float4 p = *(const float4*)(pw + (long long)srow * DM + tid * 4);
  float4* xr = (float4*)(x + (long long)srow * DM) + tid;
  *xr = make_float4(e.x + p.x, e.y + p.y, e.z + p.z, e.w + p.w);
}

// MODE 0: write H+L planes; MODE 1: write H plane only (plain bf16)
template<int MODE>
__global__ __launch_bounds__(256)
void ln_kernel(const float* __restrict__ x, const float* __restrict__ g,
               const float* __restrict__ b, ushort_t* __restrict__ outH,
               ushort_t* __restrict__ outL)
{
  int row = blockIdx.x, tid = threadIdx.x;
  float4 v = ((const float4*)(x + (long long)row * DM))[tid];
  __shared__ float sm1[4], sm2[4];
  float s = v.x + v.y + v.z + v.w;
  for (int o = 32; o > 0; o >>= 1) s += __shfl_down(s, o);
  if ((tid & 63) == 0) sm1[tid >> 6] = s;
  __syncthreads();
  float mean = (sm1[0] + sm1[1] + sm1[2] + sm1[3]) * (1.0f / DM);
  float d0 = v.x - mean, d1 = v.y - mean, d2 = v.z - mean, d3 = v.w - mean;
  float q = d0 * d0 + d1 * d1 + d2 * d2 + d3 * d3;
  for (int o = 32; o > 0; o >>= 1) q += __shfl_down(q, o);
  if ((tid & 63) == 0) sm2[tid >> 6] = q;
  __syncthreads();
  float var = (sm2[0] + sm2[1] + sm2[2] + sm2[3]) * (1.0f / DM);
  float rstd = rsqrtf(var + 1e-5f);
  float4 gv = ((const float4*)g)[tid];
  float4 bv = ((const float4*)b)[tid];
  float o0 = d0 * rstd * gv.x + bv.x, o1 = d1 * rstd * gv.y + bv.y;
  float o2 = d2 * rstd * gv.z + bv.z, o3 = d3 * rstd * gv.w + bv.w;
  long long base = (long long)row * DM + tid * 4;
  if (MODE == 0) {
    ushort_t hh, ll;
    split2(o0, hh, ll); outH[base + 0] = hh; outL[base + 0] = ll;
    split2(o1, hh, ll); outH[base + 1] = hh; outL[base + 1] = ll;
    split2(o2, hh, ll); outH[base + 2] = hh; outL[base + 2] = ll;
    split2(o3, hh, ll); outH[base + 3] = hh; outL[base + 3] = ll;
  } else {
    outH[base + 0] = f2b(o0); outH[base + 1] = f2b(o1);
    outH[base + 2] = f2b(o2); outH[base + 3] = f2b(o3);
  }
}

__global__ __launch_bounds__(256)
void softmax_hl(ushort_t* __restrict__ pH, ushort_t* __restrict__ pL)
{
  long long row = blockIdx.x;
  ushort_t* prH = pH + row * (long long)SQ;
  ushort_t* prL = pL + row * (long long)SQ;
  int tid = threadIdx.x;
  s8v rh = ((s8v*)prH)[tid], rl = ((s8v*)prL)[tid];
  float v[8];
#pragma unroll
  for (int i = 0; i < 8; ++i)
    v[i] = b2f((unsigned short)rh[i]) + b2f((unsigned short)rl[i]);
  float mx = v[0];
#pragma unroll
  for (int i = 1; i < 8; ++i) mx = fmaxf(mx, v[i]);
  for (int o = 32; o > 0; o >>= 1) mx = fmaxf(mx, __shfl_down(mx, o));
  __shared__ float smx[4], ssm[4];
  if ((tid & 63) == 0) smx[tid >> 6] = mx;
  __syncthreads();
  mx = fmaxf(fmaxf(smx[0], smx[1]), fmaxf(smx[2], smx[3]));
  float s = 0.f;
#pragma unroll
  for (int i = 0; i < 8; ++i) { v[i] = expf(v[i] - mx); s += v[i]; }
  for (int o = 32; o > 0; o >>= 1) s += __shfl_down(s, o);
  if ((tid & 63) == 0) ssm[tid >> 6] = s;
  __syncthreads();
  float inv = 1.0f / (ssm[0] + ssm[1] + ssm[2] + ssm[3]);
  s8v oh, ol; ushort_t hh, ll;
#pragma unroll
  for (int i = 0; i < 8; ++i) {
    split2(v[i] * inv, hh, ll); oh[i] = (short)hh; ol[i] = (short)ll;
  }
  ((s8v*)prH)[tid] = oh; ((s8v*)prL)[tid] = ol;
}

// Vt[h][d][j] = qkv[j][2D + h*64 + d], both planes
__global__ __launch_bounds__(256)
void transpose_v2(const ushort_t* __restrict__ qH, const ushort_t* __restrict__ qL,
                  ushort_t* __restrict__ vH, ushort_t* __restrict__ vL)
{
  __shared__ ushort_t tH[64][65], tL[64][65];
  int j0 = blockIdx.x * 64, h = blockIdx.y;
  int tid = threadIdx.x;
  int jr = tid >> 2, d0 = (tid & 3) * 16;
  long long so = (long long)(j0 + jr) * (3 * DM) + 2 * DM + h * 64 + d0;
#pragma unroll
  for (int i = 0; i < 16; ++i) { tH[jr][d0 + i] = qH[so + i]; tL[jr][d0 + i] = qL[so + i]; }
  __syncthreads();
  int dd = tid >> 2, jc = (tid & 3) * 16;
  long long dofs = (long long)(h * 64 + dd) * SQ + j0 + jc;
#pragma unroll
  for (int i = 0; i < 16; ++i) { vH[dofs + i] = tH[jc + i][dd]; vL[dofs + i] = tL[jc + i][dd]; }
}

// attnH/L = split(sum of 4 PV partial planes)
__global__ __launch_bounds__(256)
void attn_sum(const float* __restrict__ P, ushort_t* __restrict__ aH,
              ushort_t* __restrict__ aL)
{
  long long i = (long long)blockIdx.x * 256 + threadIdx.x;  // float4 index
  const long long pstride = (long long)SQ * DM / 4;
  float4 a = ((const float4*)P)[i];
  float4 b = ((const float4*)P)[i + pstride];
  float4 c = ((const float4*)P)[i + 2 * pstride];
  float4 d = ((const float4*)P)[i + 3 * pstride];
  float4 t = make_float4(a.x + b.x + c.x + d.x, a.y + b.y + c.y + d.y,
                         a.z + b.z + c.z + d.z, a.w + b.w + c.w + d.w);
  s4v h, l; ushort_t hh, ll;
  split2(t.x, hh, ll); h[0] = (short)hh; l[0] = (short)ll;
  split2(t.y, hh, ll); h[1] = (short)hh; l[1] = (short)ll;
  split2(t.z, hh, ll); h[2] = (short)hh; l[2] = (short)ll;
  split2(t.w, hh, ll); h[3] = (short)hh; l[3] = (short)ll;
  ((s4v*)aH)[i] = h; ((s4v*)aL)[i] = l;
}

__global__ __launch_bounds__(256)
void ln_gate_top2(const float* __restrict__ x, const float* __restrict__ g,
                  const float* __restrict__ b, const float* __restrict__ gw,
                  const float* __restrict__ gb, int* __restrict__ topi,
                  float* __restrict__ topw, int* __restrict__ counts)
{
  int row = blockIdx.x, tid = threadIdx.x;
  float4 v = ((const float4*)(x + (long long)row * DM))[tid];
  __shared__ float sm1[4], sm2[4];
  __shared__ float se[8][4];
  float s = v.x + v.y + v.z + v.w;
  for (int o = 32; o > 0; o >>= 1) s += __shfl_down(s, o);
  if ((tid & 63) == 0) sm1[tid >> 6] = s;
  __syncthreads();
  float mean = (sm1[0] + sm1[1] + sm1[2] + sm1[3]) * (1.0f / DM);
  float d0 = v.x - mean, d1 = v.y - mean, d2 = v.z - mean, d3 = v.w - mean;
  float q = d0 * d0 + d1 * d1 + d2 * d2 + d3 * d3;
  for (int o = 32; o > 0; o >>= 1) q += __shfl_down(q, o);
  if ((tid & 63) == 0) sm2[tid >> 6] = q;
  __syncthreads();
  float var = (sm2[0] + sm2[1] + sm2[2] + sm2[3]) * (1.0f / DM);
  float rstd = rsqrtf(var + 1e-5f);
  float4 gv = ((const float4*)g)[tid];
  float4 bv = ((const float4*)b)[tid];
  float h0 = d0 * rstd * gv.x + bv.x, h1 = d1 * rstd * gv.y + bv.y;
  float h2 = d2 * rstd * gv.z + bv.z, h3 = d3 * rstd * gv.w + bv.w;
#pragma unroll
  for (int e = 0; e < 8; ++e) {
    float4 w = ((const float4*)(gw + (long long)e * DM))[tid];
    float p = h0 * w.x + h1 * w.y + h2 * w.z + h3 * w.w;
    for (int o = 32; o > 0; o >>= 1) p += __shfl_down(p, o);
    if ((tid & 63) == 0) se[e][tid >> 6] = p;
  }
  __syncthreads();
  if (tid == 0) {
    float sc[8];
#pragma unroll
    for (int e = 0; e < 8; ++e)
      sc[e] = se[e][0] + se[e][1] + se[e][2] + se[e][3] + gb[e];
    int i1 = 0; float m1 = sc[0];
    for (int e = 1; e < 8; ++e) if (sc[e] > m1) { m1 = sc[e]; i1 = e; }
    int i2 = -1; float m2 = -1e30f;
    for (int e = 0; e < 8; ++e) if (e != i1 && sc[e] > m2) { m2 = sc[e]; i2 = e; }
    float e2 = expf(m2 - m1);
    float w1 = 1.f / (1.f + e2);
    topi[row * 2] = i1; topi[row * 2 + 1] = i2;
    topw[row * 2] = w1; topw[row * 2 + 1] = 1.f - w1;
    atomicAdd(&counts[i1], 1);
    atomicAdd(&counts[i2], 1);
  }
}

__global__ void moe_zero(int* counts) { if (threadIdx.x < 8) counts[threadIdx.x] = 0; }

__global__ void moe_prefix(const int* __restrict__ counts, int* __restrict__ offs,
                           int* __restrict__ cursors)
{
  if (threadIdx.x == 0 && blockIdx.x == 0) {
    int a = 0;
    for (int e = 0; e < 8; ++e) { offs[e] = a; a += counts[e]; cursors[e] = 0; }
    offs[8] = a;
  }
}

__global__ __launch_bounds__(256)
void moe_gather(const ushort_t* __restrict__ hH, const int* __restrict__ topi,
                const float* __restrict__ topw, const int* __restrict__ offs,
                int* __restrict__ cursors, int* __restrict__ tokIdx,
                float* __restrict__ tokW, int* __restrict__ slotOf,
                ushort_t* __restrict__ Xg)
{
  int tok = blockIdx.x, tid = threadIdx.x;
  __shared__ int s0s, s1s;
  if (tid == 0) {
    int e0 = topi[tok * 2], e1 = topi[tok * 2 + 1];
    int s0 = offs[e0] + atomicAdd(&cursors[e0], 1);
    int s1 = offs[e1] + atomicAdd(&cursors[e1], 1);
    tokIdx[s0] = tok; tokW[s0] = topw[tok * 2];
    tokIdx[s1] = tok; tokW[s1] = topw[tok * 2 + 1];
    slotOf[tok * 2] = s0; slotOf[tok * 2 + 1] = s1;
    s0s = s0; s1s = s1;
  }
  __syncthreads();
  s4v v = ((const s4v*)(hH + (long long)tok * DM))[tid];
  ((s4v*)(Xg + (long long)s0s * DM))[tid] = v;
  ((s4v*)(Xg + (long long)s1s * DM))[tid] = v;
}

// x[tok] += w0*(eo[s0]+b2[e0]) + w1*(eo[s1]+b2[e1])
__global__ __launch_bounds__(256)
void moe_reduce(float* __restrict__ x, const float* __restrict__ eo,
                const int* __restrict__ slotOf, const int* __restrict__ topi,
                const float* __restrict__ topw, const float* __restrict__ b2)
{
  int tok = blockIdx.x, tid = threadIdx.x;
  int s0 = slotOf[tok * 2], s1 = slotOf[tok * 2 + 1];
  int e0 = topi[tok * 2], e1 = topi[tok * 2 + 1];
  float w0 = topw[tok * 2], w1 = topw[tok * 2 + 1];
  float4 a = ((const float4*)(eo + (long long)s0 * DM))[tid];
  float4 b = ((const float4*)(eo + (long long)s1 * DM))[tid];
  float4 ba = ((const float4*)(b2 + (long long)e0 * DM))[tid];
  float4 bb = ((const float4*)(b2 + (long long)e1 * DM))[tid];
  float4* xr = (float4*)(x + (long long)tok * DM) + tid;
  float4 xv = *xr;
  xv.x += w0 * (a.x + ba.x) + w1 * (b.x + bb.x);
  xv.y += w0 * (a.y + ba.y) + w1 * (b.y + bb.y);
  xv.z += w0 * (a.z + ba.z) + w1 * (b.z + bb.z);
  xv.w += w0 * (a.w + ba.w) + w1 * (b.w + bb.w);
  *xr = xv;
}

extern "C" void kernel_launch(void* const* d_in, const int* in_sizes, int n_in,
                              void* d_out, int out_size, void* d_ws, size_t ws_size,
                              hipStream_t stream)
{
  const int* ids = (const int*)d_in[0];
  const float* embed_w = (const float*)d_in[1];
  const float* pos_w   = (const float*)d_in[2];
  const float* ln1_g[2] = {(const float*)d_in[3],  (const float*)d_in[11]};
  const float* ln1_b[2] = {(const float*)d_in[4],  (const float*)d_in[12]};
  const float* in_w[2]  = {(const float*)d_in[5],  (const float*)d_in[13]};
  const float* in_b[2]  = {(const float*)d_in[6],  (const float*)d_in[14]};
  const float* out_w[2] = {(const float*)d_in[7],  (const float*)d_in[15]};
  const float* out_b[2] = {(const float*)d_in[8],  (const float*)d_in[16]};
  const float* ln2_g[2] = {(const float*)d_in[9],  (const float*)d_in[17]};
  const float* ln2_b[2] = {(const float*)d_in[10], (const float*)d_in[18]};
  const float* ffn_w1 = (const float*)d_in[19];
  const float* ffn_b1 = (const float*)d_in[20];
  const float* ffn_w2 = (const float*)d_in[21];
  const float* ffn_b2 = (const float*)d_in[22];
  const float* gate_w = (const float*)d_in[23];
  const float* gate_b = (const float*)d_in[24];
  const float* moe_w1 = (const float*)d_in[25];
  const float* moe_b1 = (const float*)d_in[26];
  const float* moe_w2 = (const float*)d_in[27];
  const float* moe_b2 = (const float*)d_in[28];
  const float* norm_g = (const float*)d_in[29];
  const float* norm_b = (const float*)d_in[30];
  const float* head_w = (const float*)d_in[31];

  // ---- Scratch layout in d_out (262.1 MB). All sizes are 256B multiples.
  char* ob = (char*)d_out;
  size_t off = 0;
  auto alloc = [&](size_t bytes) {
    char* p = ob + off;
    off = (off + bytes + 255) & ~(size_t)255;
    return p;
  };
  float*    x      = (float*)alloc((size_t)SQ * DM * 4);
  ushort_t* hbufH  = (ushort_t*)alloc((size_t)SQ * DM * 2);
  ushort_t* hbufL  = (ushort_t*)alloc((size_t)SQ * DM * 2);
  ushort_t* qkvH   = (ushort_t*)alloc((size_t)SQ * 3 * DM * 2);   // ┐
  ushort_t* qkvL   = (ushort_t*)alloc((size_t)SQ * 3 * DM * 2);   // │ w2b
  ushort_t* VtH    = (ushort_t*)alloc((size_t)NH * HDIM * SQ * 2);// │ 64MiB
  ushort_t* VtL    = (ushort_t*)alloc((size_t)NH * HDIM * SQ * 2);// │ exact
  float*    attnP  = (float*)alloc((size_t)4 * SQ * DM * 4);      // ┘
  ushort_t* attnH  = (ushort_t*)alloc((size_t)SQ * DM * 2);
  ushort_t* attnL  = (ushort_t*)alloc((size_t)SQ * DM * 2);
  ushort_t* Xg     = (ushort_t*)alloc((size_t)2 * SQ * DM * 2);
  int*      topi   = (int*)alloc(SQ * 2 * 4);
  float*    topw   = (float*)alloc(SQ * 2 * 4);
  int*      tokIdx = (int*)alloc(2 * SQ * 4);
  float*    tokW   = (float*)alloc(2 * SQ * 4);
  int*      slotOf = (int*)alloc(2 * SQ * 4);
  int*      counts = (int*)alloc(256);
  int*      offsb  = (int*)alloc(256);
  int*      cursors= (int*)alloc(256);
  ushort_t* ffnH   = (ushort_t*)alloc((size_t)SQ * FFD * 2);      // ┐ moehid
  ushort_t* ffnL   = (ushort_t*)alloc((size_t)SQ * FFD * 2);      // ┘ 32MiB
  const int G = 2;
  ushort_t* probsH = (ushort_t*)alloc((size_t)G * SQ * SQ * 2);   // ┐ eo 16MiB
  ushort_t* probsL = (ushort_t*)alloc((size_t)G * SQ * SQ * 2);   // ┘
  // pre-split weight planes (dead after L1 out-proj -> w1b)
  ushort_t* inwH[2], *inwL[2], *outwH[2], *outwL[2];
  ushort_t* wsplit0 = (ushort_t*)alloc(0);
  inwH[0]  = (ushort_t*)alloc((size_t)3 * DM * DM * 2);
  inwL[0]  = (ushort_t*)alloc((size_t)3 * DM * DM * 2);
  inwH[1]  = (ushort_t*)alloc((size_t)3 * DM * DM * 2);
  inwL[1]  = (ushort_t*)alloc((size_t)3 * DM * DM * 2);
  outwH[0] = (ushort_t*)alloc((size_t)DM * DM * 2);
  outwL[0] = (ushort_t*)alloc((size_t)DM * DM * 2);
  outwH[1] = (ushort_t*)alloc((size_t)DM * DM * 2);
  outwL[1] = (ushort_t*)alloc((size_t)DM * DM * 2);
  ushort_t* f1H = (ushort_t*)alloc((size_t)FFD * DM * 2);
  ushort_t* f1L = (ushort_t*)alloc((size_t)FFD * DM * 2);
  ushort_t* f2H = (ushort_t*)alloc((size_t)DM * FFD * 2);
  ushort_t* f2L = (ushort_t*)alloc((size_t)DM * FFD * 2);
  // MoE-phase aliases (regions dead by then; sizes verified exact-fit)
  ushort_t* moe_w1b = wsplit0;            // 64 MiB over weight planes
  ushort_t* moe_w2b = qkvH;               // 64 MiB over qkv+Vt+attnP
  ushort_t* moehid  = ffnH;               // 32 MiB over ffn planes
  float*    eo      = (float*)probsH;     // 16 MiB over probs planes
  ushort_t* hfin    = (ushort_t*)d_ws;
  bool wsBig = ws_size >= ((size_t)70 << 20);
  ushort_t* head_wb = (ushort_t*)((char*)d_ws + ((size_t)4 << 20));

  moe_zero<<<1, 64, 0, stream>>>(counts);
  embed_kernel<<<SQ, 256, 0, stream>>>(ids, embed_w, pos_w, x);
  // pre-split all attention/FFN weights once
  cvt_split<<<512, 256, 0, stream>>>(in_w[0], inwH[0], inwL[0], 3 * DM * DM / 4);
  cvt_split<<<512, 256, 0, stream>>>(in_w[1], inwH[1], inwL[1], 3 * DM * DM / 4);
  cvt_split<<<512, 256, 0, stream>>>(out_w[0], outwH[0], outwL[0], DM * DM / 4);
  cvt_split<<<512, 256, 0, stream>>>(out_w[1], outwH[1], outwL[1], DM * DM / 4);
  cvt_split<<<512, 256, 0, stream>>>(ffn_w1, f1H, f1L, FFD * DM / 4);
  cvt_split<<<512, 256, 0, stream>>>(ffn_w2, f2H, f2L, DM * FFD / 4);
  if (wsBig)
    cvt_bf16<<<1024, 256, 0, stream>>>(head_w, head_wb, NVOC * DM / 4);

  for (int L = 0; L < 2; ++L) {
    ln_kernel<0><<<SQ, 256, 0, stream>>>(x, ln1_g[L], ln1_b[L], hbufH, hbufL);
    // qkv = h @ in_w^T + in_b  -> split planes
    k_qkv<<<dim3(16, 24, 1), 256, 0, stream>>>(
        hbufH, hbufL, DM, 0, inwH[L], inwL[L], DM, 0,
        nullptr, qkvH, qkvL, 3 * DM, 0, 0,
        SQ, 3 * DM, DM, in_b[L], 1.f);
    transpose_v2<<<dim3(SQ / 64, NH), 256, 0, stream>>>(qkvH, qkvL, VtH, VtL);
    for (int h0 = 0; h0 < NH; h0 += G) {
      // scores*0.125 -> probs planes
      k_qkt<<<dim3(16, 16, G), 256, 0, stream>>>(
          qkvH + h0 * 64, qkvL + h0 * 64, 3 * DM, 64,
          qkvH + DM + h0 * 64, qkvL + DM + h0 * 64, 3 * DM, 64,
          nullptr, probsH, probsL, SQ, (long long)SQ * SQ, 0,
          SQ, SQ, 64, nullptr, 0.125f);
      softmax_hl<<<G * SQ, 256, 0, stream>>>(probsH, probsL);
      // PV: 4-way K-split partial planes (plain stores, no atomics)
      k_pv<<<dim3(16, 1, G * 4), 256, 0, stream>>>(
          probsH, probsL, SQ, (long long)SQ * SQ,
          VtH + (long long)h0 * 64 * SQ, VtL + (long long)h0 * 64 * SQ, SQ, 64LL * SQ,
          attnP + h0 * 64, nullptr, nullptr, DM, 64, (long long)SQ * DM,
          SQ, 64, SQ / 4, nullptr, 1.f);
    }
    attn_sum<<<SQ * DM / 1024, 256, 0, stream>>>(attnP, attnH, attnL);
    // x += attn @ out_w^T + out_b
    k_outp<<<dim3(16, 16, 1), 256, 0, stream>>>(
        attnH, attnL, DM, 0, outwH[L], outwL[L], DM, 0,
        x, nullptr, nullptr, DM, 0, 0,
        SQ, DM, DM, out_b[L], 1.f);
    if (L == 0) {
      ln_kernel<0><<<SQ, 256, 0, stream>>>(x, ln2_g[0], ln2_b[0], hbufH, hbufL);
      k_ffn1<<<dim3(16, 32, 1), 256, 0, stream>>>(
          hbufH, hbufL, DM, 0, f1H, f1L, DM, 0,
          nullptr, ffnH, ffnL, FFD, 0, 0,
          SQ, FFD, DM, ffn_b1, 1.f);
      k_ffn2<<<dim3(16, 16, 1), 256, 0, stream>>>(
          ffnH, ffnL, FFD, 0, f2H, f2L, FFD, 0,
          x, nullptr, nullptr, DM, 0, 0,
          SQ, DM, FFD, ffn_b2, 1.f);
    } else {
      // attention scratch + weight planes dead -> MoE weights
      cvt_bf16<<<2048, 256, 0, stream>>>(moe_w1, moe_w1b, 8 * FFD * DM / 4);
      cvt_bf16<<<2048, 256, 0, stream>>>(moe_w2, moe_w2b, 8 * DM * FFD / 4);
      ln_gate_top2<<<SQ, 256, 0, stream>>>(x, ln2_g[1], ln2_b[1], gate_w, gate_b,
                                           topi, topw, counts);
      moe_prefix<<<1, 64, 0, stream>>>(counts, offsb, cursors);
      ln_kernel<1><<<SQ, 256, 0, stream>>>(x, ln2_g[1], ln2_b[1], hbufH, nullptr);
      moe_gather<<<SQ, 256, 0, stream>>>(hbufH, topi, topw, offsb, cursors,
                                         tokIdx, tokW, slotOf, Xg);
      // hid = gelu(Xg @ w1[e]^T + b1[e])
      k_moe1<<<dim3(16, 32, 8), 256, 0, stream>>>(
          Xg, DM, 0, moe_w1b, DM, (long long)FFD * DM,
          moehid, FFD, 0, SQ, FFD, DM, moe_b1, FFD, offsb);
      // eo[slot] = hid @ w2[e]^T  (bias + weighting in reduce)
      k_moe2<<<dim3(16, 8, 8), 256, 0, stream>>>(
          moehid, FFD, 0, moe_w2b, FFD, (long long)DM * FFD,
          eo, DM, 0, SQ, DM, FFD, nullptr, 0, offsb);
      moe_reduce<<<SQ, 256, 0, stream>>>(x, eo, slotOf, topi, topw, moe_b2);
    }
  }
  ln_kernel<1><<<SQ, 256, 0, stream>>>(x, norm_g, norm_b, hfin, nullptr);
  if (wsBig)
    k_head_bf<<<dim3(16, 250, 1), 256, 0, stream>>>(
        hfin, DM, 0, head_wb, DM, 0, d_out, NVOC, 0,
        SQ, NVOC, DM, nullptr, 0, nullptr);
  else
    k_head_f<<<dim3(16, 250, 1), 256, 0, stream>>>(
        hfin, DM, 0, head_w, DM, 0, d_out, NVOC, 0,
        SQ, NVOC, DM, nullptr, 0, nullptr);
}

// Round 8
// 1860.522 us; speedup vs baseline: 1.1993x; 1.1993x over previous
//
#include <hip/hip_runtime.h>
#include <hip/hip_bf16.h>
#include <math.h>

typedef unsigned short ushort_t;
typedef __attribute__((ext_vector_type(8))) __bf16 bf16x8;
typedef __attribute__((ext_vector_type(4))) float f32x4;
typedef __attribute__((ext_vector_type(8))) short s8v;
typedef __attribute__((ext_vector_type(4))) short s4v;

#define SQ 2048
#define DM 1024
#define NH 16
#define HDIM 64
#define FFD 4096
#define NVOC 32000

__device__ inline float b2f(unsigned short u) {
  union { unsigned int i; float f; } x; x.i = ((unsigned int)u) << 16; return x.f;
}
__device__ inline unsigned short f2b(float f) {
  __hip_bfloat16 h = __float2bfloat16(f);
  return *reinterpret_cast<unsigned short*>(&h);
}
__device__ inline void split2(float x, ushort_t& h, ushort_t& l) {
  h = f2b(x);
  l = f2b(x - b2f(h));
}
__device__ inline float geluf(float v) {
  return 0.5f * v * (1.0f + erff(v * 0.70710678118654752f));
}
__device__ __forceinline__ void gld16(const void* g, void* l) {
  __builtin_amdgcn_global_load_lds(
      (const __attribute__((address_space(1))) void*)g,
      (__attribute__((address_space(3))) void*)l, 16, 0, 0);
}

// ---------------------------------------------------------------------------
// Split GEMM engine: C = epi((AH+AL)[M,K] * (BH+BL)[N,K]^T), planes bf16.
// LDS rows = 32 shorts (64B = 4x16B chunks). Bank-conflict fix: source-side
// chunk swizzle  chunk' = chunk ^ ((row>>1)&3)  (LDS dest linear for gld16,
// read XORs the same way) -> 2-way aliasing (free) instead of 8-way.
// EPI: 0 split-store+bias, 1 split-store*alpha (+h*bC), 2 f32 partial store
//      (kc*pC + h*bC), 3 f32 += v+bias, 4 gelu+bias split-store.
// ---------------------------------------------------------------------------
template<int EPI, int NT, int KS>
__device__ __forceinline__ void gemmsp_body(
    const ushort_t* __restrict__ AH, const ushort_t* __restrict__ AL,
    int lda, long long bA,
    const ushort_t* __restrict__ BH, const ushort_t* __restrict__ BL,
    int ldb, long long bB,
    float* __restrict__ C, ushort_t* __restrict__ CH, ushort_t* __restrict__ CL,
    int ldc, long long bC, long long pC,
    int M, int N, int K, const float* __restrict__ bias, float alpha)
{
  int z = blockIdx.z, h = z / KS, kc = z % KS;
  const ushort_t* AHp = AH + (long long)h * bA + (long long)kc * K;
  const ushort_t* ALp = AL + (long long)h * bA + (long long)kc * K;
  const ushort_t* BHp = BH + (long long)h * bB + (long long)kc * K;
  const ushort_t* BLp = BL + (long long)h * bB + (long long)kc * K;
  int m0 = blockIdx.x * 128, n0 = blockIdx.y * NT;
  const int NF = NT / 32;

  __shared__ __align__(16) ushort_t sAH[128 * 32], sAL[128 * 32];
  __shared__ __align__(16) ushort_t sBH[NT * 32],  sBL[NT * 32];

  int tid = threadIdx.x, lane = tid & 63, wave = tid >> 6;
  int wr = (wave >> 1) * 64, wc = (wave & 1) * (NT >> 1);
  int l15 = lane & 15, l4 = lane >> 4;

  f32x4 acc[4][NF];
#pragma unroll
  for (int m = 0; m < 4; ++m)
#pragma unroll
    for (int n = 0; n < NF; ++n) acc[m][n] = (f32x4){0.f, 0.f, 0.f, 0.f};

  for (int k0 = 0; k0 < K; k0 += 32) {
#pragma unroll
    for (int i = 0; i < 2; ++i) {           // A planes: 128x32 each
      int fi = i * 2048 + tid * 8;
      int r = fi >> 5, chk = (fi >> 3) & 3;
      int scol = ((chk ^ ((r >> 1) & 3)) << 3);
      int ra = m0 + r; if (ra > M - 1) ra = M - 1;
      long long go = (long long)ra * lda + k0 + scol;
      gld16(AHp + go, &sAH[fi]);
      gld16(ALp + go, &sAL[fi]);
    }
#pragma unroll
    for (int i = 0; i < NT / 64; ++i) {     // B planes: NTx32 each
      int fi = i * 2048 + tid * 8;
      int r = fi >> 5, chk = (fi >> 3) & 3;
      int scol = ((chk ^ ((r >> 1) & 3)) << 3);
      int rb = n0 + r; if (rb > N - 1) rb = N - 1;
      long long go = (long long)rb * ldb + k0 + scol;
      gld16(BHp + go, &sBH[fi]);
      gld16(BLp + go, &sBL[fi]);
    }
    __syncthreads();
    bf16x8 ah[4], al[4], bh[NF], bl[NF];
#pragma unroll
    for (int m = 0; m < 4; ++m) {
      int r = wr + m * 16 + l15;
      int o = r * 32 + ((l4 ^ ((r >> 1) & 3)) << 3);
      ah[m] = *(const bf16x8*)&sAH[o];
      al[m] = *(const bf16x8*)&sAL[o];
    }
#pragma unroll
    for (int n = 0; n < NF; ++n) {
      int r = wc + n * 16 + l15;
      int o = r * 32 + ((l4 ^ ((r >> 1) & 3)) << 3);
      bh[n] = *(const bf16x8*)&sBH[o];
      bl[n] = *(const bf16x8*)&sBL[o];
    }
#pragma unroll
    for (int m = 0; m < 4; ++m)
#pragma unroll
      for (int n = 0; n < NF; ++n) {
        acc[m][n] = __builtin_amdgcn_mfma_f32_16x16x32_bf16(ah[m], bh[n], acc[m][n], 0, 0, 0);
        acc[m][n] = __builtin_amdgcn_mfma_f32_16x16x32_bf16(al[m], bh[n], acc[m][n], 0, 0, 0);
        acc[m][n] = __builtin_amdgcn_mfma_f32_16x16x32_bf16(ah[m], bl[n], acc[m][n], 0, 0, 0);
      }
    __syncthreads();
  }

#pragma unroll
  for (int m = 0; m < 4; ++m) {
#pragma unroll
    for (int n = 0; n < NF; ++n) {
      int c = n0 + wc + n * 16 + l15;
      if (c >= N) continue;
      float bv = (EPI == 0 || EPI == 3 || EPI == 4) ? bias[c] : 0.f;
#pragma unroll
      for (int q = 0; q < 4; ++q) {
        int rr = m0 + wr + m * 16 + l4 * 4 + q;
        if (rr >= M) continue;
        float v = acc[m][n][q];
        if (EPI == 0) {
          ushort_t hh, ll; split2(v + bv, hh, ll);
          long long o = (long long)rr * ldc + c; CH[o] = hh; CL[o] = ll;
        } else if (EPI == 1) {
          ushort_t hh, ll; split2(v * alpha, hh, ll);
          long long o = (long long)h * bC + (long long)rr * ldc + c;
          CH[o] = hh; CL[o] = ll;
        } else if (EPI == 2) {
          C[(long long)kc * pC + (long long)rr * ldc + (long long)h * bC + c] = v;
        } else if (EPI == 3) {
          C[(long long)rr * ldc + c] += v + bv;
        } else if (EPI == 4) {
          ushort_t hh, ll; split2(geluf(v + bv), hh, ll);
          long long o = (long long)rr * ldc + c; CH[o] = hh; CL[o] = ll;
        }
      }
    }
  }
}

#define SP_ARGS const ushort_t* AH, const ushort_t* AL, int lda, long long bA, \
    const ushort_t* BH, const ushort_t* BL, int ldb, long long bB, \
    float* C, ushort_t* CH, ushort_t* CL, int ldc, long long bC, long long pC, \
    int M, int N, int K, const float* bias, float alpha
#define SP_PASS AH, AL, lda, bA, BH, BL, ldb, bB, C, CH, CL, ldc, bC, pC, M, N, K, bias, alpha

__global__ __launch_bounds__(256) void k_qkv (SP_ARGS) { gemmsp_body<0,128,1>(SP_PASS); }
__global__ __launch_bounds__(256) void k_qkt (SP_ARGS) { gemmsp_body<1,128,1>(SP_PASS); }
__global__ __launch_bounds__(256) void k_pv  (SP_ARGS) { gemmsp_body<2, 64,4>(SP_PASS); }
__global__ __launch_bounds__(256) void k_outp(SP_ARGS) { gemmsp_body<3, 64,1>(SP_PASS); }
__global__ __launch_bounds__(256) void k_ffn1(SP_ARGS) { gemmsp_body<4,128,1>(SP_PASS); }
__global__ __launch_bounds__(256) void k_ffn2(SP_ARGS) { gemmsp_body<3, 64,1>(SP_PASS); }

// ---------------------------------------------------------------------------
// bf16 GEMM engine (post-gate). LDS rows 64 shorts (128B = 8 chunks); swizzle
// chunk' = chunk ^ (row&7) -> 2-way (was 16-way). SWAP=1: m-tile on
// blockIdx.y (early-exit axis), n-tile on blockIdx.x (XCD spread). KS: K-split
// with f32 partial-plane store (EPI 7).
// EPI: 2 gelu(+bias) bf16 store, 6 f32 store, 7 f32 partial store (kc*pC).
// ---------------------------------------------------------------------------
template<int EPI, int BSRC, int SWAP, int KS>
__device__ __forceinline__ void gemm16_body(
    const ushort_t* __restrict__ A, int lda, long long bA,
    const void* __restrict__ Bv, int ldb, long long bB,
    void* __restrict__ Cv, int ldc, long long bC, long long pC,
    int M, int N, int K, const float* __restrict__ bias, int bBias,
    const int* __restrict__ offs)
{
  int bz = blockIdx.z;
  int z = bz / KS, kc = bz % KS;
  int Kc = K / KS;
  const ushort_t* Ap = A + (long long)z * bA + (long long)kc * Kc;
  int rowStart = 0, Meff = M;
  if (offs) { rowStart = offs[z]; Meff = offs[z + 1] - rowStart; }
  int m0 = (SWAP ? blockIdx.y : blockIdx.x) * 128;
  if (m0 >= Meff) return;
  int n0 = (SWAP ? blockIdx.x : blockIdx.y) * 128;

  __shared__ __align__(16) ushort_t As[128 * 64];
  __shared__ __align__(16) ushort_t Bs[128 * 64];

  int tid = threadIdx.x, lane = tid & 63, wave = tid >> 6;
  int wr = (wave >> 1) * 64, wc = (wave & 1) * 64;
  int l15 = lane & 15, l4 = lane >> 4;

  f32x4 acc[4][4];
#pragma unroll
  for (int m = 0; m < 4; ++m)
#pragma unroll
    for (int n = 0; n < 4; ++n) acc[m][n] = (f32x4){0.f, 0.f, 0.f, 0.f};

  for (int k0 = 0; k0 < Kc; k0 += 64) {
#pragma unroll
    for (int i = 0; i < 4; ++i) {
      int idx = i * 2048 + tid * 8;
      int row = idx >> 6, chk = (idx >> 3) & 7;
      int scol = ((chk ^ (row & 7)) << 3);
      int ra = m0 + row; if (ra > Meff - 1) ra = Meff - 1;
      gld16(Ap + (long long)(rowStart + ra) * lda + k0 + scol, &As[idx]);
    }
    if (BSRC == 1) {
      const ushort_t* Bp = (const ushort_t*)Bv + (long long)z * bB + (long long)kc * Kc;
#pragma unroll
      for (int i = 0; i < 4; ++i) {
        int idx = i * 2048 + tid * 8;
        int row = idx >> 6, chk = (idx >> 3) & 7;
        int scol = ((chk ^ (row & 7)) << 3);
        int rb = n0 + row; if (rb > N - 1) rb = N - 1;
        gld16(Bp + (long long)rb * ldb + k0 + scol, &Bs[idx]);
      }
    } else {
      const float* Bf = (const float*)Bv + (long long)z * bB + (long long)kc * Kc;
#pragma unroll
      for (int i = 0; i < 8; ++i) {
        int g = tid + i * 256;
        int r = g >> 4, c4 = (g & 15) * 4;
        int rb = n0 + r; if (rb > N - 1) rb = N - 1;
        float4 f = *(const float4*)(Bf + (long long)rb * ldb + k0 + c4);
        s4v o; o[0] = (short)f2b(f.x); o[1] = (short)f2b(f.y);
        o[2] = (short)f2b(f.z); o[3] = (short)f2b(f.w);
        int dst = r * 64 + (((c4 >> 3) ^ (r & 7)) << 3) + (c4 & 7);
        *(s4v*)&Bs[dst] = o;
      }
    }
    __syncthreads();
#pragma unroll
    for (int kk = 0; kk < 64; kk += 32) {
      bf16x8 af[4], bfr[4];
#pragma unroll
      for (int m = 0; m < 4; ++m) {
        int r = wr + m * 16 + l15;
        af[m] = *(const bf16x8*)&As[r * 64 + ((((kk >> 3) + l4) ^ (r & 7)) << 3)];
      }
#pragma unroll
      for (int n = 0; n < 4; ++n) {
        int r = wc + n * 16 + l15;
        bfr[n] = *(const bf16x8*)&Bs[r * 64 + ((((kk >> 3) + l4) ^ (r & 7)) << 3)];
      }
#pragma unroll
      for (int m = 0; m < 4; ++m)
#pragma unroll
        for (int n = 0; n < 4; ++n)
          acc[m][n] = __builtin_amdgcn_mfma_f32_16x16x32_bf16(af[m], bfr[n], acc[m][n], 0, 0, 0);
    }
    __syncthreads();
  }

#pragma unroll
  for (int m = 0; m < 4; ++m) {
#pragma unroll
    for (int n = 0; n < 4; ++n) {
      int c = n0 + wc + n * 16 + l15;
      if (c >= N) continue;
      float bv = (EPI == 2) ? bias[(long long)z * bBias + c] : 0.f;
#pragma unroll
      for (int q = 0; q < 4; ++q) {
        int rr = m0 + wr + m * 16 + l4 * 4 + q;
        if (rr >= Meff) continue;
        float v = acc[m][n][q];
        long long crow = rowStart + rr;
        if (EPI == 2)
          ((ushort_t*)Cv)[crow * ldc + (long long)z * bC + c] = f2b(geluf(v + bv));
        else if (EPI == 6)
          ((float*)Cv)[crow * ldc + c] = v;
        else if (EPI == 7)
          ((float*)Cv)[(long long)kc * pC + crow * ldc + c] = v;
      }
    }
  }
}

#define G16_ARGS const ushort_t* A, int lda, long long bA, const void* Bv, \
    int ldb, long long bB, void* Cv, int ldc, long long bC, long long pC, \
    int M, int N, int K, const float* bias, int bBias, const int* offs
#define G16_PASS A, lda, bA, Bv, ldb, bB, Cv, ldc, bC, pC, M, N, K, bias, bBias, offs

__global__ __launch_bounds__(256) void k_moe1   (G16_ARGS) { gemm16_body<2,1,1,1>(G16_PASS); }
__global__ __launch_bounds__(256) void k_moe2   (G16_ARGS) { gemm16_body<7,1,1,2>(G16_PASS); }
__global__ __launch_bounds__(256) void k_head_bf(G16_ARGS) { gemm16_body<6,1,0,1>(G16_PASS); }
__global__ __launch_bounds__(256) void k_head_f (G16_ARGS) { gemm16_body<6,0,0,1>(G16_PASS); }

// ---------------------------------------------------------------------------
__global__ __launch_bounds__(256)
void cvt_split(const float* __restrict__ s, ushort_t* __restrict__ dh,
               ushort_t* __restrict__ dl, int n4)
{
  int i = blockIdx.x * blockDim.x + threadIdx.x;
  int stride = gridDim.x * blockDim.x;
  for (; i < n4; i += stride) {
    float4 f = ((const float4*)s)[i];
    s4v h, l; ushort_t hh, ll;
    split2(f.x, hh, ll); h[0] = (short)hh; l[0] = (short)ll;
    split2(f.y, hh, ll); h[1] = (short)hh; l[1] = (short)ll;
    split2(f.z, hh, ll); h[2] = (short)hh; l[2] = (short)ll;
    split2(f.w, hh, ll); h[3] = (short)hh; l[3] = (short)ll;
    ((s4v*)dh)[i] = h; ((s4v*)dl)[i] = l;
  }
}

__global__ __launch_bounds__(256)
void cvt_bf16(const float* __restrict__ s, ushort_t* __restrict__ d, int n4)
{
  int i = blockIdx.x * blockDim.x + threadIdx.x;
  int stride = gridDim.x * blockDim.x;
  for (; i < n4; i += stride) {
    float4 f = ((const float4*)s)[i];
    s4v o; o[0] = (short)f2b(f.x); o[1] = (short)f2b(f.y);
    o[2] = (short)f2b(f.z); o[3] = (short)f2b(f.w);
    ((s4v*)d)[i] = o;
  }
}

__global__ __launch_bounds__(256)
void embed_kernel(const int* __restrict__ ids, const float* __restrict__ ew,
                  const float* __restrict__ pw, float* __restrict__ x)
{
  int srow = blockIdx.x, tid = threadIdx.x;
  int id = ids[srow];
  const float4 e = *(const float4*)(ew + (long long)id * DM + tid * 4);
  const float4 p = *(const float4*)(pw + (long long)srow * DM + tid * 4);
  float4* xr = (float4*)(x + (long long)srow * DM) + tid;
  *xr = make_float4(e.x + p.x, e.y + p.y, e.z + p.z, e.w + p.w);
}

template<int MODE>
__global__ __launch_bounds__(256)
void ln_kernel(const float* __restrict__ x, const float* __restrict__ g,
               const float* __restrict__ b, ushort_t* __restrict__ outH,
               ushort_t* __restrict__ outL)
{
  int row = blockIdx.x, tid = threadIdx.x;
  float4 v = ((const float4*)(x + (long long)row * DM))[tid];
  __shared__ float sm1[4], sm2[4];
  float s = v.x + v.y + v.z + v.w;
  for (int o = 32; o > 0; o >>= 1) s += __shfl_down(s, o);
  if ((tid & 63) == 0) sm1[tid >> 6] = s;
  __syncthreads();
  float mean = (sm1[0] + sm1[1] + sm1[2] + sm1[3]) * (1.0f / DM);
  float d0 = v.x - mean, d1 = v.y - mean, d2 = v.z - mean, d3 = v.w - mean;
  float q = d0 * d0 + d1 * d1 + d2 * d2 + d3 * d3;
  for (int o = 32; o > 0; o >>= 1) q += __shfl_down(q, o);
  if ((tid & 63) == 0) sm2[tid >> 6] = q;
  __syncthreads();
  float var = (sm2[0] + sm2[1] + sm2[2] + sm2[3]) * (1.0f / DM);
  float rstd = rsqrtf(var + 1e-5f);
  float4 gv = ((const float4*)g)[tid];
  float4 bv = ((const float4*)b)[tid];
  float o0 = d0 * rstd * gv.x + bv.x, o1 = d1 * rstd * gv.y + bv.y;
  float o2 = d2 * rstd * gv.z + bv.z, o3 = d3 * rstd * gv.w + bv.w;
  long long base = (long long)row * DM + tid * 4;
  if (MODE == 0) {
    ushort_t hh, ll;
    split2(o0, hh, ll); outH[base + 0] = hh; outL[base + 0] = ll;
    split2(o1, hh, ll); outH[base + 1] = hh; outL[base + 1] = ll;
    split2(o2, hh, ll); outH[base + 2] = hh; outL[base + 2] = ll;
    split2(o3, hh, ll); outH[base + 3] = hh; outL[base + 3] = ll;
  } else {
    outH[base + 0] = f2b(o0); outH[base + 1] = f2b(o1);
    outH[base + 2] = f2b(o2); outH[base + 3] = f2b(o3);
  }
}

__global__ __launch_bounds__(256)
void softmax_hl(ushort_t* __restrict__ pH, ushort_t* __restrict__ pL)
{
  long long row = blockIdx.x;
  ushort_t* prH = pH + row * (long long)SQ;
  ushort_t* prL = pL + row * (long long)SQ;
  int tid = threadIdx.x;
  s8v rh = ((s8v*)prH)[tid], rl = ((s8v*)prL)[tid];
  float v[8];
#pragma unroll
  for (int i = 0; i < 8; ++i)
    v[i] = b2f((unsigned short)rh[i]) + b2f((unsigned short)rl[i]);
  float mx = v[0];
#pragma unroll
  for (int i = 1; i < 8; ++i) mx = fmaxf(mx, v[i]);
  for (int o = 32; o > 0; o >>= 1) mx = fmaxf(mx, __shfl_down(mx, o));
  __shared__ float smx[4], ssm[4];
  if ((tid & 63) == 0) smx[tid >> 6] = mx;
  __syncthreads();
  mx = fmaxf(fmaxf(smx[0], smx[1]), fmaxf(smx[2], smx[3]));
  float s = 0.f;
#pragma unroll
  for (int i = 0; i < 8; ++i) { v[i] = expf(v[i] - mx); s += v[i]; }
  for (int o = 32; o > 0; o >>= 1) s += __shfl_down(s, o);
  if ((tid & 63) == 0) ssm[tid >> 6] = s;
  __syncthreads();
  float inv = 1.0f / (ssm[0] + ssm[1] + ssm[2] + ssm[3]);
  s8v oh, ol; ushort_t hh, ll;
#pragma unroll
  for (int i = 0; i < 8; ++i) {
    split2(v[i] * inv, hh, ll); oh[i] = (short)hh; ol[i] = (short)ll;
  }
  ((s8v*)prH)[tid] = oh; ((s8v*)prL)[tid] = ol;
}

__global__ __launch_bounds__(256)
void transpose_v2(const ushort_t* __restrict__ qH, const ushort_t* __restrict__ qL,
                  ushort_t* __restrict__ vH, ushort_t* __restrict__ vL)
{
  __shared__ ushort_t tH[64][65], tL[64][65];
  int j0 = blockIdx.x * 64, h = blockIdx.y;
  int tid = threadIdx.x;
  int jr = tid >> 2, d0 = (tid & 3) * 16;
  long long so = (long long)(j0 + jr) * (3 * DM) + 2 * DM + h * 64 + d0;
#pragma unroll
  for (int i = 0; i < 16; ++i) { tH[jr][d0 + i] = qH[so + i]; tL[jr][d0 + i] = qL[so + i]; }
  __syncthreads();
  int dd = tid >> 2, jc = (tid & 3) * 16;
  long long dofs = (long long)(h * 64 + dd) * SQ + j0 + jc;
#pragma unroll
  for (int i = 0; i < 16; ++i) { vH[dofs + i] = tH[jc + i][dd]; vL[dofs + i] = tL[jc + i][dd]; }
}

__global__ __launch_bounds__(256)
void attn_sum(const float* __restrict__ P, ushort_t* __restrict__ aH,
              ushort_t* __restrict__ aL)
{
  long long i = (long long)blockIdx.x * 256 + threadIdx.x;
  const long long pstride = (long long)SQ * DM / 4;
  float4 a = ((const float4*)P)[i];
  float4 b = ((const float4*)P)[i + pstride];
  float4 c = ((const float4*)P)[i + 2 * pstride];
  float4 d = ((const float4*)P)[i + 3 * pstride];
  float4 t = make_float4(a.x + b.x + c.x + d.x, a.y + b.y + c.y + d.y,
                         a.z + b.z + c.z + d.z, a.w + b.w + c.w + d.w);
  s4v h, l; ushort_t hh, ll;
  split2(t.x, hh, ll); h[0] = (short)hh; l[0] = (short)ll;
  split2(t.y, hh, ll); h[1] = (short)hh; l[1] = (short)ll;
  split2(t.z, hh, ll); h[2] = (short)hh; l[2] = (short)ll;
  split2(t.w, hh, ll); h[3] = (short)hh; l[3] = (short)ll;
  ((s4v*)aH)[i] = h; ((s4v*)aL)[i] = l;
}

__global__ __launch_bounds__(256)
void ln_gate_top2(const float* __restrict__ x, const float* __restrict__ g,
                  const float* __restrict__ b, const float* __restrict__ gw,
                  const float* __restrict__ gb, int* __restrict__ topi,
                  float* __restrict__ topw, int* __restrict__ counts)
{
  int row = blockIdx.x, tid = threadIdx.x;
  float4 v = ((const float4*)(x + (long long)row * DM))[tid];
  __shared__ float sm1[4], sm2[4];
  __shared__ float se[8][4];
  float s = v.x + v.y + v.z + v.w;
  for (int o = 32; o > 0; o >>= 1) s += __shfl_down(s, o);
  if ((tid & 63) == 0) sm1[tid >> 6] = s;
  __syncthreads();
  float mean = (sm1[0] + sm1[1] + sm1[2] + sm1[3]) * (1.0f / DM);
  float d0 = v.x - mean, d1 = v.y - mean, d2 = v.z - mean, d3 = v.w - mean;
  float q = d0 * d0 + d1 * d1 + d2 * d2 + d3 * d3;
  for (int o = 32; o > 0; o >>= 1) q += __shfl_down(q, o);
  if ((tid & 63) == 0) sm2[tid >> 6] = q;
  __syncthreads();
  float var = (sm2[0] + sm2[1] + sm2[2] + sm2[3]) * (1.0f / DM);
  float rstd = rsqrtf(var + 1e-5f);
  float4 gv = ((const float4*)g)[tid];
  float4 bv = ((const float4*)b)[tid];
  float h0 = d0 * rstd * gv.x + bv.x, h1 = d1 * rstd * gv.y + bv.y;
  float h2 = d2 * rstd * gv.z + bv.z, h3 = d3 * rstd * gv.w + bv.w;
#pragma unroll
  for (int e = 0; e < 8; ++e) {
    float4 w = ((const float4*)(gw + (long long)e * DM))[tid];
    float p = h0 * w.x + h1 * w.y + h2 * w.z + h3 * w.w;
    for (int o = 32; o > 0; o >>= 1) p += __shfl_down(p, o);
    if ((tid & 63) == 0) se[e][tid >> 6] = p;
  }
  __syncthreads();
  if (tid == 0) {
    float sc[8];
#pragma unroll
    for (int e = 0; e < 8; ++e)
      sc[e] = se[e][0] + se[e][1] + se[e][2] + se[e][3] + gb[e];
    int i1 = 0; float m1 = sc[0];
    for (int e = 1; e < 8; ++e) if (sc[e] > m1) { m1 = sc[e]; i1 = e; }
    int i2 = -1; float m2 = -1e30f;
    for (int e = 0; e < 8; ++e) if (e != i1 && sc[e] > m2) { m2 = sc[e]; i2 = e; }
    float e2 = expf(m2 - m1);
    float w1 = 1.f / (1.f + e2);
    topi[row * 2] = i1; topi[row * 2 + 1] = i2;
    topw[row * 2] = w1; topw[row * 2 + 1] = 1.f - w1;
    atomicAdd(&counts[i1], 1);
    atomicAdd(&counts[i2], 1);
  }
}

__global__ void moe_zero(int* counts) { if (threadIdx.x < 8) counts[threadIdx.x] = 0; }

__global__ void moe_prefix(const int* __restrict__ counts, int* __restrict__ offs,
                           int* __restrict__ cursors)
{
  if (threadIdx.x == 0 && blockIdx.x == 0) {
    int a = 0;
    for (int e = 0; e < 8; ++e) { offs[e] = a; a += counts[e]; cursors[e] = 0; }
    offs[8] = a;
  }
}

__global__ __launch_bounds__(256)
void moe_gather(const ushort_t* __restrict__ hH, const int* __restrict__ topi,
                const float* __restrict__ topw, const int* __restrict__ offs,
                int* __restrict__ cursors, int* __restrict__ tokIdx,
                float* __restrict__ tokW, int* __restrict__ slotOf,
                ushort_t* __restrict__ Xg)
{
  int tok = blockIdx.x, tid = threadIdx.x;
  __shared__ int s0s, s1s;
  if (tid == 0) {
    int e0 = topi[tok * 2], e1 = topi[tok * 2 + 1];
    int s0 = offs[e0] + atomicAdd(&cursors[e0], 1);
    int s1 = offs[e1] + atomicAdd(&cursors[e1], 1);
    tokIdx[s0] = tok; tokW[s0] = topw[tok * 2];
    tokIdx[s1] = tok; tokW[s1] = topw[tok * 2 + 1];
    slotOf[tok * 2] = s0; slotOf[tok * 2 + 1] = s1;
    s0s = s0; s1s = s1;
  }
  __syncthreads();
  s4v v = ((const s4v*)(hH + (long long)tok * DM))[tid];
  ((s4v*)(Xg + (long long)s0s * DM))[tid] = v;
  ((s4v*)(Xg + (long long)s1s * DM))[tid] = v;
}

// x[tok] += w0*(eo0[s0]+eo1[s0]+b2[e0]) + w1*(eo0[s1]+eo1[s1]+b2[e1])
__global__ __launch_bounds__(256)
void moe_reduce(float* __restrict__ x, const float* __restrict__ eo, long long pC,
                const int* __restrict__ slotOf, const int* __restrict__ topi,
                const float* __restrict__ topw, const float* __restrict__ b2)
{
  int tok = blockIdx.x, tid = threadIdx.x;
  int s0 = slotOf[tok * 2], s1 = slotOf[tok * 2 + 1];
  int e0 = topi[tok * 2], e1 = topi[tok * 2 + 1];
  float w0 = topw[tok * 2], w1 = topw[tok * 2 + 1];
  float4 a  = ((const float4*)(eo + (long long)s0 * DM))[tid];
  float4 a2 = ((const float4*)(eo + pC + (long long)s0 * DM))[tid];
  float4 b  = ((const float4*)(eo + (long long)s1 * DM))[tid];
  float4 b2v= ((const float4*)(eo + pC + (long long)s1 * DM))[tid];
  float4 ba = ((const float4*)(b2 + (long long)e0 * DM))[tid];
  float4 bb = ((const float4*)(b2 + (long long)e1 * DM))[tid];
  float4* xr = (float4*)(x + (long long)tok * DM) + tid;
  float4 xv = *xr;
  xv.x += w0 * (a.x + a2.x + ba.x) + w1 * (b.x + b2v.x + bb.x);
  xv.y += w0 * (a.y + a2.y + ba.y) + w1 * (b.y + b2v.y + bb.y);
  xv.z += w0 * (a.z + a2.z + ba.z) + w1 * (b.z + b2v.z + bb.z);
  xv.w += w0 * (a.w + a2.w + ba.w) + w1 * (b.w + b2v.w + bb.w);
  *xr = xv;
}

extern "C" void kernel_launch(void* const* d_in, const int* in_sizes, int n_in,
                              void* d_out, int out_size, void* d_ws, size_t ws_size,
                              hipStream_t stream)
{
  const int* ids = (const int*)d_in[0];
  const float* embed_w = (const float*)d_in[1];
  const float* pos_w   = (const float*)d_in[2];
  const float* ln1_g[2] = {(const float*)d_in[3],  (const float*)d_in[11]};
  const float* ln1_b[2] = {(const float*)d_in[4],  (const float*)d_in[12]};
  const float* in_w[2]  = {(const float*)d_in[5],  (const float*)d_in[13]};
  const float* in_b[2]  = {(const float*)d_in[6],  (const float*)d_in[14]};
  const float* out_w[2] = {(const float*)d_in[7],  (const float*)d_in[15]};
  const float* out_b[2] = {(const float*)d_in[8],  (const float*)d_in[16]};
  const float* ln2_g[2] = {(const float*)d_in[9],  (const float*)d_in[17]};
  const float* ln2_b[2] = {(const float*)d_in[10], (const float*)d_in[18]};
  const float* ffn_w1 = (const float*)d_in[19];
  const float* ffn_b1 = (const float*)d_in[20];
  const float* ffn_w2 = (const float*)d_in[21];
  const float* ffn_b2 = (const float*)d_in[22];
  const float* gate_w = (const float*)d_in[23];
  const float* gate_b = (const float*)d_in[24];
  const float* moe_w1 = (const float*)d_in[25];
  const float* moe_b1 = (const float*)d_in[26];
  const float* moe_w2 = (const float*)d_in[27];
  const float* moe_b2 = (const float*)d_in[28];
  const float* norm_g = (const float*)d_in[29];
  const float* norm_b = (const float*)d_in[30];
  const float* head_w = (const float*)d_in[31];

  char* ob = (char*)d_out;
  size_t off = 0;
  auto alloc = [&](size_t bytes) {
    char* p = ob + off;
    off = (off + bytes + 255) & ~(size_t)255;
    return p;
  };
  float*    x      = (float*)alloc((size_t)SQ * DM * 4);
  ushort_t* hbufH  = (ushort_t*)alloc((size_t)SQ * DM * 2);
  ushort_t* hbufL  = (ushort_t*)alloc((size_t)SQ * DM * 2);
  ushort_t* qkvH   = (ushort_t*)alloc((size_t)SQ * 3 * DM * 2);   // ┐
  ushort_t* qkvL   = (ushort_t*)alloc((size_t)SQ * 3 * DM * 2);   // │ w2b
  ushort_t* VtH    = (ushort_t*)alloc((size_t)NH * HDIM * SQ * 2);// │ 64MiB
  ushort_t* VtL    = (ushort_t*)alloc((size_t)NH * HDIM * SQ * 2);// │ exact
  float*    attnP  = (float*)alloc((size_t)4 * SQ * DM * 4);      // ┘
  ushort_t* attnH  = (ushort_t*)alloc((size_t)SQ * DM * 2);
  ushort_t* attnL  = (ushort_t*)alloc((size_t)SQ * DM * 2);
  ushort_t* Xg     = (ushort_t*)alloc((size_t)2 * SQ * DM * 2);
  int*      topi   = (int*)alloc(SQ * 2 * 4);
  float*    topw   = (float*)alloc(SQ * 2 * 4);
  int*      tokIdx = (int*)alloc(2 * SQ * 4);
  float*    tokW   = (float*)alloc(2 * SQ * 4);
  int*      slotOf = (int*)alloc(2 * SQ * 4);
  int*      counts = (int*)alloc(256);
  int*      offsb  = (int*)alloc(256);
  int*      cursors= (int*)alloc(256);
  ushort_t* ffnH   = (ushort_t*)alloc((size_t)SQ * FFD * 2);      // ┐ moehid
  ushort_t* ffnL   = (ushort_t*)alloc((size_t)SQ * FFD * 2);      // ┘ 32MiB
  const int G = 2;
  ushort_t* probsH = (ushort_t*)alloc((size_t)G * SQ * SQ * 2);   // ┐ eo 32MiB
  ushort_t* probsL = (ushort_t*)alloc((size_t)G * SQ * SQ * 2);   // ┘ (2 planes)
  ushort_t* inwH[2], *inwL[2], *outwH[2], *outwL[2];
  ushort_t* wsplit0 = (ushort_t*)alloc(0);
  inwH[0]  = (ushort_t*)alloc((size_t)3 * DM * DM * 2);
  inwL[0]  = (ushort_t*)alloc((size_t)3 * DM * DM * 2);
  inwH[1]  = (ushort_t*)alloc((size_t)3 * DM * DM * 2);
  inwL[1]  = (ushort_t*)alloc((size_t)3 * DM * DM * 2);
  outwH[0] = (ushort_t*)alloc((size_t)DM * DM * 2);
  outwL[0] = (ushort_t*)alloc((size_t)DM * DM * 2);
  outwH[1] = (ushort_t*)alloc((size_t)DM * DM * 2);
  outwL[1] = (ushort_t*)alloc((size_t)DM * DM * 2);
  ushort_t* f1H = (ushort_t*)alloc((size_t)FFD * DM * 2);
  ushort_t* f1L = (ushort_t*)alloc((size_t)FFD * DM * 2);
  ushort_t* f2H = (ushort_t*)alloc((size_t)DM * FFD * 2);
  ushort_t* f2L = (ushort_t*)alloc((size_t)DM * FFD * 2);
  ushort_t* moe_w1b = wsplit0;            // 64 MiB over weight planes
  ushort_t* moe_w2b = qkvH;               // 64 MiB over qkv+Vt+attnP
  ushort_t* moehid  = ffnH;               // 32 MiB over ffn planes
  float*    eo      = (float*)probsH;     // 2x16 MiB planes over probs
  const long long eoPC = (long long)2 * SQ * DM;  // 4096*1024 f32 per plane
  ushort_t* hfin    = (ushort_t*)d_ws;
  bool wsBig = ws_size >= ((size_t)70 << 20);
  ushort_t* head_wb = (ushort_t*)((char*)d_ws + ((size_t)4 << 20));

  moe_zero<<<1, 64, 0, stream>>>(counts);
  embed_kernel<<<SQ, 256, 0, stream>>>(ids, embed_w, pos_w, x);
  cvt_split<<<512, 256, 0, stream>>>(in_w[0], inwH[0], inwL[0], 3 * DM * DM / 4);
  cvt_split<<<512, 256, 0, stream>>>(in_w[1], inwH[1], inwL[1], 3 * DM * DM / 4);
  cvt_split<<<512, 256, 0, stream>>>(out_w[0], outwH[0], outwL[0], DM * DM / 4);
  cvt_split<<<512, 256, 0, stream>>>(out_w[1], outwH[1], outwL[1], DM * DM / 4);
  cvt_split<<<512, 256, 0, stream>>>(ffn_w1, f1H, f1L, FFD * DM / 4);
  cvt_split<<<512, 256, 0, stream>>>(ffn_w2, f2H, f2L, DM * FFD / 4);
  if (wsBig)
    cvt_bf16<<<1024, 256, 0, stream>>>(head_w, head_wb, NVOC * DM / 4);

  for (int L = 0; L < 2; ++L) {
    ln_kernel<0><<<SQ, 256, 0, stream>>>(x, ln1_g[L], ln1_b[L], hbufH, hbufL);
    k_qkv<<<dim3(16, 24, 1), 256, 0, stream>>>(
        hbufH, hbufL, DM, 0, inwH[L], inwL[L], DM, 0,
        nullptr, qkvH, qkvL, 3 * DM, 0, 0,
        SQ, 3 * DM, DM, in_b[L], 1.f);
    transpose_v2<<<dim3(SQ / 64, NH), 256, 0, stream>>>(qkvH, qkvL, VtH, VtL);
    for (int h0 = 0; h0 < NH; h0 += G) {
      k_qkt<<<dim3(16, 16, G), 256, 0, stream>>>(
          qkvH + h0 * 64, qkvL + h0 * 64, 3 * DM, 64,
          qkvH + DM + h0 * 64, qkvL + DM + h0 * 64, 3 * DM, 64,
          nullptr, probsH, probsL, SQ, (long long)SQ * SQ, 0,
          SQ, SQ, 64, nullptr, 0.125f);
      softmax_hl<<<G * SQ, 256, 0, stream>>>(probsH, probsL);
      k_pv<<<dim3(16, 1, G * 4), 256, 0, stream>>>(
          probsH, probsL, SQ, (long long)SQ * SQ,
          VtH + (long long)h0 * 64 * SQ, VtL + (long long)h0 * 64 * SQ, SQ, 64LL * SQ,
          attnP + h0 * 64, nullptr, nullptr, DM, 64, (long long)SQ * DM,
          SQ, 64, SQ / 4, nullptr, 1.f);
    }
    attn_sum<<<SQ * DM / 1024, 256, 0, stream>>>(attnP, attnH, attnL);
    k_outp<<<dim3(16, 16, 1), 256, 0, stream>>>(
        attnH, attnL, DM, 0, outwH[L], outwL[L], DM, 0,
        x, nullptr, nullptr, DM, 0, 0,
        SQ, DM, DM, out_b[L], 1.f);
    if (L == 0) {
      ln_kernel<0><<<SQ, 256, 0, stream>>>(x, ln2_g[0], ln2_b[0], hbufH, hbufL);
      k_ffn1<<<dim3(16, 32, 1), 256, 0, stream>>>(
          hbufH, hbufL, DM, 0, f1H, f1L, DM, 0,
          nullptr, ffnH, ffnL, FFD, 0, 0,
          SQ, FFD, DM, ffn_b1, 1.f);
      k_ffn2<<<dim3(16, 16, 1), 256, 0, stream>>>(
          ffnH, ffnL, FFD, 0, f2H, f2L, FFD, 0,
          x, nullptr, nullptr, DM, 0, 0,
          SQ, DM, FFD, ffn_b2, 1.f);
    } else {
      cvt_bf16<<<2048, 256, 0, stream>>>(moe_w1, moe_w1b, 8 * FFD * DM / 4);
      cvt_bf16<<<2048, 256, 0, stream>>>(moe_w2, moe_w2b, 8 * DM * FFD / 4);
      ln_gate_top2<<<SQ, 256, 0, stream>>>(x, ln2_g[1], ln2_b[1], gate_w, gate_b,
                                           topi, topw, counts);
      moe_prefix<<<1, 64, 0, stream>>>(counts, offsb, cursors);
      ln_kernel<1><<<SQ, 256, 0, stream>>>(x, ln2_g[1], ln2_b[1], hbufH, nullptr);
      moe_gather<<<SQ, 256, 0, stream>>>(hbufH, topi, topw, offsb, cursors,
                                         tokIdx, tokW, slotOf, Xg);
      // SWAP grid: x = n-tiles (all useful), y = m-tiles (early-exit axis)
      k_moe1<<<dim3(32, 16, 8), 256, 0, stream>>>(
          Xg, DM, 0, moe_w1b, DM, (long long)FFD * DM,
          moehid, FFD, 0, 0, SQ, FFD, DM, moe_b1, FFD, offsb);
      // KS=2 partial planes into eo
      k_moe2<<<dim3(8, 16, 16), 256, 0, stream>>>(
          moehid, FFD, 0, moe_w2b, FFD, (long long)DM * FFD,
          eo, DM, 0, eoPC, SQ, DM, FFD, nullptr, 0, offsb);
      moe_reduce<<<SQ, 256, 0, stream>>>(x, eo, eoPC, slotOf, topi, topw, moe_b2);
    }
  }
  ln_kernel<1><<<SQ, 256, 0, stream>>>(x, norm_g, norm_b, hfin, nullptr);
  if (wsBig)
    k_head_bf<<<dim3(16, 250, 1), 256, 0, stream>>>(
        hfin, DM, 0, head_wb, DM, 0, d_out, NVOC, 0, 0,
        SQ, NVOC, DM, nullptr, 0, nullptr);
  else
    k_head_f<<<dim3(16, 250, 1), 256, 0, stream>>>(
        hfin, DM, 0, head_w, DM, 0, d_out, NVOC, 0, 0,
        SQ, NVOC, DM, nullptr, 0, nullptr);
}

// Round 9
// 1336.468 us; speedup vs baseline: 1.6695x; 1.3921x over previous
//
#include <hip/hip_runtime.h>
#include <hip/hip_bf16.h>
#include <math.h>

typedef unsigned short ushort_t;
typedef __attribute__((ext_vector_type(8))) __bf16 bf16x8;
typedef __attribute__((ext_vector_type(4))) float f32x4;
typedef __attribute__((ext_vector_type(8))) short s8v;
typedef __attribute__((ext_vector_type(4))) short s4v;

#define SQ 2048
#define DM 1024
#define NH 16
#define HDIM 64
#define FFD 4096
#define NVOC 32000

__device__ inline float b2f(unsigned short u) {
  union { unsigned int i; float f; } x; x.i = ((unsigned int)u) << 16; return x.f;
}
__device__ inline unsigned short f2b(float f) {
  __hip_bfloat16 h = __float2bfloat16(f);
  return *reinterpret_cast<unsigned short*>(&h);
}
__device__ inline void split2(float x, ushort_t& h, ushort_t& l) {
  h = f2b(x);
  l = f2b(x - b2f(h));
}
__device__ inline float geluf(float v) {
  return 0.5f * v * (1.0f + erff(v * 0.70710678118654752f));
}
__device__ __forceinline__ void gld16(const void* g, void* l) {
  __builtin_amdgcn_global_load_lds(
      (const __attribute__((address_space(1))) void*)g,
      (__attribute__((address_space(3))) void*)l, 16, 0, 0);
}
#define MFMA __builtin_amdgcn_mfma_f32_16x16x32_bf16

// ---------------------------------------------------------------------------
// Split GEMM engine (pre-gate math): C = epi((AH+AL)*(BH+BL)^T), planes bf16.
// ---------------------------------------------------------------------------
template<int EPI, int NT, int KS>
__device__ __forceinline__ void gemmsp_body(
    const ushort_t* __restrict__ AH, const ushort_t* __restrict__ AL,
    int lda, long long bA,
    const ushort_t* __restrict__ BH, const ushort_t* __restrict__ BL,
    int ldb, long long bB,
    float* __restrict__ C, ushort_t* __restrict__ CH, ushort_t* __restrict__ CL,
    int ldc, long long bC, long long pC,
    int M, int N, int K, const float* __restrict__ bias, float alpha)
{
  int z = blockIdx.z, h = z / KS, kc = z % KS;
  const ushort_t* AHp = AH + (long long)h * bA + (long long)kc * K;
  const ushort_t* ALp = AL + (long long)h * bA + (long long)kc * K;
  const ushort_t* BHp = BH + (long long)h * bB + (long long)kc * K;
  const ushort_t* BLp = BL + (long long)h * bB + (long long)kc * K;
  int m0 = blockIdx.x * 128, n0 = blockIdx.y * NT;
  const int NF = NT / 32;

  __shared__ __align__(16) ushort_t sAH[128 * 32], sAL[128 * 32];
  __shared__ __align__(16) ushort_t sBH[NT * 32],  sBL[NT * 32];

  int tid = threadIdx.x, lane = tid & 63, wave = tid >> 6;
  int wr = (wave >> 1) * 64, wc = (wave & 1) * (NT >> 1);
  int l15 = lane & 15, l4 = lane >> 4;

  f32x4 acc[4][NF];
#pragma unroll
  for (int m = 0; m < 4; ++m)
#pragma unroll
    for (int n = 0; n < NF; ++n) acc[m][n] = (f32x4){0.f, 0.f, 0.f, 0.f};

  for (int k0 = 0; k0 < K; k0 += 32) {
#pragma unroll
    for (int i = 0; i < 2; ++i) {
      int fi = i * 2048 + tid * 8;
      int r = fi >> 5, chk = (fi >> 3) & 3;
      int scol = ((chk ^ ((r >> 1) & 3)) << 3);
      int ra = m0 + r; if (ra > M - 1) ra = M - 1;
      long long go = (long long)ra * lda + k0 + scol;
      gld16(AHp + go, &sAH[fi]);
      gld16(ALp + go, &sAL[fi]);
    }
#pragma unroll
    for (int i = 0; i < NT / 64; ++i) {
      int fi = i * 2048 + tid * 8;
      int r = fi >> 5, chk = (fi >> 3) & 3;
      int scol = ((chk ^ ((r >> 1) & 3)) << 3);
      int rb = n0 + r; if (rb > N - 1) rb = N - 1;
      long long go = (long long)rb * ldb + k0 + scol;
      gld16(BHp + go, &sBH[fi]);
      gld16(BLp + go, &sBL[fi]);
    }
    __syncthreads();
    bf16x8 ah[4], al[4], bh[NF], bl[NF];
#pragma unroll
    for (int m = 0; m < 4; ++m) {
      int r = wr + m * 16 + l15;
      int o = r * 32 + ((l4 ^ ((r >> 1) & 3)) << 3);
      ah[m] = *(const bf16x8*)&sAH[o];
      al[m] = *(const bf16x8*)&sAL[o];
    }
#pragma unroll
    for (int n = 0; n < NF; ++n) {
      int r = wc + n * 16 + l15;
      int o = r * 32 + ((l4 ^ ((r >> 1) & 3)) << 3);
      bh[n] = *(const bf16x8*)&sBH[o];
      bl[n] = *(const bf16x8*)&sBL[o];
    }
#pragma unroll
    for (int m = 0; m < 4; ++m)
#pragma unroll
      for (int n = 0; n < NF; ++n) {
        acc[m][n] = MFMA(ah[m], bh[n], acc[m][n], 0, 0, 0);
        acc[m][n] = MFMA(al[m], bh[n], acc[m][n], 0, 0, 0);
        acc[m][n] = MFMA(ah[m], bl[n], acc[m][n], 0, 0, 0);
      }
    __syncthreads();
  }

#pragma unroll
  for (int m = 0; m < 4; ++m) {
#pragma unroll
    for (int n = 0; n < NF; ++n) {
      int c = n0 + wc + n * 16 + l15;
      if (c >= N) continue;
      float bv = (EPI == 0 || EPI == 3 || EPI == 4) ? bias[c] : 0.f;
#pragma unroll
      for (int q = 0; q < 4; ++q) {
        int rr = m0 + wr + m * 16 + l4 * 4 + q;
        if (rr >= M) continue;
        float v = acc[m][n][q];
        if (EPI == 0) {
          ushort_t hh, ll; split2(v + bv, hh, ll);
          long long o = (long long)rr * ldc + c; CH[o] = hh; CL[o] = ll;
        } else if (EPI == 3) {
          C[(long long)rr * ldc + c] += v + bv;
        } else if (EPI == 4) {
          ushort_t hh, ll; split2(geluf(v + bv), hh, ll);
          long long o = (long long)rr * ldc + c; CH[o] = hh; CL[o] = ll;
        }
      }
    }
  }
}

#define SP_ARGS const ushort_t* AH, const ushort_t* AL, int lda, long long bA, \
    const ushort_t* BH, const ushort_t* BL, int ldb, long long bB, \
    float* C, ushort_t* CH, ushort_t* CL, int ldc, long long bC, long long pC, \
    int M, int N, int K, const float* bias, float alpha
#define SP_PASS AH, AL, lda, bA, BH, BL, ldb, bB, C, CH, CL, ldc, bC, pC, M, N, K, bias, alpha

__global__ __launch_bounds__(256) void k_qkv (SP_ARGS) { gemmsp_body<0,128,1>(SP_PASS); }
__global__ __launch_bounds__(256) void k_outp(SP_ARGS) { gemmsp_body<3, 64,1>(SP_PASS); }
__global__ __launch_bounds__(256) void k_ffn1(SP_ARGS) { gemmsp_body<4,128,1>(SP_PASS); }
__global__ __launch_bounds__(256) void k_ffn2(SP_ARGS) { gemmsp_body<3, 64,1>(SP_PASS); }

// ---------------------------------------------------------------------------
// Fused flash attention, split-f32 precision.
// Grid: (SQ/64, NH). 4 waves; wave w owns q-strip rows [w*16, w*16+16).
// Per 64-key tile: S = 0.125*Q K^T (3-MFMA split), online softmax in regs
// (stats per lane for rows (lane>>4)*4+reg, shfl_xor reduce over cols),
// P split-written to per-wave LDS strip, O += P*Vt (3-MFMA split).
// ---------------------------------------------------------------------------
__global__ __launch_bounds__(256)
void k_attn(const ushort_t* __restrict__ qkvH, const ushort_t* __restrict__ qkvL,
            const ushort_t* __restrict__ VtH, const ushort_t* __restrict__ VtL,
            ushort_t* __restrict__ aH, ushort_t* __restrict__ aL)
{
  int q0 = blockIdx.x * 64;
  int h  = blockIdx.y;
  __shared__ __align__(16) ushort_t sQH[4096], sQL[4096];
  __shared__ __align__(16) ushort_t sKH[4096], sKL[4096];
  __shared__ __align__(16) ushort_t sVH[4096], sVL[4096];
  __shared__ __align__(16) ushort_t sPH[4096], sPL[4096];

  int tid = threadIdx.x, lane = tid & 63, wave = tid >> 6;
  int l15 = lane & 15, l4 = lane >> 4;

  // stage Q once (swizzled)
#pragma unroll
  for (int i = 0; i < 2; ++i) {
    int idx = i * 2048 + tid * 8;
    int row = idx >> 6, chk = (idx >> 3) & 7;
    int scol = ((chk ^ (row & 7)) << 3);
    long long go = (long long)(q0 + row) * (3 * DM) + h * 64 + scol;
    gld16(qkvH + go, &sQH[idx]);
    gld16(qkvL + go, &sQL[idx]);
  }

  float mrow[4], lrow[4];
  f32x4 Oacc[4];
#pragma unroll
  for (int r = 0; r < 4; ++r) { mrow[r] = -1e30f; lrow[r] = 0.f; }
#pragma unroll
  for (int n = 0; n < 4; ++n) Oacc[n] = (f32x4){0.f, 0.f, 0.f, 0.f};

  for (int kt = 0; kt < SQ / 64; ++kt) {
    // stage K,V tiles (swizzled)
#pragma unroll
    for (int i = 0; i < 2; ++i) {
      int idx = i * 2048 + tid * 8;
      int row = idx >> 6, chk = (idx >> 3) & 7;
      int scol = ((chk ^ (row & 7)) << 3);
      long long gk = (long long)(kt * 64 + row) * (3 * DM) + DM + h * 64 + scol;
      long long gv = (long long)(h * 64 + row) * SQ + kt * 64 + scol;
      gld16(qkvH + gk, &sKH[idx]);
      gld16(qkvL + gk, &sKL[idx]);
      gld16(VtH + gv, &sVH[idx]);
      gld16(VtL + gv, &sVL[idx]);
    }
    __syncthreads();

    // S = Q K^T for this wave's strip
    f32x4 S[4];
#pragma unroll
    for (int n = 0; n < 4; ++n) S[n] = (f32x4){0.f, 0.f, 0.f, 0.f};
#pragma unroll
    for (int kk = 0; kk < 64; kk += 32) {
      int ar = wave * 16 + l15;
      int ao = ar * 64 + ((((kk >> 3) + l4) ^ (ar & 7)) << 3);
      bf16x8 qh = *(const bf16x8*)&sQH[ao];
      bf16x8 ql = *(const bf16x8*)&sQL[ao];
#pragma unroll
      for (int n = 0; n < 4; ++n) {
        int br = n * 16 + l15;
        int bo = br * 64 + ((((kk >> 3) + l4) ^ (br & 7)) << 3);
        bf16x8 kh = *(const bf16x8*)&sKH[bo];
        bf16x8 kl = *(const bf16x8*)&sKL[bo];
        S[n] = MFMA(qh, kh, S[n], 0, 0, 0);
        S[n] = MFMA(ql, kh, S[n], 0, 0, 0);
        S[n] = MFMA(qh, kl, S[n], 0, 0, 0);
      }
    }
    // online softmax
    float tm[4], ts[4];
#pragma unroll
    for (int r = 0; r < 4; ++r) {
#pragma unroll
      for (int n = 0; n < 4; ++n) S[n][r] *= 0.125f;
      tm[r] = fmaxf(fmaxf(S[0][r], S[1][r]), fmaxf(S[2][r], S[3][r]));
    }
#pragma unroll
    for (int mk = 1; mk <= 8; mk <<= 1)
#pragma unroll
      for (int r = 0; r < 4; ++r) tm[r] = fmaxf(tm[r], __shfl_xor(tm[r], mk));
#pragma unroll
    for (int r = 0; r < 4; ++r) {
      float mn = fmaxf(mrow[r], tm[r]);
      float corr = __expf(mrow[r] - mn);
      mrow[r] = mn;
      float s = 0.f;
#pragma unroll
      for (int n = 0; n < 4; ++n) { S[n][r] = __expf(S[n][r] - mn); s += S[n][r]; }
      ts[r] = s;
      lrow[r] *= corr;
#pragma unroll
      for (int n = 0; n < 4; ++n) Oacc[n][r] *= corr;
    }
#pragma unroll
    for (int mk = 1; mk <= 8; mk <<= 1)
#pragma unroll
      for (int r = 0; r < 4; ++r) ts[r] += __shfl_xor(ts[r], mk);
#pragma unroll
    for (int r = 0; r < 4; ++r) lrow[r] += ts[r];

    // write P planes into per-wave strip (swizzled)
    {
      ushort_t* pH = &sPH[wave * 1024];
      ushort_t* pL = &sPL[wave * 1024];
#pragma unroll
      for (int n = 0; n < 4; ++n)
#pragma unroll
        for (int r = 0; r < 4; ++r) {
          int row = l4 * 4 + r, col = n * 16 + l15;
          int ad = row * 64 + (((col >> 3) ^ (row & 7)) << 3) + (col & 7);
          ushort_t hh, ll; split2(S[n][r], hh, ll);
          pH[ad] = hh; pL[ad] = ll;
        }
    }
    __syncthreads();
    // O += P * Vt-tile
#pragma unroll
    for (int kk = 0; kk < 64; kk += 32) {
      int ao = wave * 1024 + l15 * 64 + ((((kk >> 3) + l4) ^ (l15 & 7)) << 3);
      bf16x8 ph = *(const bf16x8*)&sPH[ao];
      bf16x8 pl = *(const bf16x8*)&sPL[ao];
#pragma unroll
      for (int n = 0; n < 4; ++n) {
        int br = n * 16 + l15;
        int bo = br * 64 + ((((kk >> 3) + l4) ^ (br & 7)) << 3);
        bf16x8 vh = *(const bf16x8*)&sVH[bo];
        bf16x8 vl = *(const bf16x8*)&sVL[bo];
        Oacc[n] = MFMA(ph, vh, Oacc[n], 0, 0, 0);
        Oacc[n] = MFMA(pl, vh, Oacc[n], 0, 0, 0);
        Oacc[n] = MFMA(ph, vl, Oacc[n], 0, 0, 0);
      }
    }
    __syncthreads();
  }

#pragma unroll
  for (int n = 0; n < 4; ++n)
#pragma unroll
    for (int r = 0; r < 4; ++r) {
      int q = q0 + wave * 16 + l4 * 4 + r;
      int d = h * 64 + n * 16 + l15;
      float val = Oacc[n][r] / lrow[r];
      ushort_t hh, ll; split2(val, hh, ll);
      long long o = (long long)q * DM + d;
      aH[o] = hh; aL[o] = ll;
    }
}

// ---------------------------------------------------------------------------
// bf16 GEMM engine (post-gate). XS=1: XCD-chunked block swizzle (grid%8==0).
// EPI: 2 gelu(+bias) bf16 store, 6 f32 store, 7 f32 partial store (kc*pC).
// ---------------------------------------------------------------------------
template<int EPI, int BSRC, int SWAP, int KS, int XS>
__device__ __forceinline__ void gemm16_body(
    const ushort_t* __restrict__ A, int lda, long long bA,
    const void* __restrict__ Bv, int ldb, long long bB,
    void* __restrict__ Cv, int ldc, long long bC, long long pC,
    int M, int N, int K, const float* __restrict__ bias, int bBias,
    const int* __restrict__ offs)
{
  int bz = blockIdx.z;
  int z = bz / KS, kc = bz % KS;
  int Kc = K / KS;
  const ushort_t* Ap = A + (long long)z * bA + (long long)kc * Kc;
  int rowStart = 0, Meff = M;
  if (offs) { rowStart = offs[z]; Meff = offs[z + 1] - rowStart; }
  int bx = blockIdx.x, by = blockIdx.y;
  if (XS) {
    int flat = bx + by * gridDim.x;
    int cpx = (gridDim.x * gridDim.y) >> 3;
    int s = (flat & 7) * cpx + (flat >> 3);
    bx = s % gridDim.x; by = s / gridDim.x;
  }
  int m0 = (SWAP ? by : bx) * 128;
  if (m0 >= Meff) return;
  int n0 = (SWAP ? bx : by) * 128;

  __shared__ __align__(16) ushort_t As[128 * 64];
  __shared__ __align__(16) ushort_t Bs[128 * 64];

  int tid = threadIdx.x, lane = tid & 63, wave = tid >> 6;
  int wr = (wave >> 1) * 64, wc = (wave & 1) * 64;
  int l15 = lane & 15, l4 = lane >> 4;

  f32x4 acc[4][4];
#pragma unroll
  for (int m = 0; m < 4; ++m)
#pragma unroll
    for (int n = 0; n < 4; ++n) acc[m][n] = (f32x4){0.f, 0.f, 0.f, 0.f};

  for (int k0 = 0; k0 < Kc; k0 += 64) {
#pragma unroll
    for (int i = 0; i < 4; ++i) {
      int idx = i * 2048 + tid * 8;
      int row = idx >> 6, chk = (idx >> 3) & 7;
      int scol = ((chk ^ (row & 7)) << 3);
      int ra = m0 + row; if (ra > Meff - 1) ra = Meff - 1;
      gld16(Ap + (long long)(rowStart + ra) * lda + k0 + scol, &As[idx]);
    }
    if (BSRC == 1) {
      const ushort_t* Bp = (const ushort_t*)Bv + (long long)z * bB + (long long)kc * Kc;
#pragma unroll
      for (int i = 0; i < 4; ++i) {
        int idx = i * 2048 + tid * 8;
        int row = idx >> 6, chk = (idx >> 3) & 7;
        int scol = ((chk ^ (row & 7)) << 3);
        int rb = n0 + row; if (rb > N - 1) rb = N - 1;
        gld16(Bp + (long long)rb * ldb + k0 + scol, &Bs[idx]);
      }
    } else {
      const float* Bf = (const float*)Bv + (long long)z * bB + (long long)kc * Kc;
#pragma unroll
      for (int i = 0; i < 8; ++i) {
        int g = tid + i * 256;
        int r = g >> 4, c4 = (g & 15) * 4;
        int rb = n0 + r; if (rb > N - 1) rb = N - 1;
        float4 f = *(const float4*)(Bf + (long long)rb * ldb + k0 + c4);
        s4v o; o[0] = (short)f2b(f.x); o[1] = (short)f2b(f.y);
        o[2] = (short)f2b(f.z); o[3] = (short)f2b(f.w);
        int dst = r * 64 + (((c4 >> 3) ^ (r & 7)) << 3) + (c4 & 7);
        *(s4v*)&Bs[dst] = o;
      }
    }
    __syncthreads();
#pragma unroll
    for (int kk = 0; kk < 64; kk += 32) {
      bf16x8 af[4], bfr[4];
#pragma unroll
      for (int m = 0; m < 4; ++m) {
        int r = wr + m * 16 + l15;
        af[m] = *(const bf16x8*)&As[r * 64 + ((((kk >> 3) + l4) ^ (r & 7)) << 3)];
      }
#pragma unroll
      for (int n = 0; n < 4; ++n) {
        int r = wc + n * 16 + l15;
        bfr[n] = *(const bf16x8*)&Bs[r * 64 + ((((kk >> 3) + l4) ^ (r & 7)) << 3)];
      }
#pragma unroll
      for (int m = 0; m < 4; ++m)
#pragma unroll
        for (int n = 0; n < 4; ++n)
          acc[m][n] = MFMA(af[m], bfr[n], acc[m][n], 0, 0, 0);
    }
    __syncthreads();
  }

#pragma unroll
  for (int m = 0; m < 4; ++m) {
#pragma unroll
    for (int n = 0; n < 4; ++n) {
      int c = n0 + wc + n * 16 + l15;
      if (c >= N) continue;
      float bv = (EPI == 2) ? bias[(long long)z * bBias + c] : 0.f;
#pragma unroll
      for (int q = 0; q < 4; ++q) {
        int rr = m0 + wr + m * 16 + l4 * 4 + q;
        if (rr >= Meff) continue;
        float v = acc[m][n][q];
        long long crow = rowStart + rr;
        if (EPI == 2)
          ((ushort_t*)Cv)[crow * ldc + (long long)z * bC + c] = f2b(geluf(v + bv));
        else if (EPI == 6)
          ((float*)Cv)[crow * ldc + c] = v;
        else if (EPI == 7)
          ((float*)Cv)[(long long)kc * pC + crow * ldc + c] = v;
      }
    }
  }
}

#define G16_ARGS const ushort_t* A, int lda, long long bA, const void* Bv, \
    int ldb, long long bB, void* Cv, int ldc, long long bC, long long pC, \
    int M, int N, int K, const float* bias, int bBias, const int* offs
#define G16_PASS A, lda, bA, Bv, ldb, bB, Cv, ldc, bC, pC, M, N, K, bias, bBias, offs

__global__ __launch_bounds__(256) void k_moe1   (G16_ARGS) { gemm16_body<2,1,1,1,0>(G16_PASS); }
__global__ __launch_bounds__(256) void k_moe2   (G16_ARGS) { gemm16_body<7,1,1,2,0>(G16_PASS); }
__global__ __launch_bounds__(256) void k_head_bf(G16_ARGS) { gemm16_body<6,1,0,1,1>(G16_PASS); }
__global__ __launch_bounds__(256) void k_head_f (G16_ARGS) { gemm16_body<6,0,0,1,1>(G16_PASS); }

// ---------------------------------------------------------------------------
__global__ __launch_bounds__(256)
void cvt_split(const float* __restrict__ s, ushort_t* __restrict__ dh,
               ushort_t* __restrict__ dl, int n4)
{
  int i = blockIdx.x * blockDim.x + threadIdx.x;
  int stride = gridDim.x * blockDim.x;
  for (; i < n4; i += stride) {
    float4 f = ((const float4*)s)[i];
    s4v h, l; ushort_t hh, ll;
    split2(f.x, hh, ll); h[0] = (short)hh; l[0] = (short)ll;
    split2(f.y, hh, ll); h[1] = (short)hh; l[1] = (short)ll;
    split2(f.z, hh, ll); h[2] = (short)hh; l[2] = (short)ll;
    split2(f.w, hh, ll); h[3] = (short)hh; l[3] = (short)ll;
    ((s4v*)dh)[i] = h; ((s4v*)dl)[i] = l;
  }
}

__global__ __launch_bounds__(256)
void cvt_bf16(const float* __restrict__ s, ushort_t* __restrict__ d, int n4)
{
  int i = blockIdx.x * blockDim.x + threadIdx.x;
  int stride = gridDim.x * blockDim.x;
  for (; i < n4; i += stride) {
    float4 f = ((const float4*)s)[i];
    s4v o; o[0] = (short)f2b(f.x); o[1] = (short)f2b(f.y);
    o[2] = (short)f2b(f.z); o[3] = (short)f2b(f.w);
    ((s4v*)d)[i] = o;
  }
}

__global__ __launch_bounds__(256)
void embed_kernel(const int* __restrict__ ids, const float* __restrict__ ew,
                  const float* __restrict__ pw, float* __restrict__ x)
{
  int srow = blockIdx.x, tid = threadIdx.x;
  int id = ids[srow];
  const float4 e = *(const float4*)(ew + (long long)id * DM + tid * 4);
  const float4 p = *(const float4*)(pw + (long long)srow * DM + tid * 4);
  float4* xr = (float4*)(x + (long long)srow * DM) + tid;
  *xr = make_float4(e.x + p.x, e.y + p.y, e.z + p.z, e.w + p.w);
}

template<int MODE>
__global__ __launch_bounds__(256)
void ln_kernel(const float* __restrict__ x, const float* __restrict__ g,
               const float* __restrict__ b, ushort_t* __restrict__ outH,
               ushort_t* __restrict__ outL)
{
  int row = blockIdx.x, tid = threadIdx.x;
  float4 v = ((const float4*)(x + (long long)row * DM))[tid];
  __shared__ float sm1[4], sm2[4];
  float s = v.x + v.y + v.z + v.w;
  for (int o = 32; o > 0; o >>= 1) s += __shfl_down(s, o);
  if ((tid & 63) == 0) sm1[tid >> 6] = s;
  __syncthreads();
  float mean = (sm1[0] + sm1[1] + sm1[2] + sm1[3]) * (1.0f / DM);
  float d0 = v.x - mean, d1 = v.y - mean, d2 = v.z - mean, d3 = v.w - mean;
  float q = d0 * d0 + d1 * d1 + d2 * d2 + d3 * d3;
  for (int o = 32; o > 0; o >>= 1) q += __shfl_down(q, o);
  if ((tid & 63) == 0) sm2[tid >> 6] = q;
  __syncthreads();
  float var = (sm2[0] + sm2[1] + sm2[2] + sm2[3]) * (1.0f / DM);
  float rstd = rsqrtf(var + 1e-5f);
  float4 gv = ((const float4*)g)[tid];
  float4 bv = ((const float4*)b)[tid];
  float o0 = d0 * rstd * gv.x + bv.x, o1 = d1 * rstd * gv.y + bv.y;
  float o2 = d2 * rstd * gv.z + bv.z, o3 = d3 * rstd * gv.w + bv.w;
  long long base = (long long)row * DM + tid * 4;
  if (MODE == 0) {
    ushort_t hh, ll;
    split2(o0, hh, ll); outH[base + 0] = hh; outL[base + 0] = ll;
    split2(o1, hh, ll); outH[base + 1] = hh; outL[base + 1] = ll;
    split2(o2, hh, ll); outH[base + 2] = hh; outL[base + 2] = ll;
    split2(o3, hh, ll); outH[base + 3] = hh; outL[base + 3] = ll;
  } else {
    outH[base + 0] = f2b(o0); outH[base + 1] = f2b(o1);
    outH[base + 2] = f2b(o2); outH[base + 3] = f2b(o3);
  }
}

__global__ __launch_bounds__(256)
void transpose_v2(const ushort_t* __restrict__ qH, const ushort_t* __restrict__ qL,
                  ushort_t* __restrict__ vH, ushort_t* __restrict__ vL)
{
  __shared__ ushort_t tH[64][65], tL[64][65];
  int j0 = blockIdx.x * 64, h = blockIdx.y;
  int tid = threadIdx.x;
  int jr = tid >> 2, d0 = (tid & 3) * 16;
  long long so = (long long)(j0 + jr) * (3 * DM) + 2 * DM + h * 64 + d0;
#pragma unroll
  for (int i = 0; i < 16; ++i) { tH[jr][d0 + i] = qH[so + i]; tL[jr][d0 + i] = qL[so + i]; }
  __syncthreads();
  int dd = tid >> 2, jc = (tid & 3) * 16;
  long long dofs = (long long)(h * 64 + dd) * SQ + j0 + jc;
#pragma unroll
  for (int i = 0; i < 16; ++i) { vH[dofs + i] = tH[jc + i][dd]; vL[dofs + i] = tL[jc + i][dd]; }
}

__global__ __launch_bounds__(256)
void ln_gate_top2(const float* __restrict__ x, const float* __restrict__ g,
                  const float* __restrict__ b, const float* __restrict__ gw,
                  const float* __restrict__ gb, int* __restrict__ topi,
                  float* __restrict__ topw, int* __restrict__ counts)
{
  int row = blockIdx.x, tid = threadIdx.x;
  float4 v = ((const float4*)(x + (long long)row * DM))[tid];
  __shared__ float sm1[4], sm2[4];
  __shared__ float se[8][4];
  float s = v.x + v.y + v.z + v.w;
  for (int o = 32; o > 0; o >>= 1) s += __shfl_down(s, o);
  if ((tid & 63) == 0) sm1[tid >> 6] = s;
  __syncthreads();
  float mean = (sm1[0] + sm1[1] + sm1[2] + sm1[3]) * (1.0f / DM);
  float d0 = v.x - mean, d1 = v.y - mean, d2 = v.z - mean, d3 = v.w - mean;
  float q = d0 * d0 + d1 * d1 + d2 * d2 + d3 * d3;
  for (int o = 32; o > 0; o >>= 1) q += __shfl_down(q, o);
  if ((tid & 63) == 0) sm2[tid >> 6] = q;
  __syncthreads();
  float var = (sm2[0] + sm2[1] + sm2[2] + sm2[3]) * (1.0f / DM);
  float rstd = rsqrtf(var + 1e-5f);
  float4 gv = ((const float4*)g)[tid];
  float4 bv = ((const float4*)b)[tid];
  float h0 = d0 * rstd * gv.x + bv.x, h1 = d1 * rstd * gv.y + bv.y;
  float h2 = d2 * rstd * gv.z + bv.z, h3 = d3 * rstd * gv.w + bv.w;
#pragma unroll
  for (int e = 0; e < 8; ++e) {
    float4 w = ((const float4*)(gw + (long long)e * DM))[tid];
    float p = h0 * w.x + h1 * w.y + h2 * w.z + h3 * w.w;
    for (int o = 32; o > 0; o >>= 1) p += __shfl_down(p, o);
    if ((tid & 63) == 0) se[e][tid >> 6] = p;
  }
  __syncthreads();
  if (tid == 0) {
    float sc[8];
#pragma unroll
    for (int e = 0; e < 8; ++e)
      sc[e] = se[e][0] + se[e][1] + se[e][2] + se[e][3] + gb[e];
    int i1 = 0; float m1 = sc[0];
    for (int e = 1; e < 8; ++e) if (sc[e] > m1) { m1 = sc[e]; i1 = e; }
    int i2 = -1; float m2 = -1e30f;
    for (int e = 0; e < 8; ++e) if (e != i1 && sc[e] > m2) { m2 = sc[e]; i2 = e; }
    float e2 = __expf(m2 - m1);
    float w1 = 1.f / (1.f + e2);
    topi[row * 2] = i1; topi[row * 2 + 1] = i2;
    topw[row * 2] = w1; topw[row * 2 + 1] = 1.f - w1;
    atomicAdd(&counts[i1], 1);
    atomicAdd(&counts[i2], 1);
  }
}

__global__ void moe_zero(int* counts) { if (threadIdx.x < 8) counts[threadIdx.x] = 0; }

__global__ void moe_prefix(const int* __restrict__ counts, int* __restrict__ offs,
                           int* __restrict__ cursors)
{
  if (threadIdx.x == 0 && blockIdx.x == 0) {
    int a = 0;
    for (int e = 0; e < 8; ++e) { offs[e] = a; a += counts[e]; cursors[e] = 0; }
    offs[8] = a;
  }
}

__global__ __launch_bounds__(256)
void moe_gather(const ushort_t* __restrict__ hH, const int* __restrict__ topi,
                const float* __restrict__ topw, const int* __restrict__ offs,
                int* __restrict__ cursors, int* __restrict__ tokIdx,
                float* __restrict__ tokW, int* __restrict__ slotOf,
                ushort_t* __restrict__ Xg)
{
  int tok = blockIdx.x, tid = threadIdx.x;
  __shared__ int s0s, s1s;
  if (tid == 0) {
    int e0 = topi[tok * 2], e1 = topi[tok * 2 + 1];
    int s0 = offs[e0] + atomicAdd(&cursors[e0], 1);
    int s1 = offs[e1] + atomicAdd(&cursors[e1], 1);
    tokIdx[s0] = tok; tokW[s0] = topw[tok * 2];
    tokIdx[s1] = tok; tokW[s1] = topw[tok * 2 + 1];
    slotOf[tok * 2] = s0; slotOf[tok * 2 + 1] = s1;
    s0s = s0; s1s = s1;
  }
  __syncthreads();
  s4v v = ((const s4v*)(hH + (long long)tok * DM))[tid];
  ((s4v*)(Xg + (long long)s0s * DM))[tid] = v;
  ((s4v*)(Xg + (long long)s1s * DM))[tid] = v;
}

__global__ __launch_bounds__(256)
void moe_reduce(float* __restrict__ x, const float* __restrict__ eo, long long pC,
                const int* __restrict__ slotOf, const int* __restrict__ topi,
                const float* __restrict__ topw, const float* __restrict__ b2)
{
  int tok = blockIdx.x, tid = threadIdx.x;
  int s0 = slotOf[tok * 2], s1 = slotOf[tok * 2 + 1];
  int e0 = topi[tok * 2], e1 = topi[tok * 2 + 1];
  float w0 = topw[tok * 2], w1 = topw[tok * 2 + 1];
  float4 a  = ((const float4*)(eo + (long long)s0 * DM))[tid];
  float4 a2 = ((const float4*)(eo + pC + (long long)s0 * DM))[tid];
  float4 b  = ((const float4*)(eo + (long long)s1 * DM))[tid];
  float4 b2v= ((const float4*)(eo + pC + (long long)s1 * DM))[tid];
  float4 ba = ((const float4*)(b2 + (long long)e0 * DM))[tid];
  float4 bb = ((const float4*)(b2 + (long long)e1 * DM))[tid];
  float4* xr = (float4*)(x + (long long)tok * DM) + tid;
  float4 xv = *xr;
  xv.x += w0 * (a.x + a2.x + ba.x) + w1 * (b.x + b2v.x + bb.x);
  xv.y += w0 * (a.y + a2.y + ba.y) + w1 * (b.y + b2v.y + bb.y);
  xv.z += w0 * (a.z + a2.z + ba.z) + w1 * (b.z + b2v.z + bb.z);
  xv.w += w0 * (a.w + a2.w + ba.w) + w1 * (b.w + b2v.w + bb.w);
  *xr = xv;
}

extern "C" void kernel_launch(void* const* d_in, const int* in_sizes, int n_in,
                              void* d_out, int out_size, void* d_ws, size_t ws_size,
                              hipStream_t stream)
{
  const int* ids = (const int*)d_in[0];
  const float* embed_w = (const float*)d_in[1];
  const float* pos_w   = (const float*)d_in[2];
  const float* ln1_g[2] = {(const float*)d_in[3],  (const float*)d_in[11]};
  const float* ln1_b[2] = {(const float*)d_in[4],  (const float*)d_in[12]};
  const float* in_w[2]  = {(const float*)d_in[5],  (const float*)d_in[13]};
  const float* in_b[2]  = {(const float*)d_in[6],  (const float*)d_in[14]};
  const float* out_w[2] = {(const float*)d_in[7],  (const float*)d_in[15]};
  const float* out_b[2] = {(const float*)d_in[8],  (const float*)d_in[16]};
  const float* ln2_g[2] = {(const float*)d_in[9],  (const float*)d_in[17]};
  const float* ln2_b[2] = {(const float*)d_in[10], (const float*)d_in[18]};
  const float* ffn_w1 = (const float*)d_in[19];
  const float* ffn_b1 = (const float*)d_in[20];
  const float* ffn_w2 = (const float*)d_in[21];
  const float* ffn_b2 = (const float*)d_in[22];
  const float* gate_w = (const float*)d_in[23];
  const float* gate_b = (const float*)d_in[24];
  const float* moe_w1 = (const float*)d_in[25];
  const float* moe_b1 = (const float*)d_in[26];
  const float* moe_w2 = (const float*)d_in[27];
  const float* moe_b2 = (const float*)d_in[28];
  const float* norm_g = (const float*)d_in[29];
  const float* norm_b = (const float*)d_in[30];
  const float* head_w = (const float*)d_in[31];

  char* ob = (char*)d_out;
  size_t off = 0;
  auto alloc = [&](size_t bytes) {
    char* p = ob + off;
    off = (off + bytes + 255) & ~(size_t)255;
    return p;
  };
  float*    x      = (float*)alloc((size_t)SQ * DM * 4);
  ushort_t* hbufH  = (ushort_t*)alloc((size_t)SQ * DM * 2);
  ushort_t* hbufL  = (ushort_t*)alloc((size_t)SQ * DM * 2);
  ushort_t* qkvH   = (ushort_t*)alloc((size_t)SQ * 3 * DM * 2);   // ┐
  ushort_t* qkvL   = (ushort_t*)alloc((size_t)SQ * 3 * DM * 2);   // │ w2b
  ushort_t* VtH    = (ushort_t*)alloc((size_t)NH * HDIM * SQ * 2);// │ 64MiB
  ushort_t* VtL    = (ushort_t*)alloc((size_t)NH * HDIM * SQ * 2);// │
  char*     resv   = (char*)alloc((size_t)32 << 20);              // ┘ filler
  ushort_t* attnH  = (ushort_t*)alloc((size_t)SQ * DM * 2);
  ushort_t* attnL  = (ushort_t*)alloc((size_t)SQ * DM * 2);
  ushort_t* Xg     = (ushort_t*)alloc((size_t)2 * SQ * DM * 2);
  int*      topi   = (int*)alloc(SQ * 2 * 4);
  float*    topw   = (float*)alloc(SQ * 2 * 4);
  int*      tokIdx = (int*)alloc(2 * SQ * 4);
  float*    tokW   = (float*)alloc(2 * SQ * 4);
  int*      slotOf = (int*)alloc(2 * SQ * 4);
  int*      counts = (int*)alloc(256);
  int*      offsb  = (int*)alloc(256);
  int*      cursors= (int*)alloc(256);
  ushort_t* ffnH   = (ushort_t*)alloc((size_t)SQ * FFD * 2);      // ┐ moehid
  ushort_t* ffnL   = (ushort_t*)alloc((size_t)SQ * FFD * 2);      // ┘ 32MiB
  float*    eo     = (float*)alloc((size_t)2 * 2 * SQ * DM * 4);  // 32MiB
  ushort_t* inwH[2], *inwL[2], *outwH[2], *outwL[2];
  ushort_t* wsplit0 = (ushort_t*)alloc(0);
  inwH[0]  = (ushort_t*)alloc((size_t)3 * DM * DM * 2);
  inwL[0]  = (ushort_t*)alloc((size_t)3 * DM * DM * 2);
  inwH[1]  = (ushort_t*)alloc((size_t)3 * DM * DM * 2);
  inwL[1]  = (ushort_t*)alloc((size_t)3 * DM * DM * 2);
  outwH[0] = (ushort_t*)alloc((size_t)DM * DM * 2);
  outwL[0] = (ushort_t*)alloc((size_t)DM * DM * 2);
  outwH[1] = (ushort_t*)alloc((size_t)DM * DM * 2);
  outwL[1] = (ushort_t*)alloc((size_t)DM * DM * 2);
  ushort_t* f1H = (ushort_t*)alloc((size_t)FFD * DM * 2);
  ushort_t* f1L = (ushort_t*)alloc((size_t)FFD * DM * 2);
  ushort_t* f2H = (ushort_t*)alloc((size_t)DM * FFD * 2);
  ushort_t* f2L = (ushort_t*)alloc((size_t)DM * FFD * 2);
  ushort_t* moe_w1b = wsplit0;            // 64 MiB over weight planes
  ushort_t* moe_w2b = qkvH;               // 64 MiB over qkv+Vt+resv
  ushort_t* moehid  = ffnH;               // 32 MiB over ffn planes
  const long long eoPC = (long long)2 * SQ * DM;
  ushort_t* hfin    = (ushort_t*)d_ws;
  bool wsBig = ws_size >= ((size_t)70 << 20);
  ushort_t* head_wb = (ushort_t*)((char*)d_ws + ((size_t)4 << 20));
  (void)resv;

  moe_zero<<<1, 64, 0, stream>>>(counts);
  embed_kernel<<<SQ, 256, 0, stream>>>(ids, embed_w, pos_w, x);
  cvt_split<<<512, 256, 0, stream>>>(in_w[0], inwH[0], inwL[0], 3 * DM * DM / 4);
  cvt_split<<<512, 256, 0, stream>>>(in_w[1], inwH[1], inwL[1], 3 * DM * DM / 4);
  cvt_split<<<512, 256, 0, stream>>>(out_w[0], outwH[0], outwL[0], DM * DM / 4);
  cvt_split<<<512, 256, 0, stream>>>(out_w[1], outwH[1], outwL[1], DM * DM / 4);
  cvt_split<<<512, 256, 0, stream>>>(ffn_w1, f1H, f1L, FFD * DM / 4);
  cvt_split<<<512, 256, 0, stream>>>(ffn_w2, f2H, f2L, DM * FFD / 4);
  if (wsBig)
    cvt_bf16<<<1024, 256, 0, stream>>>(head_w, head_wb, NVOC * DM / 4);

  for (int L = 0; L < 2; ++L) {
    ln_kernel<0><<<SQ, 256, 0, stream>>>(x, ln1_g[L], ln1_b[L], hbufH, hbufL);
    k_qkv<<<dim3(16, 24, 1), 256, 0, stream>>>(
        hbufH, hbufL, DM, 0, inwH[L], inwL[L], DM, 0,
        nullptr, qkvH, qkvL, 3 * DM, 0, 0,
        SQ, 3 * DM, DM, in_b[L], 1.f);
    transpose_v2<<<dim3(SQ / 64, NH), 256, 0, stream>>>(qkvH, qkvL, VtH, VtL);
    // fused flash attention: qkv planes -> attn planes
    k_attn<<<dim3(SQ / 64, NH), 256, 0, stream>>>(qkvH, qkvL, VtH, VtL,
                                                  attnH, attnL);
    k_outp<<<dim3(16, 16, 1), 256, 0, stream>>>(
        attnH, attnL, DM, 0, outwH[L], outwL[L], DM, 0,
        x, nullptr, nullptr, DM, 0, 0,
        SQ, DM, DM, out_b[L], 1.f);
    if (L == 0) {
      ln_kernel<0><<<SQ, 256, 0, stream>>>(x, ln2_g[0], ln2_b[0], hbufH, hbufL);
      k_ffn1<<<dim3(16, 32, 1), 256, 0, stream>>>(
          hbufH, hbufL, DM, 0, f1H, f1L, DM, 0,
          nullptr, ffnH, ffnL, FFD, 0, 0,
          SQ, FFD, DM, ffn_b1, 1.f);
      k_ffn2<<<dim3(16, 16, 1), 256, 0, stream>>>(
          ffnH, ffnL, FFD, 0, f2H, f2L, FFD, 0,
          x, nullptr, nullptr, DM, 0, 0,
          SQ, DM, FFD, ffn_b2, 1.f);
    } else {
      cvt_bf16<<<2048, 256, 0, stream>>>(moe_w1, moe_w1b, 8 * FFD * DM / 4);
      cvt_bf16<<<2048, 256, 0, stream>>>(moe_w2, moe_w2b, 8 * DM * FFD / 4);
      ln_gate_top2<<<SQ, 256, 0, stream>>>(x, ln2_g[1], ln2_b[1], gate_w, gate_b,
                                           topi, topw, counts);
      moe_prefix<<<1, 64, 0, stream>>>(counts, offsb, cursors);
      ln_kernel<1><<<SQ, 256, 0, stream>>>(x, ln2_g[1], ln2_b[1], hbufH, nullptr);
      moe_gather<<<SQ, 256, 0, stream>>>(hbufH, topi, topw, offsb, cursors,
                                         tokIdx, tokW, slotOf, Xg);
      k_moe1<<<dim3(32, 16, 8), 256, 0, stream>>>(
          Xg, DM, 0, moe_w1b, DM, (long long)FFD * DM,
          moehid, FFD, 0, 0, SQ, FFD, DM, moe_b1, FFD, offsb);
      k_moe2<<<dim3(8, 16, 16), 256, 0, stream>>>(
          moehid, FFD, 0, moe_w2b, FFD, (long long)DM * FFD,
          eo, DM, 0, eoPC, SQ, DM, FFD, nullptr, 0, offsb);
      moe_reduce<<<SQ, 256, 0, stream>>>(x, eo, eoPC, slotOf, topi, topw, moe_b2);
    }
  }
  ln_kernel<1><<<SQ, 256, 0, stream>>>(x, norm_g, norm_b, hfin, nullptr);
  if (wsBig)
    k_head_bf<<<dim3(16, 250, 1), 256, 0, stream>>>(
        hfin, DM, 0, head_wb, DM, 0, d_out, NVOC, 0, 0,
        SQ, NVOC, DM, nullptr, 0, nullptr);
  else
    k_head_f<<<dim3(16, 250, 1), 256, 0, stream>>>(
        hfin, DM, 0, head_w, DM, 0, d_out, NVOC, 0, 0,
        SQ, NVOC, DM, nullptr, 0, nullptr);
}

// Round 10
// 1332.108 us; speedup vs baseline: 1.6750x; 1.0033x over previous
//
#include <hip/hip_runtime.h>
#include <hip/hip_bf16.h>
#include <math.h>

typedef unsigned short ushort_t;
typedef __attribute__((ext_vector_type(8))) __bf16 bf16x8;
typedef __attribute__((ext_vector_type(4))) float f32x4;
typedef __attribute__((ext_vector_type(8))) short s8v;
typedef __attribute__((ext_vector_type(4))) short s4v;

#define SQ 2048
#define DM 1024
#define NH 16
#define HDIM 64
#define FFD 4096
#define NVOC 32000

__device__ inline float b2f(unsigned short u) {
  union { unsigned int i; float f; } x; x.i = ((unsigned int)u) << 16; return x.f;
}
__device__ inline unsigned short f2b(float f) {
  __hip_bfloat16 h = __float2bfloat16(f);
  return *reinterpret_cast<unsigned short*>(&h);
}
__device__ inline void split2(float x, ushort_t& h, ushort_t& l) {
  h = f2b(x);
  l = f2b(x - b2f(h));
}
__device__ inline float geluf(float v) {
  return 0.5f * v * (1.0f + erff(v * 0.70710678118654752f));
}
__device__ __forceinline__ void gld16(const void* g, void* l) {
  __builtin_amdgcn_global_load_lds(
      (const __attribute__((address_space(1))) void*)g,
      (__attribute__((address_space(3))) void*)l, 16, 0, 0);
}
#define MFMA __builtin_amdgcn_mfma_f32_16x16x32_bf16

// ---------------------------------------------------------------------------
// Split GEMM engine (pre-gate math): C = epi((AH+AL)*(BH+BL)^T), planes bf16.
// ---------------------------------------------------------------------------
template<int EPI, int NT, int KS>
__device__ __forceinline__ void gemmsp_body(
    const ushort_t* __restrict__ AH, const ushort_t* __restrict__ AL,
    int lda, long long bA,
    const ushort_t* __restrict__ BH, const ushort_t* __restrict__ BL,
    int ldb, long long bB,
    float* __restrict__ C, ushort_t* __restrict__ CH, ushort_t* __restrict__ CL,
    int ldc, long long bC, long long pC,
    int M, int N, int K, const float* __restrict__ bias, float alpha)
{
  int z = blockIdx.z, h = z / KS, kc = z % KS;
  const ushort_t* AHp = AH + (long long)h * bA + (long long)kc * K;
  const ushort_t* ALp = AL + (long long)h * bA + (long long)kc * K;
  const ushort_t* BHp = BH + (long long)h * bB + (long long)kc * K;
  const ushort_t* BLp = BL + (long long)h * bB + (long long)kc * K;
  int m0 = blockIdx.x * 128, n0 = blockIdx.y * NT;
  const int NF = NT / 32;

  __shared__ __align__(16) ushort_t sAH[128 * 32], sAL[128 * 32];
  __shared__ __align__(16) ushort_t sBH[NT * 32],  sBL[NT * 32];

  int tid = threadIdx.x, lane = tid & 63, wave = tid >> 6;
  int wr = (wave >> 1) * 64, wc = (wave & 1) * (NT >> 1);
  int l15 = lane & 15, l4 = lane >> 4;

  f32x4 acc[4][NF];
#pragma unroll
  for (int m = 0; m < 4; ++m)
#pragma unroll
    for (int n = 0; n < NF; ++n) acc[m][n] = (f32x4){0.f, 0.f, 0.f, 0.f};

  for (int k0 = 0; k0 < K; k0 += 32) {
#pragma unroll
    for (int i = 0; i < 2; ++i) {
      int fi = i * 2048 + tid * 8;
      int r = fi >> 5, chk = (fi >> 3) & 3;
      int scol = ((chk ^ ((r >> 1) & 3)) << 3);
      int ra = m0 + r; if (ra > M - 1) ra = M - 1;
      long long go = (long long)ra * lda + k0 + scol;
      gld16(AHp + go, &sAH[fi]);
      gld16(ALp + go, &sAL[fi]);
    }
#pragma unroll
    for (int i = 0; i < NT / 64; ++i) {
      int fi = i * 2048 + tid * 8;
      int r = fi >> 5, chk = (fi >> 3) & 3;
      int scol = ((chk ^ ((r >> 1) & 3)) << 3);
      int rb = n0 + r; if (rb > N - 1) rb = N - 1;
      long long go = (long long)rb * ldb + k0 + scol;
      gld16(BHp + go, &sBH[fi]);
      gld16(BLp + go, &sBL[fi]);
    }
    __syncthreads();
    bf16x8 ah[4], al[4], bh[NF], bl[NF];
#pragma unroll
    for (int m = 0; m < 4; ++m) {
      int r = wr + m * 16 + l15;
      int o = r * 32 + ((l4 ^ ((r >> 1) & 3)) << 3);
      ah[m] = *(const bf16x8*)&sAH[o];
      al[m] = *(const bf16x8*)&sAL[o];
    }
#pragma unroll
    for (int n = 0; n < NF; ++n) {
      int r = wc + n * 16 + l15;
      int o = r * 32 + ((l4 ^ ((r >> 1) & 3)) << 3);
      bh[n] = *(const bf16x8*)&sBH[o];
      bl[n] = *(const bf16x8*)&sBL[o];
    }
#pragma unroll
    for (int m = 0; m < 4; ++m)
#pragma unroll
      for (int n = 0; n < NF; ++n) {
        acc[m][n] = MFMA(ah[m], bh[n], acc[m][n], 0, 0, 0);
        acc[m][n] = MFMA(al[m], bh[n], acc[m][n], 0, 0, 0);
        acc[m][n] = MFMA(ah[m], bl[n], acc[m][n], 0, 0, 0);
      }
    __syncthreads();
  }

#pragma unroll
  for (int m = 0; m < 4; ++m) {
#pragma unroll
    for (int n = 0; n < NF; ++n) {
      int c = n0 + wc + n * 16 + l15;
      if (c >= N) continue;
      float bv = (EPI == 0 || EPI == 3 || EPI == 4) ? bias[c] : 0.f;
#pragma unroll
      for (int q = 0; q < 4; ++q) {
        int rr = m0 + wr + m * 16 + l4 * 4 + q;
        if (rr >= M) continue;
        float v = acc[m][n][q];
        if (EPI == 0) {
          ushort_t hh, ll; split2(v + bv, hh, ll);
          long long o = (long long)rr * ldc + c; CH[o] = hh; CL[o] = ll;
        } else if (EPI == 3) {
          C[(long long)rr * ldc + c] += v + bv;
        } else if (EPI == 4) {
          ushort_t hh, ll; split2(geluf(v + bv), hh, ll);
          long long o = (long long)rr * ldc + c; CH[o] = hh; CL[o] = ll;
        }
      }
    }
  }
}

#define SP_ARGS const ushort_t* AH, const ushort_t* AL, int lda, long long bA, \
    const ushort_t* BH, const ushort_t* BL, int ldb, long long bB, \
    float* C, ushort_t* CH, ushort_t* CL, int ldc, long long bC, long long pC, \
    int M, int N, int K, const float* bias, float alpha
#define SP_PASS AH, AL, lda, bA, BH, BL, ldb, bB, C, CH, CL, ldc, bC, pC, M, N, K, bias, alpha

__global__ __launch_bounds__(256) void k_qkv (SP_ARGS) { gemmsp_body<0,128,1>(SP_PASS); }
__global__ __launch_bounds__(256) void k_outp(SP_ARGS) { gemmsp_body<3, 64,1>(SP_PASS); }
__global__ __launch_bounds__(256) void k_ffn1(SP_ARGS) { gemmsp_body<4,128,1>(SP_PASS); }
__global__ __launch_bounds__(256) void k_ffn2(SP_ARGS) { gemmsp_body<3, 64,1>(SP_PASS); }

// ---------------------------------------------------------------------------
// Fused flash attention, split-f32 precision. Grid (32,16).
// XCD-chunked remap: 64 consecutive logical blocks per XCD -> 2 heads/XCD,
// K/V planes L2-resident. Q fragments hoisted to registers (LDS 48KB ->
// 3 blocks/CU).
// ---------------------------------------------------------------------------
__global__ __launch_bounds__(256)
void k_attn(const ushort_t* __restrict__ qkvH, const ushort_t* __restrict__ qkvL,
            const ushort_t* __restrict__ VtH, const ushort_t* __restrict__ VtL,
            ushort_t* __restrict__ aH, ushort_t* __restrict__ aL)
{
  int f = blockIdx.x + blockIdx.y * gridDim.x;       // 0..511
  int logical = (f & 7) * 64 + (f >> 3);             // chunked per-XCD
  int q0 = (logical & 31) * 64;
  int h  = logical >> 5;

  __shared__ __align__(16) ushort_t sKH[4096], sKL[4096];
  __shared__ __align__(16) ushort_t sVH[4096], sVL[4096];
  __shared__ __align__(16) ushort_t sPH[4096], sPL[4096];

  int tid = threadIdx.x, lane = tid & 63, wave = tid >> 6;
  int l15 = lane & 15, l4 = lane >> 4;

  // Q fragments in registers (wave owns rows q0+wave*16 .. +15)
  bf16x8 qh[2], ql[2];
  {
    long long base = (long long)(q0 + wave * 16 + l15) * (3 * DM) + h * 64 + l4 * 8;
    qh[0] = *(const bf16x8*)(qkvH + base);
    qh[1] = *(const bf16x8*)(qkvH + base + 32);
    ql[0] = *(const bf16x8*)(qkvL + base);
    ql[1] = *(const bf16x8*)(qkvL + base + 32);
  }

  float mrow[4], lrow[4];
  f32x4 Oacc[4];
#pragma unroll
  for (int r = 0; r < 4; ++r) { mrow[r] = -1e30f; lrow[r] = 0.f; }
#pragma unroll
  for (int n = 0; n < 4; ++n) Oacc[n] = (f32x4){0.f, 0.f, 0.f, 0.f};

  for (int kt = 0; kt < SQ / 64; ++kt) {
#pragma unroll
    for (int i = 0; i < 2; ++i) {
      int idx = i * 2048 + tid * 8;
      int row = idx >> 6, chk = (idx >> 3) & 7;
      int scol = ((chk ^ (row & 7)) << 3);
      long long gk = (long long)(kt * 64 + row) * (3 * DM) + DM + h * 64 + scol;
      long long gv = (long long)(h * 64 + row) * SQ + kt * 64 + scol;
      gld16(qkvH + gk, &sKH[idx]);
      gld16(qkvL + gk, &sKL[idx]);
      gld16(VtH + gv, &sVH[idx]);
      gld16(VtL + gv, &sVL[idx]);
    }
    __syncthreads();

    f32x4 S[4];
#pragma unroll
    for (int n = 0; n < 4; ++n) S[n] = (f32x4){0.f, 0.f, 0.f, 0.f};
#pragma unroll
    for (int kk = 0; kk < 64; kk += 32) {
      int kkI = kk >> 5;
      bf16x8 qhf = qh[kkI], qlf = ql[kkI];
#pragma unroll
      for (int n = 0; n < 4; ++n) {
        int br = n * 16 + l15;
        int bo = br * 64 + ((((kk >> 3) + l4) ^ (br & 7)) << 3);
        bf16x8 kh = *(const bf16x8*)&sKH[bo];
        bf16x8 kl = *(const bf16x8*)&sKL[bo];
        S[n] = MFMA(qhf, kh, S[n], 0, 0, 0);
        S[n] = MFMA(qlf, kh, S[n], 0, 0, 0);
        S[n] = MFMA(qhf, kl, S[n], 0, 0, 0);
      }
    }
    float tm[4], ts[4];
#pragma unroll
    for (int r = 0; r < 4; ++r) {
#pragma unroll
      for (int n = 0; n < 4; ++n) S[n][r] *= 0.125f;
      tm[r] = fmaxf(fmaxf(S[0][r], S[1][r]), fmaxf(S[2][r], S[3][r]));
    }
#pragma unroll
    for (int mk = 1; mk <= 8; mk <<= 1)
#pragma unroll
      for (int r = 0; r < 4; ++r) tm[r] = fmaxf(tm[r], __shfl_xor(tm[r], mk));
#pragma unroll
    for (int r = 0; r < 4; ++r) {
      float mn = fmaxf(mrow[r], tm[r]);
      float corr = __expf(mrow[r] - mn);
      mrow[r] = mn;
      float s = 0.f;
#pragma unroll
      for (int n = 0; n < 4; ++n) { S[n][r] = __expf(S[n][r] - mn); s += S[n][r]; }
      ts[r] = s;
      lrow[r] *= corr;
#pragma unroll
      for (int n = 0; n < 4; ++n) Oacc[n][r] *= corr;
    }
#pragma unroll
    for (int mk = 1; mk <= 8; mk <<= 1)
#pragma unroll
      for (int r = 0; r < 4; ++r) ts[r] += __shfl_xor(ts[r], mk);
#pragma unroll
    for (int r = 0; r < 4; ++r) lrow[r] += ts[r];

    {
      ushort_t* pH = &sPH[wave * 1024];
      ushort_t* pL = &sPL[wave * 1024];
#pragma unroll
      for (int n = 0; n < 4; ++n)
#pragma unroll
        for (int r = 0; r < 4; ++r) {
          int row = l4 * 4 + r, col = n * 16 + l15;
          int ad = row * 64 + (((col >> 3) ^ (row & 7)) << 3) + (col & 7);
          ushort_t hh, ll; split2(S[n][r], hh, ll);
          pH[ad] = hh; pL[ad] = ll;
        }
    }
    __syncthreads();
#pragma unroll
    for (int kk = 0; kk < 64; kk += 32) {
      int ao = wave * 1024 + l15 * 64 + ((((kk >> 3) + l4) ^ (l15 & 7)) << 3);
      bf16x8 ph = *(const bf16x8*)&sPH[ao];
      bf16x8 pl = *(const bf16x8*)&sPL[ao];
#pragma unroll
      for (int n = 0; n < 4; ++n) {
        int br = n * 16 + l15;
        int bo = br * 64 + ((((kk >> 3) + l4) ^ (br & 7)) << 3);
        bf16x8 vh = *(const bf16x8*)&sVH[bo];
        bf16x8 vl = *(const bf16x8*)&sVL[bo];
        Oacc[n] = MFMA(ph, vh, Oacc[n], 0, 0, 0);
        Oacc[n] = MFMA(pl, vh, Oacc[n], 0, 0, 0);
        Oacc[n] = MFMA(ph, vl, Oacc[n], 0, 0, 0);
      }
    }
    __syncthreads();
  }

#pragma unroll
  for (int n = 0; n < 4; ++n)
#pragma unroll
    for (int r = 0; r < 4; ++r) {
      int q = q0 + wave * 16 + l4 * 4 + r;
      int d = h * 64 + n * 16 + l15;
      float val = Oacc[n][r] / lrow[r];
      ushort_t hh, ll; split2(val, hh, ll);
      long long o = (long long)q * DM + d;
      aH[o] = hh; aL[o] = ll;
    }
}

// ---------------------------------------------------------------------------
// bf16 GEMM engine (post-gate). EPI 6/7 use an LDS-transposed float4-coalesced
// epilogue (store path was 64B quarter-wave segments -> 1KB/wave rows).
// ---------------------------------------------------------------------------
template<int EPI, int BSRC, int SWAP, int KS, int XS>
__device__ __forceinline__ void gemm16_body(
    const ushort_t* __restrict__ A, int lda, long long bA,
    const void* __restrict__ Bv, int ldb, long long bB,
    void* __restrict__ Cv, int ldc, long long bC, long long pC,
    int M, int N, int K, const float* __restrict__ bias, int bBias,
    const int* __restrict__ offs)
{
  int bz = blockIdx.z;
  int z = bz / KS, kc = bz % KS;
  int Kc = K / KS;
  const ushort_t* Ap = A + (long long)z * bA + (long long)kc * Kc;
  int rowStart = 0, Meff = M;
  if (offs) { rowStart = offs[z]; Meff = offs[z + 1] - rowStart; }
  int bx = blockIdx.x, by = blockIdx.y;
  if (XS) {
    int flat = bx + by * gridDim.x;
    int cpx = (gridDim.x * gridDim.y) >> 3;
    int s = (flat & 7) * cpx + (flat >> 3);
    bx = s % gridDim.x; by = s / gridDim.x;
  }
  int m0 = (SWAP ? by : bx) * 128;
  if (m0 >= Meff) return;
  int n0 = (SWAP ? bx : by) * 128;

  __shared__ __align__(16) char smem[32768];
  ushort_t* As = (ushort_t*)smem;            // 128x64 = 16KB
  ushort_t* Bs = (ushort_t*)(smem + 16384);  // 16KB

  int tid = threadIdx.x, lane = tid & 63, wave = tid >> 6;
  int wr = (wave >> 1) * 64, wc = (wave & 1) * 64;
  int l15 = lane & 15, l4 = lane >> 4;

  f32x4 acc[4][4];
#pragma unroll
  for (int m = 0; m < 4; ++m)
#pragma unroll
    for (int n = 0; n < 4; ++n) acc[m][n] = (f32x4){0.f, 0.f, 0.f, 0.f};

  for (int k0 = 0; k0 < Kc; k0 += 64) {
#pragma unroll
    for (int i = 0; i < 4; ++i) {
      int idx = i * 2048 + tid * 8;
      int row = idx >> 6, chk = (idx >> 3) & 7;
      int scol = ((chk ^ (row & 7)) << 3);
      int ra = m0 + row; if (ra > Meff - 1) ra = Meff - 1;
      gld16(Ap + (long long)(rowStart + ra) * lda + k0 + scol, &As[idx]);
    }
    if (BSRC == 1) {
      const ushort_t* Bp = (const ushort_t*)Bv + (long long)z * bB + (long long)kc * Kc;
#pragma unroll
      for (int i = 0; i < 4; ++i) {
        int idx = i * 2048 + tid * 8;
        int row = idx >> 6, chk = (idx >> 3) & 7;
        int scol = ((chk ^ (row & 7)) << 3);
        int rb = n0 + row; if (rb > N - 1) rb = N - 1;
        gld16(Bp + (long long)rb * ldb + k0 + scol, &Bs[idx]);
      }
    } else {
      const float* Bf = (const float*)Bv + (long long)z * bB + (long long)kc * Kc;
#pragma unroll
      for (int i = 0; i < 8; ++i) {
        int g = tid + i * 256;
        int r = g >> 4, c4 = (g & 15) * 4;
        int rb = n0 + r; if (rb > N - 1) rb = N - 1;
        float4 fv = *(const float4*)(Bf + (long long)rb * ldb + k0 + c4);
        s4v o; o[0] = (short)f2b(fv.x); o[1] = (short)f2b(fv.y);
        o[2] = (short)f2b(fv.z); o[3] = (short)f2b(fv.w);
        int dst = r * 64 + (((c4 >> 3) ^ (r & 7)) << 3) + (c4 & 7);
        *(s4v*)&Bs[dst] = o;
      }
    }
    __syncthreads();
#pragma unroll
    for (int kk = 0; kk < 64; kk += 32) {
      bf16x8 af[4], bfr[4];
#pragma unroll
      for (int m = 0; m < 4; ++m) {
        int r = wr + m * 16 + l15;
        af[m] = *(const bf16x8*)&As[r * 64 + ((((kk >> 3) + l4) ^ (r & 7)) << 3)];
      }
#pragma unroll
      for (int n = 0; n < 4; ++n) {
        int r = wc + n * 16 + l15;
        bfr[n] = *(const bf16x8*)&Bs[r * 64 + ((((kk >> 3) + l4) ^ (r & 7)) << 3)];
      }
#pragma unroll
      for (int m = 0; m < 4; ++m)
#pragma unroll
        for (int n = 0; n < 4; ++n)
          acc[m][n] = MFMA(af[m], bfr[n], acc[m][n], 0, 0, 0);
    }
    __syncthreads();
  }

  if (EPI == 6 || EPI == 7) {
    // LDS-transpose epilogue: reuse smem as 64x128 f32 half-tile buffer
    float* fE = (float*)smem;
#pragma unroll
    for (int h2 = 0; h2 < 2; ++h2) {
      if ((wave >> 1) == h2) {
#pragma unroll
        for (int m = 0; m < 4; ++m)
#pragma unroll
          for (int n = 0; n < 4; ++n)
#pragma unroll
            for (int q = 0; q < 4; ++q)
              fE[(m * 16 + l4 * 4 + q) * 128 + wc + n * 16 + l15] = acc[m][n][q];
      }
      __syncthreads();
#pragma unroll
      for (int i = 0; i < 8; ++i) {
        int lin = tid + i * 256;                  // float4 units, [0,2048)
        int row = lin >> 5, c4 = (lin & 31) << 2;
        int gr = m0 + h2 * 64 + row;
        if (gr < Meff) {
          float4 v4 = *(const float4*)&fE[row * 128 + c4];
          long long crow = rowStart + gr;
          float* dst = (float*)Cv + (EPI == 7 ? (long long)kc * pC : 0LL)
                       + crow * ldc + n0 + c4;
          *(float4*)dst = v4;
        }
      }
      __syncthreads();
    }
    return;
  }

#pragma unroll
  for (int m = 0; m < 4; ++m) {
#pragma unroll
    for (int n = 0; n < 4; ++n) {
      int c = n0 + wc + n * 16 + l15;
      if (c >= N) continue;
      float bv = (EPI == 2) ? bias[(long long)z * bBias + c] : 0.f;
#pragma unroll
      for (int q = 0; q < 4; ++q) {
        int rr = m0 + wr + m * 16 + l4 * 4 + q;
        if (rr >= Meff) continue;
        float v = acc[m][n][q];
        long long crow = rowStart + rr;
        if (EPI == 2)
          ((ushort_t*)Cv)[crow * ldc + (long long)z * bC + c] = f2b(geluf(v + bv));
      }
    }
  }
}

#define G16_ARGS const ushort_t* A, int lda, long long bA, const void* Bv, \
    int ldb, long long bB, void* Cv, int ldc, long long bC, long long pC, \
    int M, int N, int K, const float* bias, int bBias, const int* offs
#define G16_PASS A, lda, bA, Bv, ldb, bB, Cv, ldc, bC, pC, M, N, K, bias, bBias, offs

__global__ __launch_bounds__(256) void k_moe1   (G16_ARGS) { gemm16_body<2,1,1,1,0>(G16_PASS); }
__global__ __launch_bounds__(256) void k_moe2   (G16_ARGS) { gemm16_body<7,1,1,2,0>(G16_PASS); }
__global__ __launch_bounds__(256) void k_head_bf(G16_ARGS) { gemm16_body<6,1,0,1,1>(G16_PASS); }
__global__ __launch_bounds__(256) void k_head_f (G16_ARGS) { gemm16_body<6,0,0,1,1>(G16_PASS); }

// ---------------------------------------------------------------------------
__global__ __launch_bounds__(256)
void cvt_split(const float* __restrict__ s, ushort_t* __restrict__ dh,
               ushort_t* __restrict__ dl, int n4)
{
  int i = blockIdx.x * blockDim.x + threadIdx.x;
  int stride = gridDim.x * blockDim.x;
  for (; i < n4; i += stride) {
    float4 f = ((const float4*)s)[i];
    s4v h, l; ushort_t hh, ll;
    split2(f.x, hh, ll); h[0] = (short)hh; l[0] = (short)ll;
    split2(f.y, hh, ll); h[1] = (short)hh; l[1] = (short)ll;
    split2(f.z, hh, ll); h[2] = (short)hh; l[2] = (short)ll;
    split2(f.w, hh, ll); h[3] = (short)hh; l[3] = (short)ll;
    ((s4v*)dh)[i] = h; ((s4v*)dl)[i] = l;
  }
}

__global__ __launch_bounds__(256)
void cvt_bf16(const float* __restrict__ s, ushort_t* __restrict__ d, int n4)
{
  int i = blockIdx.x * blockDim.x + threadIdx.x;
  int stride = gridDim.x * blockDim.x;
  for (; i < n4; i += stride) {
    float4 f = ((const float4*)s)[i];
    s4v o; o[0] = (short)f2b(f.x); o[1] = (short)f2b(f.y);
    o[2] = (short)f2b(f.z); o[3] = (short)f2b(f.w);
    ((s4v*)d)[i] = o;
  }
}

__global__ __launch_bounds__(256)
void embed_kernel(const int* __restrict__ ids, const float* __restrict__ ew,
                  const float* __restrict__ pw, float* __restrict__ x)
{
  int srow = blockIdx.x, tid = threadIdx.x;
  int id = ids[srow];
  const float4 e = *(const float4*)(ew + (long long)id * DM + tid * 4);
  const float4 p = *(const float4*)(pw + (long long)srow * DM + tid * 4);
  float4* xr = (float4*)(x + (long long)srow * DM) + tid;
  *xr = make_float4(e.x + p.x, e.y + p.y, e.z + p.z, e.w + p.w);
}

template<int MODE>
__global__ __launch_bounds__(256)
void ln_kernel(const float* __restrict__ x, const float* __restrict__ g,
               const float* __restrict__ b, ushort_t* __restrict__ outH,
               ushort_t* __restrict__ outL)
{
  int row = blockIdx.x, tid = threadIdx.x;
  float4 v = ((const float4*)(x + (long long)row * DM))[tid];
  __shared__ float sm1[4], sm2[4];
  float s = v.x + v.y + v.z + v.w;
  for (int o = 32; o > 0; o >>= 1) s += __shfl_down(s, o);
  if ((tid & 63) == 0) sm1[tid >> 6] = s;
  __syncthreads();
  float mean = (sm1[0] + sm1[1] + sm1[2] + sm1[3]) * (1.0f / DM);
  float d0 = v.x - mean, d1 = v.y - mean, d2 = v.z - mean, d3 = v.w - mean;
  float q = d0 * d0 + d1 * d1 + d2 * d2 + d3 * d3;
  for (int o = 32; o > 0; o >>= 1) q += __shfl_down(q, o);
  if ((tid & 63) == 0) sm2[tid >> 6] = q;
  __syncthreads();
  float var = (sm2[0] + sm2[1] + sm2[2] + sm2[3]) * (1.0f / DM);
  float rstd = rsqrtf(var + 1e-5f);
  float4 gv = ((const float4*)g)[tid];
  float4 bv = ((const float4*)b)[tid];
  float o0 = d0 * rstd * gv.x + bv.x, o1 = d1 * rstd * gv.y + bv.y;
  float o2 = d2 * rstd * gv.z + bv.z, o3 = d3 * rstd * gv.w + bv.w;
  long long base = (long long)row * DM + tid * 4;
  if (MODE == 0) {
    ushort_t hh, ll;
    split2(o0, hh, ll); outH[base + 0] = hh; outL[base + 0] = ll;
    split2(o1, hh, ll); outH[base + 1] = hh; outL[base + 1] = ll;
    split2(o2, hh, ll); outH[base + 2] = hh; outL[base + 2] = ll;
    split2(o3, hh, ll); outH[base + 3] = hh; outL[base + 3] = ll;
  } else {
    outH[base + 0] = f2b(o0); outH[base + 1] = f2b(o1);
    outH[base + 2] = f2b(o2); outH[base + 3] = f2b(o3);
  }
}

__global__ __launch_bounds__(256)
void transpose_v2(const ushort_t* __restrict__ qH, const ushort_t* __restrict__ qL,
                  ushort_t* __restrict__ vH, ushort_t* __restrict__ vL)
{
  __shared__ ushort_t tH[64][65], tL[64][65];
  int j0 = blockIdx.x * 64, h = blockIdx.y;
  int tid = threadIdx.x;
  int jr = tid >> 2, d0 = (tid & 3) * 16;
  long long so = (long long)(j0 + jr) * (3 * DM) + 2 * DM + h * 64 + d0;
#pragma unroll
  for (int i = 0; i < 16; ++i) { tH[jr][d0 + i] = qH[so + i]; tL[jr][d0 + i] = qL[so + i]; }
  __syncthreads();
  int dd = tid >> 2, jc = (tid & 3) * 16;
  long long dofs = (long long)(h * 64 + dd) * SQ + j0 + jc;
#pragma unroll
  for (int i = 0; i < 16; ++i) { vH[dofs + i] = tH[jc + i][dd]; vL[dofs + i] = tL[jc + i][dd]; }
}

// LN + gate + top2 in f32; also writes bf16 LN output (fuses old ln_kernel<1>)
__global__ __launch_bounds__(256)
void ln_gate_top2(const float* __restrict__ x, const float* __restrict__ g,
                  const float* __restrict__ b, const float* __restrict__ gw,
                  const float* __restrict__ gb, int* __restrict__ topi,
                  float* __restrict__ topw, int* __restrict__ counts,
                  ushort_t* __restrict__ outH)
{
  int row = blockIdx.x, tid = threadIdx.x;
  float4 v = ((const float4*)(x + (long long)row * DM))[tid];
  __shared__ float sm1[4], sm2[4];
  __shared__ float se[8][4];
  float s = v.x + v.y + v.z + v.w;
  for (int o = 32; o > 0; o >>= 1) s += __shfl_down(s, o);
  if ((tid & 63) == 0) sm1[tid >> 6] = s;
  __syncthreads();
  float mean = (sm1[0] + sm1[1] + sm1[2] + sm1[3]) * (1.0f / DM);
  float d0 = v.x - mean, d1 = v.y - mean, d2 = v.z - mean, d3 = v.w - mean;
  float q = d0 * d0 + d1 * d1 + d2 * d2 + d3 * d3;
  for (int o = 32; o > 0; o >>= 1) q += __shfl_down(q, o);
  if ((tid & 63) == 0) sm2[tid >> 6] = q;
  __syncthreads();
  float var = (sm2[0] + sm2[1] + sm2[2] + sm2[3]) * (1.0f / DM);
  float rstd = rsqrtf(var + 1e-5f);
  float4 gv = ((const float4*)g)[tid];
  float4 bv = ((const float4*)b)[tid];
  float h0 = d0 * rstd * gv.x + bv.x, h1 = d1 * rstd * gv.y + bv.y;
  float h2 = d2 * rstd * gv.z + bv.z, h3 = d3 * rstd * gv.w + bv.w;
  long long base = (long long)row * DM + tid * 4;
  outH[base + 0] = f2b(h0); outH[base + 1] = f2b(h1);
  outH[base + 2] = f2b(h2); outH[base + 3] = f2b(h3);
#pragma unroll
  for (int e = 0; e < 8; ++e) {
    float4 w = ((const float4*)(gw + (long long)e * DM))[tid];
    float p = h0 * w.x + h1 * w.y + h2 * w.z + h3 * w.w;
    for (int o = 32; o > 0; o >>= 1) p += __shfl_down(p, o);
    if ((tid & 63) == 0) se[e][tid >> 6] = p;
  }
  __syncthreads();
  if (tid == 0) {
    float sc[8];
#pragma unroll
    for (int e = 0; e < 8; ++e)
      sc[e] = se[e][0] + se[e][1] + se[e][2] + se[e][3] + gb[e];
    int i1 = 0; float m1 = sc[0];
    for (int e = 1; e < 8; ++e) if (sc[e] > m1) { m1 = sc[e]; i1 = e; }
    int i2 = -1; float m2 = -1e30f;
    for (int e = 0; e < 8; ++e) if (e != i1 && sc[e] > m2) { m2 = sc[e]; i2 = e; }
    float e2 = __expf(m2 - m1);
    float w1 = 1.f / (1.f + e2);
    topi[row * 2] = i1; topi[row * 2 + 1] = i2;
    topw[row * 2] = w1; topw[row * 2 + 1] = 1.f - w1;
    atomicAdd(&counts[i1], 1);
    atomicAdd(&counts[i2], 1);
  }
}

__global__ void moe_zero(int* counts) { if (threadIdx.x < 8) counts[threadIdx.x] = 0; }

__global__ void moe_prefix(const int* __restrict__ counts, int* __restrict__ offs,
                           int* __restrict__ cursors)
{
  if (threadIdx.x == 0 && blockIdx.x == 0) {
    int a = 0;
    for (int e = 0; e < 8; ++e) { offs[e] = a; a += counts[e]; cursors[e] = 0; }
    offs[8] = a;
  }
}

__global__ __launch_bounds__(256)
void moe_gather(const ushort_t* __restrict__ hH, const int* __restrict__ topi,
                const float* __restrict__ topw, const int* __restrict__ offs,
                int* __restrict__ cursors, int* __restrict__ tokIdx,
                float* __restrict__ tokW, int* __restrict__ slotOf,
                ushort_t* __restrict__ Xg)
{
  int tok = blockIdx.x, tid = threadIdx.x;
  __shared__ int s0s, s1s;
  if (tid == 0) {
    int e0 = topi[tok * 2], e1 = topi[tok * 2 + 1];
    int s0 = offs[e0] + atomicAdd(&cursors[e0], 1);
    int s1 = offs[e1] + atomicAdd(&cursors[e1], 1);
    tokIdx[s0] = tok; tokW[s0] = topw[tok * 2];
    tokIdx[s1] = tok; tokW[s1] = topw[tok * 2 + 1];
    slotOf[tok * 2] = s0; slotOf[tok * 2 + 1] = s1;
    s0s = s0; s1s = s1;
  }
  __syncthreads();
  s4v v = ((const s4v*)(hH + (long long)tok * DM))[tid];
  ((s4v*)(Xg + (long long)s0s * DM))[tid] = v;
  ((s4v*)(Xg + (long long)s1s * DM))[tid] = v;
}

__global__ __launch_bounds__(256)
void moe_reduce(float* __restrict__ x, const float* __restrict__ eo, long long pC,
                const int* __restrict__ slotOf, const int* __restrict__ topi,
                const float* __restrict__ topw, const float* __restrict__ b2)
{
  int tok = blockIdx.x, tid = threadIdx.x;
  int s0 = slotOf[tok * 2], s1 = slotOf[tok * 2 + 1];
  int e0 = topi[tok * 2], e1 = topi[tok * 2 + 1];
  float w0 = topw[tok * 2], w1 = topw[tok * 2 + 1];
  float4 a  = ((const float4*)(eo + (long long)s0 * DM))[tid];
  float4 a2 = ((const float4*)(eo + pC + (long long)s0 * DM))[tid];
  float4 b  = ((const float4*)(eo + (long long)s1 * DM))[tid];
  float4 b2v= ((const float4*)(eo + pC + (long long)s1 * DM))[tid];
  float4 ba = ((const float4*)(b2 + (long long)e0 * DM))[tid];
  float4 bb = ((const float4*)(b2 + (long long)e1 * DM))[tid];
  float4* xr = (float4*)(x + (long long)tok * DM) + tid;
  float4 xv = *xr;
  xv.x += w0 * (a.x + a2.x + ba.x) + w1 * (b.x + b2v.x + bb.x);
  xv.y += w0 * (a.y + a2.y + ba.y) + w1 * (b.y + b2v.y + bb.y);
  xv.z += w0 * (a.z + a2.z + ba.z) + w1 * (b.z + b2v.z + bb.z);
  xv.w += w0 * (a.w + a2.w + ba.w) + w1 * (b.w + b2v.w + bb.w);
  *xr = xv;
}

extern "C" void kernel_launch(void* const* d_in, const int* in_sizes, int n_in,
                              void* d_out, int out_size, void* d_ws, size_t ws_size,
                              hipStream_t stream)
{
  const int* ids = (const int*)d_in[0];
  const float* embed_w = (const float*)d_in[1];
  const float* pos_w   = (const float*)d_in[2];
  const float* ln1_g[2] = {(const float*)d_in[3],  (const float*)d_in[11]};
  const float* ln1_b[2] = {(const float*)d_in[4],  (const float*)d_in[12]};
  const float* in_w[2]  = {(const float*)d_in[5],  (const float*)d_in[13]};
  const float* in_b[2]  = {(const float*)d_in[6],  (const float*)d_in[14]};
  const float* out_w[2] = {(const float*)d_in[7],  (const float*)d_in[15]};
  const float* out_b[2] = {(const float*)d_in[8],  (const float*)d_in[16]};
  const float* ln2_g[2] = {(const float*)d_in[9],  (const float*)d_in[17]};
  const float* ln2_b[2] = {(const float*)d_in[10], (const float*)d_in[18]};
  const float* ffn_w1 = (const float*)d_in[19];
  const float* ffn_b1 = (const float*)d_in[20];
  const float* ffn_w2 = (const float*)d_in[21];
  const float* ffn_b2 = (const float*)d_in[22];
  const float* gate_w = (const float*)d_in[23];
  const float* gate_b = (const float*)d_in[24];
  const float* moe_w1 = (const float*)d_in[25];
  const float* moe_b1 = (const float*)d_in[26];
  const float* moe_w2 = (const float*)d_in[27];
  const float* moe_b2 = (const float*)d_in[28];
  const float* norm_g = (const float*)d_in[29];
  const float* norm_b = (const float*)d_in[30];
  const float* head_w = (const float*)d_in[31];

  char* ob = (char*)d_out;
  size_t off = 0;
  auto alloc = [&](size_t bytes) {
    char* p = ob + off;
    off = (off + bytes + 255) & ~(size_t)255;
    return p;
  };
  float*    x      = (float*)alloc((size_t)SQ * DM * 4);
  ushort_t* hbufH  = (ushort_t*)alloc((size_t)SQ * DM * 2);
  ushort_t* hbufL  = (ushort_t*)alloc((size_t)SQ * DM * 2);
  ushort_t* qkvH   = (ushort_t*)alloc((size_t)SQ * 3 * DM * 2);   // ┐
  ushort_t* qkvL   = (ushort_t*)alloc((size_t)SQ * 3 * DM * 2);   // │ w2b
  ushort_t* VtH    = (ushort_t*)alloc((size_t)NH * HDIM * SQ * 2);// │ 64MiB
  ushort_t* VtL    = (ushort_t*)alloc((size_t)NH * HDIM * SQ * 2);// │
  char*     resv   = (char*)alloc((size_t)32 << 20);              // ┘ filler
  ushort_t* attnH  = (ushort_t*)alloc((size_t)SQ * DM * 2);
  ushort_t* attnL  = (ushort_t*)alloc((size_t)SQ * DM * 2);
  ushort_t* Xg     = (ushort_t*)alloc((size_t)2 * SQ * DM * 2);
  int*      topi   = (int*)alloc(SQ * 2 * 4);
  float*    topw   = (float*)alloc(SQ * 2 * 4);
  int*      tokIdx = (int*)alloc(2 * SQ * 4);
  float*    tokW   = (float*)alloc(2 * SQ * 4);
  int*      slotOf = (int*)alloc(2 * SQ * 4);
  int*      counts = (int*)alloc(256);
  int*      offsb  = (int*)alloc(256);
  int*      cursors= (int*)alloc(256);
  ushort_t* ffnH   = (ushort_t*)alloc((size_t)SQ * FFD * 2);      // ┐ moehid
  ushort_t* ffnL   = (ushort_t*)alloc((size_t)SQ * FFD * 2);      // ┘ 32MiB
  float*    eo     = (float*)alloc((size_t)2 * 2 * SQ * DM * 4);  // 32MiB
  ushort_t* inwH[2], *inwL[2], *outwH[2], *outwL[2];
  ushort_t* wsplit0 = (ushort_t*)alloc(0);
  inwH[0]  = (ushort_t*)alloc((size_t)3 * DM * DM * 2);
  inwL[0]  = (ushort_t*)alloc((size_t)3 * DM * DM * 2);
  inwH[1]  = (ushort_t*)alloc((size_t)3 * DM * DM * 2);
  inwL[1]  = (ushort_t*)alloc((size_t)3 * DM * DM * 2);
  outwH[0] = (ushort_t*)alloc((size_t)DM * DM * 2);
  outwL[0] = (ushort_t*)alloc((size_t)DM * DM * 2);
  outwH[1] = (ushort_t*)alloc((size_t)DM * DM * 2);
  outwL[1] = (ushort_t*)alloc((size_t)DM * DM * 2);
  ushort_t* f1H = (ushort_t*)alloc((size_t)FFD * DM * 2);
  ushort_t* f1L = (ushort_t*)alloc((size_t)FFD * DM * 2);
  ushort_t* f2H = (ushort_t*)alloc((size_t)DM * FFD * 2);
  ushort_t* f2L = (ushort_t*)alloc((size_t)DM * FFD * 2);
  ushort_t* moe_w1b = wsplit0;            // 64 MiB over weight planes
  ushort_t* moe_w2b = qkvH;               // 64 MiB over qkv+Vt+resv
  ushort_t* moehid  = ffnH;               // 32 MiB over ffn planes
  const long long eoPC = (long long)2 * SQ * DM;
  ushort_t* hfin    = (ushort_t*)d_ws;
  bool wsBig = ws_size >= ((size_t)70 << 20);
  ushort_t* head_wb = (ushort_t*)((char*)d_ws + ((size_t)4 << 20));
  (void)resv;

  moe_zero<<<1, 64, 0, stream>>>(counts);
  embed_kernel<<<SQ, 256, 0, stream>>>(ids, embed_w, pos_w, x);
  cvt_split<<<512, 256, 0, stream>>>(in_w[0], inwH[0], inwL[0], 3 * DM * DM / 4);
  cvt_split<<<512, 256, 0, stream>>>(in_w[1], inwH[1], inwL[1], 3 * DM * DM / 4);
  cvt_split<<<512, 256, 0, stream>>>(out_w[0], outwH[0], outwL[0], DM * DM / 4);
  cvt_split<<<512, 256, 0, stream>>>(out_w[1], outwH[1], outwL[1], DM * DM / 4);
  cvt_split<<<512, 256, 0, stream>>>(ffn_w1, f1H, f1L, FFD * DM / 4);
  cvt_split<<<512, 256, 0, stream>>>(ffn_w2, f2H, f2L, DM * FFD / 4);
  if (wsBig)
    cvt_bf16<<<1024, 256, 0, stream>>>(head_w, head_wb, NVOC * DM / 4);

  for (int L = 0; L < 2; ++L) {
    ln_kernel<0><<<SQ, 256, 0, stream>>>(x, ln1_g[L], ln1_b[L], hbufH, hbufL);
    k_qkv<<<dim3(16, 24, 1), 256, 0, stream>>>(
        hbufH, hbufL, DM, 0, inwH[L], inwL[L], DM, 0,
        nullptr, qkvH, qkvL, 3 * DM, 0, 0,
        SQ, 3 * DM, DM, in_b[L], 1.f);
    transpose_v2<<<dim3(SQ / 64, NH), 256, 0, stream>>>(qkvH, qkvL, VtH, VtL);
    k_attn<<<dim3(SQ / 64, NH), 256, 0, stream>>>(qkvH, qkvL, VtH, VtL,
                                                  attnH, attnL);
    k_outp<<<dim3(16, 16, 1), 256, 0, stream>>>(
        attnH, attnL, DM, 0, outwH[L], outwL[L], DM, 0,
        x, nullptr, nullptr, DM, 0, 0,
        SQ, DM, DM, out_b[L], 1.f);
    if (L == 0) {
      ln_kernel<0><<<SQ, 256, 0, stream>>>(x, ln2_g[0], ln2_b[0], hbufH, hbufL);
      k_ffn1<<<dim3(16, 32, 1), 256, 0, stream>>>(
          hbufH, hbufL, DM, 0, f1H, f1L, DM, 0,
          nullptr, ffnH, ffnL, FFD, 0, 0,
          SQ, FFD, DM, ffn_b1, 1.f);
      k_ffn2<<<dim3(16, 16, 1), 256, 0, stream>>>(
          ffnH, ffnL, FFD, 0, f2H, f2L, FFD, 0,
          x, nullptr, nullptr, DM, 0, 0,
          SQ, DM, FFD, ffn_b2, 1.f);
    } else {
      cvt_bf16<<<2048, 256, 0, stream>>>(moe_w1, moe_w1b, 8 * FFD * DM / 4);
      cvt_bf16<<<2048, 256, 0, stream>>>(moe_w2, moe_w2b, 8 * DM * FFD / 4);
      ln_gate_top2<<<SQ, 256, 0, stream>>>(x, ln2_g[1], ln2_b[1], gate_w, gate_b,
                                           topi, topw, counts, hbufH);
      moe_prefix<<<1, 64, 0, stream>>>(counts, offsb, cursors);
      moe_gather<<<SQ, 256, 0, stream>>>(hbufH, topi, topw, offsb, cursors,
                                         tokIdx, tokW, slotOf, Xg);
      k_moe1<<<dim3(32, 16, 8), 256, 0, stream>>>(
          Xg, DM, 0, moe_w1b, DM, (long long)FFD * DM,
          moehid, FFD, 0, 0, SQ, FFD, DM, moe_b1, FFD, offsb);
      k_moe2<<<dim3(8, 16, 16), 256, 0, stream>>>(
          moehid, FFD, 0, moe_w2b, FFD, (long long)DM * FFD,
          eo, DM, 0, eoPC, SQ, DM, FFD, nullptr, 0, offsb);
      moe_reduce<<<SQ, 256, 0, stream>>>(x, eo, eoPC, slotOf, topi, topw, moe_b2);
    }
  }
  ln_kernel<1><<<SQ, 256, 0, stream>>>(x, norm_g, norm_b, hfin, nullptr);
  if (wsBig)
    k_head_bf<<<dim3(16, 250, 1), 256, 0, stream>>>(
        hfin, DM, 0, head_wb, DM, 0, d_out, NVOC, 0, 0,
        SQ, NVOC, DM, nullptr, 0, nullptr);
  else
    k_head_f<<<dim3(16, 250, 1), 256, 0, stream>>>(
        hfin, DM, 0, head_w, DM, 0, d_out, NVOC, 0, 0,
        SQ, NVOC, DM, nullptr, 0, nullptr);
}

// Round 11
// 1235.141 us; speedup vs baseline: 1.8065x; 1.0785x over previous
//
#include <hip/hip_runtime.h>
#include <hip/hip_bf16.h>
#include <math.h>

typedef unsigned short ushort_t;
typedef __attribute__((ext_vector_type(8))) __bf16 bf16x8;
typedef __attribute__((ext_vector_type(4))) float f32x4;
typedef __attribute__((ext_vector_type(8))) short s8v;
typedef __attribute__((ext_vector_type(4))) short s4v;

#define SQ 2048
#define DM 1024
#define NH 16
#define HDIM 64
#define FFD 4096
#define NVOC 32000

__device__ inline float b2f(unsigned short u) {
  union { unsigned int i; float f; } x; x.i = ((unsigned int)u) << 16; return x.f;
}
__device__ inline unsigned short f2b(float f) {
  __hip_bfloat16 h = __float2bfloat16(f);
  return *reinterpret_cast<unsigned short*>(&h);
}
__device__ inline void split2(float x, ushort_t& h, ushort_t& l) {
  h = f2b(x);
  l = f2b(x - b2f(h));
}
__device__ inline float geluf(float v) {
  return 0.5f * v * (1.0f + erff(v * 0.70710678118654752f));
}
__device__ __forceinline__ void gld16(const void* g, void* l) {
  __builtin_amdgcn_global_load_lds(
      (const __attribute__((address_space(1))) void*)g,
      (__attribute__((address_space(3))) void*)l, 16, 0, 0);
}
#define MFMA __builtin_amdgcn_mfma_f32_16x16x32_bf16

// ---------------------------------------------------------------------------
// Split GEMM engine (pre-gate math): C = epi((AH+AL)*(BH+BL)^T), planes bf16.
// EPI: 0 split-store+bias, 2 f32 partial store (kc*pC), 3 f32 += v+bias,
//      4 gelu+bias split-store.
// ---------------------------------------------------------------------------
template<int EPI, int NT, int KS>
__device__ __forceinline__ void gemmsp_body(
    const ushort_t* __restrict__ AH, const ushort_t* __restrict__ AL,
    int lda, long long bA,
    const ushort_t* __restrict__ BH, const ushort_t* __restrict__ BL,
    int ldb, long long bB,
    float* __restrict__ C, ushort_t* __restrict__ CH, ushort_t* __restrict__ CL,
    int ldc, long long bC, long long pC,
    int M, int N, int K, const float* __restrict__ bias, float alpha)
{
  int z = blockIdx.z, h = z / KS, kc = z % KS;
  const ushort_t* AHp = AH + (long long)h * bA + (long long)kc * K;
  const ushort_t* ALp = AL + (long long)h * bA + (long long)kc * K;
  const ushort_t* BHp = BH + (long long)h * bB + (long long)kc * K;
  const ushort_t* BLp = BL + (long long)h * bB + (long long)kc * K;
  int m0 = blockIdx.x * 128, n0 = blockIdx.y * NT;
  const int NF = NT / 32;

  __shared__ __align__(16) ushort_t sAH[128 * 32], sAL[128 * 32];
  __shared__ __align__(16) ushort_t sBH[NT * 32],  sBL[NT * 32];

  int tid = threadIdx.x, lane = tid & 63, wave = tid >> 6;
  int wr = (wave >> 1) * 64, wc = (wave & 1) * (NT >> 1);
  int l15 = lane & 15, l4 = lane >> 4;

  f32x4 acc[4][NF];
#pragma unroll
  for (int m = 0; m < 4; ++m)
#pragma unroll
    for (int n = 0; n < NF; ++n) acc[m][n] = (f32x4){0.f, 0.f, 0.f, 0.f};

  for (int k0 = 0; k0 < K; k0 += 32) {
#pragma unroll
    for (int i = 0; i < 2; ++i) {
      int fi = i * 2048 + tid * 8;
      int r = fi >> 5, chk = (fi >> 3) & 3;
      int scol = ((chk ^ ((r >> 1) & 3)) << 3);
      int ra = m0 + r; if (ra > M - 1) ra = M - 1;
      long long go = (long long)ra * lda + k0 + scol;
      gld16(AHp + go, &sAH[fi]);
      gld16(ALp + go, &sAL[fi]);
    }
#pragma unroll
    for (int i = 0; i < NT / 64; ++i) {
      int fi = i * 2048 + tid * 8;
      int r = fi >> 5, chk = (fi >> 3) & 3;
      int scol = ((chk ^ ((r >> 1) & 3)) << 3);
      int rb = n0 + r; if (rb > N - 1) rb = N - 1;
      long long go = (long long)rb * ldb + k0 + scol;
      gld16(BHp + go, &sBH[fi]);
      gld16(BLp + go, &sBL[fi]);
    }
    __syncthreads();
    bf16x8 ah[4], al[4], bh[NF], bl[NF];
#pragma unroll
    for (int m = 0; m < 4; ++m) {
      int r = wr + m * 16 + l15;
      int o = r * 32 + ((l4 ^ ((r >> 1) & 3)) << 3);
      ah[m] = *(const bf16x8*)&sAH[o];
      al[m] = *(const bf16x8*)&sAL[o];
    }
#pragma unroll
    for (int n = 0; n < NF; ++n) {
      int r = wc + n * 16 + l15;
      int o = r * 32 + ((l4 ^ ((r >> 1) & 3)) << 3);
      bh[n] = *(const bf16x8*)&sBH[o];
      bl[n] = *(const bf16x8*)&sBL[o];
    }
#pragma unroll
    for (int m = 0; m < 4; ++m)
#pragma unroll
      for (int n = 0; n < NF; ++n) {
        acc[m][n] = MFMA(ah[m], bh[n], acc[m][n], 0, 0, 0);
        acc[m][n] = MFMA(al[m], bh[n], acc[m][n], 0, 0, 0);
        acc[m][n] = MFMA(ah[m], bl[n], acc[m][n], 0, 0, 0);
      }
    __syncthreads();
  }

#pragma unroll
  for (int m = 0; m < 4; ++m) {
#pragma unroll
    for (int n = 0; n < NF; ++n) {
      int c = n0 + wc + n * 16 + l15;
      if (c >= N) continue;
      float bv = (EPI == 0 || EPI == 3 || EPI == 4) ? bias[c] : 0.f;
#pragma unroll
      for (int q = 0; q < 4; ++q) {
        int rr = m0 + wr + m * 16 + l4 * 4 + q;
        if (rr >= M) continue;
        float v = acc[m][n][q];
        if (EPI == 0) {
          ushort_t hh, ll; split2(v + bv, hh, ll);
          long long o = (long long)rr * ldc + c; CH[o] = hh; CL[o] = ll;
        } else if (EPI == 2) {
          C[(long long)kc * pC + (long long)rr * ldc + (long long)h * bC + c] = v;
        } else if (EPI == 3) {
          C[(long long)rr * ldc + c] += v + bv;
        } else if (EPI == 4) {
          ushort_t hh, ll; split2(geluf(v + bv), hh, ll);
          long long o = (long long)rr * ldc + c; CH[o] = hh; CL[o] = ll;
        }
      }
    }
  }
}

#define SP_ARGS const ushort_t* AH, const ushort_t* AL, int lda, long long bA, \
    const ushort_t* BH, const ushort_t* BL, int ldb, long long bB, \
    float* C, ushort_t* CH, ushort_t* CL, int ldc, long long bC, long long pC, \
    int M, int N, int K, const float* bias, float alpha
#define SP_PASS AH, AL, lda, bA, BH, BL, ldb, bB, C, CH, CL, ldc, bC, pC, M, N, K, bias, alpha

__global__ __launch_bounds__(256) void k_qkv (SP_ARGS) { gemmsp_body<0,128,1>(SP_PASS); }
__global__ __launch_bounds__(256) void k_outp(SP_ARGS) { gemmsp_body<2, 64,4>(SP_PASS); }
__global__ __launch_bounds__(256) void k_ffn1(SP_ARGS) { gemmsp_body<4,128,1>(SP_PASS); }
__global__ __launch_bounds__(256) void k_ffn2(SP_ARGS) { gemmsp_body<2, 64,2>(SP_PASS); }

// x[row] += sum_{p<NP} P[p*pC + row*DM..] + bias
template<int NP>
__global__ __launch_bounds__(256)
void reduce_add(float* __restrict__ x, const float* __restrict__ P, long long pC,
                const float* __restrict__ bias)
{
  int row = blockIdx.x, tid = threadIdx.x;
  long long o = (long long)row * DM + tid * 4;
  float4 xv = *(float4*)(x + o);
  float4 bv = *(const float4*)(bias + tid * 4);
  float sx = bv.x, sy = bv.y, sz = bv.z, sw = bv.w;
#pragma unroll
  for (int p = 0; p < NP; ++p) {
    float4 v = *(const float4*)(P + (long long)p * pC + o);
    sx += v.x; sy += v.y; sz += v.z; sw += v.w;
  }
  xv.x += sx; xv.y += sy; xv.z += sz; xv.w += sw;
  *(float4*)(x + o) = xv;
}

// ---------------------------------------------------------------------------
// Fused flash attention, split-f32 precision. Grid (32,16).
// ---------------------------------------------------------------------------
__global__ __launch_bounds__(256)
void k_attn(const ushort_t* __restrict__ qkvH, const ushort_t* __restrict__ qkvL,
            const ushort_t* __restrict__ VtH, const ushort_t* __restrict__ VtL,
            ushort_t* __restrict__ aH, ushort_t* __restrict__ aL)
{
  int f = blockIdx.x + blockIdx.y * gridDim.x;       // 0..511
  int logical = (f & 7) * 64 + (f >> 3);             // chunked per-XCD
  int q0 = (logical & 31) * 64;
  int h  = logical >> 5;

  __shared__ __align__(16) ushort_t sKH[4096], sKL[4096];
  __shared__ __align__(16) ushort_t sVH[4096], sVL[4096];
  __shared__ __align__(16) ushort_t sPH[4096], sPL[4096];

  int tid = threadIdx.x, lane = tid & 63, wave = tid >> 6;
  int l15 = lane & 15, l4 = lane >> 4;

  bf16x8 qh[2], ql[2];
  {
    long long base = (long long)(q0 + wave * 16 + l15) * (3 * DM) + h * 64 + l4 * 8;
    qh[0] = *(const bf16x8*)(qkvH + base);
    qh[1] = *(const bf16x8*)(qkvH + base + 32);
    ql[0] = *(const bf16x8*)(qkvL + base);
    ql[1] = *(const bf16x8*)(qkvL + base + 32);
  }

  float mrow[4], lrow[4];
  f32x4 Oacc[4];
#pragma unroll
  for (int r = 0; r < 4; ++r) { mrow[r] = -1e30f; lrow[r] = 0.f; }
#pragma unroll
  for (int n = 0; n < 4; ++n) Oacc[n] = (f32x4){0.f, 0.f, 0.f, 0.f};

  for (int kt = 0; kt < SQ / 64; ++kt) {
#pragma unroll
    for (int i = 0; i < 2; ++i) {
      int idx = i * 2048 + tid * 8;
      int row = idx >> 6, chk = (idx >> 3) & 7;
      int scol = ((chk ^ (row & 7)) << 3);
      long long gk = (long long)(kt * 64 + row) * (3 * DM) + DM + h * 64 + scol;
      long long gv = (long long)(h * 64 + row) * SQ + kt * 64 + scol;
      gld16(qkvH + gk, &sKH[idx]);
      gld16(qkvL + gk, &sKL[idx]);
      gld16(VtH + gv, &sVH[idx]);
      gld16(VtL + gv, &sVL[idx]);
    }
    __syncthreads();

    f32x4 S[4];
#pragma unroll
    for (int n = 0; n < 4; ++n) S[n] = (f32x4){0.f, 0.f, 0.f, 0.f};
#pragma unroll
    for (int kk = 0; kk < 64; kk += 32) {
      int kkI = kk >> 5;
      bf16x8 qhf = qh[kkI], qlf = ql[kkI];
#pragma unroll
      for (int n = 0; n < 4; ++n) {
        int br = n * 16 + l15;
        int bo = br * 64 + ((((kk >> 3) + l4) ^ (br & 7)) << 3);
        bf16x8 kh = *(const bf16x8*)&sKH[bo];
        bf16x8 kl = *(const bf16x8*)&sKL[bo];
        S[n] = MFMA(qhf, kh, S[n], 0, 0, 0);
        S[n] = MFMA(qlf, kh, S[n], 0, 0, 0);
        S[n] = MFMA(qhf, kl, S[n], 0, 0, 0);
      }
    }
    float tm[4], ts[4];
#pragma unroll
    for (int r = 0; r < 4; ++r) {
#pragma unroll
      for (int n = 0; n < 4; ++n) S[n][r] *= 0.125f;
      tm[r] = fmaxf(fmaxf(S[0][r], S[1][r]), fmaxf(S[2][r], S[3][r]));
    }
#pragma unroll
    for (int mk = 1; mk <= 8; mk <<= 1)
#pragma unroll
      for (int r = 0; r < 4; ++r) tm[r] = fmaxf(tm[r], __shfl_xor(tm[r], mk));
#pragma unroll
    for (int r = 0; r < 4; ++r) {
      float mn = fmaxf(mrow[r], tm[r]);
      float corr = __expf(mrow[r] - mn);
      mrow[r] = mn;
      float s = 0.f;
#pragma unroll
      for (int n = 0; n < 4; ++n) { S[n][r] = __expf(S[n][r] - mn); s += S[n][r]; }
      ts[r] = s;
      lrow[r] *= corr;
#pragma unroll
      for (int n = 0; n < 4; ++n) Oacc[n][r] *= corr;
    }
#pragma unroll
    for (int mk = 1; mk <= 8; mk <<= 1)
#pragma unroll
      for (int r = 0; r < 4; ++r) ts[r] += __shfl_xor(ts[r], mk);
#pragma unroll
    for (int r = 0; r < 4; ++r) lrow[r] += ts[r];

    {
      ushort_t* pH = &sPH[wave * 1024];
      ushort_t* pL = &sPL[wave * 1024];
#pragma unroll
      for (int n = 0; n < 4; ++n)
#pragma unroll
        for (int r = 0; r < 4; ++r) {
          int row = l4 * 4 + r, col = n * 16 + l15;
          int ad = row * 64 + (((col >> 3) ^ (row & 7)) << 3) + (col & 7);
          ushort_t hh, ll; split2(S[n][r], hh, ll);
          pH[ad] = hh; pL[ad] = ll;
        }
    }
    __syncthreads();
#pragma unroll
    for (int kk = 0; kk < 64; kk += 32) {
      int ao = wave * 1024 + l15 * 64 + ((((kk >> 3) + l4) ^ (l15 & 7)) << 3);
      bf16x8 ph = *(const bf16x8*)&sPH[ao];
      bf16x8 pl = *(const bf16x8*)&sPL[ao];
#pragma unroll
      for (int n = 0; n < 4; ++n) {
        int br = n * 16 + l15;
        int bo = br * 64 + ((((kk >> 3) + l4) ^ (br & 7)) << 3);
        bf16x8 vh = *(const bf16x8*)&sVH[bo];
        bf16x8 vl = *(const bf16x8*)&sVL[bo];
        Oacc[n] = MFMA(ph, vh, Oacc[n], 0, 0, 0);
        Oacc[n] = MFMA(pl, vh, Oacc[n], 0, 0, 0);
        Oacc[n] = MFMA(ph, vl, Oacc[n], 0, 0, 0);
      }
    }
    __syncthreads();
  }

#pragma unroll
  for (int n = 0; n < 4; ++n)
#pragma unroll
    for (int r = 0; r < 4; ++r) {
      int q = q0 + wave * 16 + l4 * 4 + r;
      int d = h * 64 + n * 16 + l15;
      float val = Oacc[n][r] / lrow[r];
      ushort_t hh, ll; split2(val, hh, ll);
      long long o = (long long)q * DM + d;
      aH[o] = hh; aL[o] = ll;
    }
}

// ---------------------------------------------------------------------------
// bf16 GEMM engine (post-gate). EPI 6/7 LDS-transposed float4 epilogue;
// EPI 6 (head) uses NON-TEMPORAL stores (256MB stream must not flush L3).
// ---------------------------------------------------------------------------
template<int EPI, int BSRC, int SWAP, int KS, int XS>
__device__ __forceinline__ void gemm16_body(
    const ushort_t* __restrict__ A, int lda, long long bA,
    const void* __restrict__ Bv, int ldb, long long bB,
    void* __restrict__ Cv, int ldc, long long bC, long long pC,
    int M, int N, int K, const float* __restrict__ bias, int bBias,
    const int* __restrict__ offs)
{
  int bz = blockIdx.z;
  int z = bz / KS, kc = bz % KS;
  int Kc = K / KS;
  const ushort_t* Ap = A + (long long)z * bA + (long long)kc * Kc;
  int rowStart = 0, Meff = M;
  if (offs) { rowStart = offs[z]; Meff = offs[z + 1] - rowStart; }
  int bx = blockIdx.x, by = blockIdx.y;
  if (XS) {
    int flat = bx + by * gridDim.x;
    int cpx = (gridDim.x * gridDim.y) >> 3;
    int s = (flat & 7) * cpx + (flat >> 3);
    bx = s % gridDim.x; by = s / gridDim.x;
  }
  int m0 = (SWAP ? by : bx) * 128;
  if (m0 >= Meff) return;
  int n0 = (SWAP ? bx : by) * 128;

  __shared__ __align__(16) char smem[32768];
  ushort_t* As = (ushort_t*)smem;
  ushort_t* Bs = (ushort_t*)(smem + 16384);

  int tid = threadIdx.x, lane = tid & 63, wave = tid >> 6;
  int wr = (wave >> 1) * 64, wc = (wave & 1) * 64;
  int l15 = lane & 15, l4 = lane >> 4;

  f32x4 acc[4][4];
#pragma unroll
  for (int m = 0; m < 4; ++m)
#pragma unroll
    for (int n = 0; n < 4; ++n) acc[m][n] = (f32x4){0.f, 0.f, 0.f, 0.f};

  for (int k0 = 0; k0 < Kc; k0 += 64) {
#pragma unroll
    for (int i = 0; i < 4; ++i) {
      int idx = i * 2048 + tid * 8;
      int row = idx >> 6, chk = (idx >> 3) & 7;
      int scol = ((chk ^ (row & 7)) << 3);
      int ra = m0 + row; if (ra > Meff - 1) ra = Meff - 1;
      gld16(Ap + (long long)(rowStart + ra) * lda + k0 + scol, &As[idx]);
    }
    if (BSRC == 1) {
      const ushort_t* Bp = (const ushort_t*)Bv + (long long)z * bB + (long long)kc * Kc;
#pragma unroll
      for (int i = 0; i < 4; ++i) {
        int idx = i * 2048 + tid * 8;
        int row = idx >> 6, chk = (idx >> 3) & 7;
        int scol = ((chk ^ (row & 7)) << 3);
        int rb = n0 + row; if (rb > N - 1) rb = N - 1;
        gld16(Bp + (long long)rb * ldb + k0 + scol, &Bs[idx]);
      }
    } else {
      const float* Bf = (const float*)Bv + (long long)z * bB + (long long)kc * Kc;
#pragma unroll
      for (int i = 0; i < 8; ++i) {
        int g = tid + i * 256;
        int r = g >> 4, c4 = (g & 15) * 4;
        int rb = n0 + r; if (rb > N - 1) rb = N - 1;
        float4 fv = *(const float4*)(Bf + (long long)rb * ldb + k0 + c4);
        s4v o; o[0] = (short)f2b(fv.x); o[1] = (short)f2b(fv.y);
        o[2] = (short)f2b(fv.z); o[3] = (short)f2b(fv.w);
        int dst = r * 64 + (((c4 >> 3) ^ (r & 7)) << 3) + (c4 & 7);
        *(s4v*)&Bs[dst] = o;
      }
    }
    __syncthreads();
#pragma unroll
    for (int kk = 0; kk < 64; kk += 32) {
      bf16x8 af[4], bfr[4];
#pragma unroll
      for (int m = 0; m < 4; ++m) {
        int r = wr + m * 16 + l15;
        af[m] = *(const bf16x8*)&As[r * 64 + ((((kk >> 3) + l4) ^ (r & 7)) << 3)];
      }
#pragma unroll
      for (int n = 0; n < 4; ++n) {
        int r = wc + n * 16 + l15;
        bfr[n] = *(const bf16x8*)&Bs[r * 64 + ((((kk >> 3) + l4) ^ (r & 7)) << 3)];
      }
#pragma unroll
      for (int m = 0; m < 4; ++m)
#pragma unroll
        for (int n = 0; n < 4; ++n)
          acc[m][n] = MFMA(af[m], bfr[n], acc[m][n], 0, 0, 0);
    }
    __syncthreads();
  }

  if (EPI == 6 || EPI == 7) {
    float* fE = (float*)smem;
#pragma unroll
    for (int h2 = 0; h2 < 2; ++h2) {
      if ((wave >> 1) == h2) {
#pragma unroll
        for (int m = 0; m < 4; ++m)
#pragma unroll
          for (int n = 0; n < 4; ++n)
#pragma unroll
            for (int q = 0; q < 4; ++q)
              fE[(m * 16 + l4 * 4 + q) * 128 + wc + n * 16 + l15] = acc[m][n][q];
      }
      __syncthreads();
#pragma unroll
      for (int i = 0; i < 8; ++i) {
        int lin = tid + i * 256;
        int row = lin >> 5, c4 = (lin & 31) << 2;
        int gr = m0 + h2 * 64 + row;
        if (gr < Meff) {
          f32x4 v4 = *(const f32x4*)&fE[row * 128 + c4];
          long long crow = rowStart + gr;
          float* dst = (float*)Cv + (EPI == 7 ? (long long)kc * pC : 0LL)
                       + crow * ldc + n0 + c4;
          if (EPI == 6) __builtin_nontemporal_store(v4, (f32x4*)dst);
          else          *(f32x4*)dst = v4;
        }
      }
      __syncthreads();
    }
    return;
  }

#pragma unroll
  for (int m = 0; m < 4; ++m) {
#pragma unroll
    for (int n = 0; n < 4; ++n) {
      int c = n0 + wc + n * 16 + l15;
      if (c >= N) continue;
      float bv = (EPI == 2) ? bias[(long long)z * bBias + c] : 0.f;
#pragma unroll
      for (int q = 0; q < 4; ++q) {
        int rr = m0 + wr + m * 16 + l4 * 4 + q;
        if (rr >= Meff) continue;
        float v = acc[m][n][q];
        long long crow = rowStart + rr;
        if (EPI == 2)
          ((ushort_t*)Cv)[crow * ldc + (long long)z * bC + c] = f2b(geluf(v + bv));
      }
    }
  }
}

#define G16_ARGS const ushort_t* A, int lda, long long bA, const void* Bv, \
    int ldb, long long bB, void* Cv, int ldc, long long bC, long long pC, \
    int M, int N, int K, const float* bias, int bBias, const int* offs
#define G16_PASS A, lda, bA, Bv, ldb, bB, Cv, ldc, bC, pC, M, N, K, bias, bBias, offs

__global__ __launch_bounds__(256) void k_moe1   (G16_ARGS) { gemm16_body<2,1,1,1,0>(G16_PASS); }
__global__ __launch_bounds__(256) void k_moe2   (G16_ARGS) { gemm16_body<7,1,1,2,0>(G16_PASS); }
__global__ __launch_bounds__(256) void k_head_bf(G16_ARGS) { gemm16_body<6,1,0,1,1>(G16_PASS); }
__global__ __launch_bounds__(256) void k_head_f (G16_ARGS) { gemm16_body<6,0,0,1,1>(G16_PASS); }

// ---------------------------------------------------------------------------
// paired split-convert: z=0 -> (s0->dh0,dl0), z=1 -> (s1->dh1,dl1)
__global__ __launch_bounds__(256)
void cvt_split2(const float* __restrict__ s0, ushort_t* __restrict__ dh0,
                ushort_t* __restrict__ dl0,
                const float* __restrict__ s1, ushort_t* __restrict__ dh1,
                ushort_t* __restrict__ dl1, int n4)
{
  const float* s = blockIdx.y ? s1 : s0;
  ushort_t* dh = blockIdx.y ? dh1 : dh0;
  ushort_t* dl = blockIdx.y ? dl1 : dl0;
  int i = blockIdx.x * blockDim.x + threadIdx.x;
  int stride = gridDim.x * blockDim.x;
  for (; i < n4; i += stride) {
    float4 f = ((const float4*)s)[i];
    s4v h, l; ushort_t hh, ll;
    split2(f.x, hh, ll); h[0] = (short)hh; l[0] = (short)ll;
    split2(f.y, hh, ll); h[1] = (short)hh; l[1] = (short)ll;
    split2(f.z, hh, ll); h[2] = (short)hh; l[2] = (short)ll;
    split2(f.w, hh, ll); h[3] = (short)hh; l[3] = (short)ll;
    ((s4v*)dh)[i] = h; ((s4v*)dl)[i] = l;
  }
}

__global__ __launch_bounds__(256)
void cvt_bf16(const float* __restrict__ s, ushort_t* __restrict__ d, int n4)
{
  int i = blockIdx.x * blockDim.x + threadIdx.x;
  int stride = gridDim.x * blockDim.x;
  for (; i < n4; i += stride) {
    float4 f = ((const float4*)s)[i];
    s4v o; o[0] = (short)f2b(f.x); o[1] = (short)f2b(f.y);
    o[2] = (short)f2b(f.z); o[3] = (short)f2b(f.w);
    ((s4v*)d)[i] = o;
  }
}

__global__ __launch_bounds__(256)
void embed_kernel(const int* __restrict__ ids, const float* __restrict__ ew,
                  const float* __restrict__ pw, float* __restrict__ x,
                  int* __restrict__ counts)
{
  int srow = blockIdx.x, tid = threadIdx.x;
  if (srow == 0 && tid < 8) counts[tid] = 0;
  int id = ids[srow];
  const float4 e = *(const float4*)(ew + (long long)id * DM + tid * 4);
  const float4 p = *(const float4*)(pw + (long long)srow * DM + tid * 4);
  float4* xr = (float4*)(x + (long long)srow * DM) + tid;
  *xr = make_float4(e.x + p.x, e.y + p.y, e.z + p.z, e.w + p.w);
}

template<int MODE>
__global__ __launch_bounds__(256)
void ln_kernel(const float* __restrict__ x, const float* __restrict__ g,
               const float* __restrict__ b, ushort_t* __restrict__ outH,
               ushort_t* __restrict__ outL)
{
  int row = blockIdx.x, tid = threadIdx.x;
  float4 v = ((const float4*)(x + (long long)row * DM))[tid];
  __shared__ float sm1[4], sm2[4];
  float s = v.x + v.y + v.z + v.w;
  for (int o = 32; o > 0; o >>= 1) s += __shfl_down(s, o);
  if ((tid & 63) == 0) sm1[tid >> 6] = s;
  __syncthreads();
  float mean = (sm1[0] + sm1[1] + sm1[2] + sm1[3]) * (1.0f / DM);
  float d0 = v.x - mean, d1 = v.y - mean, d2 = v.z - mean, d3 = v.w - mean;
  float q = d0 * d0 + d1 * d1 + d2 * d2 + d3 * d3;
  for (int o = 32; o > 0; o >>= 1) q += __shfl_down(q, o);
  if ((tid & 63) == 0) sm2[tid >> 6] = q;
  __syncthreads();
  float var = (sm2[0] + sm2[1] + sm2[2] + sm2[3]) * (1.0f / DM);
  float rstd = rsqrtf(var + 1e-5f);
  float4 gv = ((const float4*)g)[tid];
  float4 bv = ((const float4*)b)[tid];
  float o0 = d0 * rstd * gv.x + bv.x, o1 = d1 * rstd * gv.y + bv.y;
  float o2 = d2 * rstd * gv.z + bv.z, o3 = d3 * rstd * gv.w + bv.w;
  long long base = (long long)row * DM + tid * 4;
  if (MODE == 0) {
    ushort_t hh, ll;
    split2(o0, hh, ll); outH[base + 0] = hh; outL[base + 0] = ll;
    split2(o1, hh, ll); outH[base + 1] = hh; outL[base + 1] = ll;
    split2(o2, hh, ll); outH[base + 2] = hh; outL[base + 2] = ll;
    split2(o3, hh, ll); outH[base + 3] = hh; outL[base + 3] = ll;
  } else {
    outH[base + 0] = f2b(o0); outH[base + 1] = f2b(o1);
    outH[base + 2] = f2b(o2); outH[base + 3] = f2b(o3);
  }
}

__global__ __launch_bounds__(256)
void transpose_v2(const ushort_t* __restrict__ qH, const ushort_t* __restrict__ qL,
                  ushort_t* __restrict__ vH, ushort_t* __restrict__ vL)
{
  __shared__ ushort_t tH[64][65], tL[64][65];
  int j0 = blockIdx.x * 64, h = blockIdx.y;
  int tid = threadIdx.x;
  int jr = tid >> 2, d0 = (tid & 3) * 16;
  long long so = (long long)(j0 + jr) * (3 * DM) + 2 * DM + h * 64 + d0;
#pragma unroll
  for (int i = 0; i < 16; ++i) { tH[jr][d0 + i] = qH[so + i]; tL[jr][d0 + i] = qL[so + i]; }
  __syncthreads();
  int dd = tid >> 2, jc = (tid & 3) * 16;
  long long dofs = (long long)(h * 64 + dd) * SQ + j0 + jc;
#pragma unroll
  for (int i = 0; i < 16; ++i) { vH[dofs + i] = tH[jc + i][dd]; vL[dofs + i] = tL[jc + i][dd]; }
}

// LN + gate + top2 in f32; also writes bf16 LN output
__global__ __launch_bounds__(256)
void ln_gate_top2(const float* __restrict__ x, const float* __restrict__ g,
                  const float* __restrict__ b, const float* __restrict__ gw,
                  const float* __restrict__ gb, int* __restrict__ topi,
                  float* __restrict__ topw, int* __restrict__ counts,
                  ushort_t* __restrict__ outH)
{
  int row = blockIdx.x, tid = threadIdx.x;
  float4 v = ((const float4*)(x + (long long)row * DM))[tid];
  __shared__ float sm1[4], sm2[4];
  __shared__ float se[8][4];
  float s = v.x + v.y + v.z + v.w;
  for (int o = 32; o > 0; o >>= 1) s += __shfl_down(s, o);
  if ((tid & 63) == 0) sm1[tid >> 6] = s;
  __syncthreads();
  float mean = (sm1[0] + sm1[1] + sm1[2] + sm1[3]) * (1.0f / DM);
  float d0 = v.x - mean, d1 = v.y - mean, d2 = v.z - mean, d3 = v.w - mean;
  float q = d0 * d0 + d1 * d1 + d2 * d2 + d3 * d3;
  for (int o = 32; o > 0; o >>= 1) q += __shfl_down(q, o);
  if ((tid & 63) == 0) sm2[tid >> 6] = q;
  __syncthreads();
  float var = (sm2[0] + sm2[1] + sm2[2] + sm2[3]) * (1.0f / DM);
  float rstd = rsqrtf(var + 1e-5f);
  float4 gv = ((const float4*)g)[tid];
  float4 bv = ((const float4*)b)[tid];
  float h0 = d0 * rstd * gv.x + bv.x, h1 = d1 * rstd * gv.y + bv.y;
  float h2 = d2 * rstd * gv.z + bv.z, h3 = d3 * rstd * gv.w + bv.w;
  long long base = (long long)row * DM + tid * 4;
  outH[base + 0] = f2b(h0); outH[base + 1] = f2b(h1);
  outH[base + 2] = f2b(h2); outH[base + 3] = f2b(h3);
#pragma unroll
  for (int e = 0; e < 8; ++e) {
    float4 w = ((const float4*)(gw + (long long)e * DM))[tid];
    float p = h0 * w.x + h1 * w.y + h2 * w.z + h3 * w.w;
    for (int o = 32; o > 0; o >>= 1) p += __shfl_down(p, o);
    if ((tid & 63) == 0) se[e][tid >> 6] = p;
  }
  __syncthreads();
  if (tid == 0) {
    float sc[8];
#pragma unroll
    for (int e = 0; e < 8; ++e)
      sc[e] = se[e][0] + se[e][1] + se[e][2] + se[e][3] + gb[e];
    int i1 = 0; float m1 = sc[0];
    for (int e = 1; e < 8; ++e) if (sc[e] > m1) { m1 = sc[e]; i1 = e; }
    int i2 = -1; float m2 = -1e30f;
    for (int e = 0; e < 8; ++e) if (e != i1 && sc[e] > m2) { m2 = sc[e]; i2 = e; }
    float e2 = __expf(m2 - m1);
    float w1 = 1.f / (1.f + e2);
    topi[row * 2] = i1; topi[row * 2 + 1] = i2;
    topw[row * 2] = w1; topw[row * 2 + 1] = 1.f - w1;
    atomicAdd(&counts[i1], 1);
    atomicAdd(&counts[i2], 1);
  }
}

__global__ void moe_prefix(const int* __restrict__ counts, int* __restrict__ offs,
                           int* __restrict__ cursors)
{
  if (threadIdx.x == 0 && blockIdx.x == 0) {
    int a = 0;
    for (int e = 0; e < 8; ++e) { offs[e] = a; a += counts[e]; cursors[e] = 0; }
    offs[8] = a;
  }
}

__global__ __launch_bounds__(256)
void moe_gather(const ushort_t* __restrict__ hH, const int* __restrict__ topi,
                const float* __restrict__ topw, const int* __restrict__ offs,
                int* __restrict__ cursors, int* __restrict__ tokIdx,
                float* __restrict__ tokW, int* __restrict__ slotOf,
                ushort_t* __restrict__ Xg)
{
  int tok = blockIdx.x, tid = threadIdx.x;
  __shared__ int s0s, s1s;
  if (tid == 0) {
    int e0 = topi[tok * 2], e1 = topi[tok * 2 + 1];
    int s0 = offs[e0] + atomicAdd(&cursors[e0], 1);
    int s1 = offs[e1] + atomicAdd(&cursors[e1], 1);
    tokIdx[s0] = tok; tokW[s0] = topw[tok * 2];
    tokIdx[s1] = tok; tokW[s1] = topw[tok * 2 + 1];
    slotOf[tok * 2] = s0; slotOf[tok * 2 + 1] = s1;
    s0s = s0; s1s = s1;
  }
  __syncthreads();
  s4v v = ((const s4v*)(hH + (long long)tok * DM))[tid];
  ((s4v*)(Xg + (long long)s0s * DM))[tid] = v;
  ((s4v*)(Xg + (long long)s1s * DM))[tid] = v;
}

__global__ __launch_bounds__(256)
void moe_reduce(float* __restrict__ x, const float* __restrict__ eo, long long pC,
                const int* __restrict__ slotOf, const int* __restrict__ topi,
                const float* __restrict__ topw, const float* __restrict__ b2)
{
  int tok = blockIdx.x, tid = threadIdx.x;
  int s0 = slotOf[tok * 2], s1 = slotOf[tok * 2 + 1];
  int e0 = topi[tok * 2], e1 = topi[tok * 2 + 1];
  float w0 = topw[tok * 2], w1 = topw[tok * 2 + 1];
  float4 a  = ((const float4*)(eo + (long long)s0 * DM))[tid];
  float4 a2 = ((const float4*)(eo + pC + (long long)s0 * DM))[tid];
  float4 b  = ((const float4*)(eo + (long long)s1 * DM))[tid];
  float4 b2v= ((const float4*)(eo + pC + (long long)s1 * DM))[tid];
  float4 ba = ((const float4*)(b2 + (long long)e0 * DM))[tid];
  float4 bb = ((const float4*)(b2 + (long long)e1 * DM))[tid];
  float4* xr = (float4*)(x + (long long)tok * DM) + tid;
  float4 xv = *xr;
  xv.x += w0 * (a.x + a2.x + ba.x) + w1 * (b.x + b2v.x + bb.x);
  xv.y += w0 * (a.y + a2.y + ba.y) + w1 * (b.y + b2v.y + bb.y);
  xv.z += w0 * (a.z + a2.z + ba.z) + w1 * (b.z + b2v.z + bb.z);
  xv.w += w0 * (a.w + a2.w + ba.w) + w1 * (b.w + b2v.w + bb.w);
  *xr = xv;
}

extern "C" void kernel_launch(void* const* d_in, const int* in_sizes, int n_in,
                              void* d_out, int out_size, void* d_ws, size_t ws_size,
                              hipStream_t stream)
{
  const int* ids = (const int*)d_in[0];
  const float* embed_w = (const float*)d_in[1];
  const float* pos_w   = (const float*)d_in[2];
  const float* ln1_g[2] = {(const float*)d_in[3],  (const float*)d_in[11]};
  const float* ln1_b[2] = {(const float*)d_in[4],  (const float*)d_in[12]};
  const float* in_w[2]  = {(const float*)d_in[5],  (const float*)d_in[13]};
  const float* in_b[2]  = {(const float*)d_in[6],  (const float*)d_in[14]};
  const float* out_w[2] = {(const float*)d_in[7],  (const float*)d_in[15]};
  const float* out_b[2] = {(const float*)d_in[8],  (const float*)d_in[16]};
  const float* ln2_g[2] = {(const float*)d_in[9],  (const float*)d_in[17]};
  const float* ln2_b[2] = {(const float*)d_in[10], (const float*)d_in[18]};
  const float* ffn_w1 = (const float*)d_in[19];
  const float* ffn_b1 = (const float*)d_in[20];
  const float* ffn_w2 = (const float*)d_in[21];
  const float* ffn_b2 = (const float*)d_in[22];
  const float* gate_w = (const float*)d_in[23];
  const float* gate_b = (const float*)d_in[24];
  const float* moe_w1 = (const float*)d_in[25];
  const float* moe_b1 = (const float*)d_in[26];
  const float* moe_w2 = (const float*)d_in[27];
  const float* moe_b2 = (const float*)d_in[28];
  const float* norm_g = (const float*)d_in[29];
  const float* norm_b = (const float*)d_in[30];
  const float* head_w = (const float*)d_in[31];

  char* ob = (char*)d_out;
  size_t off = 0;
  auto alloc = [&](size_t bytes) {
    char* p = ob + off;
    off = (off + bytes + 255) & ~(size_t)255;
    return p;
  };
  float*    x      = (float*)alloc((size_t)SQ * DM * 4);
  ushort_t* hbufH  = (ushort_t*)alloc((size_t)SQ * DM * 2);
  ushort_t* hbufL  = (ushort_t*)alloc((size_t)SQ * DM * 2);
  ushort_t* qkvH   = (ushort_t*)alloc((size_t)SQ * 3 * DM * 2);   // ┐
  ushort_t* qkvL   = (ushort_t*)alloc((size_t)SQ * 3 * DM * 2);   // │ w2b
  ushort_t* VtH    = (ushort_t*)alloc((size_t)NH * HDIM * SQ * 2);// │ 64MiB
  ushort_t* VtL    = (ushort_t*)alloc((size_t)NH * HDIM * SQ * 2);// │
  char*     resv   = (char*)alloc((size_t)32 << 20);              // ┘ filler
  ushort_t* attnH  = (ushort_t*)alloc((size_t)SQ * DM * 2);
  ushort_t* attnL  = (ushort_t*)alloc((size_t)SQ * DM * 2);
  ushort_t* Xg     = (ushort_t*)alloc((size_t)2 * SQ * DM * 2);
  int*      topi   = (int*)alloc(SQ * 2 * 4);
  float*    topw   = (float*)alloc(SQ * 2 * 4);
  int*      tokIdx = (int*)alloc(2 * SQ * 4);
  float*    tokW   = (float*)alloc(2 * SQ * 4);
  int*      slotOf = (int*)alloc(2 * SQ * 4);
  int*      counts = (int*)alloc(256);
  int*      offsb  = (int*)alloc(256);
  int*      cursors= (int*)alloc(256);
  ushort_t* ffnH   = (ushort_t*)alloc((size_t)SQ * FFD * 2);      // ┐ moehid
  ushort_t* ffnL   = (ushort_t*)alloc((size_t)SQ * FFD * 2);      // ┘ 32MiB
  float*    eo     = (float*)alloc((size_t)2 * 2 * SQ * DM * 4);  // 32MiB (also KS partials)
  ushort_t* inwH[2], *inwL[2], *outwH[2], *outwL[2];
  ushort_t* wsplit0 = (ushort_t*)alloc(0);
  inwH[0]  = (ushort_t*)alloc((size_t)3 * DM * DM * 2);
  inwL[0]  = (ushort_t*)alloc((size_t)3 * DM * DM * 2);
  inwH[1]  = (ushort_t*)alloc((size_t)3 * DM * DM * 2);
  inwL[1]  = (ushort_t*)alloc((size_t)3 * DM * DM * 2);
  outwH[0] = (ushort_t*)alloc((size_t)DM * DM * 2);
  outwL[0] = (ushort_t*)alloc((size_t)DM * DM * 2);
  outwH[1] = (ushort_t*)alloc((size_t)DM * DM * 2);
  outwL[1] = (ushort_t*)alloc((size_t)DM * DM * 2);
  ushort_t* f1H = (ushort_t*)alloc((size_t)FFD * DM * 2);
  ushort_t* f1L = (ushort_t*)alloc((size_t)FFD * DM * 2);
  ushort_t* f2H = (ushort_t*)alloc((size_t)DM * FFD * 2);
  ushort_t* f2L = (ushort_t*)alloc((size_t)DM * FFD * 2);
  ushort_t* moe_w1b = wsplit0;            // 64 MiB over weight planes
  ushort_t* moe_w2b = qkvH;               // 64 MiB over qkv+Vt+resv
  ushort_t* moehid  = ffnH;               // 32 MiB over ffn planes
  float*    pp      = eo;                 // KS partial planes (outp/ffn2)
  const long long eoPC = (long long)2 * SQ * DM;
  const long long ppPC = (long long)SQ * DM;
  ushort_t* hfin    = (ushort_t*)d_ws;
  bool wsBig = ws_size >= ((size_t)70 << 20);
  ushort_t* head_wb = (ushort_t*)((char*)d_ws + ((size_t)4 << 20));
  (void)resv;

  embed_kernel<<<SQ, 256, 0, stream>>>(ids, embed_w, pos_w, x, counts);
  cvt_split2<<<dim3(512, 2), 256, 0, stream>>>(
      in_w[0], inwH[0], inwL[0], in_w[1], inwH[1], inwL[1], 3 * DM * DM / 4);
  cvt_split2<<<dim3(512, 2), 256, 0, stream>>>(
      out_w[0], outwH[0], outwL[0], out_w[1], outwH[1], outwL[1], DM * DM / 4);
  cvt_split2<<<dim3(512, 2), 256, 0, stream>>>(
      ffn_w1, f1H, f1L, ffn_w2, f2H, f2L, FFD * DM / 4);
  if (wsBig)
    cvt_bf16<<<1024, 256, 0, stream>>>(head_w, head_wb, NVOC * DM / 4);

  for (int L = 0; L < 2; ++L) {
    ln_kernel<0><<<SQ, 256, 0, stream>>>(x, ln1_g[L], ln1_b[L], hbufH, hbufL);
    k_qkv<<<dim3(16, 24, 1), 256, 0, stream>>>(
        hbufH, hbufL, DM, 0, inwH[L], inwL[L], DM, 0,
        nullptr, qkvH, qkvL, 3 * DM, 0, 0,
        SQ, 3 * DM, DM, in_b[L], 1.f);
    transpose_v2<<<dim3(SQ / 64, NH), 256, 0, stream>>>(qkvH, qkvL, VtH, VtL);
    k_attn<<<dim3(SQ / 64, NH), 256, 0, stream>>>(qkvH, qkvL, VtH, VtL,
                                                  attnH, attnL);
    // x += attn @ out_w^T + out_b : KS=4 partial planes -> reduce
    k_outp<<<dim3(16, 16, 4), 256, 0, stream>>>(
        attnH, attnL, DM, 0, outwH[L], outwL[L], DM, 0,
        pp, nullptr, nullptr, DM, 0, ppPC,
        SQ, DM, DM / 4, nullptr, 1.f);
    reduce_add<4><<<SQ, 256, 0, stream>>>(x, pp, ppPC, out_b[L]);
    if (L == 0) {
      ln_kernel<0><<<SQ, 256, 0, stream>>>(x, ln2_g[0], ln2_b[0], hbufH, hbufL);
      k_ffn1<<<dim3(16, 32, 1), 256, 0, stream>>>(
          hbufH, hbufL, DM, 0, f1H, f1L, DM, 0,
          nullptr, ffnH, ffnL, FFD, 0, 0,
          SQ, FFD, DM, ffn_b1, 1.f);
      // x += ffnhid @ w2^T + b2 : KS=2 partial planes -> reduce
      k_ffn2<<<dim3(16, 16, 2), 256, 0, stream>>>(
          ffnH, ffnL, FFD, 0, f2H, f2L, FFD, 0,
          pp, nullptr, nullptr, DM, 0, ppPC,
          SQ, DM, FFD / 2, nullptr, 1.f);
      reduce_add<2><<<SQ, 256, 0, stream>>>(x, pp, ppPC, ffn_b2);
    } else {
      cvt_bf16<<<2048, 256, 0, stream>>>(moe_w1, moe_w1b, 8 * FFD * DM / 4);
      cvt_bf16<<<2048, 256, 0, stream>>>(moe_w2, moe_w2b, 8 * DM * FFD / 4);
      ln_gate_top2<<<SQ, 256, 0, stream>>>(x, ln2_g[1], ln2_b[1], gate_w, gate_b,
                                           topi, topw, counts, hbufH);
      moe_prefix<<<1, 64, 0, stream>>>(counts, offsb, cursors);
      moe_gather<<<SQ, 256, 0, stream>>>(hbufH, topi, topw, offsb, cursors,
                                         tokIdx, tokW, slotOf, Xg);
      k_moe1<<<dim3(32, 16, 8), 256, 0, stream>>>(
          Xg, DM, 0, moe_w1b, DM, (long long)FFD * DM,
          moehid, FFD, 0, 0, SQ, FFD, DM, moe_b1, FFD, offsb);
      k_moe2<<<dim3(8, 16, 16), 256, 0, stream>>>(
          moehid, FFD, 0, moe_w2b, FFD, (long long)DM * FFD,
          eo, DM, 0, eoPC, SQ, DM, FFD, nullptr, 0, offsb);
      moe_reduce<<<SQ, 256, 0, stream>>>(x, eo, eoPC, slotOf, topi, topw, moe_b2);
    }
  }
  ln_kernel<1><<<SQ, 256, 0, stream>>>(x, norm_g, norm_b, hfin, nullptr);
  if (wsBig)
    k_head_bf<<<dim3(16, 250, 1), 256, 0, stream>>>(
        hfin, DM, 0, head_wb, DM, 0, d_out, NVOC, 0, 0,
        SQ, NVOC, DM, nullptr, 0, nullptr);
  else
    k_head_f<<<dim3(16, 250, 1), 256, 0, stream>>>(
        hfin, DM, 0, head_w, DM, 0, d_out, NVOC, 0, 0,
        SQ, NVOC, DM, nullptr, 0, nullptr);
}

// Round 12
// 1215.762 us; speedup vs baseline: 1.8353x; 1.0159x over previous
//
#include <hip/hip_runtime.h>
#include <hip/hip_bf16.h>
#include <math.h>

typedef unsigned short ushort_t;
typedef __attribute__((ext_vector_type(8))) __bf16 bf16x8;
typedef __attribute__((ext_vector_type(4))) float f32x4;
typedef __attribute__((ext_vector_type(8))) short s8v;
typedef __attribute__((ext_vector_type(4))) short s4v;

#define SQ 2048
#define DM 1024
#define NH 16
#define HDIM 64
#define FFD 4096
#define NVOC 32000

__device__ inline float b2f(unsigned short u) {
  union { unsigned int i; float f; } x; x.i = ((unsigned int)u) << 16; return x.f;
}
__device__ inline unsigned short f2b(float f) {
  __hip_bfloat16 h = __float2bfloat16(f);
  return *reinterpret_cast<unsigned short*>(&h);
}
__device__ inline void split2(float x, ushort_t& h, ushort_t& l) {
  h = f2b(x);
  l = f2b(x - b2f(h));
}
__device__ inline float geluf(float v) {
  return 0.5f * v * (1.0f + erff(v * 0.70710678118654752f));
}
__device__ __forceinline__ void gld16(const void* g, void* l) {
  __builtin_amdgcn_global_load_lds(
      (const __attribute__((address_space(1))) void*)g,
      (__attribute__((address_space(3))) void*)l, 16, 0, 0);
}
#define MFMA __builtin_amdgcn_mfma_f32_16x16x32_bf16

// ---------------------------------------------------------------------------
// Split GEMM engine (pre-gate math): C = epi((AH+AL)*(BH+BL)^T), planes bf16.
// EPI: 2 f32 partial store (kc*pC), 4 gelu+bias split-store,
//      5 split-store+bias with V-region (n0>=2048) written TRANSPOSED to TH/TL.
// ---------------------------------------------------------------------------
template<int EPI, int NT, int KS>
__device__ __forceinline__ void gemmsp_body(
    const ushort_t* __restrict__ AH, const ushort_t* __restrict__ AL,
    int lda, long long bA,
    const ushort_t* __restrict__ BH, const ushort_t* __restrict__ BL,
    int ldb, long long bB,
    float* __restrict__ C, ushort_t* __restrict__ CH, ushort_t* __restrict__ CL,
    int ldc, long long bC, long long pC,
    int M, int N, int K, const float* __restrict__ bias, float alpha,
    ushort_t* __restrict__ TH, ushort_t* __restrict__ TL)
{
  int z = blockIdx.z, h = z / KS, kc = z % KS;
  const ushort_t* AHp = AH + (long long)h * bA + (long long)kc * K;
  const ushort_t* ALp = AL + (long long)h * bA + (long long)kc * K;
  const ushort_t* BHp = BH + (long long)h * bB + (long long)kc * K;
  const ushort_t* BLp = BL + (long long)h * bB + (long long)kc * K;
  int m0 = blockIdx.x * 128, n0 = blockIdx.y * NT;
  const int NF = NT / 32;

  __shared__ __align__(16) ushort_t sAH[128 * 32], sAL[128 * 32];
  __shared__ __align__(16) ushort_t sBH[NT * 32],  sBL[NT * 32];

  int tid = threadIdx.x, lane = tid & 63, wave = tid >> 6;
  int wr = (wave >> 1) * 64, wc = (wave & 1) * (NT >> 1);
  int l15 = lane & 15, l4 = lane >> 4;

  f32x4 acc[4][NF];
#pragma unroll
  for (int m = 0; m < 4; ++m)
#pragma unroll
    for (int n = 0; n < NF; ++n) acc[m][n] = (f32x4){0.f, 0.f, 0.f, 0.f};

  for (int k0 = 0; k0 < K; k0 += 32) {
#pragma unroll
    for (int i = 0; i < 2; ++i) {
      int fi = i * 2048 + tid * 8;
      int r = fi >> 5, chk = (fi >> 3) & 3;
      int scol = ((chk ^ ((r >> 1) & 3)) << 3);
      int ra = m0 + r; if (ra > M - 1) ra = M - 1;
      long long go = (long long)ra * lda + k0 + scol;
      gld16(AHp + go, &sAH[fi]);
      gld16(ALp + go, &sAL[fi]);
    }
#pragma unroll
    for (int i = 0; i < NT / 64; ++i) {
      int fi = i * 2048 + tid * 8;
      int r = fi >> 5, chk = (fi >> 3) & 3;
      int scol = ((chk ^ ((r >> 1) & 3)) << 3);
      int rb = n0 + r; if (rb > N - 1) rb = N - 1;
      long long go = (long long)rb * ldb + k0 + scol;
      gld16(BHp + go, &sBH[fi]);
      gld16(BLp + go, &sBL[fi]);
    }
    __syncthreads();
    bf16x8 ah[4], al[4], bh[NF], bl[NF];
#pragma unroll
    for (int m = 0; m < 4; ++m) {
      int r = wr + m * 16 + l15;
      int o = r * 32 + ((l4 ^ ((r >> 1) & 3)) << 3);
      ah[m] = *(const bf16x8*)&sAH[o];
      al[m] = *(const bf16x8*)&sAL[o];
    }
#pragma unroll
    for (int n = 0; n < NF; ++n) {
      int r = wc + n * 16 + l15;
      int o = r * 32 + ((l4 ^ ((r >> 1) & 3)) << 3);
      bh[n] = *(const bf16x8*)&sBH[o];
      bl[n] = *(const bf16x8*)&sBL[o];
    }
#pragma unroll
    for (int m = 0; m < 4; ++m)
#pragma unroll
      for (int n = 0; n < NF; ++n) {
        acc[m][n] = MFMA(ah[m], bh[n], acc[m][n], 0, 0, 0);
        acc[m][n] = MFMA(al[m], bh[n], acc[m][n], 0, 0, 0);
        acc[m][n] = MFMA(ah[m], bl[n], acc[m][n], 0, 0, 0);
      }
    __syncthreads();
  }

  if (EPI == 5 && n0 >= 2 * DM) {
    // V-region: write transposed directly into Vt planes (8B q-vector stores)
#pragma unroll
    for (int m = 0; m < 4; ++m) {
      int rbase = m0 + wr + m * 16 + l4 * 4;
#pragma unroll
      for (int n = 0; n < NF; ++n) {
        int c = n0 + wc + n * 16 + l15;
        int d = c - 2 * DM;
        float bv = bias[c];
        s4v hv, lv;
#pragma unroll
        for (int q = 0; q < 4; ++q) {
          ushort_t hh, ll; split2(acc[m][n][q] + bv, hh, ll);
          hv[q] = (short)hh; lv[q] = (short)ll;
        }
        *(s4v*)&TH[(long long)d * SQ + rbase] = hv;
        *(s4v*)&TL[(long long)d * SQ + rbase] = lv;
      }
    }
    return;
  }

#pragma unroll
  for (int m = 0; m < 4; ++m) {
#pragma unroll
    for (int n = 0; n < NF; ++n) {
      int c = n0 + wc + n * 16 + l15;
      if (c >= N) continue;
      float bv = (EPI == 4 || EPI == 5) ? bias[c] : 0.f;
#pragma unroll
      for (int q = 0; q < 4; ++q) {
        int rr = m0 + wr + m * 16 + l4 * 4 + q;
        if (rr >= M) continue;
        float v = acc[m][n][q];
        if (EPI == 5) {
          ushort_t hh, ll; split2(v + bv, hh, ll);
          long long o = (long long)rr * ldc + c; CH[o] = hh; CL[o] = ll;
        } else if (EPI == 2) {
          C[(long long)kc * pC + (long long)rr * ldc + (long long)h * bC + c] = v;
        } else if (EPI == 4) {
          ushort_t hh, ll; split2(geluf(v + bv), hh, ll);
          long long o = (long long)rr * ldc + c; CH[o] = hh; CL[o] = ll;
        }
      }
    }
  }
}

#define SP_ARGS const ushort_t* AH, const ushort_t* AL, int lda, long long bA, \
    const ushort_t* BH, const ushort_t* BL, int ldb, long long bB, \
    float* C, ushort_t* CH, ushort_t* CL, int ldc, long long bC, long long pC, \
    int M, int N, int K, const float* bias, float alpha, \
    ushort_t* TH, ushort_t* TL
#define SP_PASS AH, AL, lda, bA, BH, BL, ldb, bB, C, CH, CL, ldc, bC, pC, M, N, K, bias, alpha, TH, TL

__global__ __launch_bounds__(256) void k_qkv (SP_ARGS) { gemmsp_body<5,128,1>(SP_PASS); }
__global__ __launch_bounds__(256) void k_outp(SP_ARGS) { gemmsp_body<2, 64,4>(SP_PASS); }
__global__ __launch_bounds__(256) void k_ffn1(SP_ARGS) { gemmsp_body<4,128,1>(SP_PASS); }
__global__ __launch_bounds__(256) void k_ffn2(SP_ARGS) { gemmsp_body<2, 64,2>(SP_PASS); }

// ---------------------------------------------------------------------------
// Fused flash attention, split-f32 precision. Grid (32,16).
// ---------------------------------------------------------------------------
__global__ __launch_bounds__(256)
void k_attn(const ushort_t* __restrict__ qkvH, const ushort_t* __restrict__ qkvL,
            const ushort_t* __restrict__ VtH, const ushort_t* __restrict__ VtL,
            ushort_t* __restrict__ aH, ushort_t* __restrict__ aL)
{
  int f = blockIdx.x + blockIdx.y * gridDim.x;
  int logical = (f & 7) * 64 + (f >> 3);
  int q0 = (logical & 31) * 64;
  int h  = logical >> 5;

  __shared__ __align__(16) ushort_t sKH[4096], sKL[4096];
  __shared__ __align__(16) ushort_t sVH[4096], sVL[4096];
  __shared__ __align__(16) ushort_t sPH[4096], sPL[4096];

  int tid = threadIdx.x, lane = tid & 63, wave = tid >> 6;
  int l15 = lane & 15, l4 = lane >> 4;

  bf16x8 qh[2], ql[2];
  {
    long long base = (long long)(q0 + wave * 16 + l15) * (3 * DM) + h * 64 + l4 * 8;
    qh[0] = *(const bf16x8*)(qkvH + base);
    qh[1] = *(const bf16x8*)(qkvH + base + 32);
    ql[0] = *(const bf16x8*)(qkvL + base);
    ql[1] = *(const bf16x8*)(qkvL + base + 32);
  }

  float mrow[4], lrow[4];
  f32x4 Oacc[4];
#pragma unroll
  for (int r = 0; r < 4; ++r) { mrow[r] = -1e30f; lrow[r] = 0.f; }
#pragma unroll
  for (int n = 0; n < 4; ++n) Oacc[n] = (f32x4){0.f, 0.f, 0.f, 0.f};

  for (int kt = 0; kt < SQ / 64; ++kt) {
#pragma unroll
    for (int i = 0; i < 2; ++i) {
      int idx = i * 2048 + tid * 8;
      int row = idx >> 6, chk = (idx >> 3) & 7;
      int scol = ((chk ^ (row & 7)) << 3);
      long long gk = (long long)(kt * 64 + row) * (3 * DM) + DM + h * 64 + scol;
      long long gv = (long long)(h * 64 + row) * SQ + kt * 64 + scol;
      gld16(qkvH + gk, &sKH[idx]);
      gld16(qkvL + gk, &sKL[idx]);
      gld16(VtH + gv, &sVH[idx]);
      gld16(VtL + gv, &sVL[idx]);
    }
    __syncthreads();

    f32x4 S[4];
#pragma unroll
    for (int n = 0; n < 4; ++n) S[n] = (f32x4){0.f, 0.f, 0.f, 0.f};
#pragma unroll
    for (int kk = 0; kk < 64; kk += 32) {
      int kkI = kk >> 5;
      bf16x8 qhf = qh[kkI], qlf = ql[kkI];
#pragma unroll
      for (int n = 0; n < 4; ++n) {
        int br = n * 16 + l15;
        int bo = br * 64 + ((((kk >> 3) + l4) ^ (br & 7)) << 3);
        bf16x8 kh = *(const bf16x8*)&sKH[bo];
        bf16x8 kl = *(const bf16x8*)&sKL[bo];
        S[n] = MFMA(qhf, kh, S[n], 0, 0, 0);
        S[n] = MFMA(qlf, kh, S[n], 0, 0, 0);
        S[n] = MFMA(qhf, kl, S[n], 0, 0, 0);
      }
    }
    float tm[4], ts[4];
#pragma unroll
    for (int r = 0; r < 4; ++r) {
#pragma unroll
      for (int n = 0; n < 4; ++n) S[n][r] *= 0.125f;
      tm[r] = fmaxf(fmaxf(S[0][r], S[1][r]), fmaxf(S[2][r], S[3][r]));
    }
#pragma unroll
    for (int mk = 1; mk <= 8; mk <<= 1)
#pragma unroll
      for (int r = 0; r < 4; ++r) tm[r] = fmaxf(tm[r], __shfl_xor(tm[r], mk));
#pragma unroll
    for (int r = 0; r < 4; ++r) {
      float mn = fmaxf(mrow[r], tm[r]);
      float corr = __expf(mrow[r] - mn);
      mrow[r] = mn;
      float s = 0.f;
#pragma unroll
      for (int n = 0; n < 4; ++n) { S[n][r] = __expf(S[n][r] - mn); s += S[n][r]; }
      ts[r] = s;
      lrow[r] *= corr;
#pragma unroll
      for (int n = 0; n < 4; ++n) Oacc[n][r] *= corr;
    }
#pragma unroll
    for (int mk = 1; mk <= 8; mk <<= 1)
#pragma unroll
      for (int r = 0; r < 4; ++r) ts[r] += __shfl_xor(ts[r], mk);
#pragma unroll
    for (int r = 0; r < 4; ++r) lrow[r] += ts[r];

    {
      ushort_t* pH = &sPH[wave * 1024];
      ushort_t* pL = &sPL[wave * 1024];
#pragma unroll
      for (int n = 0; n < 4; ++n)
#pragma unroll
        for (int r = 0; r < 4; ++r) {
          int row = l4 * 4 + r, col = n * 16 + l15;
          int ad = row * 64 + (((col >> 3) ^ (row & 7)) << 3) + (col & 7);
          ushort_t hh, ll; split2(S[n][r], hh, ll);
          pH[ad] = hh; pL[ad] = ll;
        }
    }
    __syncthreads();
#pragma unroll
    for (int kk = 0; kk < 64; kk += 32) {
      int ao = wave * 1024 + l15 * 64 + ((((kk >> 3) + l4) ^ (l15 & 7)) << 3);
      bf16x8 ph = *(const bf16x8*)&sPH[ao];
      bf16x8 pl = *(const bf16x8*)&sPL[ao];
#pragma unroll
      for (int n = 0; n < 4; ++n) {
        int br = n * 16 + l15;
        int bo = br * 64 + ((((kk >> 3) + l4) ^ (br & 7)) << 3);
        bf16x8 vh = *(const bf16x8*)&sVH[bo];
        bf16x8 vl = *(const bf16x8*)&sVL[bo];
        Oacc[n] = MFMA(ph, vh, Oacc[n], 0, 0, 0);
        Oacc[n] = MFMA(pl, vh, Oacc[n], 0, 0, 0);
        Oacc[n] = MFMA(ph, vl, Oacc[n], 0, 0, 0);
      }
    }
    __syncthreads();
  }

#pragma unroll
  for (int n = 0; n < 4; ++n)
#pragma unroll
    for (int r = 0; r < 4; ++r) {
      int q = q0 + wave * 16 + l4 * 4 + r;
      int d = h * 64 + n * 16 + l15;
      float val = Oacc[n][r] / lrow[r];
      ushort_t hh, ll; split2(val, hh, ll);
      long long o = (long long)q * DM + d;
      aH[o] = hh; aL[o] = ll;
    }
}

// ---------------------------------------------------------------------------
// bf16 GEMM engine (post-gate).
// ---------------------------------------------------------------------------
template<int EPI, int BSRC, int SWAP, int KS, int XS>
__device__ __forceinline__ void gemm16_body(
    const ushort_t* __restrict__ A, int lda, long long bA,
    const void* __restrict__ Bv, int ldb, long long bB,
    void* __restrict__ Cv, int ldc, long long bC, long long pC,
    int M, int N, int K, const float* __restrict__ bias, int bBias,
    const int* __restrict__ offs)
{
  int bz = blockIdx.z;
  int z = bz / KS, kc = bz % KS;
  int Kc = K / KS;
  const ushort_t* Ap = A + (long long)z * bA + (long long)kc * Kc;
  int rowStart = 0, Meff = M;
  if (offs) { rowStart = offs[z]; Meff = offs[z + 1] - rowStart; }
  int bx = blockIdx.x, by = blockIdx.y;
  if (XS) {
    int flat = bx + by * gridDim.x;
    int cpx = (gridDim.x * gridDim.y) >> 3;
    int s = (flat & 7) * cpx + (flat >> 3);
    bx = s % gridDim.x; by = s / gridDim.x;
  }
  int m0 = (SWAP ? by : bx) * 128;
  if (m0 >= Meff) return;
  int n0 = (SWAP ? bx : by) * 128;

  __shared__ __align__(16) char smem[32768];
  ushort_t* As = (ushort_t*)smem;
  ushort_t* Bs = (ushort_t*)(smem + 16384);

  int tid = threadIdx.x, lane = tid & 63, wave = tid >> 6;
  int wr = (wave >> 1) * 64, wc = (wave & 1) * 64;
  int l15 = lane & 15, l4 = lane >> 4;

  f32x4 acc[4][4];
#pragma unroll
  for (int m = 0; m < 4; ++m)
#pragma unroll
    for (int n = 0; n < 4; ++n) acc[m][n] = (f32x4){0.f, 0.f, 0.f, 0.f};

  for (int k0 = 0; k0 < Kc; k0 += 64) {
#pragma unroll
    for (int i = 0; i < 4; ++i) {
      int idx = i * 2048 + tid * 8;
      int row = idx >> 6, chk = (idx >> 3) & 7;
      int scol = ((chk ^ (row & 7)) << 3);
      int ra = m0 + row; if (ra > Meff - 1) ra = Meff - 1;
      gld16(Ap + (long long)(rowStart + ra) * lda + k0 + scol, &As[idx]);
    }
    if (BSRC == 1) {
      const ushort_t* Bp = (const ushort_t*)Bv + (long long)z * bB + (long long)kc * Kc;
#pragma unroll
      for (int i = 0; i < 4; ++i) {
        int idx = i * 2048 + tid * 8;
        int row = idx >> 6, chk = (idx >> 3) & 7;
        int scol = ((chk ^ (row & 7)) << 3);
        int rb = n0 + row; if (rb > N - 1) rb = N - 1;
        gld16(Bp + (long long)rb * ldb + k0 + scol, &Bs[idx]);
      }
    } else {
      const float* Bf = (const float*)Bv + (long long)z * bB + (long long)kc * Kc;
#pragma unroll
      for (int i = 0; i < 8; ++i) {
        int g = tid + i * 256;
        int r = g >> 4, c4 = (g & 15) * 4;
        int rb = n0 + r; if (rb > N - 1) rb = N - 1;
        float4 fv = *(const float4*)(Bf + (long long)rb * ldb + k0 + c4);
        s4v o; o[0] = (short)f2b(fv.x); o[1] = (short)f2b(fv.y);
        o[2] = (short)f2b(fv.z); o[3] = (short)f2b(fv.w);
        int dst = r * 64 + (((c4 >> 3) ^ (r & 7)) << 3) + (c4 & 7);
        *(s4v*)&Bs[dst] = o;
      }
    }
    __syncthreads();
#pragma unroll
    for (int kk = 0; kk < 64; kk += 32) {
      bf16x8 af[4], bfr[4];
#pragma unroll
      for (int m = 0; m < 4; ++m) {
        int r = wr + m * 16 + l15;
        af[m] = *(const bf16x8*)&As[r * 64 + ((((kk >> 3) + l4) ^ (r & 7)) << 3)];
      }
#pragma unroll
      for (int n = 0; n < 4; ++n) {
        int r = wc + n * 16 + l15;
        bfr[n] = *(const bf16x8*)&Bs[r * 64 + ((((kk >> 3) + l4) ^ (r & 7)) << 3)];
      }
#pragma unroll
      for (int m = 0; m < 4; ++m)
#pragma unroll
        for (int n = 0; n < 4; ++n)
          acc[m][n] = MFMA(af[m], bfr[n], acc[m][n], 0, 0, 0);
    }
    __syncthreads();
  }

  if (EPI == 6 || EPI == 7) {
    float* fE = (float*)smem;
#pragma unroll
    for (int h2 = 0; h2 < 2; ++h2) {
      if ((wave >> 1) == h2) {
#pragma unroll
        for (int m = 0; m < 4; ++m)
#pragma unroll
          for (int n = 0; n < 4; ++n)
#pragma unroll
            for (int q = 0; q < 4; ++q)
              fE[(m * 16 + l4 * 4 + q) * 128 + wc + n * 16 + l15] = acc[m][n][q];
      }
      __syncthreads();
#pragma unroll
      for (int i = 0; i < 8; ++i) {
        int lin = tid + i * 256;
        int row = lin >> 5, c4 = (lin & 31) << 2;
        int gr = m0 + h2 * 64 + row;
        if (gr < Meff) {
          f32x4 v4 = *(const f32x4*)&fE[row * 128 + c4];
          long long crow = rowStart + gr;
          float* dst = (float*)Cv + (EPI == 7 ? (long long)kc * pC : 0LL)
                       + crow * ldc + n0 + c4;
          if (EPI == 6) __builtin_nontemporal_store(v4, (f32x4*)dst);
          else          *(f32x4*)dst = v4;
        }
      }
      __syncthreads();
    }
    return;
  }

#pragma unroll
  for (int m = 0; m < 4; ++m) {
#pragma unroll
    for (int n = 0; n < 4; ++n) {
      int c = n0 + wc + n * 16 + l15;
      if (c >= N) continue;
      float bv = (EPI == 2) ? bias[(long long)z * bBias + c] : 0.f;
#pragma unroll
      for (int q = 0; q < 4; ++q) {
        int rr = m0 + wr + m * 16 + l4 * 4 + q;
        if (rr >= Meff) continue;
        float v = acc[m][n][q];
        long long crow = rowStart + rr;
        if (EPI == 2)
          ((ushort_t*)Cv)[crow * ldc + (long long)z * bC + c] = f2b(geluf(v + bv));
      }
    }
  }
}

#define G16_ARGS const ushort_t* A, int lda, long long bA, const void* Bv, \
    int ldb, long long bB, void* Cv, int ldc, long long bC, long long pC, \
    int M, int N, int K, const float* bias, int bBias, const int* offs
#define G16_PASS A, lda, bA, Bv, ldb, bB, Cv, ldc, bC, pC, M, N, K, bias, bBias, offs

__global__ __launch_bounds__(256) void k_moe1   (G16_ARGS) { gemm16_body<2,1,1,1,0>(G16_PASS); }
__global__ __launch_bounds__(256) void k_moe2   (G16_ARGS) { gemm16_body<7,1,1,2,0>(G16_PASS); }
__global__ __launch_bounds__(256) void k_head_bf(G16_ARGS) { gemm16_body<6,1,0,1,1>(G16_PASS); }
__global__ __launch_bounds__(256) void k_head_f (G16_ARGS) { gemm16_body<6,0,0,1,1>(G16_PASS); }

// ---------------------------------------------------------------------------
__global__ __launch_bounds__(256)
void cvt_split2(const float* __restrict__ s0, ushort_t* __restrict__ dh0,
                ushort_t* __restrict__ dl0,
                const float* __restrict__ s1, ushort_t* __restrict__ dh1,
                ushort_t* __restrict__ dl1, int n4)
{
  const float* s = blockIdx.y ? s1 : s0;
  ushort_t* dh = blockIdx.y ? dh1 : dh0;
  ushort_t* dl = blockIdx.y ? dl1 : dl0;
  int i = blockIdx.x * blockDim.x + threadIdx.x;
  int stride = gridDim.x * blockDim.x;
  for (; i < n4; i += stride) {
    float4 f = ((const float4*)s)[i];
    s4v h, l; ushort_t hh, ll;
    split2(f.x, hh, ll); h[0] = (short)hh; l[0] = (short)ll;
    split2(f.y, hh, ll); h[1] = (short)hh; l[1] = (short)ll;
    split2(f.z, hh, ll); h[2] = (short)hh; l[2] = (short)ll;
    split2(f.w, hh, ll); h[3] = (short)hh; l[3] = (short)ll;
    ((s4v*)dh)[i] = h; ((s4v*)dl)[i] = l;
  }
}

__global__ __launch_bounds__(256)
void cvt_bf16(const float* __restrict__ s, ushort_t* __restrict__ d, int n4)
{
  int i = blockIdx.x * blockDim.x + threadIdx.x;
  int stride = gridDim.x * blockDim.x;
  for (; i < n4; i += stride) {
    float4 f = ((const float4*)s)[i];
    s4v o; o[0] = (short)f2b(f.x); o[1] = (short)f2b(f.y);
    o[2] = (short)f2b(f.z); o[3] = (short)f2b(f.w);
    ((s4v*)d)[i] = o;
  }
}

__global__ __launch_bounds__(256)
void embed_kernel(const int* __restrict__ ids, const float* __restrict__ ew,
                  const float* __restrict__ pw, float* __restrict__ x,
                  int* __restrict__ counts)
{
  int srow = blockIdx.x, tid = threadIdx.x;
  if (srow == 0 && tid < 8) counts[tid] = 0;
  int id = ids[srow];
  const float4 e = *(const float4*)(ew + (long long)id * DM + tid * 4);
  const float4 p = *(const float4*)(pw + (long long)srow * DM + tid * 4);
  float4* xr = (float4*)(x + (long long)srow * DM) + tid;
  *xr = make_float4(e.x + p.x, e.y + p.y, e.z + p.z, e.w + p.w);
}

// Fused: x += sum(NP partial planes)+bias_pre (written back), then LayerNorm.
// MODE 0: split H+L planes out; MODE 1: bf16 H only.
template<int MODE, int NP>
__global__ __launch_bounds__(256)
void ln_fused(float* __restrict__ x, const float* __restrict__ P, long long pC,
              const float* __restrict__ bias_pre,
              const float* __restrict__ g, const float* __restrict__ b,
              ushort_t* __restrict__ outH, ushort_t* __restrict__ outL)
{
  int row = blockIdx.x, tid = threadIdx.x;
  long long xo = (long long)row * DM + tid * 4;
  float4 v = *(const float4*)(x + xo);
  if (NP > 0) {
    float4 bp = *(const float4*)(bias_pre + tid * 4);
    float sx = bp.x, sy = bp.y, sz = bp.z, sw = bp.w;
#pragma unroll
    for (int p = 0; p < NP; ++p) {
      float4 pv = *(const float4*)(P + (long long)p * pC + xo);
      sx += pv.x; sy += pv.y; sz += pv.z; sw += pv.w;
    }
    v.x += sx; v.y += sy; v.z += sz; v.w += sw;
    *(float4*)(x + xo) = v;
  }
  __shared__ float sm1[4], sm2[4];
  float s = v.x + v.y + v.z + v.w;
  for (int o = 32; o > 0; o >>= 1) s += __shfl_down(s, o);
  if ((tid & 63) == 0) sm1[tid >> 6] = s;
  __syncthreads();
  float mean = (sm1[0] + sm1[1] + sm1[2] + sm1[3]) * (1.0f / DM);
  float d0 = v.x - mean, d1 = v.y - mean, d2 = v.z - mean, d3 = v.w - mean;
  float q = d0 * d0 + d1 * d1 + d2 * d2 + d3 * d3;
  for (int o = 32; o > 0; o >>= 1) q += __shfl_down(q, o);
  if ((tid & 63) == 0) sm2[tid >> 6] = q;
  __syncthreads();
  float var = (sm2[0] + sm2[1] + sm2[2] + sm2[3]) * (1.0f / DM);
  float rstd = rsqrtf(var + 1e-5f);
  float4 gv = ((const float4*)g)[tid];
  float4 bv = ((const float4*)b)[tid];
  float o0 = d0 * rstd * gv.x + bv.x, o1 = d1 * rstd * gv.y + bv.y;
  float o2 = d2 * rstd * gv.z + bv.z, o3 = d3 * rstd * gv.w + bv.w;
  long long base = (long long)row * DM + tid * 4;
  if (MODE == 0) {
    ushort_t hh, ll;
    split2(o0, hh, ll); outH[base + 0] = hh; outL[base + 0] = ll;
    split2(o1, hh, ll); outH[base + 1] = hh; outL[base + 1] = ll;
    split2(o2, hh, ll); outH[base + 2] = hh; outL[base + 2] = ll;
    split2(o3, hh, ll); outH[base + 3] = hh; outL[base + 3] = ll;
  } else {
    outH[base + 0] = f2b(o0); outH[base + 1] = f2b(o1);
    outH[base + 2] = f2b(o2); outH[base + 3] = f2b(o3);
  }
}

// Fused: x += sum(4 planes)+bias_pre (written back); LN (f32); gate scores;
// top2; bf16 LN output for expert gather.
__global__ __launch_bounds__(256)
void ln_gate_top2(float* __restrict__ x, const float* __restrict__ P,
                  long long pC, const float* __restrict__ bias_pre,
                  const float* __restrict__ g, const float* __restrict__ b,
                  const float* __restrict__ gw, const float* __restrict__ gb,
                  int* __restrict__ topi, float* __restrict__ topw,
                  int* __restrict__ counts, ushort_t* __restrict__ outH)
{
  int row = blockIdx.x, tid = threadIdx.x;
  long long xo = (long long)row * DM + tid * 4;
  float4 v = *(const float4*)(x + xo);
  {
    float4 bp = *(const float4*)(bias_pre + tid * 4);
    float sx = bp.x, sy = bp.y, sz = bp.z, sw = bp.w;
#pragma unroll
    for (int p = 0; p < 4; ++p) {
      float4 pv = *(const float4*)(P + (long long)p * pC + xo);
      sx += pv.x; sy += pv.y; sz += pv.z; sw += pv.w;
    }
    v.x += sx; v.y += sy; v.z += sz; v.w += sw;
    *(float4*)(x + xo) = v;
  }
  __shared__ float sm1[4], sm2[4];
  __shared__ float se[8][4];
  float s = v.x + v.y + v.z + v.w;
  for (int o = 32; o > 0; o >>= 1) s += __shfl_down(s, o);
  if ((tid & 63) == 0) sm1[tid >> 6] = s;
  __syncthreads();
  float mean = (sm1[0] + sm1[1] + sm1[2] + sm1[3]) * (1.0f / DM);
  float d0 = v.x - mean, d1 = v.y - mean, d2 = v.z - mean, d3 = v.w - mean;
  float q = d0 * d0 + d1 * d1 + d2 * d2 + d3 * d3;
  for (int o = 32; o > 0; o >>= 1) q += __shfl_down(q, o);
  if ((tid & 63) == 0) sm2[tid >> 6] = q;
  __syncthreads();
  float var = (sm2[0] + sm2[1] + sm2[2] + sm2[3]) * (1.0f / DM);
  float rstd = rsqrtf(var + 1e-5f);
  float4 gv = ((const float4*)g)[tid];
  float4 bv = ((const float4*)b)[tid];
  float h0 = d0 * rstd * gv.x + bv.x, h1 = d1 * rstd * gv.y + bv.y;
  float h2 = d2 * rstd * gv.z + bv.z, h3 = d3 * rstd * gv.w + bv.w;
  long long base = (long long)row * DM + tid * 4;
  outH[base + 0] = f2b(h0); outH[base + 1] = f2b(h1);
  outH[base + 2] = f2b(h2); outH[base + 3] = f2b(h3);
#pragma unroll
  for (int e = 0; e < 8; ++e) {
    float4 w = ((const float4*)(gw + (long long)e * DM))[tid];
    float p = h0 * w.x + h1 * w.y + h2 * w.z + h3 * w.w;
    for (int o = 32; o > 0; o >>= 1) p += __shfl_down(p, o);
    if ((tid & 63) == 0) se[e][tid >> 6] = p;
  }
  __syncthreads();
  if (tid == 0) {
    float sc[8];
#pragma unroll
    for (int e = 0; e < 8; ++e)
      sc[e] = se[e][0] + se[e][1] + se[e][2] + se[e][3] + gb[e];
    int i1 = 0; float m1 = sc[0];
    for (int e = 1; e < 8; ++e) if (sc[e] > m1) { m1 = sc[e]; i1 = e; }
    int i2 = -1; float m2 = -1e30f;
    for (int e = 0; e < 8; ++e) if (e != i1 && sc[e] > m2) { m2 = sc[e]; i2 = e; }
    float e2 = __expf(m2 - m1);
    float w1 = 1.f / (1.f + e2);
    topi[row * 2] = i1; topi[row * 2 + 1] = i2;
    topw[row * 2] = w1; topw[row * 2 + 1] = 1.f - w1;
    atomicAdd(&counts[i1], 1);
    atomicAdd(&counts[i2], 1);
  }
}

__global__ void moe_prefix(const int* __restrict__ counts, int* __restrict__ offs,
                           int* __restrict__ cursors)
{
  if (threadIdx.x == 0 && blockIdx.x == 0) {
    int a = 0;
    for (int e = 0; e < 8; ++e) { offs[e] = a; a += counts[e]; cursors[e] = 0; }
    offs[8] = a;
  }
}

__global__ __launch_bounds__(256)
void moe_gather(const ushort_t* __restrict__ hH, const int* __restrict__ topi,
                const float* __restrict__ topw, const int* __restrict__ offs,
                int* __restrict__ cursors, int* __restrict__ tokIdx,
                float* __restrict__ tokW, int* __restrict__ slotOf,
                ushort_t* __restrict__ Xg)
{
  int tok = blockIdx.x, tid = threadIdx.x;
  __shared__ int s0s, s1s;
  if (tid == 0) {
    int e0 = topi[tok * 2], e1 = topi[tok * 2 + 1];
    int s0 = offs[e0] + atomicAdd(&cursors[e0], 1);
    int s1 = offs[e1] + atomicAdd(&cursors[e1], 1);
    tokIdx[s0] = tok; tokW[s0] = topw[tok * 2];
    tokIdx[s1] = tok; tokW[s1] = topw[tok * 2 + 1];
    slotOf[tok * 2] = s0; slotOf[tok * 2 + 1] = s1;
    s0s = s0; s1s = s1;
  }
  __syncthreads();
  s4v v = ((const s4v*)(hH + (long long)tok * DM))[tid];
  ((s4v*)(Xg + (long long)s0s * DM))[tid] = v;
  ((s4v*)(Xg + (long long)s1s * DM))[tid] = v;
}

// Fused: x[tok] += MoE combine; then FINAL LayerNorm -> bf16 hfin (x not stored)
__global__ __launch_bounds__(256)
void moe_ln_final(const float* __restrict__ x, const float* __restrict__ eo,
                  long long pC, const int* __restrict__ slotOf,
                  const int* __restrict__ topi, const float* __restrict__ topw,
                  const float* __restrict__ b2, const float* __restrict__ g,
                  const float* __restrict__ b, ushort_t* __restrict__ outH)
{
  int tok = blockIdx.x, tid = threadIdx.x;
  int s0 = slotOf[tok * 2], s1 = slotOf[tok * 2 + 1];
  int e0 = topi[tok * 2], e1 = topi[tok * 2 + 1];
  float w0 = topw[tok * 2], w1 = topw[tok * 2 + 1];
  float4 a  = ((const float4*)(eo + (long long)s0 * DM))[tid];
  float4 a2 = ((const float4*)(eo + pC + (long long)s0 * DM))[tid];
  float4 bb1= ((const float4*)(eo + (long long)s1 * DM))[tid];
  float4 bb2= ((const float4*)(eo + pC + (long long)s1 * DM))[tid];
  float4 ba = ((const float4*)(b2 + (long long)e0 * DM))[tid];
  float4 bbb= ((const float4*)(b2 + (long long)e1 * DM))[tid];
  float4 v = ((const float4*)(x + (long long)tok * DM))[tid];
  v.x += w0 * (a.x + a2.x + ba.x) + w1 * (bb1.x + bb2.x + bbb.x);
  v.y += w0 * (a.y + a2.y + ba.y) + w1 * (bb1.y + bb2.y + bbb.y);
  v.z += w0 * (a.z + a2.z + ba.z) + w1 * (bb1.z + bb2.z + bbb.z);
  v.w += w0 * (a.w + a2.w + ba.w) + w1 * (bb1.w + bb2.w + bbb.w);
  __shared__ float sm1[4], sm2[4];
  float s = v.x + v.y + v.z + v.w;
  for (int o = 32; o > 0; o >>= 1) s += __shfl_down(s, o);
  if ((tid & 63) == 0) sm1[tid >> 6] = s;
  __syncthreads();
  float mean = (sm1[0] + sm1[1] + sm1[2] + sm1[3]) * (1.0f / DM);
  float d0 = v.x - mean, d1 = v.y - mean, d2 = v.z - mean, d3 = v.w - mean;
  float q = d0 * d0 + d1 * d1 + d2 * d2 + d3 * d3;
  for (int o = 32; o > 0; o >>= 1) q += __shfl_down(q, o);
  if ((tid & 63) == 0) sm2[tid >> 6] = q;
  __syncthreads();
  float var = (sm2[0] + sm2[1] + sm2[2] + sm2[3]) * (1.0f / DM);
  float rstd = rsqrtf(var + 1e-5f);
  float4 gv = ((const float4*)g)[tid];
  float4 bv = ((const float4*)b)[tid];
  long long base = (long long)tok * DM + tid * 4;
  outH[base + 0] = f2b(d0 * rstd * gv.x + bv.x);
  outH[base + 1] = f2b(d1 * rstd * gv.y + bv.y);
  outH[base + 2] = f2b(d2 * rstd * gv.z + bv.z);
  outH[base + 3] = f2b(d3 * rstd * gv.w + bv.w);
}

extern "C" void kernel_launch(void* const* d_in, const int* in_sizes, int n_in,
                              void* d_out, int out_size, void* d_ws, size_t ws_size,
                              hipStream_t stream)
{
  const int* ids = (const int*)d_in[0];
  const float* embed_w = (const float*)d_in[1];
  const float* pos_w   = (const float*)d_in[2];
  const float* ln1_g[2] = {(const float*)d_in[3],  (const float*)d_in[11]};
  const float* ln1_b[2] = {(const float*)d_in[4],  (const float*)d_in[12]};
  const float* in_w[2]  = {(const float*)d_in[5],  (const float*)d_in[13]};
  const float* in_b[2]  = {(const float*)d_in[6],  (const float*)d_in[14]};
  const float* out_w[2] = {(const float*)d_in[7],  (const float*)d_in[15]};
  const float* out_b[2] = {(const float*)d_in[8],  (const float*)d_in[16]};
  const float* ln2_g[2] = {(const float*)d_in[9],  (const float*)d_in[17]};
  const float* ln2_b[2] = {(const float*)d_in[10], (const float*)d_in[18]};
  const float* ffn_w1 = (const float*)d_in[19];
  const float* ffn_b1 = (const float*)d_in[20];
  const float* ffn_w2 = (const float*)d_in[21];
  const float* ffn_b2 = (const float*)d_in[22];
  const float* gate_w = (const float*)d_in[23];
  const float* gate_b = (const float*)d_in[24];
  const float* moe_w1 = (const float*)d_in[25];
  const float* moe_b1 = (const float*)d_in[26];
  const float* moe_w2 = (const float*)d_in[27];
  const float* moe_b2 = (const float*)d_in[28];
  const float* norm_g = (const float*)d_in[29];
  const float* norm_b = (const float*)d_in[30];
  const float* head_w = (const float*)d_in[31];

  char* ob = (char*)d_out;
  size_t off = 0;
  auto alloc = [&](size_t bytes) {
    char* p = ob + off;
    off = (off + bytes + 255) & ~(size_t)255;
    return p;
  };
  float*    x      = (float*)alloc((size_t)SQ * DM * 4);
  ushort_t* hbufH  = (ushort_t*)alloc((size_t)SQ * DM * 2);
  ushort_t* hbufL  = (ushort_t*)alloc((size_t)SQ * DM * 2);
  ushort_t* qkvH   = (ushort_t*)alloc((size_t)SQ * 3 * DM * 2);   // ┐
  ushort_t* qkvL   = (ushort_t*)alloc((size_t)SQ * 3 * DM * 2);   // │ w2b
  ushort_t* VtH    = (ushort_t*)alloc((size_t)NH * HDIM * SQ * 2);// │ 64MiB
  ushort_t* VtL    = (ushort_t*)alloc((size_t)NH * HDIM * SQ * 2);// │
  char*     resv   = (char*)alloc((size_t)32 << 20);              // ┘ filler
  ushort_t* attnH  = (ushort_t*)alloc((size_t)SQ * DM * 2);
  ushort_t* attnL  = (ushort_t*)alloc((size_t)SQ * DM * 2);
  ushort_t* Xg     = (ushort_t*)alloc((size_t)2 * SQ * DM * 2);
  int*      topi   = (int*)alloc(SQ * 2 * 4);
  float*    topw   = (float*)alloc(SQ * 2 * 4);
  int*      tokIdx = (int*)alloc(2 * SQ * 4);
  float*    tokW   = (float*)alloc(2 * SQ * 4);
  int*      slotOf = (int*)alloc(2 * SQ * 4);
  int*      counts = (int*)alloc(256);
  int*      offsb  = (int*)alloc(256);
  int*      cursors= (int*)alloc(256);
  ushort_t* ffnH   = (ushort_t*)alloc((size_t)SQ * FFD * 2);      // ┐ moehid
  ushort_t* ffnL   = (ushort_t*)alloc((size_t)SQ * FFD * 2);      // ┘ 32MiB
  float*    eo     = (float*)alloc((size_t)2 * 2 * SQ * DM * 4);  // 32MiB (also KS partials)
  ushort_t* inwH[2], *inwL[2], *outwH[2], *outwL[2];
  ushort_t* wsplit0 = (ushort_t*)alloc(0);
  inwH[0]  = (ushort_t*)alloc((size_t)3 * DM * DM * 2);
  inwL[0]  = (ushort_t*)alloc((size_t)3 * DM * DM * 2);
  inwH[1]  = (ushort_t*)alloc((size_t)3 * DM * DM * 2);
  inwL[1]  = (ushort_t*)alloc((size_t)3 * DM * DM * 2);
  outwH[0] = (ushort_t*)alloc((size_t)DM * DM * 2);
  outwL[0] = (ushort_t*)alloc((size_t)DM * DM * 2);
  outwH[1] = (ushort_t*)alloc((size_t)DM * DM * 2);
  outwL[1] = (ushort_t*)alloc((size_t)DM * DM * 2);
  ushort_t* f1H = (ushort_t*)alloc((size_t)FFD * DM * 2);
  ushort_t* f1L = (ushort_t*)alloc((size_t)FFD * DM * 2);
  ushort_t* f2H = (ushort_t*)alloc((size_t)DM * FFD * 2);
  ushort_t* f2L = (ushort_t*)alloc((size_t)DM * FFD * 2);
  ushort_t* moe_w1b = wsplit0;            // 64 MiB over weight planes
  ushort_t* moe_w2b = qkvH;               // 64 MiB over qkv+Vt+resv
  ushort_t* moehid  = ffnH;               // 32 MiB over ffn planes
  float*    pp      = eo;                 // KS partial planes
  const long long eoPC = (long long)2 * SQ * DM;
  const long long ppPC = (long long)SQ * DM;
  ushort_t* hfin    = (ushort_t*)d_ws;
  bool wsBig = ws_size >= ((size_t)70 << 20);
  ushort_t* head_wb = (ushort_t*)((char*)d_ws + ((size_t)4 << 20));
  (void)resv;

  embed_kernel<<<SQ, 256, 0, stream>>>(ids, embed_w, pos_w, x, counts);
  cvt_split2<<<dim3(512, 2), 256, 0, stream>>>(
      in_w[0], inwH[0], inwL[0], in_w[1], inwH[1], inwL[1], 3 * DM * DM / 4);
  cvt_split2<<<dim3(512, 2), 256, 0, stream>>>(
      out_w[0], outwH[0], outwL[0], out_w[1], outwH[1], outwL[1], DM * DM / 4);
  cvt_split2<<<dim3(512, 2), 256, 0, stream>>>(
      ffn_w1, f1H, f1L, ffn_w2, f2H, f2L, FFD * DM / 4);
  if (wsBig)
    cvt_bf16<<<1024, 256, 0, stream>>>(head_w, head_wb, NVOC * DM / 4);

  // ---- Layer 0 ----
  ln_fused<0, 0><<<SQ, 256, 0, stream>>>(x, nullptr, 0, nullptr,
                                         ln1_g[0], ln1_b[0], hbufH, hbufL);
  k_qkv<<<dim3(16, 24, 1), 256, 0, stream>>>(
      hbufH, hbufL, DM, 0, inwH[0], inwL[0], DM, 0,
      nullptr, qkvH, qkvL, 3 * DM, 0, 0,
      SQ, 3 * DM, DM, in_b[0], 1.f, VtH, VtL);
  k_attn<<<dim3(SQ / 64, NH), 256, 0, stream>>>(qkvH, qkvL, VtH, VtL,
                                                attnH, attnL);
  k_outp<<<dim3(16, 16, 4), 256, 0, stream>>>(
      attnH, attnL, DM, 0, outwH[0], outwL[0], DM, 0,
      pp, nullptr, nullptr, DM, 0, ppPC,
      SQ, DM, DM / 4, nullptr, 1.f, nullptr, nullptr);
  ln_fused<0, 4><<<SQ, 256, 0, stream>>>(x, pp, ppPC, out_b[0],
                                         ln2_g[0], ln2_b[0], hbufH, hbufL);
  k_ffn1<<<dim3(16, 32, 1), 256, 0, stream>>>(
      hbufH, hbufL, DM, 0, f1H, f1L, DM, 0,
      nullptr, ffnH, ffnL, FFD, 0, 0,
      SQ, FFD, DM, ffn_b1, 1.f, nullptr, nullptr);
  k_ffn2<<<dim3(16, 16, 2), 256, 0, stream>>>(
      ffnH, ffnL, FFD, 0, f2H, f2L, FFD, 0,
      pp, nullptr, nullptr, DM, 0, ppPC,
      SQ, DM, FFD / 2, nullptr, 1.f, nullptr, nullptr);
  // ---- Layer 1 (ln1 fused with ffn2 reduce) ----
  ln_fused<0, 2><<<SQ, 256, 0, stream>>>(x, pp, ppPC, ffn_b2,
                                         ln1_g[1], ln1_b[1], hbufH, hbufL);
  k_qkv<<<dim3(16, 24, 1), 256, 0, stream>>>(
      hbufH, hbufL, DM, 0, inwH[1], inwL[1], DM, 0,
      nullptr, qkvH, qkvL, 3 * DM, 0, 0,
      SQ, 3 * DM, DM, in_b[1], 1.f, VtH, VtL);
  k_attn<<<dim3(SQ / 64, NH), 256, 0, stream>>>(qkvH, qkvL, VtH, VtL,
                                                attnH, attnL);
  k_outp<<<dim3(16, 16, 4), 256, 0, stream>>>(
      attnH, attnL, DM, 0, outwH[1], outwL[1], DM, 0,
      pp, nullptr, nullptr, DM, 0, ppPC,
      SQ, DM, DM / 4, nullptr, 1.f, nullptr, nullptr);
  // qkv/Vt and weight planes dead -> MoE weight conversion
  cvt_bf16<<<2048, 256, 0, stream>>>(moe_w1, moe_w1b, 8 * FFD * DM / 4);
  cvt_bf16<<<2048, 256, 0, stream>>>(moe_w2, moe_w2b, 8 * DM * FFD / 4);
  // gate (fused with outp reduce, f32 routing) + bf16 LN out
  ln_gate_top2<<<SQ, 256, 0, stream>>>(x, pp, ppPC, out_b[1],
                                       ln2_g[1], ln2_b[1], gate_w, gate_b,
                                       topi, topw, counts, hbufH);
  moe_prefix<<<1, 64, 0, stream>>>(counts, offsb, cursors);
  moe_gather<<<SQ, 256, 0, stream>>>(hbufH, topi, topw, offsb, cursors,
                                     tokIdx, tokW, slotOf, Xg);
  k_moe1<<<dim3(32, 16, 8), 256, 0, stream>>>(
      Xg, DM, 0, moe_w1b, DM, (long long)FFD * DM,
      moehid, FFD, 0, 0, SQ, FFD, DM, moe_b1, FFD, offsb);
  k_moe2<<<dim3(8, 16, 16), 256, 0, stream>>>(
      moehid, FFD, 0, moe_w2b, FFD, (long long)DM * FFD,
      eo, DM, 0, eoPC, SQ, DM, FFD, nullptr, 0, offsb);
  // MoE combine + FINAL LayerNorm fused -> hfin
  moe_ln_final<<<SQ, 256, 0, stream>>>(x, eo, eoPC, slotOf, topi, topw,
                                       moe_b2, norm_g, norm_b, hfin);
  if (wsBig)
    k_head_bf<<<dim3(16, 250, 1), 256, 0, stream>>>(
        hfin, DM, 0, head_wb, DM, 0, d_out, NVOC, 0, 0,
        SQ, NVOC, DM, nullptr, 0, nullptr);
  else
    k_head_f<<<dim3(16, 250, 1), 256, 0, stream>>>(
        hfin, DM, 0, head_w, DM, 0, d_out, NVOC, 0, 0,
        SQ, NVOC, DM, nullptr, 0, nullptr);
}

// Round 13
// 1158.559 us; speedup vs baseline: 1.9259x; 1.0494x over previous
//
#include <hip/hip_runtime.h>
#include <hip/hip_bf16.h>
#include <math.h>

typedef unsigned short ushort_t;
typedef __attribute__((ext_vector_type(8))) __bf16 bf16x8;
typedef __attribute__((ext_vector_type(4))) float f32x4;
typedef __attribute__((ext_vector_type(8))) short s8v;
typedef __attribute__((ext_vector_type(4))) short s4v;

#define SQ 2048
#define DM 1024
#define NH 16
#define HDIM 64
#define FFD 4096
#define NVOC 32000

__device__ inline float b2f(unsigned short u) {
  union { unsigned int i; float f; } x; x.i = ((unsigned int)u) << 16; return x.f;
}
__device__ inline unsigned short f2b(float f) {
  __hip_bfloat16 h = __float2bfloat16(f);
  return *reinterpret_cast<unsigned short*>(&h);
}
__device__ inline void split2(float x, ushort_t& h, ushort_t& l) {
  h = f2b(x);
  l = f2b(x - b2f(h));
}
__device__ inline float geluf(float v) {
  return 0.5f * v * (1.0f + erff(v * 0.70710678118654752f));
}
__device__ __forceinline__ void gld16(const void* g, void* l) {
  __builtin_amdgcn_global_load_lds(
      (const __attribute__((address_space(1))) void*)g,
      (__attribute__((address_space(3))) void*)l, 16, 0, 0);
}
#define MFMA __builtin_amdgcn_mfma_f32_16x16x32_bf16

// ---------------------------------------------------------------------------
// Split GEMM engine (pre-gate math): C = epi((AH+AL)*(BH+BL)^T), planes bf16.
// EPI: 2 f32 partial store (kc*pC), 4 gelu+bias split-store,
//      5 split-store+bias with V-region (n0>=2048) written TRANSPOSED to TH/TL.
// ---------------------------------------------------------------------------
template<int EPI, int NT, int KS>
__device__ __forceinline__ void gemmsp_body(
    const ushort_t* __restrict__ AH, const ushort_t* __restrict__ AL,
    int lda, long long bA,
    const ushort_t* __restrict__ BH, const ushort_t* __restrict__ BL,
    int ldb, long long bB,
    float* __restrict__ C, ushort_t* __restrict__ CH, ushort_t* __restrict__ CL,
    int ldc, long long bC, long long pC,
    int M, int N, int K, const float* __restrict__ bias, float alpha,
    ushort_t* __restrict__ TH, ushort_t* __restrict__ TL)
{
  int z = blockIdx.z, h = z / KS, kc = z % KS;
  const ushort_t* AHp = AH + (long long)h * bA + (long long)kc * K;
  const ushort_t* ALp = AL + (long long)h * bA + (long long)kc * K;
  const ushort_t* BHp = BH + (long long)h * bB + (long long)kc * K;
  const ushort_t* BLp = BL + (long long)h * bB + (long long)kc * K;
  int m0 = blockIdx.x * 128, n0 = blockIdx.y * NT;
  const int NF = NT / 32;

  __shared__ __align__(16) ushort_t sAH[128 * 32], sAL[128 * 32];
  __shared__ __align__(16) ushort_t sBH[NT * 32],  sBL[NT * 32];

  int tid = threadIdx.x, lane = tid & 63, wave = tid >> 6;
  int wr = (wave >> 1) * 64, wc = (wave & 1) * (NT >> 1);
  int l15 = lane & 15, l4 = lane >> 4;

  f32x4 acc[4][NF];
#pragma unroll
  for (int m = 0; m < 4; ++m)
#pragma unroll
    for (int n = 0; n < NF; ++n) acc[m][n] = (f32x4){0.f, 0.f, 0.f, 0.f};

  for (int k0 = 0; k0 < K; k0 += 32) {
#pragma unroll
    for (int i = 0; i < 2; ++i) {
      int fi = i * 2048 + tid * 8;
      int r = fi >> 5, chk = (fi >> 3) & 3;
      int scol = ((chk ^ ((r >> 1) & 3)) << 3);
      int ra = m0 + r; if (ra > M - 1) ra = M - 1;
      long long go = (long long)ra * lda + k0 + scol;
      gld16(AHp + go, &sAH[fi]);
      gld16(ALp + go, &sAL[fi]);
    }
#pragma unroll
    for (int i = 0; i < NT / 64; ++i) {
      int fi = i * 2048 + tid * 8;
      int r = fi >> 5, chk = (fi >> 3) & 3;
      int scol = ((chk ^ ((r >> 1) & 3)) << 3);
      int rb = n0 + r; if (rb > N - 1) rb = N - 1;
      long long go = (long long)rb * ldb + k0 + scol;
      gld16(BHp + go, &sBH[fi]);
      gld16(BLp + go, &sBL[fi]);
    }
    __syncthreads();
    bf16x8 ah[4], al[4], bh[NF], bl[NF];
#pragma unroll
    for (int m = 0; m < 4; ++m) {
      int r = wr + m * 16 + l15;
      int o = r * 32 + ((l4 ^ ((r >> 1) & 3)) << 3);
      ah[m] = *(const bf16x8*)&sAH[o];
      al[m] = *(const bf16x8*)&sAL[o];
    }
#pragma unroll
    for (int n = 0; n < NF; ++n) {
      int r = wc + n * 16 + l15;
      int o = r * 32 + ((l4 ^ ((r >> 1) & 3)) << 3);
      bh[n] = *(const bf16x8*)&sBH[o];
      bl[n] = *(const bf16x8*)&sBL[o];
    }
#pragma unroll
    for (int m = 0; m < 4; ++m)
#pragma unroll
      for (int n = 0; n < NF; ++n) {
        acc[m][n] = MFMA(ah[m], bh[n], acc[m][n], 0, 0, 0);
        acc[m][n] = MFMA(al[m], bh[n], acc[m][n], 0, 0, 0);
        acc[m][n] = MFMA(ah[m], bl[n], acc[m][n], 0, 0, 0);
      }
    __syncthreads();
  }

  if (EPI == 5 && n0 >= 2 * DM) {
#pragma unroll
    for (int m = 0; m < 4; ++m) {
      int rbase = m0 + wr + m * 16 + l4 * 4;
#pragma unroll
      for (int n = 0; n < NF; ++n) {
        int c = n0 + wc + n * 16 + l15;
        int d = c - 2 * DM;
        float bv = bias[c];
        s4v hv, lv;
#pragma unroll
        for (int q = 0; q < 4; ++q) {
          ushort_t hh, ll; split2(acc[m][n][q] + bv, hh, ll);
          hv[q] = (short)hh; lv[q] = (short)ll;
        }
        *(s4v*)&TH[(long long)d * SQ + rbase] = hv;
        *(s4v*)&TL[(long long)d * SQ + rbase] = lv;
      }
    }
    return;
  }

#pragma unroll
  for (int m = 0; m < 4; ++m) {
#pragma unroll
    for (int n = 0; n < NF; ++n) {
      int c = n0 + wc + n * 16 + l15;
      if (c >= N) continue;
      float bv = (EPI == 4 || EPI == 5) ? bias[c] : 0.f;
#pragma unroll
      for (int q = 0; q < 4; ++q) {
        int rr = m0 + wr + m * 16 + l4 * 4 + q;
        if (rr >= M) continue;
        float v = acc[m][n][q];
        if (EPI == 5) {
          ushort_t hh, ll; split2(v + bv, hh, ll);
          long long o = (long long)rr * ldc + c; CH[o] = hh; CL[o] = ll;
        } else if (EPI == 2) {
          C[(long long)kc * pC + (long long)rr * ldc + (long long)h * bC + c] = v;
        } else if (EPI == 4) {
          ushort_t hh, ll; split2(geluf(v + bv), hh, ll);
          long long o = (long long)rr * ldc + c; CH[o] = hh; CL[o] = ll;
        }
      }
    }
  }
}

#define SP_ARGS const ushort_t* AH, const ushort_t* AL, int lda, long long bA, \
    const ushort_t* BH, const ushort_t* BL, int ldb, long long bB, \
    float* C, ushort_t* CH, ushort_t* CL, int ldc, long long bC, long long pC, \
    int M, int N, int K, const float* bias, float alpha, \
    ushort_t* TH, ushort_t* TL
#define SP_PASS AH, AL, lda, bA, BH, BL, ldb, bB, C, CH, CL, ldc, bC, pC, M, N, K, bias, alpha, TH, TL

__global__ __launch_bounds__(256) void k_qkv (SP_ARGS) { gemmsp_body<5,128,1>(SP_PASS); }
__global__ __launch_bounds__(256) void k_outp(SP_ARGS) { gemmsp_body<2, 64,4>(SP_PASS); }
__global__ __launch_bounds__(256) void k_ffn1(SP_ARGS) { gemmsp_body<4,128,1>(SP_PASS); }
__global__ __launch_bounds__(256) void k_ffn2(SP_ARGS) { gemmsp_body<2, 64,2>(SP_PASS); }

// ---------------------------------------------------------------------------
// Fused flash attention, split-f32 precision. Grid (32,16).
// ---------------------------------------------------------------------------
__global__ __launch_bounds__(256)
void k_attn(const ushort_t* __restrict__ qkvH, const ushort_t* __restrict__ qkvL,
            const ushort_t* __restrict__ VtH, const ushort_t* __restrict__ VtL,
            ushort_t* __restrict__ aH, ushort_t* __restrict__ aL)
{
  int f = blockIdx.x + blockIdx.y * gridDim.x;
  int logical = (f & 7) * 64 + (f >> 3);
  int q0 = (logical & 31) * 64;
  int h  = logical >> 5;

  __shared__ __align__(16) ushort_t sKH[4096], sKL[4096];
  __shared__ __align__(16) ushort_t sVH[4096], sVL[4096];
  __shared__ __align__(16) ushort_t sPH[4096], sPL[4096];

  int tid = threadIdx.x, lane = tid & 63, wave = tid >> 6;
  int l15 = lane & 15, l4 = lane >> 4;

  bf16x8 qh[2], ql[2];
  {
    long long base = (long long)(q0 + wave * 16 + l15) * (3 * DM) + h * 64 + l4 * 8;
    qh[0] = *(const bf16x8*)(qkvH + base);
    qh[1] = *(const bf16x8*)(qkvH + base + 32);
    ql[0] = *(const bf16x8*)(qkvL + base);
    ql[1] = *(const bf16x8*)(qkvL + base + 32);
  }

  float mrow[4], lrow[4];
  f32x4 Oacc[4];
#pragma unroll
  for (int r = 0; r < 4; ++r) { mrow[r] = -1e30f; lrow[r] = 0.f; }
#pragma unroll
  for (int n = 0; n < 4; ++n) Oacc[n] = (f32x4){0.f, 0.f, 0.f, 0.f};

  for (int kt = 0; kt < SQ / 64; ++kt) {
#pragma unroll
    for (int i = 0; i < 2; ++i) {
      int idx = i * 2048 + tid * 8;
      int row = idx >> 6, chk = (idx >> 3) & 7;
      int scol = ((chk ^ (row & 7)) << 3);
      long long gk = (long long)(kt * 64 + row) * (3 * DM) + DM + h * 64 + scol;
      long long gv = (long long)(h * 64 + row) * SQ + kt * 64 + scol;
      gld16(qkvH + gk, &sKH[idx]);
      gld16(qkvL + gk, &sKL[idx]);
      gld16(VtH + gv, &sVH[idx]);
      gld16(VtL + gv, &sVL[idx]);
    }
    __syncthreads();

    f32x4 S[4];
#pragma unroll
    for (int n = 0; n < 4; ++n) S[n] = (f32x4){0.f, 0.f, 0.f, 0.f};
#pragma unroll
    for (int kk = 0; kk < 64; kk += 32) {
      int kkI = kk >> 5;
      bf16x8 qhf = qh[kkI], qlf = ql[kkI];
#pragma unroll
      for (int n = 0; n < 4; ++n) {
        int br = n * 16 + l15;
        int bo = br * 64 + ((((kk >> 3) + l4) ^ (br & 7)) << 3);
        bf16x8 kh = *(const bf16x8*)&sKH[bo];
        bf16x8 kl = *(const bf16x8*)&sKL[bo];
        S[n] = MFMA(qhf, kh, S[n], 0, 0, 0);
        S[n] = MFMA(qlf, kh, S[n], 0, 0, 0);
        S[n] = MFMA(qhf, kl, S[n], 0, 0, 0);
      }
    }
    float tm[4], ts[4];
#pragma unroll
    for (int r = 0; r < 4; ++r) {
#pragma unroll
      for (int n = 0; n < 4; ++n) S[n][r] *= 0.125f;
      tm[r] = fmaxf(fmaxf(S[0][r], S[1][r]), fmaxf(S[2][r], S[3][r]));
    }
#pragma unroll
    for (int mk = 1; mk <= 8; mk <<= 1)
#pragma unroll
      for (int r = 0; r < 4; ++r) tm[r] = fmaxf(tm[r], __shfl_xor(tm[r], mk));
#pragma unroll
    for (int r = 0; r < 4; ++r) {
      float mn = fmaxf(mrow[r], tm[r]);
      float corr = __expf(mrow[r] - mn);
      mrow[r] = mn;
      float s = 0.f;
#pragma unroll
      for (int n = 0; n < 4; ++n) { S[n][r] = __expf(S[n][r] - mn); s += S[n][r]; }
      ts[r] = s;
      lrow[r] *= corr;
#pragma unroll
      for (int n = 0; n < 4; ++n) Oacc[n][r] *= corr;
    }
#pragma unroll
    for (int mk = 1; mk <= 8; mk <<= 1)
#pragma unroll
      for (int r = 0; r < 4; ++r) ts[r] += __shfl_xor(ts[r], mk);
#pragma unroll
    for (int r = 0; r < 4; ++r) lrow[r] += ts[r];

    {
      ushort_t* pH = &sPH[wave * 1024];
      ushort_t* pL = &sPL[wave * 1024];
#pragma unroll
      for (int n = 0; n < 4; ++n)
#pragma unroll
        for (int r = 0; r < 4; ++r) {
          int row = l4 * 4 + r, col = n * 16 + l15;
          int ad = row * 64 + (((col >> 3) ^ (row & 7)) << 3) + (col & 7);
          ushort_t hh, ll; split2(S[n][r], hh, ll);
          pH[ad] = hh; pL[ad] = ll;
        }
    }
    __syncthreads();
#pragma unroll
    for (int kk = 0; kk < 64; kk += 32) {
      int ao = wave * 1024 + l15 * 64 + ((((kk >> 3) + l4) ^ (l15 & 7)) << 3);
      bf16x8 ph = *(const bf16x8*)&sPH[ao];
      bf16x8 pl = *(const bf16x8*)&sPL[ao];
#pragma unroll
      for (int n = 0; n < 4; ++n) {
        int br = n * 16 + l15;
        int bo = br * 64 + ((((kk >> 3) + l4) ^ (br & 7)) << 3);
        bf16x8 vh = *(const bf16x8*)&sVH[bo];
        bf16x8 vl = *(const bf16x8*)&sVL[bo];
        Oacc[n] = MFMA(ph, vh, Oacc[n], 0, 0, 0);
        Oacc[n] = MFMA(pl, vh, Oacc[n], 0, 0, 0);
        Oacc[n] = MFMA(ph, vl, Oacc[n], 0, 0, 0);
      }
    }
    __syncthreads();
  }

#pragma unroll
  for (int n = 0; n < 4; ++n)
#pragma unroll
    for (int r = 0; r < 4; ++r) {
      int q = q0 + wave * 16 + l4 * 4 + r;
      int d = h * 64 + n * 16 + l15;
      float val = Oacc[n][r] / lrow[r];
      ushort_t hh, ll; split2(val, hh, ll);
      long long o = (long long)q * DM + d;
      aH[o] = hh; aL[o] = ll;
    }
}

// ---------------------------------------------------------------------------
// bf16 GEMM engine (post-gate), 2-phase double-buffered (T3 minimum form):
// per K-step: barrier -> issue next tile's gld16 -> ds_read+MFMA current.
// Next-tile loads are in flight under MFMA; one barrier per K-step.
// ---------------------------------------------------------------------------
template<int EPI, int BSRC, int SWAP, int KS, int XS>
__device__ __forceinline__ void gemm16_body(
    const ushort_t* __restrict__ A, int lda, long long bA,
    const void* __restrict__ Bv, int ldb, long long bB,
    void* __restrict__ Cv, int ldc, long long bC, long long pC,
    int M, int N, int K, const float* __restrict__ bias, int bBias,
    const int* __restrict__ offs)
{
  int bz = blockIdx.z;
  int z = bz / KS, kc = bz % KS;
  int Kc = K / KS;
  const ushort_t* Ap = A + (long long)z * bA + (long long)kc * Kc;
  int rowStart = 0, Meff = M;
  if (offs) { rowStart = offs[z]; Meff = offs[z + 1] - rowStart; }
  int bx = blockIdx.x, by = blockIdx.y;
  if (XS) {
    int flat = bx + by * gridDim.x;
    int cpx = (gridDim.x * gridDim.y) >> 3;
    int s = (flat & 7) * cpx + (flat >> 3);
    bx = s % gridDim.x; by = s / gridDim.x;
  }
  int m0 = (SWAP ? by : bx) * 128;
  if (m0 >= Meff) return;
  int n0 = (SWAP ? bx : by) * 128;

  __shared__ __align__(16) char smem[65536];  // 2 x (16KB A + 16KB B)
  const ushort_t* Bp = (BSRC == 1)
      ? (const ushort_t*)Bv + (long long)z * bB + (long long)kc * Kc : nullptr;
  const float* Bf = (BSRC == 0)
      ? (const float*)Bv + (long long)z * bB + (long long)kc * Kc : nullptr;

  int tid = threadIdx.x, lane = tid & 63, wave = tid >> 6;
  int wr = (wave >> 1) * 64, wc = (wave & 1) * 64;
  int l15 = lane & 15, l4 = lane >> 4;

  f32x4 acc[4][4];
#pragma unroll
  for (int m = 0; m < 4; ++m)
#pragma unroll
    for (int n = 0; n < 4; ++n) acc[m][n] = (f32x4){0.f, 0.f, 0.f, 0.f};

  auto stageG = [&](int buf, int k0) {
    ushort_t* dA = (ushort_t*)smem + buf * 8192;
    ushort_t* dB = (ushort_t*)smem + 16384 + buf * 8192;
#pragma unroll
    for (int i = 0; i < 4; ++i) {
      int idx = i * 2048 + tid * 8;
      int row = idx >> 6, chk = (idx >> 3) & 7;
      int scol = ((chk ^ (row & 7)) << 3);
      int ra = m0 + row; if (ra > Meff - 1) ra = Meff - 1;
      gld16(Ap + (long long)(rowStart + ra) * lda + k0 + scol, &dA[idx]);
    }
    if (BSRC == 1) {
#pragma unroll
      for (int i = 0; i < 4; ++i) {
        int idx = i * 2048 + tid * 8;
        int row = idx >> 6, chk = (idx >> 3) & 7;
        int scol = ((chk ^ (row & 7)) << 3);
        int rb = n0 + row; if (rb > N - 1) rb = N - 1;
        gld16(Bp + (long long)rb * ldb + k0 + scol, &dB[idx]);
      }
    } else {
#pragma unroll
      for (int i = 0; i < 8; ++i) {
        int g = tid + i * 256;
        int r = g >> 4, c4 = (g & 15) * 4;
        int rb = n0 + r; if (rb > N - 1) rb = N - 1;
        float4 fv = *(const float4*)(Bf + (long long)rb * ldb + k0 + c4);
        s4v o; o[0] = (short)f2b(fv.x); o[1] = (short)f2b(fv.y);
        o[2] = (short)f2b(fv.z); o[3] = (short)f2b(fv.w);
        int dst = r * 64 + (((c4 >> 3) ^ (r & 7)) << 3) + (c4 & 7);
        *(s4v*)&dB[dst] = o;
      }
    }
  };

  int nIt = Kc >> 6;
  stageG(0, 0);
  for (int it = 0; it < nIt; ++it) {
    int cur = it & 1;
    __syncthreads();                       // tile 'it' landed; prev reads done
    if (it + 1 < nIt) stageG(cur ^ 1, (it + 1) << 6);
    ushort_t* As = (ushort_t*)smem + cur * 8192;
    ushort_t* Bs = (ushort_t*)smem + 16384 + cur * 8192;
#pragma unroll
    for (int kk = 0; kk < 64; kk += 32) {
      bf16x8 af[4], bfr[4];
#pragma unroll
      for (int m = 0; m < 4; ++m) {
        int r = wr + m * 16 + l15;
        af[m] = *(const bf16x8*)&As[r * 64 + ((((kk >> 3) + l4) ^ (r & 7)) << 3)];
      }
#pragma unroll
      for (int n = 0; n < 4; ++n) {
        int r = wc + n * 16 + l15;
        bfr[n] = *(const bf16x8*)&Bs[r * 64 + ((((kk >> 3) + l4) ^ (r & 7)) << 3)];
      }
#pragma unroll
      for (int m = 0; m < 4; ++m)
#pragma unroll
        for (int n = 0; n < 4; ++n)
          acc[m][n] = MFMA(af[m], bfr[n], acc[m][n], 0, 0, 0);
    }
  }
  __syncthreads();   // protect LDS before epilogue reuse

  if (EPI == 6 || EPI == 7) {
    float* fE = (float*)smem;
#pragma unroll
    for (int h2 = 0; h2 < 2; ++h2) {
      if ((wave >> 1) == h2) {
#pragma unroll
        for (int m = 0; m < 4; ++m)
#pragma unroll
          for (int n = 0; n < 4; ++n)
#pragma unroll
            for (int q = 0; q < 4; ++q)
              fE[(m * 16 + l4 * 4 + q) * 128 + wc + n * 16 + l15] = acc[m][n][q];
      }
      __syncthreads();
#pragma unroll
      for (int i = 0; i < 8; ++i) {
        int lin = tid + i * 256;
        int row = lin >> 5, c4 = (lin & 31) << 2;
        int gr = m0 + h2 * 64 + row;
        if (gr < Meff) {
          f32x4 v4 = *(const f32x4*)&fE[row * 128 + c4];
          long long crow = rowStart + gr;
          float* dst = (float*)Cv + (EPI == 7 ? (long long)kc * pC : 0LL)
                       + crow * ldc + n0 + c4;
          if (EPI == 6) __builtin_nontemporal_store(v4, (f32x4*)dst);
          else          *(f32x4*)dst = v4;
        }
      }
      __syncthreads();
    }
    return;
  }

#pragma unroll
  for (int m = 0; m < 4; ++m) {
#pragma unroll
    for (int n = 0; n < 4; ++n) {
      int c = n0 + wc + n * 16 + l15;
      if (c >= N) continue;
      float bv = (EPI == 2) ? bias[(long long)z * bBias + c] : 0.f;
#pragma unroll
      for (int q = 0; q < 4; ++q) {
        int rr = m0 + wr + m * 16 + l4 * 4 + q;
        if (rr >= Meff) continue;
        float v = acc[m][n][q];
        long long crow = rowStart + rr;
        if (EPI == 2)
          ((ushort_t*)Cv)[crow * ldc + (long long)z * bC + c] = f2b(geluf(v + bv));
      }
    }
  }
}

#define G16_ARGS const ushort_t* A, int lda, long long bA, const void* Bv, \
    int ldb, long long bB, void* Cv, int ldc, long long bC, long long pC, \
    int M, int N, int K, const float* bias, int bBias, const int* offs
#define G16_PASS A, lda, bA, Bv, ldb, bB, Cv, ldc, bC, pC, M, N, K, bias, bBias, offs

__global__ __launch_bounds__(256) void k_moe1   (G16_ARGS) { gemm16_body<2,1,1,1,0>(G16_PASS); }
__global__ __launch_bounds__(256) void k_moe2   (G16_ARGS) { gemm16_body<7,1,1,2,0>(G16_PASS); }
__global__ __launch_bounds__(256) void k_head_bf(G16_ARGS) { gemm16_body<6,1,0,1,1>(G16_PASS); }
__global__ __launch_bounds__(256) void k_head_f (G16_ARGS) { gemm16_body<6,0,0,1,1>(G16_PASS); }

// ---------------------------------------------------------------------------
__global__ __launch_bounds__(256)
void cvt_split2(const float* __restrict__ s0, ushort_t* __restrict__ dh0,
                ushort_t* __restrict__ dl0,
                const float* __restrict__ s1, ushort_t* __restrict__ dh1,
                ushort_t* __restrict__ dl1, int n4)
{
  const float* s = blockIdx.y ? s1 : s0;
  ushort_t* dh = blockIdx.y ? dh1 : dh0;
  ushort_t* dl = blockIdx.y ? dl1 : dl0;
  int i = blockIdx.x * blockDim.x + threadIdx.x;
  int stride = gridDim.x * blockDim.x;
  for (; i < n4; i += stride) {
    float4 f = ((const float4*)s)[i];
    s4v h, l; ushort_t hh, ll;
    split2(f.x, hh, ll); h[0] = (short)hh; l[0] = (short)ll;
    split2(f.y, hh, ll); h[1] = (short)hh; l[1] = (short)ll;
    split2(f.z, hh, ll); h[2] = (short)hh; l[2] = (short)ll;
    split2(f.w, hh, ll); h[3] = (short)hh; l[3] = (short)ll;
    ((s4v*)dh)[i] = h; ((s4v*)dl)[i] = l;
  }
}

__global__ __launch_bounds__(256)
void cvt_bf16(const float* __restrict__ s, ushort_t* __restrict__ d, int n4)
{
  int i = blockIdx.x * blockDim.x + threadIdx.x;
  int stride = gridDim.x * blockDim.x;
  for (; i < n4; i += stride) {
    float4 f = ((const float4*)s)[i];
    s4v o; o[0] = (short)f2b(f.x); o[1] = (short)f2b(f.y);
    o[2] = (short)f2b(f.z); o[3] = (short)f2b(f.w);
    ((s4v*)d)[i] = o;
  }
}

// paired bf16 convert (MoE w1 + w2 in one launch)
__global__ __launch_bounds__(256)
void cvt_bf16_2(const float* __restrict__ s0, ushort_t* __restrict__ d0,
                const float* __restrict__ s1, ushort_t* __restrict__ d1, int n4)
{
  const float* s = blockIdx.y ? s1 : s0;
  ushort_t* d = blockIdx.y ? d1 : d0;
  int i = blockIdx.x * blockDim.x + threadIdx.x;
  int stride = gridDim.x * blockDim.x;
  for (; i < n4; i += stride) {
    float4 f = ((const float4*)s)[i];
    s4v o; o[0] = (short)f2b(f.x); o[1] = (short)f2b(f.y);
    o[2] = (short)f2b(f.z); o[3] = (short)f2b(f.w);
    ((s4v*)d)[i] = o;
  }
}

__global__ __launch_bounds__(256)
void embed_kernel(const int* __restrict__ ids, const float* __restrict__ ew,
                  const float* __restrict__ pw, float* __restrict__ x,
                  int* __restrict__ counts)
{
  int srow = blockIdx.x, tid = threadIdx.x;
  if (srow == 0 && tid < 8) counts[tid] = 0;
  int id = ids[srow];
  const float4 e = *(const float4*)(ew + (long long)id * DM + tid * 4);
  const float4 p = *(const float4*)(pw + (long long)srow * DM + tid * 4);
  float4* xr = (float4*)(x + (long long)srow * DM) + tid;
  *xr = make_float4(e.x + p.x, e.y + p.y, e.z + p.z, e.w + p.w);
}

// Fused: x += sum(NP partial planes)+bias_pre (written back), then LayerNorm.
template<int MODE, int NP>
__global__ __launch_bounds__(256)
void ln_fused(float* __restrict__ x, const float* __restrict__ P, long long pC,
              const float* __restrict__ bias_pre,
              const float* __restrict__ g, const float* __restrict__ b,
              ushort_t* __restrict__ outH, ushort_t* __restrict__ outL)
{
  int row = blockIdx.x, tid = threadIdx.x;
  long long xo = (long long)row * DM + tid * 4;
  float4 v = *(const float4*)(x + xo);
  if (NP > 0) {
    float4 bp = *(const float4*)(bias_pre + tid * 4);
    float sx = bp.x, sy = bp.y, sz = bp.z, sw = bp.w;
#pragma unroll
    for (int p = 0; p < NP; ++p) {
      float4 pv = *(const float4*)(P + (long long)p * pC + xo);
      sx += pv.x; sy += pv.y; sz += pv.z; sw += pv.w;
    }
    v.x += sx; v.y += sy; v.z += sz; v.w += sw;
    *(float4*)(x + xo) = v;
  }
  __shared__ float sm1[4], sm2[4];
  float s = v.x + v.y + v.z + v.w;
  for (int o = 32; o > 0; o >>= 1) s += __shfl_down(s, o);
  if ((tid & 63) == 0) sm1[tid >> 6] = s;
  __syncthreads();
  float mean = (sm1[0] + sm1[1] + sm1[2] + sm1[3]) * (1.0f / DM);
  float d0 = v.x - mean, d1 = v.y - mean, d2 = v.z - mean, d3 = v.w - mean;
  float q = d0 * d0 + d1 * d1 + d2 * d2 + d3 * d3;
  for (int o = 32; o > 0; o >>= 1) q += __shfl_down(q, o);
  if ((tid & 63) == 0) sm2[tid >> 6] = q;
  __syncthreads();
  float var = (sm2[0] + sm2[1] + sm2[2] + sm2[3]) * (1.0f / DM);
  float rstd = rsqrtf(var + 1e-5f);
  float4 gv = ((const float4*)g)[tid];
  float4 bv = ((const float4*)b)[tid];
  float o0 = d0 * rstd * gv.x + bv.x, o1 = d1 * rstd * gv.y + bv.y;
  float o2 = d2 * rstd * gv.z + bv.z, o3 = d3 * rstd * gv.w + bv.w;
  long long base = (long long)row * DM + tid * 4;
  if (MODE == 0) {
    ushort_t hh, ll;
    split2(o0, hh, ll); outH[base + 0] = hh; outL[base + 0] = ll;
    split2(o1, hh, ll); outH[base + 1] = hh; outL[base + 1] = ll;
    split2(o2, hh, ll); outH[base + 2] = hh; outL[base + 2] = ll;
    split2(o3, hh, ll); outH[base + 3] = hh; outL[base + 3] = ll;
  } else {
    outH[base + 0] = f2b(o0); outH[base + 1] = f2b(o1);
    outH[base + 2] = f2b(o2); outH[base + 3] = f2b(o3);
  }
}

// Fused: x += sum(4 planes)+bias_pre; LN (f32); gate; top2; bf16 LN out.
__global__ __launch_bounds__(256)
void ln_gate_top2(float* __restrict__ x, const float* __restrict__ P,
                  long long pC, const float* __restrict__ bias_pre,
                  const float* __restrict__ g, const float* __restrict__ b,
                  const float* __restrict__ gw, const float* __restrict__ gb,
                  int* __restrict__ topi, float* __restrict__ topw,
                  int* __restrict__ counts, ushort_t* __restrict__ outH)
{
  int row = blockIdx.x, tid = threadIdx.x;
  long long xo = (long long)row * DM + tid * 4;
  float4 v = *(const float4*)(x + xo);
  {
    float4 bp = *(const float4*)(bias_pre + tid * 4);
    float sx = bp.x, sy = bp.y, sz = bp.z, sw = bp.w;
#pragma unroll
    for (int p = 0; p < 4; ++p) {
      float4 pv = *(const float4*)(P + (long long)p * pC + xo);
      sx += pv.x; sy += pv.y; sz += pv.z; sw += pv.w;
    }
    v.x += sx; v.y += sy; v.z += sz; v.w += sw;
    *(float4*)(x + xo) = v;
  }
  __shared__ float sm1[4], sm2[4];
  __shared__ float se[8][4];
  float s = v.x + v.y + v.z + v.w;
  for (int o = 32; o > 0; o >>= 1) s += __shfl_down(s, o);
  if ((tid & 63) == 0) sm1[tid >> 6] = s;
  __syncthreads();
  float mean = (sm1[0] + sm1[1] + sm1[2] + sm1[3]) * (1.0f / DM);
  float d0 = v.x - mean, d1 = v.y - mean, d2 = v.z - mean, d3 = v.w - mean;
  float q = d0 * d0 + d1 * d1 + d2 * d2 + d3 * d3;
  for (int o = 32; o > 0; o >>= 1) q += __shfl_down(q, o);
  if ((tid & 63) == 0) sm2[tid >> 6] = q;
  __syncthreads();
  float var = (sm2[0] + sm2[1] + sm2[2] + sm2[3]) * (1.0f / DM);
  float rstd = rsqrtf(var + 1e-5f);
  float4 gv = ((const float4*)g)[tid];
  float4 bv = ((const float4*)b)[tid];
  float h0 = d0 * rstd * gv.x + bv.x, h1 = d1 * rstd * gv.y + bv.y;
  float h2 = d2 * rstd * gv.z + bv.z, h3 = d3 * rstd * gv.w + bv.w;
  long long base = (long long)row * DM + tid * 4;
  outH[base + 0] = f2b(h0); outH[base + 1] = f2b(h1);
  outH[base + 2] = f2b(h2); outH[base + 3] = f2b(h3);
#pragma unroll
  for (int e = 0; e < 8; ++e) {
    float4 w = ((const float4*)(gw + (long long)e * DM))[tid];
    float p = h0 * w.x + h1 * w.y + h2 * w.z + h3 * w.w;
    for (int o = 32; o > 0; o >>= 1) p += __shfl_down(p, o);
    if ((tid & 63) == 0) se[e][tid >> 6] = p;
  }
  __syncthreads();
  if (tid == 0) {
    float sc[8];
#pragma unroll
    for (int e = 0; e < 8; ++e)
      sc[e] = se[e][0] + se[e][1] + se[e][2] + se[e][3] + gb[e];
    int i1 = 0; float m1 = sc[0];
    for (int e = 1; e < 8; ++e) if (sc[e] > m1) { m1 = sc[e]; i1 = e; }
    int i2 = -1; float m2 = -1e30f;
    for (int e = 0; e < 8; ++e) if (e != i1 && sc[e] > m2) { m2 = sc[e]; i2 = e; }
    float e2 = __expf(m2 - m1);
    float w1 = 1.f / (1.f + e2);
    topi[row * 2] = i1; topi[row * 2 + 1] = i2;
    topw[row * 2] = w1; topw[row * 2 + 1] = 1.f - w1;
    atomicAdd(&counts[i1], 1);
    atomicAdd(&counts[i2], 1);
  }
}

__global__ void moe_prefix(const int* __restrict__ counts, int* __restrict__ offs,
                           int* __restrict__ cursors)
{
  if (threadIdx.x == 0 && blockIdx.x == 0) {
    int a = 0;
    for (int e = 0; e < 8; ++e) { offs[e] = a; a += counts[e]; cursors[e] = 0; }
    offs[8] = a;
  }
}

__global__ __launch_bounds__(256)
void moe_gather(const ushort_t* __restrict__ hH, const int* __restrict__ topi,
                const float* __restrict__ topw, const int* __restrict__ offs,
                int* __restrict__ cursors, int* __restrict__ tokIdx,
                float* __restrict__ tokW, int* __restrict__ slotOf,
                ushort_t* __restrict__ Xg)
{
  int tok = blockIdx.x, tid = threadIdx.x;
  __shared__ int s0s, s1s;
  if (tid == 0) {
    int e0 = topi[tok * 2], e1 = topi[tok * 2 + 1];
    int s0 = offs[e0] + atomicAdd(&cursors[e0], 1);
    int s1 = offs[e1] + atomicAdd(&cursors[e1], 1);
    tokIdx[s0] = tok; tokW[s0] = topw[tok * 2];
    tokIdx[s1] = tok; tokW[s1] = topw[tok * 2 + 1];
    slotOf[tok * 2] = s0; slotOf[tok * 2 + 1] = s1;
    s0s = s0; s1s = s1;
  }
  __syncthreads();
  s4v v = ((const s4v*)(hH + (long long)tok * DM))[tid];
  ((s4v*)(Xg + (long long)s0s * DM))[tid] = v;
  ((s4v*)(Xg + (long long)s1s * DM))[tid] = v;
}

// Fused: x[tok] += MoE combine; then FINAL LayerNorm -> bf16 hfin
__global__ __launch_bounds__(256)
void moe_ln_final(const float* __restrict__ x, const float* __restrict__ eo,
                  long long pC, const int* __restrict__ slotOf,
                  const int* __restrict__ topi, const float* __restrict__ topw,
                  const float* __restrict__ b2, const float* __restrict__ g,
                  const float* __restrict__ b, ushort_t* __restrict__ outH)
{
  int tok = blockIdx.x, tid = threadIdx.x;
  int s0 = slotOf[tok * 2], s1 = slotOf[tok * 2 + 1];
  int e0 = topi[tok * 2], e1 = topi[tok * 2 + 1];
  float w0 = topw[tok * 2], w1 = topw[tok * 2 + 1];
  float4 a  = ((const float4*)(eo + (long long)s0 * DM))[tid];
  float4 a2 = ((const float4*)(eo + pC + (long long)s0 * DM))[tid];
  float4 bb1= ((const float4*)(eo + (long long)s1 * DM))[tid];
  float4 bb2= ((const float4*)(eo + pC + (long long)s1 * DM))[tid];
  float4 ba = ((const float4*)(b2 + (long long)e0 * DM))[tid];
  float4 bbb= ((const float4*)(b2 + (long long)e1 * DM))[tid];
  float4 v = ((const float4*)(x + (long long)tok * DM))[tid];
  v.x += w0 * (a.x + a2.x + ba.x) + w1 * (bb1.x + bb2.x + bbb.x);
  v.y += w0 * (a.y + a2.y + ba.y) + w1 * (bb1.y + bb2.y + bbb.y);
  v.z += w0 * (a.z + a2.z + ba.z) + w1 * (bb1.z + bb2.z + bbb.z);
  v.w += w0 * (a.w + a2.w + ba.w) + w1 * (bb1.w + bb2.w + bbb.w);
  __shared__ float sm1[4], sm2[4];
  float s = v.x + v.y + v.z + v.w;
  for (int o = 32; o > 0; o >>= 1) s += __shfl_down(s, o);
  if ((tid & 63) == 0) sm1[tid >> 6] = s;
  __syncthreads();
  float mean = (sm1[0] + sm1[1] + sm1[2] + sm1[3]) * (1.0f / DM);
  float d0 = v.x - mean, d1 = v.y - mean, d2 = v.z - mean, d3 = v.w - mean;
  float q = d0 * d0 + d1 * d1 + d2 * d2 + d3 * d3;
  for (int o = 32; o > 0; o >>= 1) q += __shfl_down(q, o);
  if ((tid & 63) == 0) sm2[tid >> 6] = q;
  __syncthreads();
  float var = (sm2[0] + sm2[1] + sm2[2] + sm2[3]) * (1.0f / DM);
  float rstd = rsqrtf(var + 1e-5f);
  float4 gv = ((const float4*)g)[tid];
  float4 bv = ((const float4*)b)[tid];
  long long base = (long long)tok * DM + tid * 4;
  outH[base + 0] = f2b(d0 * rstd * gv.x + bv.x);
  outH[base + 1] = f2b(d1 * rstd * gv.y + bv.y);
  outH[base + 2] = f2b(d2 * rstd * gv.z + bv.z);
  outH[base + 3] = f2b(d3 * rstd * gv.w + bv.w);
}

extern "C" void kernel_launch(void* const* d_in, const int* in_sizes, int n_in,
                              void* d_out, int out_size, void* d_ws, size_t ws_size,
                              hipStream_t stream)
{
  const int* ids = (const int*)d_in[0];
  const float* embed_w = (const float*)d_in[1];
  const float* pos_w   = (const float*)d_in[2];
  const float* ln1_g[2] = {(const float*)d_in[3],  (const float*)d_in[11]};
  const float* ln1_b[2] = {(const float*)d_in[4],  (const float*)d_in[12]};
  const float* in_w[2]  = {(const float*)d_in[5],  (const float*)d_in[13]};
  const float* in_b[2]  = {(const float*)d_in[6],  (const float*)d_in[14]};
  const float* out_w[2] = {(const float*)d_in[7],  (const float*)d_in[15]};
  const float* out_b[2] = {(const float*)d_in[8],  (const float*)d_in[16]};
  const float* ln2_g[2] = {(const float*)d_in[9],  (const float*)d_in[17]};
  const float* ln2_b[2] = {(const float*)d_in[10], (const float*)d_in[18]};
  const float* ffn_w1 = (const float*)d_in[19];
  const float* ffn_b1 = (const float*)d_in[20];
  const float* ffn_w2 = (const float*)d_in[21];
  const float* ffn_b2 = (const float*)d_in[22];
  const float* gate_w = (const float*)d_in[23];
  const float* gate_b = (const float*)d_in[24];
  const float* moe_w1 = (const float*)d_in[25];
  const float* moe_b1 = (const float*)d_in[26];
  const float* moe_w2 = (const float*)d_in[27];
  const float* moe_b2 = (const float*)d_in[28];
  const float* norm_g = (const float*)d_in[29];
  const float* norm_b = (const float*)d_in[30];
  const float* head_w = (const float*)d_in[31];

  char* ob = (char*)d_out;
  size_t off = 0;
  auto alloc = [&](size_t bytes) {
    char* p = ob + off;
    off = (off + bytes + 255) & ~(size_t)255;
    return p;
  };
  float*    x      = (float*)alloc((size_t)SQ * DM * 4);
  ushort_t* hbufH  = (ushort_t*)alloc((size_t)SQ * DM * 2);
  ushort_t* hbufL  = (ushort_t*)alloc((size_t)SQ * DM * 2);
  ushort_t* qkvH   = (ushort_t*)alloc((size_t)SQ * 3 * DM * 2);   // ┐
  ushort_t* qkvL   = (ushort_t*)alloc((size_t)SQ * 3 * DM * 2);   // │ w2b
  ushort_t* VtH    = (ushort_t*)alloc((size_t)NH * HDIM * SQ * 2);// │ 64MiB
  ushort_t* VtL    = (ushort_t*)alloc((size_t)NH * HDIM * SQ * 2);// │
  char*     resv   = (char*)alloc((size_t)32 << 20);              // ┘ filler
  ushort_t* attnH  = (ushort_t*)alloc((size_t)SQ * DM * 2);
  ushort_t* attnL  = (ushort_t*)alloc((size_t)SQ * DM * 2);
  ushort_t* Xg     = (ushort_t*)alloc((size_t)2 * SQ * DM * 2);
  int*      topi   = (int*)alloc(SQ * 2 * 4);
  float*    topw   = (float*)alloc(SQ * 2 * 4);
  int*      tokIdx = (int*)alloc(2 * SQ * 4);
  float*    tokW   = (float*)alloc(2 * SQ * 4);
  int*      slotOf = (int*)alloc(2 * SQ * 4);
  int*      counts = (int*)alloc(256);
  int*      offsb  = (int*)alloc(256);
  int*      cursors= (int*)alloc(256);
  ushort_t* ffnH   = (ushort_t*)alloc((size_t)SQ * FFD * 2);      // ┐ moehid
  ushort_t* ffnL   = (ushort_t*)alloc((size_t)SQ * FFD * 2);      // ┘ 32MiB
  float*    eo     = (float*)alloc((size_t)2 * 2 * SQ * DM * 4);  // 32MiB (also KS partials)
  ushort_t* inwH[2], *inwL[2], *outwH[2], *outwL[2];
  ushort_t* wsplit0 = (ushort_t*)alloc(0);
  inwH[0]  = (ushort_t*)alloc((size_t)3 * DM * DM * 2);
  inwL[0]  = (ushort_t*)alloc((size_t)3 * DM * DM * 2);
  inwH[1]  = (ushort_t*)alloc((size_t)3 * DM * DM * 2);
  inwL[1]  = (ushort_t*)alloc((size_t)3 * DM * DM * 2);
  outwH[0] = (ushort_t*)alloc((size_t)DM * DM * 2);
  outwL[0] = (ushort_t*)alloc((size_t)DM * DM * 2);
  outwH[1] = (ushort_t*)alloc((size_t)DM * DM * 2);
  outwL[1] = (ushort_t*)alloc((size_t)DM * DM * 2);
  ushort_t* f1H = (ushort_t*)alloc((size_t)FFD * DM * 2);
  ushort_t* f1L = (ushort_t*)alloc((size_t)FFD * DM * 2);
  ushort_t* f2H = (ushort_t*)alloc((size_t)DM * FFD * 2);
  ushort_t* f2L = (ushort_t*)alloc((size_t)DM * FFD * 2);
  ushort_t* moe_w1b = wsplit0;            // 64 MiB over weight planes
  ushort_t* moe_w2b = qkvH;               // 64 MiB over qkv+Vt+resv
  ushort_t* moehid  = ffnH;               // 32 MiB over ffn planes
  float*    pp      = eo;                 // KS partial planes
  const long long eoPC = (long long)2 * SQ * DM;
  const long long ppPC = (long long)SQ * DM;
  ushort_t* hfin    = (ushort_t*)d_ws;
  bool wsBig = ws_size >= ((size_t)70 << 20);
  ushort_t* head_wb = (ushort_t*)((char*)d_ws + ((size_t)4 << 20));
  (void)resv;

  embed_kernel<<<SQ, 256, 0, stream>>>(ids, embed_w, pos_w, x, counts);
  cvt_split2<<<dim3(512, 2), 256, 0, stream>>>(
      in_w[0], inwH[0], inwL[0], in_w[1], inwH[1], inwL[1], 3 * DM * DM / 4);
  cvt_split2<<<dim3(512, 2), 256, 0, stream>>>(
      out_w[0], outwH[0], outwL[0], out_w[1], outwH[1], outwL[1], DM * DM / 4);
  cvt_split2<<<dim3(512, 2), 256, 0, stream>>>(
      ffn_w1, f1H, f1L, ffn_w2, f2H, f2L, FFD * DM / 4);
  if (wsBig)
    cvt_bf16<<<1024, 256, 0, stream>>>(head_w, head_wb, NVOC * DM / 4);

  // ---- Layer 0 ----
  ln_fused<0, 0><<<SQ, 256, 0, stream>>>(x, nullptr, 0, nullptr,
                                         ln1_g[0], ln1_b[0], hbufH, hbufL);
  k_qkv<<<dim3(16, 24, 1), 256, 0, stream>>>(
      hbufH, hbufL, DM, 0, inwH[0], inwL[0], DM, 0,
      nullptr, qkvH, qkvL, 3 * DM, 0, 0,
      SQ, 3 * DM, DM, in_b[0], 1.f, VtH, VtL);
  k_attn<<<dim3(SQ / 64, NH), 256, 0, stream>>>(qkvH, qkvL, VtH, VtL,
                                                attnH, attnL);
  k_outp<<<dim3(16, 16, 4), 256, 0, stream>>>(
      attnH, attnL, DM, 0, outwH[0], outwL[0], DM, 0,
      pp, nullptr, nullptr, DM, 0, ppPC,
      SQ, DM, DM / 4, nullptr, 1.f, nullptr, nullptr);
  ln_fused<0, 4><<<SQ, 256, 0, stream>>>(x, pp, ppPC, out_b[0],
                                         ln2_g[0], ln2_b[0], hbufH, hbufL);
  k_ffn1<<<dim3(16, 32, 1), 256, 0, stream>>>(
      hbufH, hbufL, DM, 0, f1H, f1L, DM, 0,
      nullptr, ffnH, ffnL, FFD, 0, 0,
      SQ, FFD, DM, ffn_b1, 1.f, nullptr, nullptr);
  k_ffn2<<<dim3(16, 16, 2), 256, 0, stream>>>(
      ffnH, ffnL, FFD, 0, f2H, f2L, FFD, 0,
      pp, nullptr, nullptr, DM, 0, ppPC,
      SQ, DM, FFD / 2, nullptr, 1.f, nullptr, nullptr);
  // ---- Layer 1 ----
  ln_fused<0, 2><<<SQ, 256, 0, stream>>>(x, pp, ppPC, ffn_b2,
                                         ln1_g[1], ln1_b[1], hbufH, hbufL);
  k_qkv<<<dim3(16, 24, 1), 256, 0, stream>>>(
      hbufH, hbufL, DM, 0, inwH[1], inwL[1], DM, 0,
      nullptr, qkvH, qkvL, 3 * DM, 0, 0,
      SQ, 3 * DM, DM, in_b[1], 1.f, VtH, VtL);
  k_attn<<<dim3(SQ / 64, NH), 256, 0, stream>>>(qkvH, qkvL, VtH, VtL,
                                                attnH, attnL);
  k_outp<<<dim3(16, 16, 4), 256, 0, stream>>>(
      attnH, attnL, DM, 0, outwH[1], outwL[1], DM, 0,
      pp, nullptr, nullptr, DM, 0, ppPC,
      SQ, DM, DM / 4, nullptr, 1.f, nullptr, nullptr);
  // qkv/Vt and weight planes dead -> MoE weight conversion (single launch)
  cvt_bf16_2<<<dim3(2048, 2), 256, 0, stream>>>(
      moe_w1, moe_w1b, moe_w2, moe_w2b, 8 * FFD * DM / 4);
  ln_gate_top2<<<SQ, 256, 0, stream>>>(x, pp, ppPC, out_b[1],
                                       ln2_g[1], ln2_b[1], gate_w, gate_b,
                                       topi, topw, counts, hbufH);
  moe_prefix<<<1, 64, 0, stream>>>(counts, offsb, cursors);
  moe_gather<<<SQ, 256, 0, stream>>>(hbufH, topi, topw, offsb, cursors,
                                     tokIdx, tokW, slotOf, Xg);
  k_moe1<<<dim3(32, 16, 8), 256, 0, stream>>>(
      Xg, DM, 0, moe_w1b, DM, (long long)FFD * DM,
      moehid, FFD, 0, 0, SQ, FFD, DM, moe_b1, FFD, offsb);
  k_moe2<<<dim3(8, 16, 16), 256, 0, stream>>>(
      moehid, FFD, 0, moe_w2b, FFD, (long long)DM * FFD,
      eo, DM, 0, eoPC, SQ, DM, FFD, nullptr, 0, offsb);
  moe_ln_final<<<SQ, 256, 0, stream>>>(x, eo, eoPC, slotOf, topi, topw,
                                       moe_b2, norm_g, norm_b, hfin);
  if (wsBig)
    k_head_bf<<<dim3(16, 250, 1), 256, 0, stream>>>(
        hfin, DM, 0, head_wb, DM, 0, d_out, NVOC, 0, 0,
        SQ, NVOC, DM, nullptr, 0, nullptr);
  else
    k_head_f<<<dim3(16, 250, 1), 256, 0, stream>>>(
        hfin, DM, 0, head_w, DM, 0, d_out, NVOC, 0, 0,
        SQ, NVOC, DM, nullptr, 0, nullptr);
}

// Round 14
// 1151.997 us; speedup vs baseline: 1.9369x; 1.0057x over previous
//
#include <hip/hip_runtime.h>
#include <hip/hip_bf16.h>
#include <math.h>

typedef unsigned short ushort_t;
typedef __attribute__((ext_vector_type(8))) __bf16 bf16x8;
typedef __attribute__((ext_vector_type(4))) float f32x4;
typedef __attribute__((ext_vector_type(8))) short s8v;
typedef __attribute__((ext_vector_type(4))) short s4v;

#define SQ 2048
#define DM 1024
#define NH 16
#define HDIM 64
#define FFD 4096
#define NVOC 32000

__device__ inline float b2f(unsigned short u) {
  union { unsigned int i; float f; } x; x.i = ((unsigned int)u) << 16; return x.f;
}
__device__ inline unsigned short f2b(float f) {
  __hip_bfloat16 h = __float2bfloat16(f);
  return *reinterpret_cast<unsigned short*>(&h);
}
__device__ inline void split2(float x, ushort_t& h, ushort_t& l) {
  h = f2b(x);
  l = f2b(x - b2f(h));
}
__device__ inline float geluf(float v) {
  return 0.5f * v * (1.0f + erff(v * 0.70710678118654752f));
}
__device__ __forceinline__ void gld16(const void* g, void* l) {
  __builtin_amdgcn_global_load_lds(
      (const __attribute__((address_space(1))) void*)g,
      (__attribute__((address_space(3))) void*)l, 16, 0, 0);
}
#define MFMA __builtin_amdgcn_mfma_f32_16x16x32_bf16

// ---------------------------------------------------------------------------
// Split GEMM engine (pre-gate math), 2-phase double-buffered:
// per 32-K step: barrier -> issue next step's gld16 (4 planes) -> MFMA current.
// EPI: 2 f32 partial store (kc*pC), 4 gelu+bias split-store,
//      5 split-store+bias with V-region (n0>=2048) written TRANSPOSED to TH/TL.
// ---------------------------------------------------------------------------
template<int EPI, int NT, int KS>
__device__ __forceinline__ void gemmsp_body(
    const ushort_t* __restrict__ AH, const ushort_t* __restrict__ AL,
    int lda, long long bA,
    const ushort_t* __restrict__ BH, const ushort_t* __restrict__ BL,
    int ldb, long long bB,
    float* __restrict__ C, ushort_t* __restrict__ CH, ushort_t* __restrict__ CL,
    int ldc, long long bC, long long pC,
    int M, int N, int K, const float* __restrict__ bias, float alpha,
    ushort_t* __restrict__ TH, ushort_t* __restrict__ TL)
{
  int z = blockIdx.z, h = z / KS, kc = z % KS;
  const ushort_t* AHp = AH + (long long)h * bA + (long long)kc * K;
  const ushort_t* ALp = AL + (long long)h * bA + (long long)kc * K;
  const ushort_t* BHp = BH + (long long)h * bB + (long long)kc * K;
  const ushort_t* BLp = BL + (long long)h * bB + (long long)kc * K;
  int m0 = blockIdx.x * 128, n0 = blockIdx.y * NT;
  const int NF = NT / 32;

  __shared__ __align__(16) ushort_t sAH[2][128 * 32], sAL[2][128 * 32];
  __shared__ __align__(16) ushort_t sBH[2][NT * 32],  sBL[2][NT * 32];

  int tid = threadIdx.x, lane = tid & 63, wave = tid >> 6;
  int wr = (wave >> 1) * 64, wc = (wave & 1) * (NT >> 1);
  int l15 = lane & 15, l4 = lane >> 4;

  f32x4 acc[4][NF];
#pragma unroll
  for (int m = 0; m < 4; ++m)
#pragma unroll
    for (int n = 0; n < NF; ++n) acc[m][n] = (f32x4){0.f, 0.f, 0.f, 0.f};

  auto stageG = [&](int buf, int k0) {
#pragma unroll
    for (int i = 0; i < 2; ++i) {
      int fi = i * 2048 + tid * 8;
      int r = fi >> 5, chk = (fi >> 3) & 3;
      int scol = ((chk ^ ((r >> 1) & 3)) << 3);
      int ra = m0 + r; if (ra > M - 1) ra = M - 1;
      long long go = (long long)ra * lda + k0 + scol;
      gld16(AHp + go, &sAH[buf][fi]);
      gld16(ALp + go, &sAL[buf][fi]);
    }
#pragma unroll
    for (int i = 0; i < NT / 64; ++i) {
      int fi = i * 2048 + tid * 8;
      int r = fi >> 5, chk = (fi >> 3) & 3;
      int scol = ((chk ^ ((r >> 1) & 3)) << 3);
      int rb = n0 + r; if (rb > N - 1) rb = N - 1;
      long long go = (long long)rb * ldb + k0 + scol;
      gld16(BHp + go, &sBH[buf][fi]);
      gld16(BLp + go, &sBL[buf][fi]);
    }
  };

  int nIt = K >> 5;
  stageG(0, 0);
  for (int it = 0; it < nIt; ++it) {
    int cur = it & 1;
    __syncthreads();                      // tile 'it' landed; prev reads done
    if (it + 1 < nIt) stageG(cur ^ 1, (it + 1) << 5);
    bf16x8 ah[4], al[4], bh[NF], bl[NF];
#pragma unroll
    for (int m = 0; m < 4; ++m) {
      int r = wr + m * 16 + l15;
      int o = r * 32 + ((l4 ^ ((r >> 1) & 3)) << 3);
      ah[m] = *(const bf16x8*)&sAH[cur][o];
      al[m] = *(const bf16x8*)&sAL[cur][o];
    }
#pragma unroll
    for (int n = 0; n < NF; ++n) {
      int r = wc + n * 16 + l15;
      int o = r * 32 + ((l4 ^ ((r >> 1) & 3)) << 3);
      bh[n] = *(const bf16x8*)&sBH[cur][o];
      bl[n] = *(const bf16x8*)&sBL[cur][o];
    }
#pragma unroll
    for (int m = 0; m < 4; ++m)
#pragma unroll
      for (int n = 0; n < NF; ++n) {
        acc[m][n] = MFMA(ah[m], bh[n], acc[m][n], 0, 0, 0);
        acc[m][n] = MFMA(al[m], bh[n], acc[m][n], 0, 0, 0);
        acc[m][n] = MFMA(ah[m], bl[n], acc[m][n], 0, 0, 0);
      }
  }

  if (EPI == 5 && n0 >= 2 * DM) {
#pragma unroll
    for (int m = 0; m < 4; ++m) {
      int rbase = m0 + wr + m * 16 + l4 * 4;
#pragma unroll
      for (int n = 0; n < NF; ++n) {
        int c = n0 + wc + n * 16 + l15;
        int d = c - 2 * DM;
        float bv = bias[c];
        s4v hv, lv;
#pragma unroll
        for (int q = 0; q < 4; ++q) {
          ushort_t hh, ll; split2(acc[m][n][q] + bv, hh, ll);
          hv[q] = (short)hh; lv[q] = (short)ll;
        }
        *(s4v*)&TH[(long long)d * SQ + rbase] = hv;
        *(s4v*)&TL[(long long)d * SQ + rbase] = lv;
      }
    }
    return;
  }

#pragma unroll
  for (int m = 0; m < 4; ++m) {
#pragma unroll
    for (int n = 0; n < NF; ++n) {
      int c = n0 + wc + n * 16 + l15;
      if (c >= N) continue;
      float bv = (EPI == 4 || EPI == 5) ? bias[c] : 0.f;
#pragma unroll
      for (int q = 0; q < 4; ++q) {
        int rr = m0 + wr + m * 16 + l4 * 4 + q;
        if (rr >= M) continue;
        float v = acc[m][n][q];
        if (EPI == 5) {
          ushort_t hh, ll; split2(v + bv, hh, ll);
          long long o = (long long)rr * ldc + c; CH[o] = hh; CL[o] = ll;
        } else if (EPI == 2) {
          C[(long long)kc * pC + (long long)rr * ldc + (long long)h * bC + c] = v;
        } else if (EPI == 4) {
          ushort_t hh, ll; split2(geluf(v + bv), hh, ll);
          long long o = (long long)rr * ldc + c; CH[o] = hh; CL[o] = ll;
        }
      }
    }
  }
}

#define SP_ARGS const ushort_t* AH, const ushort_t* AL, int lda, long long bA, \
    const ushort_t* BH, const ushort_t* BL, int ldb, long long bB, \
    float* C, ushort_t* CH, ushort_t* CL, int ldc, long long bC, long long pC, \
    int M, int N, int K, const float* bias, float alpha, \
    ushort_t* TH, ushort_t* TL
#define SP_PASS AH, AL, lda, bA, BH, BL, ldb, bB, C, CH, CL, ldc, bC, pC, M, N, K, bias, alpha, TH, TL

__global__ __launch_bounds__(256) void k_qkv (SP_ARGS) { gemmsp_body<5,128,1>(SP_PASS); }
__global__ __launch_bounds__(256) void k_outp(SP_ARGS) { gemmsp_body<2, 64,4>(SP_PASS); }
__global__ __launch_bounds__(256) void k_ffn1(SP_ARGS) { gemmsp_body<4,128,1>(SP_PASS); }
__global__ __launch_bounds__(256) void k_ffn2(SP_ARGS) { gemmsp_body<2, 64,2>(SP_PASS); }

// ---------------------------------------------------------------------------
// Fused flash attention, split-f32 precision. Grid (32,16).
// ---------------------------------------------------------------------------
__global__ __launch_bounds__(256)
void k_attn(const ushort_t* __restrict__ qkvH, const ushort_t* __restrict__ qkvL,
            const ushort_t* __restrict__ VtH, const ushort_t* __restrict__ VtL,
            ushort_t* __restrict__ aH, ushort_t* __restrict__ aL)
{
  int f = blockIdx.x + blockIdx.y * gridDim.x;
  int logical = (f & 7) * 64 + (f >> 3);
  int q0 = (logical & 31) * 64;
  int h  = logical >> 5;

  __shared__ __align__(16) ushort_t sKH[4096], sKL[4096];
  __shared__ __align__(16) ushort_t sVH[4096], sVL[4096];
  __shared__ __align__(16) ushort_t sPH[4096], sPL[4096];

  int tid = threadIdx.x, lane = tid & 63, wave = tid >> 6;
  int l15 = lane & 15, l4 = lane >> 4;

  bf16x8 qh[2], ql[2];
  {
    long long base = (long long)(q0 + wave * 16 + l15) * (3 * DM) + h * 64 + l4 * 8;
    qh[0] = *(const bf16x8*)(qkvH + base);
    qh[1] = *(const bf16x8*)(qkvH + base + 32);
    ql[0] = *(const bf16x8*)(qkvL + base);
    ql[1] = *(const bf16x8*)(qkvL + base + 32);
  }

  float mrow[4], lrow[4];
  f32x4 Oacc[4];
#pragma unroll
  for (int r = 0; r < 4; ++r) { mrow[r] = -1e30f; lrow[r] = 0.f; }
#pragma unroll
  for (int n = 0; n < 4; ++n) Oacc[n] = (f32x4){0.f, 0.f, 0.f, 0.f};

  for (int kt = 0; kt < SQ / 64; ++kt) {
#pragma unroll
    for (int i = 0; i < 2; ++i) {
      int idx = i * 2048 + tid * 8;
      int row = idx >> 6, chk = (idx >> 3) & 7;
      int scol = ((chk ^ (row & 7)) << 3);
      long long gk = (long long)(kt * 64 + row) * (3 * DM) + DM + h * 64 + scol;
      long long gv = (long long)(h * 64 + row) * SQ + kt * 64 + scol;
      gld16(qkvH + gk, &sKH[idx]);
      gld16(qkvL + gk, &sKL[idx]);
      gld16(VtH + gv, &sVH[idx]);
      gld16(VtL + gv, &sVL[idx]);
    }
    __syncthreads();

    f32x4 S[4];
#pragma unroll
    for (int n = 0; n < 4; ++n) S[n] = (f32x4){0.f, 0.f, 0.f, 0.f};
#pragma unroll
    for (int kk = 0; kk < 64; kk += 32) {
      int kkI = kk >> 5;
      bf16x8 qhf = qh[kkI], qlf = ql[kkI];
#pragma unroll
      for (int n = 0; n < 4; ++n) {
        int br = n * 16 + l15;
        int bo = br * 64 + ((((kk >> 3) + l4) ^ (br & 7)) << 3);
        bf16x8 kh = *(const bf16x8*)&sKH[bo];
        bf16x8 kl = *(const bf16x8*)&sKL[bo];
        S[n] = MFMA(qhf, kh, S[n], 0, 0, 0);
        S[n] = MFMA(qlf, kh, S[n], 0, 0, 0);
        S[n] = MFMA(qhf, kl, S[n], 0, 0, 0);
      }
    }
    float tm[4], ts[4];
#pragma unroll
    for (int r = 0; r < 4; ++r) {
#pragma unroll
      for (int n = 0; n < 4; ++n) S[n][r] *= 0.125f;
      tm[r] = fmaxf(fmaxf(S[0][r], S[1][r]), fmaxf(S[2][r], S[3][r]));
    }
#pragma unroll
    for (int mk = 1; mk <= 8; mk <<= 1)
#pragma unroll
      for (int r = 0; r < 4; ++r) tm[r] = fmaxf(tm[r], __shfl_xor(tm[r], mk));
#pragma unroll
    for (int r = 0; r < 4; ++r) {
      float mn = fmaxf(mrow[r], tm[r]);
      float corr = __expf(mrow[r] - mn);
      mrow[r] = mn;
      float s = 0.f;
#pragma unroll
      for (int n = 0; n < 4; ++n) { S[n][r] = __expf(S[n][r] - mn); s += S[n][r]; }
      ts[r] = s;
      lrow[r] *= corr;
#pragma unroll
      for (int n = 0; n < 4; ++n) Oacc[n][r] *= corr;
    }
#pragma unroll
    for (int mk = 1; mk <= 8; mk <<= 1)
#pragma unroll
      for (int r = 0; r < 4; ++r) ts[r] += __shfl_xor(ts[r], mk);
#pragma unroll
    for (int r = 0; r < 4; ++r) lrow[r] += ts[r];

    {
      ushort_t* pH = &sPH[wave * 1024];
      ushort_t* pL = &sPL[wave * 1024];
#pragma unroll
      for (int n = 0; n < 4; ++n)
#pragma unroll
        for (int r = 0; r < 4; ++r) {
          int row = l4 * 4 + r, col = n * 16 + l15;
          int ad = row * 64 + (((col >> 3) ^ (row & 7)) << 3) + (col & 7);
          ushort_t hh, ll; split2(S[n][r], hh, ll);
          pH[ad] = hh; pL[ad] = ll;
        }
    }
    __syncthreads();
#pragma unroll
    for (int kk = 0; kk < 64; kk += 32) {
      int ao = wave * 1024 + l15 * 64 + ((((kk >> 3) + l4) ^ (l15 & 7)) << 3);
      bf16x8 ph = *(const bf16x8*)&sPH[ao];
      bf16x8 pl = *(const bf16x8*)&sPL[ao];
#pragma unroll
      for (int n = 0; n < 4; ++n) {
        int br = n * 16 + l15;
        int bo = br * 64 + ((((kk >> 3) + l4) ^ (br & 7)) << 3);
        bf16x8 vh = *(const bf16x8*)&sVH[bo];
        bf16x8 vl = *(const bf16x8*)&sVL[bo];
        Oacc[n] = MFMA(ph, vh, Oacc[n], 0, 0, 0);
        Oacc[n] = MFMA(pl, vh, Oacc[n], 0, 0, 0);
        Oacc[n] = MFMA(ph, vl, Oacc[n], 0, 0, 0);
      }
    }
    __syncthreads();
  }

#pragma unroll
  for (int n = 0; n < 4; ++n)
#pragma unroll
    for (int r = 0; r < 4; ++r) {
      int q = q0 + wave * 16 + l4 * 4 + r;
      int d = h * 64 + n * 16 + l15;
      float val = Oacc[n][r] / lrow[r];
      ushort_t hh, ll; split2(val, hh, ll);
      long long o = (long long)q * DM + d;
      aH[o] = hh; aL[o] = ll;
    }
}

// ---------------------------------------------------------------------------
// bf16 GEMM engine (post-gate), 2-phase double-buffered.
// ---------------------------------------------------------------------------
template<int EPI, int BSRC, int SWAP, int KS, int XS>
__device__ __forceinline__ void gemm16_body(
    const ushort_t* __restrict__ A, int lda, long long bA,
    const void* __restrict__ Bv, int ldb, long long bB,
    void* __restrict__ Cv, int ldc, long long bC, long long pC,
    int M, int N, int K, const float* __restrict__ bias, int bBias,
    const int* __restrict__ offs)
{
  int bz = blockIdx.z;
  int z = bz / KS, kc = bz % KS;
  int Kc = K / KS;
  const ushort_t* Ap = A + (long long)z * bA + (long long)kc * Kc;
  int rowStart = 0, Meff = M;
  if (offs) { rowStart = offs[z]; Meff = offs[z + 1] - rowStart; }
  int bx = blockIdx.x, by = blockIdx.y;
  if (XS) {
    int flat = bx + by * gridDim.x;
    int cpx = (gridDim.x * gridDim.y) >> 3;
    int s = (flat & 7) * cpx + (flat >> 3);
    bx = s % gridDim.x; by = s / gridDim.x;
  }
  int m0 = (SWAP ? by : bx) * 128;
  if (m0 >= Meff) return;
  int n0 = (SWAP ? bx : by) * 128;

  __shared__ __align__(16) char smem[65536];  // 2 x (16KB A + 16KB B)
  const ushort_t* Bp = (BSRC == 1)
      ? (const ushort_t*)Bv + (long long)z * bB + (long long)kc * Kc : nullptr;
  const float* Bf = (BSRC == 0)
      ? (const float*)Bv + (long long)z * bB + (long long)kc * Kc : nullptr;

  int tid = threadIdx.x, lane = tid & 63, wave = tid >> 6;
  int wr = (wave >> 1) * 64, wc = (wave & 1) * 64;
  int l15 = lane & 15, l4 = lane >> 4;

  f32x4 acc[4][4];
#pragma unroll
  for (int m = 0; m < 4; ++m)
#pragma unroll
    for (int n = 0; n < 4; ++n) acc[m][n] = (f32x4){0.f, 0.f, 0.f, 0.f};

  auto stageG = [&](int buf, int k0) {
    ushort_t* dA = (ushort_t*)smem + buf * 8192;
    ushort_t* dB = (ushort_t*)smem + 16384 + buf * 8192;
#pragma unroll
    for (int i = 0; i < 4; ++i) {
      int idx = i * 2048 + tid * 8;
      int row = idx >> 6, chk = (idx >> 3) & 7;
      int scol = ((chk ^ (row & 7)) << 3);
      int ra = m0 + row; if (ra > Meff - 1) ra = Meff - 1;
      gld16(Ap + (long long)(rowStart + ra) * lda + k0 + scol, &dA[idx]);
    }
    if (BSRC == 1) {
#pragma unroll
      for (int i = 0; i < 4; ++i) {
        int idx = i * 2048 + tid * 8;
        int row = idx >> 6, chk = (idx >> 3) & 7;
        int scol = ((chk ^ (row & 7)) << 3);
        int rb = n0 + row; if (rb > N - 1) rb = N - 1;
        gld16(Bp + (long long)rb * ldb + k0 + scol, &dB[idx]);
      }
    } else {
#pragma unroll
      for (int i = 0; i < 8; ++i) {
        int g = tid + i * 256;
        int r = g >> 4, c4 = (g & 15) * 4;
        int rb = n0 + r; if (rb > N - 1) rb = N - 1;
        float4 fv = *(const float4*)(Bf + (long long)rb * ldb + k0 + c4);
        s4v o; o[0] = (short)f2b(fv.x); o[1] = (short)f2b(fv.y);
        o[2] = (short)f2b(fv.z); o[3] = (short)f2b(fv.w);
        int dst = r * 64 + (((c4 >> 3) ^ (r & 7)) << 3) + (c4 & 7);
        *(s4v*)&dB[dst] = o;
      }
    }
  };

  int nIt = Kc >> 6;
  stageG(0, 0);
  for (int it = 0; it < nIt; ++it) {
    int cur = it & 1;
    __syncthreads();
    if (it + 1 < nIt) stageG(cur ^ 1, (it + 1) << 6);
    ushort_t* As = (ushort_t*)smem + cur * 8192;
    ushort_t* Bs = (ushort_t*)smem + 16384 + cur * 8192;
#pragma unroll
    for (int kk = 0; kk < 64; kk += 32) {
      bf16x8 af[4], bfr[4];
#pragma unroll
      for (int m = 0; m < 4; ++m) {
        int r = wr + m * 16 + l15;
        af[m] = *(const bf16x8*)&As[r * 64 + ((((kk >> 3) + l4) ^ (r & 7)) << 3)];
      }
#pragma unroll
      for (int n = 0; n < 4; ++n) {
        int r = wc + n * 16 + l15;
        bfr[n] = *(const bf16x8*)&Bs[r * 64 + ((((kk >> 3) + l4) ^ (r & 7)) << 3)];
      }
#pragma unroll
      for (int m = 0; m < 4; ++m)
#pragma unroll
        for (int n = 0; n < 4; ++n)
          acc[m][n] = MFMA(af[m], bfr[n], acc[m][n], 0, 0, 0);
    }
  }
  __syncthreads();   // protect LDS before epilogue reuse

  if (EPI == 6 || EPI == 7) {
    float* fE = (float*)smem;
#pragma unroll
    for (int h2 = 0; h2 < 2; ++h2) {
      if ((wave >> 1) == h2) {
#pragma unroll
        for (int m = 0; m < 4; ++m)
#pragma unroll
          for (int n = 0; n < 4; ++n)
#pragma unroll
            for (int q = 0; q < 4; ++q)
              fE[(m * 16 + l4 * 4 + q) * 128 + wc + n * 16 + l15] = acc[m][n][q];
      }
      __syncthreads();
#pragma unroll
      for (int i = 0; i < 8; ++i) {
        int lin = tid + i * 256;
        int row = lin >> 5, c4 = (lin & 31) << 2;
        int gr = m0 + h2 * 64 + row;
        if (gr < Meff) {
          f32x4 v4 = *(const f32x4*)&fE[row * 128 + c4];
          long long crow = rowStart + gr;
          float* dst = (float*)Cv + (EPI == 7 ? (long long)kc * pC : 0LL)
                       + crow * ldc + n0 + c4;
          if (EPI == 6) __builtin_nontemporal_store(v4, (f32x4*)dst);
          else          *(f32x4*)dst = v4;
        }
      }
      __syncthreads();
    }
    return;
  }

#pragma unroll
  for (int m = 0; m < 4; ++m) {
#pragma unroll
    for (int n = 0; n < 4; ++n) {
      int c = n0 + wc + n * 16 + l15;
      if (c >= N) continue;
      float bv = (EPI == 2) ? bias[(long long)z * bBias + c] : 0.f;
#pragma unroll
      for (int q = 0; q < 4; ++q) {
        int rr = m0 + wr + m * 16 + l4 * 4 + q;
        if (rr >= Meff) continue;
        float v = acc[m][n][q];
        long long crow = rowStart + rr;
        if (EPI == 2)
          ((ushort_t*)Cv)[crow * ldc + (long long)z * bC + c] = f2b(geluf(v + bv));
      }
    }
  }
}

#define G16_ARGS const ushort_t* A, int lda, long long bA, const void* Bv, \
    int ldb, long long bB, void* Cv, int ldc, long long bC, long long pC, \
    int M, int N, int K, const float* bias, int bBias, const int* offs
#define G16_PASS A, lda, bA, Bv, ldb, bB, Cv, ldc, bC, pC, M, N, K, bias, bBias, offs

__global__ __launch_bounds__(256) void k_moe1   (G16_ARGS) { gemm16_body<2,1,1,1,0>(G16_PASS); }
__global__ __launch_bounds__(256) void k_moe2   (G16_ARGS) { gemm16_body<7,1,1,2,0>(G16_PASS); }
__global__ __launch_bounds__(256) void k_head_bf(G16_ARGS) { gemm16_body<6,1,0,1,1>(G16_PASS); }
__global__ __launch_bounds__(256) void k_head_f (G16_ARGS) { gemm16_body<6,0,0,1,1>(G16_PASS); }

// ---------------------------------------------------------------------------
__global__ __launch_bounds__(256)
void cvt_split2(const float* __restrict__ s0, ushort_t* __restrict__ dh0,
                ushort_t* __restrict__ dl0,
                const float* __restrict__ s1, ushort_t* __restrict__ dh1,
                ushort_t* __restrict__ dl1, int n4)
{
  const float* s = blockIdx.y ? s1 : s0;
  ushort_t* dh = blockIdx.y ? dh1 : dh0;
  ushort_t* dl = blockIdx.y ? dl1 : dl0;
  int i = blockIdx.x * blockDim.x + threadIdx.x;
  int stride = gridDim.x * blockDim.x;
  for (; i < n4; i += stride) {
    float4 f = ((const float4*)s)[i];
    s4v h, l; ushort_t hh, ll;
    split2(f.x, hh, ll); h[0] = (short)hh; l[0] = (short)ll;
    split2(f.y, hh, ll); h[1] = (short)hh; l[1] = (short)ll;
    split2(f.z, hh, ll); h[2] = (short)hh; l[2] = (short)ll;
    split2(f.w, hh, ll); h[3] = (short)hh; l[3] = (short)ll;
    ((s4v*)dh)[i] = h; ((s4v*)dl)[i] = l;
  }
}

__global__ __launch_bounds__(256)
void cvt_bf16(const float* __restrict__ s, ushort_t* __restrict__ d, int n4)
{
  int i = blockIdx.x * blockDim.x + threadIdx.x;
  int stride = gridDim.x * blockDim.x;
  for (; i < n4; i += stride) {
    float4 f = ((const float4*)s)[i];
    s4v o; o[0] = (short)f2b(f.x); o[1] = (short)f2b(f.y);
    o[2] = (short)f2b(f.z); o[3] = (short)f2b(f.w);
    ((s4v*)d)[i] = o;
  }
}

__global__ __launch_bounds__(256)
void cvt_bf16_2(const float* __restrict__ s0, ushort_t* __restrict__ d0,
                const float* __restrict__ s1, ushort_t* __restrict__ d1, int n4)
{
  const float* s = blockIdx.y ? s1 : s0;
  ushort_t* d = blockIdx.y ? d1 : d0;
  int i = blockIdx.x * blockDim.x + threadIdx.x;
  int stride = gridDim.x * blockDim.x;
  for (; i < n4; i += stride) {
    float4 f = ((const float4*)s)[i];
    s4v o; o[0] = (short)f2b(f.x); o[1] = (short)f2b(f.y);
    o[2] = (short)f2b(f.z); o[3] = (short)f2b(f.w);
    ((s4v*)d)[i] = o;
  }
}

__global__ __launch_bounds__(256)
void embed_kernel(const int* __restrict__ ids, const float* __restrict__ ew,
                  const float* __restrict__ pw, float* __restrict__ x,
                  int* __restrict__ counts)
{
  int srow = blockIdx.x, tid = threadIdx.x;
  if (srow == 0 && tid < 8) counts[tid] = 0;
  int id = ids[srow];
  const float4 e = *(const float4*)(ew + (long long)id * DM + tid * 4);
  const float4 p = *(const float4*)(pw + (long long)srow * DM + tid * 4);
  float4* xr = (float4*)(x + (long long)srow * DM) + tid;
  *xr = make_float4(e.x + p.x, e.y + p.y, e.z + p.z, e.w + p.w);
}

template<int MODE, int NP>
__global__ __launch_bounds__(256)
void ln_fused(float* __restrict__ x, const float* __restrict__ P, long long pC,
              const float* __restrict__ bias_pre,
              const float* __restrict__ g, const float* __restrict__ b,
              ushort_t* __restrict__ outH, ushort_t* __restrict__ outL)
{
  int row = blockIdx.x, tid = threadIdx.x;
  long long xo = (long long)row * DM + tid * 4;
  float4 v = *(const float4*)(x + xo);
  if (NP > 0) {
    float4 bp = *(const float4*)(bias_pre + tid * 4);
    float sx = bp.x, sy = bp.y, sz = bp.z, sw = bp.w;
#pragma unroll
    for (int p = 0; p < NP; ++p) {
      float4 pv = *(const float4*)(P + (long long)p * pC + xo);
      sx += pv.x; sy += pv.y; sz += pv.z; sw += pv.w;
    }
    v.x += sx; v.y += sy; v.z += sz; v.w += sw;
    *(float4*)(x + xo) = v;
  }
  __shared__ float sm1[4], sm2[4];
  float s = v.x + v.y + v.z + v.w;
  for (int o = 32; o > 0; o >>= 1) s += __shfl_down(s, o);
  if ((tid & 63) == 0) sm1[tid >> 6] = s;
  __syncthreads();
  float mean = (sm1[0] + sm1[1] + sm1[2] + sm1[3]) * (1.0f / DM);
  float d0 = v.x - mean, d1 = v.y - mean, d2 = v.z - mean, d3 = v.w - mean;
  float q = d0 * d0 + d1 * d1 + d2 * d2 + d3 * d3;
  for (int o = 32; o > 0; o >>= 1) q += __shfl_down(q, o);
  if ((tid & 63) == 0) sm2[tid >> 6] = q;
  __syncthreads();
  float var = (sm2[0] + sm2[1] + sm2[2] + sm2[3]) * (1.0f / DM);
  float rstd = rsqrtf(var + 1e-5f);
  float4 gv = ((const float4*)g)[tid];
  float4 bv = ((const float4*)b)[tid];
  float o0 = d0 * rstd * gv.x + bv.x, o1 = d1 * rstd * gv.y + bv.y;
  float o2 = d2 * rstd * gv.z + bv.z, o3 = d3 * rstd * gv.w + bv.w;
  long long base = (long long)row * DM + tid * 4;
  if (MODE == 0) {
    ushort_t hh, ll;
    split2(o0, hh, ll); outH[base + 0] = hh; outL[base + 0] = ll;
    split2(o1, hh, ll); outH[base + 1] = hh; outL[base + 1] = ll;
    split2(o2, hh, ll); outH[base + 2] = hh; outL[base + 2] = ll;
    split2(o3, hh, ll); outH[base + 3] = hh; outL[base + 3] = ll;
  } else {
    outH[base + 0] = f2b(o0); outH[base + 1] = f2b(o1);
    outH[base + 2] = f2b(o2); outH[base + 3] = f2b(o3);
  }
}

__global__ __launch_bounds__(256)
void ln_gate_top2(float* __restrict__ x, const float* __restrict__ P,
                  long long pC, const float* __restrict__ bias_pre,
                  const float* __restrict__ g, const float* __restrict__ b,
                  const float* __restrict__ gw, const float* __restrict__ gb,
                  int* __restrict__ topi, float* __restrict__ topw,
                  int* __restrict__ counts, ushort_t* __restrict__ outH)
{
  int row = blockIdx.x, tid = threadIdx.x;
  long long xo = (long long)row * DM + tid * 4;
  float4 v = *(const float4*)(x + xo);
  {
    float4 bp = *(const float4*)(bias_pre + tid * 4);
    float sx = bp.x, sy = bp.y, sz = bp.z, sw = bp.w;
#pragma unroll
    for (int p = 0; p < 4; ++p) {
      float4 pv = *(const float4*)(P + (long long)p * pC + xo);
      sx += pv.x; sy += pv.y; sz += pv.z; sw += pv.w;
    }
    v.x += sx; v.y += sy; v.z += sz; v.w += sw;
    *(float4*)(x + xo) = v;
  }
  __shared__ float sm1[4], sm2[4];
  __shared__ float se[8][4];
  float s = v.x + v.y + v.z + v.w;
  for (int o = 32; o > 0; o >>= 1) s += __shfl_down(s, o);
  if ((tid & 63) == 0) sm1[tid >> 6] = s;
  __syncthreads();
  float mean = (sm1[0] + sm1[1] + sm1[2] + sm1[3]) * (1.0f / DM);
  float d0 = v.x - mean, d1 = v.y - mean, d2 = v.z - mean, d3 = v.w - mean;
  float q = d0 * d0 + d1 * d1 + d2 * d2 + d3 * d3;
  for (int o = 32; o > 0; o >>= 1) q += __shfl_down(q, o);
  if ((tid & 63) == 0) sm2[tid >> 6] = q;
  __syncthreads();
  float var = (sm2[0] + sm2[1] + sm2[2] + sm2[3]) * (1.0f / DM);
  float rstd = rsqrtf(var + 1e-5f);
  float4 gv = ((const float4*)g)[tid];
  float4 bv = ((const float4*)b)[tid];
  float h0 = d0 * rstd * gv.x + bv.x, h1 = d1 * rstd * gv.y + bv.y;
  float h2 = d2 * rstd * gv.z + bv.z, h3 = d3 * rstd * gv.w + bv.w;
  long long base = (long long)row * DM + tid * 4;
  outH[base + 0] = f2b(h0); outH[base + 1] = f2b(h1);
  outH[base + 2] = f2b(h2); outH[base + 3] = f2b(h3);
#pragma unroll
  for (int e = 0; e < 8; ++e) {
    float4 w = ((const float4*)(gw + (long long)e * DM))[tid];
    float p = h0 * w.x + h1 * w.y + h2 * w.z + h3 * w.w;
    for (int o = 32; o > 0; o >>= 1) p += __shfl_down(p, o);
    if ((tid & 63) == 0) se[e][tid >> 6] = p;
  }
  __syncthreads();
  if (tid == 0) {
    float sc[8];
#pragma unroll
    for (int e = 0; e < 8; ++e)
      sc[e] = se[e][0] + se[e][1] + se[e][2] + se[e][3] + gb[e];
    int i1 = 0; float m1 = sc[0];
    for (int e = 1; e < 8; ++e) if (sc[e] > m1) { m1 = sc[e]; i1 = e; }
    int i2 = -1; float m2 = -1e30f;
    for (int e = 0; e < 8; ++e) if (e != i1 && sc[e] > m2) { m2 = sc[e]; i2 = e; }
    float e2 = __expf(m2 - m1);
    float w1 = 1.f / (1.f + e2);
    topi[row * 2] = i1; topi[row * 2 + 1] = i2;
    topw[row * 2] = w1; topw[row * 2 + 1] = 1.f - w1;
    atomicAdd(&counts[i1], 1);
    atomicAdd(&counts[i2], 1);
  }
}

__global__ void moe_prefix(const int* __restrict__ counts, int* __restrict__ offs,
                           int* __restrict__ cursors)
{
  if (threadIdx.x == 0 && blockIdx.x == 0) {
    int a = 0;
    for (int e = 0; e < 8; ++e) { offs[e] = a; a += counts[e]; cursors[e] = 0; }
    offs[8] = a;
  }
}

__global__ __launch_bounds__(256)
void moe_gather(const ushort_t* __restrict__ hH, const int* __restrict__ topi,
                const float* __restrict__ topw, const int* __restrict__ offs,
                int* __restrict__ cursors, int* __restrict__ tokIdx,
                float* __restrict__ tokW, int* __restrict__ slotOf,
                ushort_t* __restrict__ Xg)
{
  int tok = blockIdx.x, tid = threadIdx.x;
  __shared__ int s0s, s1s;
  if (tid == 0) {
    int e0 = topi[tok * 2], e1 = topi[tok * 2 + 1];
    int s0 = offs[e0] + atomicAdd(&cursors[e0], 1);
    int s1 = offs[e1] + atomicAdd(&cursors[e1], 1);
    tokIdx[s0] = tok; tokW[s0] = topw[tok * 2];
    tokIdx[s1] = tok; tokW[s1] = topw[tok * 2 + 1];
    slotOf[tok * 2] = s0; slotOf[tok * 2 + 1] = s1;
    s0s = s0; s1s = s1;
  }
  __syncthreads();
  s4v v = ((const s4v*)(hH + (long long)tok * DM))[tid];
  ((s4v*)(Xg + (long long)s0s * DM))[tid] = v;
  ((s4v*)(Xg + (long long)s1s * DM))[tid] = v;
}

__global__ __launch_bounds__(256)
void moe_ln_final(const float* __restrict__ x, const float* __restrict__ eo,
                  long long pC, const int* __restrict__ slotOf,
                  const int* __restrict__ topi, const float* __restrict__ topw,
                  const float* __restrict__ b2, const float* __restrict__ g,
                  const float* __restrict__ b, ushort_t* __restrict__ outH)
{
  int tok = blockIdx.x, tid = threadIdx.x;
  int s0 = slotOf[tok * 2], s1 = slotOf[tok * 2 + 1];
  int e0 = topi[tok * 2], e1 = topi[tok * 2 + 1];
  float w0 = topw[tok * 2], w1 = topw[tok * 2 + 1];
  float4 a  = ((const float4*)(eo + (long long)s0 * DM))[tid];
  float4 a2 = ((const float4*)(eo + pC + (long long)s0 * DM))[tid];
  float4 bb1= ((const float4*)(eo + (long long)s1 * DM))[tid];
  float4 bb2= ((const float4*)(eo + pC + (long long)s1 * DM))[tid];
  float4 ba = ((const float4*)(b2 + (long long)e0 * DM))[tid];
  float4 bbb= ((const float4*)(b2 + (long long)e1 * DM))[tid];
  float4 v = ((const float4*)(x + (long long)tok * DM))[tid];
  v.x += w0 * (a.x + a2.x + ba.x) + w1 * (bb1.x + bb2.x + bbb.x);
  v.y += w0 * (a.y + a2.y + ba.y) + w1 * (bb1.y + bb2.y + bbb.y);
  v.z += w0 * (a.z + a2.z + ba.z) + w1 * (bb1.z + bb2.z + bbb.z);
  v.w += w0 * (a.w + a2.w + ba.w) + w1 * (bb1.w + bb2.w + bbb.w);
  __shared__ float sm1[4], sm2[4];
  float s = v.x + v.y + v.z + v.w;
  for (int o = 32; o > 0; o >>= 1) s += __shfl_down(s, o);
  if ((tid & 63) == 0) sm1[tid >> 6] = s;
  __syncthreads();
  float mean = (sm1[0] + sm1[1] + sm1[2] + sm1[3]) * (1.0f / DM);
  float d0 = v.x - mean, d1 = v.y - mean, d2 = v.z - mean, d3 = v.w - mean;
  float q = d0 * d0 + d1 * d1 + d2 * d2 + d3 * d3;
  for (int o = 32; o > 0; o >>= 1) q += __shfl_down(q, o);
  if ((tid & 63) == 0) sm2[tid >> 6] = q;
  __syncthreads();
  float var = (sm2[0] + sm2[1] + sm2[2] + sm2[3]) * (1.0f / DM);
  float rstd = rsqrtf(var + 1e-5f);
  float4 gv = ((const float4*)g)[tid];
  float4 bv = ((const float4*)b)[tid];
  long long base = (long long)tok * DM + tid * 4;
  outH[base + 0] = f2b(d0 * rstd * gv.x + bv.x);
  outH[base + 1] = f2b(d1 * rstd * gv.y + bv.y);
  outH[base + 2] = f2b(d2 * rstd * gv.z + bv.z);
  outH[base + 3] = f2b(d3 * rstd * gv.w + bv.w);
}

extern "C" void kernel_launch(void* const* d_in, const int* in_sizes, int n_in,
                              void* d_out, int out_size, void* d_ws, size_t ws_size,
                              hipStream_t stream)
{
  const int* ids = (const int*)d_in[0];
  const float* embed_w = (const float*)d_in[1];
  const float* pos_w   = (const float*)d_in[2];
  const float* ln1_g[2] = {(const float*)d_in[3],  (const float*)d_in[11]};
  const float* ln1_b[2] = {(const float*)d_in[4],  (const float*)d_in[12]};
  const float* in_w[2]  = {(const float*)d_in[5],  (const float*)d_in[13]};
  const float* in_b[2]  = {(const float*)d_in[6],  (const float*)d_in[14]};
  const float* out_w[2] = {(const float*)d_in[7],  (const float*)d_in[15]};
  const float* out_b[2] = {(const float*)d_in[8],  (const float*)d_in[16]};
  const float* ln2_g[2] = {(const float*)d_in[9],  (const float*)d_in[17]};
  const float* ln2_b[2] = {(const float*)d_in[10], (const float*)d_in[18]};
  const float* ffn_w1 = (const float*)d_in[19];
  const float* ffn_b1 = (const float*)d_in[20];
  const float* ffn_w2 = (const float*)d_in[21];
  const float* ffn_b2 = (const float*)d_in[22];
  const float* gate_w = (const float*)d_in[23];
  const float* gate_b = (const float*)d_in[24];
  const float* moe_w1 = (const float*)d_in[25];
  const float* moe_b1 = (const float*)d_in[26];
  const float* moe_w2 = (const float*)d_in[27];
  const float* moe_b2 = (const float*)d_in[28];
  const float* norm_g = (const float*)d_in[29];
  const float* norm_b = (const float*)d_in[30];
  const float* head_w = (const float*)d_in[31];

  char* ob = (char*)d_out;
  size_t off = 0;
  auto alloc = [&](size_t bytes) {
    char* p = ob + off;
    off = (off + bytes + 255) & ~(size_t)255;
    return p;
  };
  float*    x      = (float*)alloc((size_t)SQ * DM * 4);
  ushort_t* hbufH  = (ushort_t*)alloc((size_t)SQ * DM * 2);
  ushort_t* hbufL  = (ushort_t*)alloc((size_t)SQ * DM * 2);
  ushort_t* qkvH   = (ushort_t*)alloc((size_t)SQ * 3 * DM * 2);   // ┐
  ushort_t* qkvL   = (ushort_t*)alloc((size_t)SQ * 3 * DM * 2);   // │ w2b
  ushort_t* VtH    = (ushort_t*)alloc((size_t)NH * HDIM * SQ * 2);// │ 64MiB
  ushort_t* VtL    = (ushort_t*)alloc((size_t)NH * HDIM * SQ * 2);// │
  char*     resv   = (char*)alloc((size_t)32 << 20);              // ┘ filler
  ushort_t* attnH  = (ushort_t*)alloc((size_t)SQ * DM * 2);
  ushort_t* attnL  = (ushort_t*)alloc((size_t)SQ * DM * 2);
  ushort_t* Xg     = (ushort_t*)alloc((size_t)2 * SQ * DM * 2);
  int*      topi   = (int*)alloc(SQ * 2 * 4);
  float*    topw   = (float*)alloc(SQ * 2 * 4);
  int*      tokIdx = (int*)alloc(2 * SQ * 4);
  float*    tokW   = (float*)alloc(2 * SQ * 4);
  int*      slotOf = (int*)alloc(2 * SQ * 4);
  int*      counts = (int*)alloc(256);
  int*      offsb  = (int*)alloc(256);
  int*      cursors= (int*)alloc(256);
  ushort_t* ffnH   = (ushort_t*)alloc((size_t)SQ * FFD * 2);      // ┐ moehid
  ushort_t* ffnL   = (ushort_t*)alloc((size_t)SQ * FFD * 2);      // ┘ 32MiB
  float*    eo     = (float*)alloc((size_t)2 * 2 * SQ * DM * 4);  // 32MiB (also KS partials)
  ushort_t* inwH[2], *inwL[2], *outwH[2], *outwL[2];
  ushort_t* wsplit0 = (ushort_t*)alloc(0);
  inwH[0]  = (ushort_t*)alloc((size_t)3 * DM * DM * 2);
  inwL[0]  = (ushort_t*)alloc((size_t)3 * DM * DM * 2);
  inwH[1]  = (ushort_t*)alloc((size_t)3 * DM * DM * 2);
  inwL[1]  = (ushort_t*)alloc((size_t)3 * DM * DM * 2);
  outwH[0] = (ushort_t*)alloc((size_t)DM * DM * 2);
  outwL[0] = (ushort_t*)alloc((size_t)DM * DM * 2);
  outwH[1] = (ushort_t*)alloc((size_t)DM * DM * 2);
  outwL[1] = (ushort_t*)alloc((size_t)DM * DM * 2);
  ushort_t* f1H = (ushort_t*)alloc((size_t)FFD * DM * 2);
  ushort_t* f1L = (ushort_t*)alloc((size_t)FFD * DM * 2);
  ushort_t* f2H = (ushort_t*)alloc((size_t)DM * FFD * 2);
  ushort_t* f2L = (ushort_t*)alloc((size_t)DM * FFD * 2);
  ushort_t* moe_w1b = wsplit0;            // 64 MiB over weight planes
  ushort_t* moe_w2b = qkvH;               // 64 MiB over qkv+Vt+resv
  ushort_t* moehid  = ffnH;               // 32 MiB over ffn planes
  float*    pp      = eo;                 // KS partial planes
  const long long eoPC = (long long)2 * SQ * DM;
  const long long ppPC = (long long)SQ * DM;
  ushort_t* hfin    = (ushort_t*)d_ws;
  bool wsBig = ws_size >= ((size_t)70 << 20);
  ushort_t* head_wb = (ushort_t*)((char*)d_ws + ((size_t)4 << 20));
  (void)resv;

  embed_kernel<<<SQ, 256, 0, stream>>>(ids, embed_w, pos_w, x, counts);
  cvt_split2<<<dim3(512, 2), 256, 0, stream>>>(
      in_w[0], inwH[0], inwL[0], in_w[1], inwH[1], inwL[1], 3 * DM * DM / 4);
  cvt_split2<<<dim3(512, 2), 256, 0, stream>>>(
      out_w[0], outwH[0], outwL[0], out_w[1], outwH[1], outwL[1], DM * DM / 4);
  cvt_split2<<<dim3(512, 2), 256, 0, stream>>>(
      ffn_w1, f1H, f1L, ffn_w2, f2H, f2L, FFD * DM / 4);
  if (wsBig)
    cvt_bf16<<<1024, 256, 0, stream>>>(head_w, head_wb, NVOC * DM / 4);

  // ---- Layer 0 ----
  ln_fused<0, 0><<<SQ, 256, 0, stream>>>(x, nullptr, 0, nullptr,
                                         ln1_g[0], ln1_b[0], hbufH, hbufL);
  k_qkv<<<dim3(16, 24, 1), 256, 0, stream>>>(
      hbufH, hbufL, DM, 0, inwH[0], inwL[0], DM, 0,
      nullptr, qkvH, qkvL, 3 * DM, 0, 0,
      SQ, 3 * DM, DM, in_b[0], 1.f, VtH, VtL);
  k_attn<<<dim3(SQ / 64, NH), 256, 0, stream>>>(qkvH, qkvL, VtH, VtL,
                                                attnH, attnL);
  k_outp<<<dim3(16, 16, 4), 256, 0, stream>>>(
      attnH, attnL, DM, 0, outwH[0], outwL[0], DM, 0,
      pp, nullptr, nullptr, DM, 0, ppPC,
      SQ, DM, DM / 4, nullptr, 1.f, nullptr, nullptr);
  ln_fused<0, 4><<<SQ, 256, 0, stream>>>(x, pp, ppPC, out_b[0],
                                         ln2_g[0], ln2_b[0], hbufH, hbufL);
  k_ffn1<<<dim3(16, 32, 1), 256, 0, stream>>>(
      hbufH, hbufL, DM, 0, f1H, f1L, DM, 0,
      nullptr, ffnH, ffnL, FFD, 0, 0,
      SQ, FFD, DM, ffn_b1, 1.f, nullptr, nullptr);
  k_ffn2<<<dim3(16, 16, 2), 256, 0, stream>>>(
      ffnH, ffnL, FFD, 0, f2H, f2L, FFD, 0,
      pp, nullptr, nullptr, DM, 0, ppPC,
      SQ, DM, FFD / 2, nullptr, 1.f, nullptr, nullptr);
  // ---- Layer 1 ----
  ln_fused<0, 2><<<SQ, 256, 0, stream>>>(x, pp, ppPC, ffn_b2,
                                         ln1_g[1], ln1_b[1], hbufH, hbufL);
  k_qkv<<<dim3(16, 24, 1), 256, 0, stream>>>(
      hbufH, hbufL, DM, 0, inwH[1], inwL[1], DM, 0,
      nullptr, qkvH, qkvL, 3 * DM, 0, 0,
      SQ, 3 * DM, DM, in_b[1], 1.f, VtH, VtL);
  k_attn<<<dim3(SQ / 64, NH), 256, 0, stream>>>(qkvH, qkvL, VtH, VtL,
                                                attnH, attnL);
  k_outp<<<dim3(16, 16, 4), 256, 0, stream>>>(
      attnH, attnL, DM, 0, outwH[1], outwL[1], DM, 0,
      pp, nullptr, nullptr, DM, 0, ppPC,
      SQ, DM, DM / 4, nullptr, 1.f, nullptr, nullptr);
  cvt_bf16_2<<<dim3(2048, 2), 256, 0, stream>>>(
      moe_w1, moe_w1b, moe_w2, moe_w2b, 8 * FFD * DM / 4);
  ln_gate_top2<<<SQ, 256, 0, stream>>>(x, pp, ppPC, out_b[1],
                                       ln2_g[1], ln2_b[1], gate_w, gate_b,
                                       topi, topw, counts, hbufH);
  moe_prefix<<<1, 64, 0, stream>>>(counts, offsb, cursors);
  moe_gather<<<SQ, 256, 0, stream>>>(hbufH, topi, topw, offsb, cursors,
                                     tokIdx, tokW, slotOf, Xg);
  k_moe1<<<dim3(32, 16, 8), 256, 0, stream>>>(
      Xg, DM, 0, moe_w1b, DM, (long long)FFD * DM,
      moehid, FFD, 0, 0, SQ, FFD, DM, moe_b1, FFD, offsb);
  k_moe2<<<dim3(8, 16, 16), 256, 0, stream>>>(
      moehid, FFD, 0, moe_w2b, FFD, (long long)DM * FFD,
      eo, DM, 0, eoPC, SQ, DM, FFD, nullptr, 0, offsb);
  moe_ln_final<<<SQ, 256, 0, stream>>>(x, eo, eoPC, slotOf, topi, topw,
                                       moe_b2, norm_g, norm_b, hfin);
  if (wsBig)
    k_head_bf<<<dim3(16, 250, 1), 256, 0, stream>>>(
        hfin, DM, 0, head_wb, DM, 0, d_out, NVOC, 0, 0,
        SQ, NVOC, DM, nullptr, 0, nullptr);
  else
    k_head_f<<<dim3(16, 250, 1), 256, 0, stream>>>(
        hfin, DM, 0, head_w, DM, 0, d_out, NVOC, 0, 0,
        SQ, NVOC, DM, nullptr, 0, nullptr);
}

// Round 15
// 1144.694 us; speedup vs baseline: 1.9492x; 1.0064x over previous
//
#include <hip/hip_runtime.h>
#include <hip/hip_bf16.h>
#include <math.h>

typedef unsigned short ushort_t;
typedef __attribute__((ext_vector_type(8))) __bf16 bf16x8;
typedef __attribute__((ext_vector_type(4))) float f32x4;
typedef __attribute__((ext_vector_type(8))) short s8v;
typedef __attribute__((ext_vector_type(4))) short s4v;

#define SQ 2048
#define DM 1024
#define NH 16
#define HDIM 64
#define FFD 4096
#define NVOC 32000

__device__ inline float b2f(unsigned short u) {
  union { unsigned int i; float f; } x; x.i = ((unsigned int)u) << 16; return x.f;
}
__device__ inline unsigned short f2b(float f) {
  __hip_bfloat16 h = __float2bfloat16(f);
  return *reinterpret_cast<unsigned short*>(&h);
}
__device__ inline void split2(float x, ushort_t& h, ushort_t& l) {
  h = f2b(x);
  l = f2b(x - b2f(h));
}
__device__ inline float geluf(float v) {
  return 0.5f * v * (1.0f + erff(v * 0.70710678118654752f));
}
__device__ __forceinline__ void gld16(const void* g, void* l) {
  __builtin_amdgcn_global_load_lds(
      (const __attribute__((address_space(1))) void*)g,
      (__attribute__((address_space(3))) void*)l, 16, 0, 0);
}
#define MFMA __builtin_amdgcn_mfma_f32_16x16x32_bf16

// ---------------------------------------------------------------------------
// Split GEMM engine (pre-gate math), 2-phase double-buffered.
// EPI: 2 f32 partial store (kc*pC), 4 gelu+bias split-store,
//      5 split-store+bias with V-region (n0>=2048) written TRANSPOSED to TH/TL.
// ---------------------------------------------------------------------------
template<int EPI, int NT, int KS>
__device__ __forceinline__ void gemmsp_body(
    const ushort_t* __restrict__ AH, const ushort_t* __restrict__ AL,
    int lda, long long bA,
    const ushort_t* __restrict__ BH, const ushort_t* __restrict__ BL,
    int ldb, long long bB,
    float* __restrict__ C, ushort_t* __restrict__ CH, ushort_t* __restrict__ CL,
    int ldc, long long bC, long long pC,
    int M, int N, int K, const float* __restrict__ bias, float alpha,
    ushort_t* __restrict__ TH, ushort_t* __restrict__ TL)
{
  int z = blockIdx.z, h = z / KS, kc = z % KS;
  const ushort_t* AHp = AH + (long long)h * bA + (long long)kc * K;
  const ushort_t* ALp = AL + (long long)h * bA + (long long)kc * K;
  const ushort_t* BHp = BH + (long long)h * bB + (long long)kc * K;
  const ushort_t* BLp = BL + (long long)h * bB + (long long)kc * K;
  int m0 = blockIdx.x * 128, n0 = blockIdx.y * NT;
  const int NF = NT / 32;

  __shared__ __align__(16) ushort_t sAH[2][128 * 32], sAL[2][128 * 32];
  __shared__ __align__(16) ushort_t sBH[2][NT * 32],  sBL[2][NT * 32];

  int tid = threadIdx.x, lane = tid & 63, wave = tid >> 6;
  int wr = (wave >> 1) * 64, wc = (wave & 1) * (NT >> 1);
  int l15 = lane & 15, l4 = lane >> 4;

  f32x4 acc[4][NF];
#pragma unroll
  for (int m = 0; m < 4; ++m)
#pragma unroll
    for (int n = 0; n < NF; ++n) acc[m][n] = (f32x4){0.f, 0.f, 0.f, 0.f};

  auto stageG = [&](int buf, int k0) {
#pragma unroll
    for (int i = 0; i < 2; ++i) {
      int fi = i * 2048 + tid * 8;
      int r = fi >> 5, chk = (fi >> 3) & 3;
      int scol = ((chk ^ ((r >> 1) & 3)) << 3);
      int ra = m0 + r; if (ra > M - 1) ra = M - 1;
      long long go = (long long)ra * lda + k0 + scol;
      gld16(AHp + go, &sAH[buf][fi]);
      gld16(ALp + go, &sAL[buf][fi]);
    }
#pragma unroll
    for (int i = 0; i < NT / 64; ++i) {
      int fi = i * 2048 + tid * 8;
      int r = fi >> 5, chk = (fi >> 3) & 3;
      int scol = ((chk ^ ((r >> 1) & 3)) << 3);
      int rb = n0 + r; if (rb > N - 1) rb = N - 1;
      long long go = (long long)rb * ldb + k0 + scol;
      gld16(BHp + go, &sBH[buf][fi]);
      gld16(BLp + go, &sBL[buf][fi]);
    }
  };

  int nIt = K >> 5;
  stageG(0, 0);
  for (int it = 0; it < nIt; ++it) {
    int cur = it & 1;
    __syncthreads();
    if (it + 1 < nIt) stageG(cur ^ 1, (it + 1) << 5);
    bf16x8 ah[4], al[4], bh[NF], bl[NF];
#pragma unroll
    for (int m = 0; m < 4; ++m) {
      int r = wr + m * 16 + l15;
      int o = r * 32 + ((l4 ^ ((r >> 1) & 3)) << 3);
      ah[m] = *(const bf16x8*)&sAH[cur][o];
      al[m] = *(const bf16x8*)&sAL[cur][o];
    }
#pragma unroll
    for (int n = 0; n < NF; ++n) {
      int r = wc + n * 16 + l15;
      int o = r * 32 + ((l4 ^ ((r >> 1) & 3)) << 3);
      bh[n] = *(const bf16x8*)&sBH[cur][o];
      bl[n] = *(const bf16x8*)&sBL[cur][o];
    }
#pragma unroll
    for (int m = 0; m < 4; ++m)
#pragma unroll
      for (int n = 0; n < NF; ++n) {
        acc[m][n] = MFMA(ah[m], bh[n], acc[m][n], 0, 0, 0);
        acc[m][n] = MFMA(al[m], bh[n], acc[m][n], 0, 0, 0);
        acc[m][n] = MFMA(ah[m], bl[n], acc[m][n], 0, 0, 0);
      }
  }

  if (EPI == 5 && n0 >= 2 * DM) {
#pragma unroll
    for (int m = 0; m < 4; ++m) {
      int rbase = m0 + wr + m * 16 + l4 * 4;
#pragma unroll
      for (int n = 0; n < NF; ++n) {
        int c = n0 + wc + n * 16 + l15;
        int d = c - 2 * DM;
        float bv = bias[c];
        s4v hv, lv;
#pragma unroll
        for (int q = 0; q < 4; ++q) {
          ushort_t hh, ll; split2(acc[m][n][q] + bv, hh, ll);
          hv[q] = (short)hh; lv[q] = (short)ll;
        }
        *(s4v*)&TH[(long long)d * SQ + rbase] = hv;
        *(s4v*)&TL[(long long)d * SQ + rbase] = lv;
      }
    }
    return;
  }

#pragma unroll
  for (int m = 0; m < 4; ++m) {
#pragma unroll
    for (int n = 0; n < NF; ++n) {
      int c = n0 + wc + n * 16 + l15;
      if (c >= N) continue;
      float bv = (EPI == 4 || EPI == 5) ? bias[c] : 0.f;
#pragma unroll
      for (int q = 0; q < 4; ++q) {
        int rr = m0 + wr + m * 16 + l4 * 4 + q;
        if (rr >= M) continue;
        float v = acc[m][n][q];
        if (EPI == 5) {
          ushort_t hh, ll; split2(v + bv, hh, ll);
          long long o = (long long)rr * ldc + c; CH[o] = hh; CL[o] = ll;
        } else if (EPI == 2) {
          C[(long long)kc * pC + (long long)rr * ldc + (long long)h * bC + c] = v;
        } else if (EPI == 4) {
          ushort_t hh, ll; split2(geluf(v + bv), hh, ll);
          long long o = (long long)rr * ldc + c; CH[o] = hh; CL[o] = ll;
        }
      }
    }
  }
}

#define SP_ARGS const ushort_t* AH, const ushort_t* AL, int lda, long long bA, \
    const ushort_t* BH, const ushort_t* BL, int ldb, long long bB, \
    float* C, ushort_t* CH, ushort_t* CL, int ldc, long long bC, long long pC, \
    int M, int N, int K, const float* bias, float alpha, \
    ushort_t* TH, ushort_t* TL
#define SP_PASS AH, AL, lda, bA, BH, BL, ldb, bB, C, CH, CL, ldc, bC, pC, M, N, K, bias, alpha, TH, TL

__global__ __launch_bounds__(256) void k_qkv (SP_ARGS) { gemmsp_body<5,128,1>(SP_PASS); }
__global__ __launch_bounds__(256) void k_outp(SP_ARGS) { gemmsp_body<2, 64,4>(SP_PASS); }
__global__ __launch_bounds__(256) void k_ffn1(SP_ARGS) { gemmsp_body<4,128,1>(SP_PASS); }
__global__ __launch_bounds__(256) void k_ffn2(SP_ARGS) { gemmsp_body<2, 64,2>(SP_PASS); }

// ---------------------------------------------------------------------------
// Fused flash attention, split-f32 precision. Grid (32,16).
// ---------------------------------------------------------------------------
__global__ __launch_bounds__(256)
void k_attn(const ushort_t* __restrict__ qkvH, const ushort_t* __restrict__ qkvL,
            const ushort_t* __restrict__ VtH, const ushort_t* __restrict__ VtL,
            ushort_t* __restrict__ aH, ushort_t* __restrict__ aL)
{
  int f = blockIdx.x + blockIdx.y * gridDim.x;
  int logical = (f & 7) * 64 + (f >> 3);
  int q0 = (logical & 31) * 64;
  int h  = logical >> 5;

  __shared__ __align__(16) ushort_t sKH[4096], sKL[4096];
  __shared__ __align__(16) ushort_t sVH[4096], sVL[4096];
  __shared__ __align__(16) ushort_t sPH[4096], sPL[4096];

  int tid = threadIdx.x, lane = tid & 63, wave = tid >> 6;
  int l15 = lane & 15, l4 = lane >> 4;

  bf16x8 qh[2], ql[2];
  {
    long long base = (long long)(q0 + wave * 16 + l15) * (3 * DM) + h * 64 + l4 * 8;
    qh[0] = *(const bf16x8*)(qkvH + base);
    qh[1] = *(const bf16x8*)(qkvH + base + 32);
    ql[0] = *(const bf16x8*)(qkvL + base);
    ql[1] = *(const bf16x8*)(qkvL + base + 32);
  }

  float mrow[4], lrow[4];
  f32x4 Oacc[4];
#pragma unroll
  for (int r = 0; r < 4; ++r) { mrow[r] = -1e30f; lrow[r] = 0.f; }
#pragma unroll
  for (int n = 0; n < 4; ++n) Oacc[n] = (f32x4){0.f, 0.f, 0.f, 0.f};

  for (int kt = 0; kt < SQ / 64; ++kt) {
#pragma unroll
    for (int i = 0; i < 2; ++i) {
      int idx = i * 2048 + tid * 8;
      int row = idx >> 6, chk = (idx >> 3) & 7;
      int scol = ((chk ^ (row & 7)) << 3);
      long long gk = (long long)(kt * 64 + row) * (3 * DM) + DM + h * 64 + scol;
      long long gv = (long long)(h * 64 + row) * SQ + kt * 64 + scol;
      gld16(qkvH + gk, &sKH[idx]);
      gld16(qkvL + gk, &sKL[idx]);
      gld16(VtH + gv, &sVH[idx]);
      gld16(VtL + gv, &sVL[idx]);
    }
    __syncthreads();

    f32x4 S[4];
#pragma unroll
    for (int n = 0; n < 4; ++n) S[n] = (f32x4){0.f, 0.f, 0.f, 0.f};
#pragma unroll
    for (int kk = 0; kk < 64; kk += 32) {
      int kkI = kk >> 5;
      bf16x8 qhf = qh[kkI], qlf = ql[kkI];
#pragma unroll
      for (int n = 0; n < 4; ++n) {
        int br = n * 16 + l15;
        int bo = br * 64 + ((((kk >> 3) + l4) ^ (br & 7)) << 3);
        bf16x8 kh = *(const bf16x8*)&sKH[bo];
        bf16x8 kl = *(const bf16x8*)&sKL[bo];
        S[n] = MFMA(qhf, kh, S[n], 0, 0, 0);
        S[n] = MFMA(qlf, kh, S[n], 0, 0, 0);
        S[n] = MFMA(qhf, kl, S[n], 0, 0, 0);
      }
    }
    float tm[4], ts[4];
#pragma unroll
    for (int r = 0; r < 4; ++r) {
#pragma unroll
      for (int n = 0; n < 4; ++n) S[n][r] *= 0.125f;
      tm[r] = fmaxf(fmaxf(S[0][r], S[1][r]), fmaxf(S[2][r], S[3][r]));
    }
#pragma unroll
    for (int mk = 1; mk <= 8; mk <<= 1)
#pragma unroll
      for (int r = 0; r < 4; ++r) tm[r] = fmaxf(tm[r], __shfl_xor(tm[r], mk));
#pragma unroll
    for (int r = 0; r < 4; ++r) {
      float mn = fmaxf(mrow[r], tm[r]);
      float corr = __expf(mrow[r] - mn);
      mrow[r] = mn;
      float s = 0.f;
#pragma unroll
      for (int n = 0; n < 4; ++n) { S[n][r] = __expf(S[n][r] - mn); s += S[n][r]; }
      ts[r] = s;
      lrow[r] *= corr;
#pragma unroll
      for (int n = 0; n < 4; ++n) Oacc[n][r] *= corr;
    }
#pragma unroll
    for (int mk = 1; mk <= 8; mk <<= 1)
#pragma unroll
      for (int r = 0; r < 4; ++r) ts[r] += __shfl_xor(ts[r], mk);
#pragma unroll
    for (int r = 0; r < 4; ++r) lrow[r] += ts[r];

    {
      ushort_t* pH = &sPH[wave * 1024];
      ushort_t* pL = &sPL[wave * 1024];
#pragma unroll
      for (int n = 0; n < 4; ++n)
#pragma unroll
        for (int r = 0; r < 4; ++r) {
          int row = l4 * 4 + r, col = n * 16 + l15;
          int ad = row * 64 + (((col >> 3) ^ (row & 7)) << 3) + (col & 7);
          ushort_t hh, ll; split2(S[n][r], hh, ll);
          pH[ad] = hh; pL[ad] = ll;
        }
    }
    __syncthreads();
#pragma unroll
    for (int kk = 0; kk < 64; kk += 32) {
      int ao = wave * 1024 + l15 * 64 + ((((kk >> 3) + l4) ^ (l15 & 7)) << 3);
      bf16x8 ph = *(const bf16x8*)&sPH[ao];
      bf16x8 pl = *(const bf16x8*)&sPL[ao];
#pragma unroll
      for (int n = 0; n < 4; ++n) {
        int br = n * 16 + l15;
        int bo = br * 64 + ((((kk >> 3) + l4) ^ (br & 7)) << 3);
        bf16x8 vh = *(const bf16x8*)&sVH[bo];
        bf16x8 vl = *(const bf16x8*)&sVL[bo];
        Oacc[n] = MFMA(ph, vh, Oacc[n], 0, 0, 0);
        Oacc[n] = MFMA(pl, vh, Oacc[n], 0, 0, 0);
        Oacc[n] = MFMA(ph, vl, Oacc[n], 0, 0, 0);
      }
    }
    __syncthreads();
  }

#pragma unroll
  for (int n = 0; n < 4; ++n)
#pragma unroll
    for (int r = 0; r < 4; ++r) {
      int q = q0 + wave * 16 + l4 * 4 + r;
      int d = h * 64 + n * 16 + l15;
      float val = Oacc[n][r] / lrow[r];
      ushort_t hh, ll; split2(val, hh, ll);
      long long o = (long long)q * DM + d;
      aH[o] = hh; aL[o] = ll;
    }
}

// ---------------------------------------------------------------------------
// bf16 GEMM engine (post-gate), 2-phase double-buffered with BK=32:
// 32KB LDS (4 x 8KB: A0 A1 B0 B1) -> 5 blocks/CU. Per K-step: barrier ->
// issue next step's gld16 -> 16 MFMA on current. Swizzle: chk ^ ((row>>1)&3).
// ---------------------------------------------------------------------------
template<int EPI, int BSRC, int SWAP, int KS, int XS>
__device__ __forceinline__ void gemm16_body(
    const ushort_t* __restrict__ A, int lda, long long bA,
    const void* __restrict__ Bv, int ldb, long long bB,
    void* __restrict__ Cv, int ldc, long long bC, long long pC,
    int M, int N, int K, const float* __restrict__ bias, int bBias,
    const int* __restrict__ offs)
{
  int bz = blockIdx.z;
  int z = bz / KS, kc = bz % KS;
  int Kc = K / KS;
  const ushort_t* Ap = A + (long long)z * bA + (long long)kc * Kc;
  int rowStart = 0, Meff = M;
  if (offs) { rowStart = offs[z]; Meff = offs[z + 1] - rowStart; }
  int bx = blockIdx.x, by = blockIdx.y;
  if (XS) {
    int flat = bx + by * gridDim.x;
    int cpx = (gridDim.x * gridDim.y) >> 3;
    int s = (flat & 7) * cpx + (flat >> 3);
    bx = s % gridDim.x; by = s / gridDim.x;
  }
  int m0 = (SWAP ? by : bx) * 128;
  if (m0 >= Meff) return;
  int n0 = (SWAP ? bx : by) * 128;

  __shared__ __align__(16) char smem[32768];  // A0 A1 B0 B1, 8KB each
  const ushort_t* Bp = (BSRC == 1)
      ? (const ushort_t*)Bv + (long long)z * bB + (long long)kc * Kc : nullptr;
  const float* Bf = (BSRC == 0)
      ? (const float*)Bv + (long long)z * bB + (long long)kc * Kc : nullptr;

  int tid = threadIdx.x, lane = tid & 63, wave = tid >> 6;
  int wr = (wave >> 1) * 64, wc = (wave & 1) * 64;
  int l15 = lane & 15, l4 = lane >> 4;

  f32x4 acc[4][4];
#pragma unroll
  for (int m = 0; m < 4; ++m)
#pragma unroll
    for (int n = 0; n < 4; ++n) acc[m][n] = (f32x4){0.f, 0.f, 0.f, 0.f};

  auto stageG = [&](int buf, int k0) {
    ushort_t* dA = (ushort_t*)(smem + buf * 8192);
    ushort_t* dB = (ushort_t*)(smem + 16384 + buf * 8192);
#pragma unroll
    for (int i = 0; i < 2; ++i) {
      int idx = i * 2048 + tid * 8;
      int row = idx >> 5, chk = (idx >> 3) & 3;
      int scol = ((chk ^ ((row >> 1) & 3)) << 3);
      int ra = m0 + row; if (ra > Meff - 1) ra = Meff - 1;
      gld16(Ap + (long long)(rowStart + ra) * lda + k0 + scol, &dA[idx]);
    }
    if (BSRC == 1) {
#pragma unroll
      for (int i = 0; i < 2; ++i) {
        int idx = i * 2048 + tid * 8;
        int row = idx >> 5, chk = (idx >> 3) & 3;
        int scol = ((chk ^ ((row >> 1) & 3)) << 3);
        int rb = n0 + row; if (rb > N - 1) rb = N - 1;
        gld16(Bp + (long long)rb * ldb + k0 + scol, &dB[idx]);
      }
    } else {
#pragma unroll
      for (int i = 0; i < 4; ++i) {
        int g = tid + i * 256;               // float4 units, [0,1024)
        int r = g >> 3, c4 = (g & 7) * 4;
        int rb = n0 + r; if (rb > N - 1) rb = N - 1;
        float4 fv = *(const float4*)(Bf + (long long)rb * ldb + k0 + c4);
        s4v o; o[0] = (short)f2b(fv.x); o[1] = (short)f2b(fv.y);
        o[2] = (short)f2b(fv.z); o[3] = (short)f2b(fv.w);
        int dst = r * 32 + ((((c4 >> 3) ^ ((r >> 1) & 3))) << 3) + (c4 & 7);
        *(s4v*)&dB[dst] = o;
      }
    }
  };

  int nIt = Kc >> 5;
  stageG(0, 0);
  for (int it = 0; it < nIt; ++it) {
    int cur = it & 1;
    __syncthreads();                 // tile 'it' landed; prev reads done
    if (it + 1 < nIt) stageG(cur ^ 1, (it + 1) << 5);
    ushort_t* As = (ushort_t*)(smem + cur * 8192);
    ushort_t* Bs = (ushort_t*)(smem + 16384 + cur * 8192);
    bf16x8 af[4], bfr[4];
#pragma unroll
    for (int m = 0; m < 4; ++m) {
      int r = wr + m * 16 + l15;
      af[m] = *(const bf16x8*)&As[r * 32 + ((l4 ^ ((r >> 1) & 3)) << 3)];
    }
#pragma unroll
    for (int n = 0; n < 4; ++n) {
      int r = wc + n * 16 + l15;
      bfr[n] = *(const bf16x8*)&Bs[r * 32 + ((l4 ^ ((r >> 1) & 3)) << 3)];
    }
#pragma unroll
    for (int m = 0; m < 4; ++m)
#pragma unroll
      for (int n = 0; n < 4; ++n)
        acc[m][n] = MFMA(af[m], bfr[n], acc[m][n], 0, 0, 0);
  }
  __syncthreads();   // protect LDS before epilogue reuse

  if (EPI == 6 || EPI == 7) {
    float* fE = (float*)smem;        // 64x128 f32 = 32KB, fits exactly
#pragma unroll
    for (int h2 = 0; h2 < 2; ++h2) {
      if ((wave >> 1) == h2) {
#pragma unroll
        for (int m = 0; m < 4; ++m)
#pragma unroll
          for (int n = 0; n < 4; ++n)
#pragma unroll
            for (int q = 0; q < 4; ++q)
              fE[(m * 16 + l4 * 4 + q) * 128 + wc + n * 16 + l15] = acc[m][n][q];
      }
      __syncthreads();
#pragma unroll
      for (int i = 0; i < 8; ++i) {
        int lin = tid + i * 256;
        int row = lin >> 5, c4 = (lin & 31) << 2;
        int gr = m0 + h2 * 64 + row;
        if (gr < Meff) {
          f32x4 v4 = *(const f32x4*)&fE[row * 128 + c4];
          long long crow = rowStart + gr;
          float* dst = (float*)Cv + (EPI == 7 ? (long long)kc * pC : 0LL)
                       + crow * ldc + n0 + c4;
          if (EPI == 6) __builtin_nontemporal_store(v4, (f32x4*)dst);
          else          *(f32x4*)dst = v4;
        }
      }
      __syncthreads();
    }
    return;
  }

#pragma unroll
  for (int m = 0; m < 4; ++m) {
#pragma unroll
    for (int n = 0; n < 4; ++n) {
      int c = n0 + wc + n * 16 + l15;
      if (c >= N) continue;
      float bv = (EPI == 2) ? bias[(long long)z * bBias + c] : 0.f;
#pragma unroll
      for (int q = 0; q < 4; ++q) {
        int rr = m0 + wr + m * 16 + l4 * 4 + q;
        if (rr >= Meff) continue;
        float v = acc[m][n][q];
        long long crow = rowStart + rr;
        if (EPI == 2)
          ((ushort_t*)Cv)[crow * ldc + (long long)z * bC + c] = f2b(geluf(v + bv));
      }
    }
  }
}

#define G16_ARGS const ushort_t* A, int lda, long long bA, const void* Bv, \
    int ldb, long long bB, void* Cv, int ldc, long long bC, long long pC, \
    int M, int N, int K, const float* bias, int bBias, const int* offs
#define G16_PASS A, lda, bA, Bv, ldb, bB, Cv, ldc, bC, pC, M, N, K, bias, bBias, offs

__global__ __launch_bounds__(256) void k_moe1   (G16_ARGS) { gemm16_body<2,1,1,1,0>(G16_PASS); }
__global__ __launch_bounds__(256) void k_moe2   (G16_ARGS) { gemm16_body<7,1,1,2,0>(G16_PASS); }
__global__ __launch_bounds__(256) void k_head_bf(G16_ARGS) { gemm16_body<6,1,0,1,1>(G16_PASS); }
__global__ __launch_bounds__(256) void k_head_f (G16_ARGS) { gemm16_body<6,0,0,1,1>(G16_PASS); }

// ---------------------------------------------------------------------------
__global__ __launch_bounds__(256)
void cvt_split2(const float* __restrict__ s0, ushort_t* __restrict__ dh0,
                ushort_t* __restrict__ dl0,
                const float* __restrict__ s1, ushort_t* __restrict__ dh1,
                ushort_t* __restrict__ dl1, int n4)
{
  const float* s = blockIdx.y ? s1 : s0;
  ushort_t* dh = blockIdx.y ? dh1 : dh0;
  ushort_t* dl = blockIdx.y ? dl1 : dl0;
  int i = blockIdx.x * blockDim.x + threadIdx.x;
  int stride = gridDim.x * blockDim.x;
  for (; i < n4; i += stride) {
    float4 f = ((const float4*)s)[i];
    s4v h, l; ushort_t hh, ll;
    split2(f.x, hh, ll); h[0] = (short)hh; l[0] = (short)ll;
    split2(f.y, hh, ll); h[1] = (short)hh; l[1] = (short)ll;
    split2(f.z, hh, ll); h[2] = (short)hh; l[2] = (short)ll;
    split2(f.w, hh, ll); h[3] = (short)hh; l[3] = (short)ll;
    ((s4v*)dh)[i] = h; ((s4v*)dl)[i] = l;
  }
}

__global__ __launch_bounds__(256)
void cvt_bf16(const float* __restrict__ s, ushort_t* __restrict__ d, int n4)
{
  int i = blockIdx.x * blockDim.x + threadIdx.x;
  int stride = gridDim.x * blockDim.x;
  for (; i < n4; i += stride) {
    float4 f = ((const float4*)s)[i];
    s4v o; o[0] = (short)f2b(f.x); o[1] = (short)f2b(f.y);
    o[2] = (short)f2b(f.z); o[3] = (short)f2b(f.w);
    ((s4v*)d)[i] = o;
  }
}

__global__ __launch_bounds__(256)
void cvt_bf16_2(const float* __restrict__ s0, ushort_t* __restrict__ d0,
                const float* __restrict__ s1, ushort_t* __restrict__ d1, int n4)
{
  const float* s = blockIdx.y ? s1 : s0;
  ushort_t* d = blockIdx.y ? d1 : d0;
  int i = blockIdx.x * blockDim.x + threadIdx.x;
  int stride = gridDim.x * blockDim.x;
  for (; i < n4; i += stride) {
    float4 f = ((const float4*)s)[i];
    s4v o; o[0] = (short)f2b(f.x); o[1] = (short)f2b(f.y);
    o[2] = (short)f2b(f.z); o[3] = (short)f2b(f.w);
    ((s4v*)d)[i] = o;
  }
}

__global__ __launch_bounds__(256)
void embed_kernel(const int* __restrict__ ids, const float* __restrict__ ew,
                  const float* __restrict__ pw, float* __restrict__ x,
                  int* __restrict__ counts)
{
  int srow = blockIdx.x, tid = threadIdx.x;
  if (srow == 0 && tid < 8) counts[tid] = 0;
  int id = ids[srow];
  const float4 e = *(const float4*)(ew + (long long)id * DM + tid * 4);
  const float4 p = *(const float4*)(pw + (long long)srow * DM + tid * 4);
  float4* xr = (float4*)(x + (long long)srow * DM) + tid;
  *xr = make_float4(e.x + p.x, e.y + p.y, e.z + p.z, e.w + p.w);
}

template<int MODE, int NP>
__global__ __launch_bounds__(256)
void ln_fused(float* __restrict__ x, const float* __restrict__ P, long long pC,
              const float* __restrict__ bias_pre,
              const float* __restrict__ g, const float* __restrict__ b,
              ushort_t* __restrict__ outH, ushort_t* __restrict__ outL)
{
  int row = blockIdx.x, tid = threadIdx.x;
  long long xo = (long long)row * DM + tid * 4;
  float4 v = *(const float4*)(x + xo);
  if (NP > 0) {
    float4 bp = *(const float4*)(bias_pre + tid * 4);
    float sx = bp.x, sy = bp.y, sz = bp.z, sw = bp.w;
#pragma unroll
    for (int p = 0; p < NP; ++p) {
      float4 pv = *(const float4*)(P + (long long)p * pC + xo);
      sx += pv.x; sy += pv.y; sz += pv.z; sw += pv.w;
    }
    v.x += sx; v.y += sy; v.z += sz; v.w += sw;
    *(float4*)(x + xo) = v;
  }
  __shared__ float sm1[4], sm2[4];
  float s = v.x + v.y + v.z + v.w;
  for (int o = 32; o > 0; o >>= 1) s += __shfl_down(s, o);
  if ((tid & 63) == 0) sm1[tid >> 6] = s;
  __syncthreads();
  float mean = (sm1[0] + sm1[1] + sm1[2] + sm1[3]) * (1.0f / DM);
  float d0 = v.x - mean, d1 = v.y - mean, d2 = v.z - mean, d3 = v.w - mean;
  float q = d0 * d0 + d1 * d1 + d2 * d2 + d3 * d3;
  for (int o = 32; o > 0; o >>= 1) q += __shfl_down(q, o);
  if ((tid & 63) == 0) sm2[tid >> 6] = q;
  __syncthreads();
  float var = (sm2[0] + sm2[1] + sm2[2] + sm2[3]) * (1.0f / DM);
  float rstd = rsqrtf(var + 1e-5f);
  float4 gv = ((const float4*)g)[tid];
  float4 bv = ((const float4*)b)[tid];
  float o0 = d0 * rstd * gv.x + bv.x, o1 = d1 * rstd * gv.y + bv.y;
  float o2 = d2 * rstd * gv.z + bv.z, o3 = d3 * rstd * gv.w + bv.w;
  long long base = (long long)row * DM + tid * 4;
  if (MODE == 0) {
    ushort_t hh, ll;
    split2(o0, hh, ll); outH[base + 0] = hh; outL[base + 0] = ll;
    split2(o1, hh, ll); outH[base + 1] = hh; outL[base + 1] = ll;
    split2(o2, hh, ll); outH[base + 2] = hh; outL[base + 2] = ll;
    split2(o3, hh, ll); outH[base + 3] = hh; outL[base + 3] = ll;
  } else {
    outH[base + 0] = f2b(o0); outH[base + 1] = f2b(o1);
    outH[base + 2] = f2b(o2); outH[base + 3] = f2b(o3);
  }
}

__global__ __launch_bounds__(256)
void ln_gate_top2(float* __restrict__ x, const float* __restrict__ P,
                  long long pC, const float* __restrict__ bias_pre,
                  const float* __restrict__ g, const float* __restrict__ b,
                  const float* __restrict__ gw, const float* __restrict__ gb,
                  int* __restrict__ topi, float* __restrict__ topw,
                  int* __restrict__ counts, ushort_t* __restrict__ outH)
{
  int row = blockIdx.x, tid = threadIdx.x;
  long long xo = (long long)row * DM + tid * 4;
  float4 v = *(const float4*)(x + xo);
  {
    float4 bp = *(const float4*)(bias_pre + tid * 4);
    float sx = bp.x, sy = bp.y, sz = bp.z, sw = bp.w;
#pragma unroll
    for (int p = 0; p < 4; ++p) {
      float4 pv = *(const float4*)(P + (long long)p * pC + xo);
      sx += pv.x; sy += pv.y; sz += pv.z; sw += pv.w;
    }
    v.x += sx; v.y += sy; v.z += sz; v.w += sw;
    *(float4*)(x + xo) = v;
  }
  __shared__ float sm1[4], sm2[4];
  __shared__ float se[8][4];
  float s = v.x + v.y + v.z + v.w;
  for (int o = 32; o > 0; o >>= 1) s += __shfl_down(s, o);
  if ((tid & 63) == 0) sm1[tid >> 6] = s;
  __syncthreads();
  float mean = (sm1[0] + sm1[1] + sm1[2] + sm1[3]) * (1.0f / DM);
  float d0 = v.x - mean, d1 = v.y - mean, d2 = v.z - mean, d3 = v.w - mean;
  float q = d0 * d0 + d1 * d1 + d2 * d2 + d3 * d3;
  for (int o = 32; o > 0; o >>= 1) q += __shfl_down(q, o);
  if ((tid & 63) == 0) sm2[tid >> 6] = q;
  __syncthreads();
  float var = (sm2[0] + sm2[1] + sm2[2] + sm2[3]) * (1.0f / DM);
  float rstd = rsqrtf(var + 1e-5f);
  float4 gv = ((const float4*)g)[tid];
  float4 bv = ((const float4*)b)[tid];
  float h0 = d0 * rstd * gv.x + bv.x, h1 = d1 * rstd * gv.y + bv.y;
  float h2 = d2 * rstd * gv.z + bv.z, h3 = d3 * rstd * gv.w + bv.w;
  long long base = (long long)row * DM + tid * 4;
  outH[base + 0] = f2b(h0); outH[base + 1] = f2b(h1);
  outH[base + 2] = f2b(h2); outH[base + 3] = f2b(h3);
#pragma unroll
  for (int e = 0; e < 8; ++e) {
    float4 w = ((const float4*)(gw + (long long)e * DM))[tid];
    float p = h0 * w.x + h1 * w.y + h2 * w.z + h3 * w.w;
    for (int o = 32; o > 0; o >>= 1) p += __shfl_down(p, o);
    if ((tid & 63) == 0) se[e][tid >> 6] = p;
  }
  __syncthreads();
  if (tid == 0) {
    float sc[8];
#pragma unroll
    for (int e = 0; e < 8; ++e)
      sc[e] = se[e][0] + se[e][1] + se[e][2] + se[e][3] + gb[e];
    int i1 = 0; float m1 = sc[0];
    for (int e = 1; e < 8; ++e) if (sc[e] > m1) { m1 = sc[e]; i1 = e; }
    int i2 = -1; float m2 = -1e30f;
    for (int e = 0; e < 8; ++e) if (e != i1 && sc[e] > m2) { m2 = sc[e]; i2 = e; }
    float e2 = __expf(m2 - m1);
    float w1 = 1.f / (1.f + e2);
    topi[row * 2] = i1; topi[row * 2 + 1] = i2;
    topw[row * 2] = w1; topw[row * 2 + 1] = 1.f - w1;
    atomicAdd(&counts[i1], 1);
    atomicAdd(&counts[i2], 1);
  }
}

__global__ void moe_prefix(const int* __restrict__ counts, int* __restrict__ offs,
                           int* __restrict__ cursors)
{
  if (threadIdx.x == 0 && blockIdx.x == 0) {
    int a = 0;
    for (int e = 0; e < 8; ++e) { offs[e] = a; a += counts[e]; cursors[e] = 0; }
    offs[8] = a;
  }
}

__global__ __launch_bounds__(256)
void moe_gather(const ushort_t* __restrict__ hH, const int* __restrict__ topi,
                const float* __restrict__ topw, const int* __restrict__ offs,
                int* __restrict__ cursors, int* __restrict__ tokIdx,
                float* __restrict__ tokW, int* __restrict__ slotOf,
                ushort_t* __restrict__ Xg)
{
  int tok = blockIdx.x, tid = threadIdx.x;
  __shared__ int s0s, s1s;
  if (tid == 0) {
    int e0 = topi[tok * 2], e1 = topi[tok * 2 + 1];
    int s0 = offs[e0] + atomicAdd(&cursors[e0], 1);
    int s1 = offs[e1] + atomicAdd(&cursors[e1], 1);
    tokIdx[s0] = tok; tokW[s0] = topw[tok * 2];
    tokIdx[s1] = tok; tokW[s1] = topw[tok * 2 + 1];
    slotOf[tok * 2] = s0; slotOf[tok * 2 + 1] = s1;
    s0s = s0; s1s = s1;
  }
  __syncthreads();
  s4v v = ((const s4v*)(hH + (long long)tok * DM))[tid];
  ((s4v*)(Xg + (long long)s0s * DM))[tid] = v;
  ((s4v*)(Xg + (long long)s1s * DM))[tid] = v;
}

__global__ __launch_bounds__(256)
void moe_ln_final(const float* __restrict__ x, const float* __restrict__ eo,
                  long long pC, const int* __restrict__ slotOf,
                  const int* __restrict__ topi, const float* __restrict__ topw,
                  const float* __restrict__ b2, const float* __restrict__ g,
                  const float* __restrict__ b, ushort_t* __restrict__ outH)
{
  int tok = blockIdx.x, tid = threadIdx.x;
  int s0 = slotOf[tok * 2], s1 = slotOf[tok * 2 + 1];
  int e0 = topi[tok * 2], e1 = topi[tok * 2 + 1];
  float w0 = topw[tok * 2], w1 = topw[tok * 2 + 1];
  float4 a  = ((const float4*)(eo + (long long)s0 * DM))[tid];
  float4 a2 = ((const float4*)(eo + pC + (long long)s0 * DM))[tid];
  float4 bb1= ((const float4*)(eo + (long long)s1 * DM))[tid];
  float4 bb2= ((const float4*)(eo + pC + (long long)s1 * DM))[tid];
  float4 ba = ((const float4*)(b2 + (long long)e0 * DM))[tid];
  float4 bbb= ((const float4*)(b2 + (long long)e1 * DM))[tid];
  float4 v = ((const float4*)(x + (long long)tok * DM))[tid];
  v.x += w0 * (a.x + a2.x + ba.x) + w1 * (bb1.x + bb2.x + bbb.x);
  v.y += w0 * (a.y + a2.y + ba.y) + w1 * (bb1.y + bb2.y + bbb.y);
  v.z += w0 * (a.z + a2.z + ba.z) + w1 * (bb1.z + bb2.z + bbb.z);
  v.w += w0 * (a.w + a2.w + ba.w) + w1 * (bb1.w + bb2.w + bbb.w);
  __shared__ float sm1[4], sm2[4];
  float s = v.x + v.y + v.z + v.w;
  for (int o = 32; o > 0; o >>= 1) s += __shfl_down(s, o);
  if ((tid & 63) == 0) sm1[tid >> 6] = s;
  __syncthreads();
  float mean = (sm1[0] + sm1[1] + sm1[2] + sm1[3]) * (1.0f / DM);
  float d0 = v.x - mean, d1 = v.y - mean, d2 = v.z - mean, d3 = v.w - mean;
  float q = d0 * d0 + d1 * d1 + d2 * d2 + d3 * d3;
  for (int o = 32; o > 0; o >>= 1) q += __shfl_down(q, o);
  if ((tid & 63) == 0) sm2[tid >> 6] = q;
  __syncthreads();
  float var = (sm2[0] + sm2[1] + sm2[2] + sm2[3]) * (1.0f / DM);
  float rstd = rsqrtf(var + 1e-5f);
  float4 gv = ((const float4*)g)[tid];
  float4 bv = ((const float4*)b)[tid];
  long long base = (long long)tok * DM + tid * 4;
  outH[base + 0] = f2b(d0 * rstd * gv.x + bv.x);
  outH[base + 1] = f2b(d1 * rstd * gv.y + bv.y);
  outH[base + 2] = f2b(d2 * rstd * gv.z + bv.z);
  outH[base + 3] = f2b(d3 * rstd * gv.w + bv.w);
}

extern "C" void kernel_launch(void* const* d_in, const int* in_sizes, int n_in,
                              void* d_out, int out_size, void* d_ws, size_t ws_size,
                              hipStream_t stream)
{
  const int* ids = (const int*)d_in[0];
  const float* embed_w = (const float*)d_in[1];
  const float* pos_w   = (const float*)d_in[2];
  const float* ln1_g[2] = {(const float*)d_in[3],  (const float*)d_in[11]};
  const float* ln1_b[2] = {(const float*)d_in[4],  (const float*)d_in[12]};
  const float* in_w[2]  = {(const float*)d_in[5],  (const float*)d_in[13]};
  const float* in_b[2]  = {(const float*)d_in[6],  (const float*)d_in[14]};
  const float* out_w[2] = {(const float*)d_in[7],  (const float*)d_in[15]};
  const float* out_b[2] = {(const float*)d_in[8],  (const float*)d_in[16]};
  const float* ln2_g[2] = {(const float*)d_in[9],  (const float*)d_in[17]};
  const float* ln2_b[2] = {(const float*)d_in[10], (const float*)d_in[18]};
  const float* ffn_w1 = (const float*)d_in[19];
  const float* ffn_b1 = (const float*)d_in[20];
  const float* ffn_w2 = (const float*)d_in[21];
  const float* ffn_b2 = (const float*)d_in[22];
  const float* gate_w = (const float*)d_in[23];
  const float* gate_b = (const float*)d_in[24];
  const float* moe_w1 = (const float*)d_in[25];
  const float* moe_b1 = (const float*)d_in[26];
  const float* moe_w2 = (const float*)d_in[27];
  const float* moe_b2 = (const float*)d_in[28];
  const float* norm_g = (const float*)d_in[29];
  const float* norm_b = (const float*)d_in[30];
  const float* head_w = (const float*)d_in[31];

  char* ob = (char*)d_out;
  size_t off = 0;
  auto alloc = [&](size_t bytes) {
    char* p = ob + off;
    off = (off + bytes + 255) & ~(size_t)255;
    return p;
  };
  float*    x      = (float*)alloc((size_t)SQ * DM * 4);
  ushort_t* hbufH  = (ushort_t*)alloc((size_t)SQ * DM * 2);
  ushort_t* hbufL  = (ushort_t*)alloc((size_t)SQ * DM * 2);
  ushort_t* qkvH   = (ushort_t*)alloc((size_t)SQ * 3 * DM * 2);   // ┐
  ushort_t* qkvL   = (ushort_t*)alloc((size_t)SQ * 3 * DM * 2);   // │ w2b
  ushort_t* VtH    = (ushort_t*)alloc((size_t)NH * HDIM * SQ * 2);// │ 64MiB
  ushort_t* VtL    = (ushort_t*)alloc((size_t)NH * HDIM * SQ * 2);// │
  char*     resv   = (char*)alloc((size_t)32 << 20);              // ┘ filler
  ushort_t* attnH  = (ushort_t*)alloc((size_t)SQ * DM * 2);
  ushort_t* attnL  = (ushort_t*)alloc((size_t)SQ * DM * 2);
  ushort_t* Xg     = (ushort_t*)alloc((size_t)2 * SQ * DM * 2);
  int*      topi   = (int*)alloc(SQ * 2 * 4);
  float*    topw   = (float*)alloc(SQ * 2 * 4);
  int*      tokIdx = (int*)alloc(2 * SQ * 4);
  float*    tokW   = (float*)alloc(2 * SQ * 4);
  int*      slotOf = (int*)alloc(2 * SQ * 4);
  int*      counts = (int*)alloc(256);
  int*      offsb  = (int*)alloc(256);
  int*      cursors= (int*)alloc(256);
  ushort_t* ffnH   = (ushort_t*)alloc((size_t)SQ * FFD * 2);      // ┐ moehid
  ushort_t* ffnL   = (ushort_t*)alloc((size_t)SQ * FFD * 2);      // ┘ 32MiB
  float*    eo     = (float*)alloc((size_t)2 * 2 * SQ * DM * 4);  // 32MiB (also KS partials)
  ushort_t* inwH[2], *inwL[2], *outwH[2], *outwL[2];
  ushort_t* wsplit0 = (ushort_t*)alloc(0);
  inwH[0]  = (ushort_t*)alloc((size_t)3 * DM * DM * 2);
  inwL[0]  = (ushort_t*)alloc((size_t)3 * DM * DM * 2);
  inwH[1]  = (ushort_t*)alloc((size_t)3 * DM * DM * 2);
  inwL[1]  = (ushort_t*)alloc((size_t)3 * DM * DM * 2);
  outwH[0] = (ushort_t*)alloc((size_t)DM * DM * 2);
  outwL[0] = (ushort_t*)alloc((size_t)DM * DM * 2);
  outwH[1] = (ushort_t*)alloc((size_t)DM * DM * 2);
  outwL[1] = (ushort_t*)alloc((size_t)DM * DM * 2);
  ushort_t* f1H = (ushort_t*)alloc((size_t)FFD * DM * 2);
  ushort_t* f1L = (ushort_t*)alloc((size_t)FFD * DM * 2);
  ushort_t* f2H = (ushort_t*)alloc((size_t)DM * FFD * 2);
  ushort_t* f2L = (ushort_t*)alloc((size_t)DM * FFD * 2);
  ushort_t* moe_w1b = wsplit0;            // 64 MiB over weight planes
  ushort_t* moe_w2b = qkvH;               // 64 MiB over qkv+Vt+resv
  ushort_t* moehid  = ffnH;               // 32 MiB over ffn planes
  float*    pp      = eo;                 // KS partial planes
  const long long eoPC = (long long)2 * SQ * DM;
  const long long ppPC = (long long)SQ * DM;
  ushort_t* hfin    = (ushort_t*)d_ws;
  bool wsBig = ws_size >= ((size_t)70 << 20);
  ushort_t* head_wb = (ushort_t*)((char*)d_ws + ((size_t)4 << 20));
  (void)resv;

  embed_kernel<<<SQ, 256, 0, stream>>>(ids, embed_w, pos_w, x, counts);
  cvt_split2<<<dim3(512, 2), 256, 0, stream>>>(
      in_w[0], inwH[0], inwL[0], in_w[1], inwH[1], inwL[1], 3 * DM * DM / 4);
  cvt_split2<<<dim3(512, 2), 256, 0, stream>>>(
      out_w[0], outwH[0], outwL[0], out_w[1], outwH[1], outwL[1], DM * DM / 4);
  cvt_split2<<<dim3(512, 2), 256, 0, stream>>>(
      ffn_w1, f1H, f1L, ffn_w2, f2H, f2L, FFD * DM / 4);
  if (wsBig)
    cvt_bf16<<<1024, 256, 0, stream>>>(head_w, head_wb, NVOC * DM / 4);

  // ---- Layer 0 ----
  ln_fused<0, 0><<<SQ, 256, 0, stream>>>(x, nullptr, 0, nullptr,
                                         ln1_g[0], ln1_b[0], hbufH, hbufL);
  k_qkv<<<dim3(16, 24, 1), 256, 0, stream>>>(
      hbufH, hbufL, DM, 0, inwH[0], inwL[0], DM, 0,
      nullptr, qkvH, qkvL, 3 * DM, 0, 0,
      SQ, 3 * DM, DM, in_b[0], 1.f, VtH, VtL);
  k_attn<<<dim3(SQ / 64, NH), 256, 0, stream>>>(qkvH, qkvL, VtH, VtL,
                                                attnH, attnL);
  k_outp<<<dim3(16, 16, 4), 256, 0, stream>>>(
      attnH, attnL, DM, 0, outwH[0], outwL[0], DM, 0,
      pp, nullptr, nullptr, DM, 0, ppPC,
      SQ, DM, DM / 4, nullptr, 1.f, nullptr, nullptr);
  ln_fused<0, 4><<<SQ, 256, 0, stream>>>(x, pp, ppPC, out_b[0],
                                         ln2_g[0], ln2_b[0], hbufH, hbufL);
  k_ffn1<<<dim3(16, 32, 1), 256, 0, stream>>>(
      hbufH, hbufL, DM, 0, f1H, f1L, DM, 0,
      nullptr, ffnH, ffnL, FFD, 0, 0,
      SQ, FFD, DM, ffn_b1, 1.f, nullptr, nullptr);
  k_ffn2<<<dim3(16, 16, 2), 256, 0, stream>>>(
      ffnH, ffnL, FFD, 0, f2H, f2L, FFD, 0,
      pp, nullptr, nullptr, DM, 0, ppPC,
      SQ, DM, FFD / 2, nullptr, 1.f, nullptr, nullptr);
  // ---- Layer 1 ----
  ln_fused<0, 2><<<SQ, 256, 0, stream>>>(x, pp, ppPC, ffn_b2,
                                         ln1_g[1], ln1_b[1], hbufH, hbufL);
  k_qkv<<<dim3(16, 24, 1), 256, 0, stream>>>(
      hbufH, hbufL, DM, 0, inwH[1], inwL[1], DM, 0,
      nullptr, qkvH, qkvL, 3 * DM, 0, 0,
      SQ, 3 * DM, DM, in_b[1], 1.f, VtH, VtL);
  k_attn<<<dim3(SQ / 64, NH), 256, 0, stream>>>(qkvH, qkvL, VtH, VtL,
                                                attnH, attnL);
  k_outp<<<dim3(16, 16, 4), 256, 0, stream>>>(
      attnH, attnL, DM, 0, outwH[1], outwL[1], DM, 0,
      pp, nullptr, nullptr, DM, 0, ppPC,
      SQ, DM, DM / 4, nullptr, 1.f, nullptr, nullptr);
  cvt_bf16_2<<<dim3(2048, 2), 256, 0, stream>>>(
      moe_w1, moe_w1b, moe_w2, moe_w2b, 8 * FFD * DM / 4);
  ln_gate_top2<<<SQ, 256, 0, stream>>>(x, pp, ppPC, out_b[1],
                                       ln2_g[1], ln2_b[1], gate_w, gate_b,
                                       topi, topw, counts, hbufH);
  moe_prefix<<<1, 64, 0, stream>>>(counts, offsb, cursors);
  moe_gather<<<SQ, 256, 0, stream>>>(hbufH, topi, topw, offsb, cursors,
                                     tokIdx, tokW, slotOf, Xg);
  k_moe1<<<dim3(32, 16, 8), 256, 0, stream>>>(
      Xg, DM, 0, moe_w1b, DM, (long long)FFD * DM,
      moehid, FFD, 0, 0, SQ, FFD, DM, moe_b1, FFD, offsb);
  k_moe2<<<dim3(8, 16, 16), 256, 0, stream>>>(
      moehid, FFD, 0, moe_w2b, FFD, (long long)DM * FFD,
      eo, DM, 0, eoPC, SQ, DM, FFD, nullptr, 0, offsb);
  moe_ln_final<<<SQ, 256, 0, stream>>>(x, eo, eoPC, slotOf, topi, topw,
                                       moe_b2, norm_g, norm_b, hfin);
  if (wsBig)
    k_head_bf<<<dim3(16, 250, 1), 256, 0, stream>>>(
        hfin, DM, 0, head_wb, DM, 0, d_out, NVOC, 0, 0,
        SQ, NVOC, DM, nullptr, 0, nullptr);
  else
    k_head_f<<<dim3(16, 250, 1), 256, 0, stream>>>(
        hfin, DM, 0, head_w, DM, 0, d_out, NVOC, 0, 0,
        SQ, NVOC, DM, nullptr, 0, nullptr);
}

// Round 16
// 1140.484 us; speedup vs baseline: 1.9564x; 1.0037x over previous
//
#include <hip/hip_runtime.h>
#include <hip/hip_bf16.h>
#include <math.h>

typedef unsigned short ushort_t;
typedef __attribute__((ext_vector_type(8))) __bf16 bf16x8;
typedef __attribute__((ext_vector_type(4))) float f32x4;
typedef __attribute__((ext_vector_type(8))) short s8v;
typedef __attribute__((ext_vector_type(4))) short s4v;

#define SQ 2048
#define DM 1024
#define NH 16
#define HDIM 64
#define FFD 4096
#define NVOC 32000

__device__ inline float b2f(unsigned short u) {
  union { unsigned int i; float f; } x; x.i = ((unsigned int)u) << 16; return x.f;
}
__device__ inline unsigned short f2b(float f) {
  __hip_bfloat16 h = __float2bfloat16(f);
  return *reinterpret_cast<unsigned short*>(&h);
}
__device__ inline void split2(float x, ushort_t& h, ushort_t& l) {
  h = f2b(x);
  l = f2b(x - b2f(h));
}
__device__ inline float geluf(float v) {
  return 0.5f * v * (1.0f + erff(v * 0.70710678118654752f));
}
__device__ __forceinline__ void gld16(const void* g, void* l) {
  __builtin_amdgcn_global_load_lds(
      (const __attribute__((address_space(1))) void*)g,
      (__attribute__((address_space(3))) void*)l, 16, 0, 0);
}
#define MFMA __builtin_amdgcn_mfma_f32_16x16x32_bf16

// ---------------------------------------------------------------------------
// Split GEMM engine (pre-gate math), 2-phase double-buffered.
// EPI: 2 f32 partial store (kc*pC), 4 gelu+bias split-store,
//      5 split-store+bias with V-region (n0>=2048) written TRANSPOSED to TH/TL.
// ---------------------------------------------------------------------------
template<int EPI, int NT, int KS>
__device__ __forceinline__ void gemmsp_body(
    const ushort_t* __restrict__ AH, const ushort_t* __restrict__ AL,
    int lda, long long bA,
    const ushort_t* __restrict__ BH, const ushort_t* __restrict__ BL,
    int ldb, long long bB,
    float* __restrict__ C, ushort_t* __restrict__ CH, ushort_t* __restrict__ CL,
    int ldc, long long bC, long long pC,
    int M, int N, int K, const float* __restrict__ bias, float alpha,
    ushort_t* __restrict__ TH, ushort_t* __restrict__ TL)
{
  int z = blockIdx.z, h = z / KS, kc = z % KS;
  const ushort_t* AHp = AH + (long long)h * bA + (long long)kc * K;
  const ushort_t* ALp = AL + (long long)h * bA + (long long)kc * K;
  const ushort_t* BHp = BH + (long long)h * bB + (long long)kc * K;
  const ushort_t* BLp = BL + (long long)h * bB + (long long)kc * K;
  int m0 = blockIdx.x * 128, n0 = blockIdx.y * NT;
  const int NF = NT / 32;

  __shared__ __align__(16) ushort_t sAH[2][128 * 32], sAL[2][128 * 32];
  __shared__ __align__(16) ushort_t sBH[2][NT * 32],  sBL[2][NT * 32];

  int tid = threadIdx.x, lane = tid & 63, wave = tid >> 6;
  int wr = (wave >> 1) * 64, wc = (wave & 1) * (NT >> 1);
  int l15 = lane & 15, l4 = lane >> 4;

  f32x4 acc[4][NF];
#pragma unroll
  for (int m = 0; m < 4; ++m)
#pragma unroll
    for (int n = 0; n < NF; ++n) acc[m][n] = (f32x4){0.f, 0.f, 0.f, 0.f};

  auto stageG = [&](int buf, int k0) {
#pragma unroll
    for (int i = 0; i < 2; ++i) {
      int fi = i * 2048 + tid * 8;
      int r = fi >> 5, chk = (fi >> 3) & 3;
      int scol = ((chk ^ ((r >> 1) & 3)) << 3);
      int ra = m0 + r; if (ra > M - 1) ra = M - 1;
      long long go = (long long)ra * lda + k0 + scol;
      gld16(AHp + go, &sAH[buf][fi]);
      gld16(ALp + go, &sAL[buf][fi]);
    }
#pragma unroll
    for (int i = 0; i < NT / 64; ++i) {
      int fi = i * 2048 + tid * 8;
      int r = fi >> 5, chk = (fi >> 3) & 3;
      int scol = ((chk ^ ((r >> 1) & 3)) << 3);
      int rb = n0 + r; if (rb > N - 1) rb = N - 1;
      long long go = (long long)rb * ldb + k0 + scol;
      gld16(BHp + go, &sBH[buf][fi]);
      gld16(BLp + go, &sBL[buf][fi]);
    }
  };

  int nIt = K >> 5;
  stageG(0, 0);
  for (int it = 0; it < nIt; ++it) {
    int cur = it & 1;
    __syncthreads();
    if (it + 1 < nIt) stageG(cur ^ 1, (it + 1) << 5);
    bf16x8 ah[4], al[4], bh[NF], bl[NF];
#pragma unroll
    for (int m = 0; m < 4; ++m) {
      int r = wr + m * 16 + l15;
      int o = r * 32 + ((l4 ^ ((r >> 1) & 3)) << 3);
      ah[m] = *(const bf16x8*)&sAH[cur][o];
      al[m] = *(const bf16x8*)&sAL[cur][o];
    }
#pragma unroll
    for (int n = 0; n < NF; ++n) {
      int r = wc + n * 16 + l15;
      int o = r * 32 + ((l4 ^ ((r >> 1) & 3)) << 3);
      bh[n] = *(const bf16x8*)&sBH[cur][o];
      bl[n] = *(const bf16x8*)&sBL[cur][o];
    }
#pragma unroll
    for (int m = 0; m < 4; ++m)
#pragma unroll
      for (int n = 0; n < NF; ++n) {
        acc[m][n] = MFMA(ah[m], bh[n], acc[m][n], 0, 0, 0);
        acc[m][n] = MFMA(al[m], bh[n], acc[m][n], 0, 0, 0);
        acc[m][n] = MFMA(ah[m], bl[n], acc[m][n], 0, 0, 0);
      }
  }

  if (EPI == 5 && n0 >= 2 * DM) {
#pragma unroll
    for (int m = 0; m < 4; ++m) {
      int rbase = m0 + wr + m * 16 + l4 * 4;
#pragma unroll
      for (int n = 0; n < NF; ++n) {
        int c = n0 + wc + n * 16 + l15;
        int d = c - 2 * DM;
        float bv = bias[c];
        s4v hv, lv;
#pragma unroll
        for (int q = 0; q < 4; ++q) {
          ushort_t hh, ll; split2(acc[m][n][q] + bv, hh, ll);
          hv[q] = (short)hh; lv[q] = (short)ll;
        }
        *(s4v*)&TH[(long long)d * SQ + rbase] = hv;
        *(s4v*)&TL[(long long)d * SQ + rbase] = lv;
      }
    }
    return;
  }

#pragma unroll
  for (int m = 0; m < 4; ++m) {
#pragma unroll
    for (int n = 0; n < NF; ++n) {
      int c = n0 + wc + n * 16 + l15;
      if (c >= N) continue;
      float bv = (EPI == 4 || EPI == 5) ? bias[c] : 0.f;
#pragma unroll
      for (int q = 0; q < 4; ++q) {
        int rr = m0 + wr + m * 16 + l4 * 4 + q;
        if (rr >= M) continue;
        float v = acc[m][n][q];
        if (EPI == 5) {
          ushort_t hh, ll; split2(v + bv, hh, ll);
          long long o = (long long)rr * ldc + c; CH[o] = hh; CL[o] = ll;
        } else if (EPI == 2) {
          C[(long long)kc * pC + (long long)rr * ldc + (long long)h * bC + c] = v;
        } else if (EPI == 4) {
          ushort_t hh, ll; split2(geluf(v + bv), hh, ll);
          long long o = (long long)rr * ldc + c; CH[o] = hh; CL[o] = ll;
        }
      }
    }
  }
}

#define SP_ARGS const ushort_t* AH, const ushort_t* AL, int lda, long long bA, \
    const ushort_t* BH, const ushort_t* BL, int ldb, long long bB, \
    float* C, ushort_t* CH, ushort_t* CL, int ldc, long long bC, long long pC, \
    int M, int N, int K, const float* bias, float alpha, \
    ushort_t* TH, ushort_t* TL
#define SP_PASS AH, AL, lda, bA, BH, BL, ldb, bB, C, CH, CL, ldc, bC, pC, M, N, K, bias, alpha, TH, TL

__global__ __launch_bounds__(256) void k_qkv (SP_ARGS) { gemmsp_body<5,128,1>(SP_PASS); }
__global__ __launch_bounds__(256) void k_outp(SP_ARGS) { gemmsp_body<2, 64,4>(SP_PASS); }
__global__ __launch_bounds__(256) void k_ffn1(SP_ARGS) { gemmsp_body<4,128,1>(SP_PASS); }
__global__ __launch_bounds__(256) void k_ffn2(SP_ARGS) { gemmsp_body<2, 64,2>(SP_PASS); }

// ---------------------------------------------------------------------------
// Fused flash attention, split-f32 precision. Grid (32,16).
// K/V double-buffered: next tile's gld16 issued right after loop-top barrier,
// in flight under QK^T+softmax+PV of the current tile. P single-buffered
// (write-after-read ordered by the loop-top barrier). LDS 80KB -> 2 blocks/CU
// (grid already caps at 2/CU, so occupancy unchanged).
// ---------------------------------------------------------------------------
__global__ __launch_bounds__(256)
void k_attn(const ushort_t* __restrict__ qkvH, const ushort_t* __restrict__ qkvL,
            const ushort_t* __restrict__ VtH, const ushort_t* __restrict__ VtL,
            ushort_t* __restrict__ aH, ushort_t* __restrict__ aL)
{
  int f = blockIdx.x + blockIdx.y * gridDim.x;
  int logical = (f & 7) * 64 + (f >> 3);
  int q0 = (logical & 31) * 64;
  int h  = logical >> 5;

  __shared__ __align__(16) ushort_t sKH[2][4096], sKL[2][4096];
  __shared__ __align__(16) ushort_t sVH[2][4096], sVL[2][4096];
  __shared__ __align__(16) ushort_t sPH[4096], sPL[4096];

  int tid = threadIdx.x, lane = tid & 63, wave = tid >> 6;
  int l15 = lane & 15, l4 = lane >> 4;

  bf16x8 qh[2], ql[2];
  {
    long long base = (long long)(q0 + wave * 16 + l15) * (3 * DM) + h * 64 + l4 * 8;
    qh[0] = *(const bf16x8*)(qkvH + base);
    qh[1] = *(const bf16x8*)(qkvH + base + 32);
    ql[0] = *(const bf16x8*)(qkvL + base);
    ql[1] = *(const bf16x8*)(qkvL + base + 32);
  }

  auto stageKV = [&](int buf, int kt) {
#pragma unroll
    for (int i = 0; i < 2; ++i) {
      int idx = i * 2048 + tid * 8;
      int row = idx >> 6, chk = (idx >> 3) & 7;
      int scol = ((chk ^ (row & 7)) << 3);
      long long gk = (long long)(kt * 64 + row) * (3 * DM) + DM + h * 64 + scol;
      long long gv = (long long)(h * 64 + row) * SQ + kt * 64 + scol;
      gld16(qkvH + gk, &sKH[buf][idx]);
      gld16(qkvL + gk, &sKL[buf][idx]);
      gld16(VtH + gv, &sVH[buf][idx]);
      gld16(VtL + gv, &sVL[buf][idx]);
    }
  };

  float mrow[4], lrow[4];
  f32x4 Oacc[4];
#pragma unroll
  for (int r = 0; r < 4; ++r) { mrow[r] = -1e30f; lrow[r] = 0.f; }
#pragma unroll
  for (int n = 0; n < 4; ++n) Oacc[n] = (f32x4){0.f, 0.f, 0.f, 0.f};

  const int NT = SQ / 64;
  stageKV(0, 0);
  for (int kt = 0; kt < NT; ++kt) {
    int cur = kt & 1;
    __syncthreads();                 // K/V[cur] landed; prev-tile P reads done
    if (kt + 1 < NT) stageKV(cur ^ 1, kt + 1);

    f32x4 S[4];
#pragma unroll
    for (int n = 0; n < 4; ++n) S[n] = (f32x4){0.f, 0.f, 0.f, 0.f};
#pragma unroll
    for (int kk = 0; kk < 64; kk += 32) {
      int kkI = kk >> 5;
      bf16x8 qhf = qh[kkI], qlf = ql[kkI];
#pragma unroll
      for (int n = 0; n < 4; ++n) {
        int br = n * 16 + l15;
        int bo = br * 64 + ((((kk >> 3) + l4) ^ (br & 7)) << 3);
        bf16x8 kh = *(const bf16x8*)&sKH[cur][bo];
        bf16x8 kl = *(const bf16x8*)&sKL[cur][bo];
        S[n] = MFMA(qhf, kh, S[n], 0, 0, 0);
        S[n] = MFMA(qlf, kh, S[n], 0, 0, 0);
        S[n] = MFMA(qhf, kl, S[n], 0, 0, 0);
      }
    }
    float tm[4], ts[4];
#pragma unroll
    for (int r = 0; r < 4; ++r) {
#pragma unroll
      for (int n = 0; n < 4; ++n) S[n][r] *= 0.125f;
      tm[r] = fmaxf(fmaxf(S[0][r], S[1][r]), fmaxf(S[2][r], S[3][r]));
    }
#pragma unroll
    for (int mk = 1; mk <= 8; mk <<= 1)
#pragma unroll
      for (int r = 0; r < 4; ++r) tm[r] = fmaxf(tm[r], __shfl_xor(tm[r], mk));
#pragma unroll
    for (int r = 0; r < 4; ++r) {
      float mn = fmaxf(mrow[r], tm[r]);
      float corr = __expf(mrow[r] - mn);
      mrow[r] = mn;
      float s = 0.f;
#pragma unroll
      for (int n = 0; n < 4; ++n) { S[n][r] = __expf(S[n][r] - mn); s += S[n][r]; }
      ts[r] = s;
      lrow[r] *= corr;
#pragma unroll
      for (int n = 0; n < 4; ++n) Oacc[n][r] *= corr;
    }
#pragma unroll
    for (int mk = 1; mk <= 8; mk <<= 1)
#pragma unroll
      for (int r = 0; r < 4; ++r) ts[r] += __shfl_xor(ts[r], mk);
#pragma unroll
    for (int r = 0; r < 4; ++r) lrow[r] += ts[r];

    {
      ushort_t* pH = &sPH[wave * 1024];
      ushort_t* pL = &sPL[wave * 1024];
#pragma unroll
      for (int n = 0; n < 4; ++n)
#pragma unroll
        for (int r = 0; r < 4; ++r) {
          int row = l4 * 4 + r, col = n * 16 + l15;
          int ad = row * 64 + (((col >> 3) ^ (row & 7)) << 3) + (col & 7);
          ushort_t hh, ll; split2(S[n][r], hh, ll);
          pH[ad] = hh; pL[ad] = ll;
        }
    }
    __syncthreads();                 // P visible; V[cur] still resident
#pragma unroll
    for (int kk = 0; kk < 64; kk += 32) {
      int ao = wave * 1024 + l15 * 64 + ((((kk >> 3) + l4) ^ (l15 & 7)) << 3);
      bf16x8 ph = *(const bf16x8*)&sPH[ao];
      bf16x8 pl = *(const bf16x8*)&sPL[ao];
#pragma unroll
      for (int n = 0; n < 4; ++n) {
        int br = n * 16 + l15;
        int bo = br * 64 + ((((kk >> 3) + l4) ^ (br & 7)) << 3);
        bf16x8 vh = *(const bf16x8*)&sVH[cur][bo];
        bf16x8 vl = *(const bf16x8*)&sVL[cur][bo];
        Oacc[n] = MFMA(ph, vh, Oacc[n], 0, 0, 0);
        Oacc[n] = MFMA(pl, vh, Oacc[n], 0, 0, 0);
        Oacc[n] = MFMA(ph, vl, Oacc[n], 0, 0, 0);
      }
    }
  }

#pragma unroll
  for (int n = 0; n < 4; ++n)
#pragma unroll
    for (int r = 0; r < 4; ++r) {
      int q = q0 + wave * 16 + l4 * 4 + r;
      int d = h * 64 + n * 16 + l15;
      float val = Oacc[n][r] / lrow[r];
      ushort_t hh, ll; split2(val, hh, ll);
      long long o = (long long)q * DM + d;
      aH[o] = hh; aL[o] = ll;
    }
}

// ---------------------------------------------------------------------------
// bf16 GEMM engine (post-gate), 2-phase double-buffered with BK=32:
// 32KB LDS (4 x 8KB: A0 A1 B0 B1) -> 5 blocks/CU.
// ---------------------------------------------------------------------------
template<int EPI, int BSRC, int SWAP, int KS, int XS>
__device__ __forceinline__ void gemm16_body(
    const ushort_t* __restrict__ A, int lda, long long bA,
    const void* __restrict__ Bv, int ldb, long long bB,
    void* __restrict__ Cv, int ldc, long long bC, long long pC,
    int M, int N, int K, const float* __restrict__ bias, int bBias,
    const int* __restrict__ offs)
{
  int bz = blockIdx.z;
  int z = bz / KS, kc = bz % KS;
  int Kc = K / KS;
  const ushort_t* Ap = A + (long long)z * bA + (long long)kc * Kc;
  int rowStart = 0, Meff = M;
  if (offs) { rowStart = offs[z]; Meff = offs[z + 1] - rowStart; }
  int bx = blockIdx.x, by = blockIdx.y;
  if (XS) {
    int flat = bx + by * gridDim.x;
    int cpx = (gridDim.x * gridDim.y) >> 3;
    int s = (flat & 7) * cpx + (flat >> 3);
    bx = s % gridDim.x; by = s / gridDim.x;
  }
  int m0 = (SWAP ? by : bx) * 128;
  if (m0 >= Meff) return;
  int n0 = (SWAP ? bx : by) * 128;

  __shared__ __align__(16) char smem[32768];
  const ushort_t* Bp = (BSRC == 1)
      ? (const ushort_t*)Bv + (long long)z * bB + (long long)kc * Kc : nullptr;
  const float* Bf = (BSRC == 0)
      ? (const float*)Bv + (long long)z * bB + (long long)kc * Kc : nullptr;

  int tid = threadIdx.x, lane = tid & 63, wave = tid >> 6;
  int wr = (wave >> 1) * 64, wc = (wave & 1) * 64;
  int l15 = lane & 15, l4 = lane >> 4;

  f32x4 acc[4][4];
#pragma unroll
  for (int m = 0; m < 4; ++m)
#pragma unroll
    for (int n = 0; n < 4; ++n) acc[m][n] = (f32x4){0.f, 0.f, 0.f, 0.f};

  auto stageG = [&](int buf, int k0) {
    ushort_t* dA = (ushort_t*)(smem + buf * 8192);
    ushort_t* dB = (ushort_t*)(smem + 16384 + buf * 8192);
#pragma unroll
    for (int i = 0; i < 2; ++i) {
      int idx = i * 2048 + tid * 8;
      int row = idx >> 5, chk = (idx >> 3) & 3;
      int scol = ((chk ^ ((row >> 1) & 3)) << 3);
      int ra = m0 + row; if (ra > Meff - 1) ra = Meff - 1;
      gld16(Ap + (long long)(rowStart + ra) * lda + k0 + scol, &dA[idx]);
    }
    if (BSRC == 1) {
#pragma unroll
      for (int i = 0; i < 2; ++i) {
        int idx = i * 2048 + tid * 8;
        int row = idx >> 5, chk = (idx >> 3) & 3;
        int scol = ((chk ^ ((row >> 1) & 3)) << 3);
        int rb = n0 + row; if (rb > N - 1) rb = N - 1;
        gld16(Bp + (long long)rb * ldb + k0 + scol, &dB[idx]);
      }
    } else {
#pragma unroll
      for (int i = 0; i < 4; ++i) {
        int g = tid + i * 256;
        int r = g >> 3, c4 = (g & 7) * 4;
        int rb = n0 + r; if (rb > N - 1) rb = N - 1;
        float4 fv = *(const float4*)(Bf + (long long)rb * ldb + k0 + c4);
        s4v o; o[0] = (short)f2b(fv.x); o[1] = (short)f2b(fv.y);
        o[2] = (short)f2b(fv.z); o[3] = (short)f2b(fv.w);
        int dst = r * 32 + ((((c4 >> 3) ^ ((r >> 1) & 3))) << 3) + (c4 & 7);
        *(s4v*)&dB[dst] = o;
      }
    }
  };

  int nIt = Kc >> 5;
  stageG(0, 0);
  for (int it = 0; it < nIt; ++it) {
    int cur = it & 1;
    __syncthreads();
    if (it + 1 < nIt) stageG(cur ^ 1, (it + 1) << 5);
    ushort_t* As = (ushort_t*)(smem + cur * 8192);
    ushort_t* Bs = (ushort_t*)(smem + 16384 + cur * 8192);
    bf16x8 af[4], bfr[4];
#pragma unroll
    for (int m = 0; m < 4; ++m) {
      int r = wr + m * 16 + l15;
      af[m] = *(const bf16x8*)&As[r * 32 + ((l4 ^ ((r >> 1) & 3)) << 3)];
    }
#pragma unroll
    for (int n = 0; n < 4; ++n) {
      int r = wc + n * 16 + l15;
      bfr[n] = *(const bf16x8*)&Bs[r * 32 + ((l4 ^ ((r >> 1) & 3)) << 3)];
    }
#pragma unroll
    for (int m = 0; m < 4; ++m)
#pragma unroll
      for (int n = 0; n < 4; ++n)
        acc[m][n] = MFMA(af[m], bfr[n], acc[m][n], 0, 0, 0);
  }
  __syncthreads();

  if (EPI == 6 || EPI == 7) {
    float* fE = (float*)smem;
#pragma unroll
    for (int h2 = 0; h2 < 2; ++h2) {
      if ((wave >> 1) == h2) {
#pragma unroll
        for (int m = 0; m < 4; ++m)
#pragma unroll
          for (int n = 0; n < 4; ++n)
#pragma unroll
            for (int q = 0; q < 4; ++q)
              fE[(m * 16 + l4 * 4 + q) * 128 + wc + n * 16 + l15] = acc[m][n][q];
      }
      __syncthreads();
#pragma unroll
      for (int i = 0; i < 8; ++i) {
        int lin = tid + i * 256;
        int row = lin >> 5, c4 = (lin & 31) << 2;
        int gr = m0 + h2 * 64 + row;
        if (gr < Meff) {
          f32x4 v4 = *(const f32x4*)&fE[row * 128 + c4];
          long long crow = rowStart + gr;
          float* dst = (float*)Cv + (EPI == 7 ? (long long)kc * pC : 0LL)
                       + crow * ldc + n0 + c4;
          if (EPI == 6) __builtin_nontemporal_store(v4, (f32x4*)dst);
          else          *(f32x4*)dst = v4;
        }
      }
      __syncthreads();
    }
    return;
  }

#pragma unroll
  for (int m = 0; m < 4; ++m) {
#pragma unroll
    for (int n = 0; n < 4; ++n) {
      int c = n0 + wc + n * 16 + l15;
      if (c >= N) continue;
      float bv = (EPI == 2) ? bias[(long long)z * bBias + c] : 0.f;
#pragma unroll
      for (int q = 0; q < 4; ++q) {
        int rr = m0 + wr + m * 16 + l4 * 4 + q;
        if (rr >= Meff) continue;
        float v = acc[m][n][q];
        long long crow = rowStart + rr;
        if (EPI == 2)
          ((ushort_t*)Cv)[crow * ldc + (long long)z * bC + c] = f2b(geluf(v + bv));
      }
    }
  }
}

#define G16_ARGS const ushort_t* A, int lda, long long bA, const void* Bv, \
    int ldb, long long bB, void* Cv, int ldc, long long bC, long long pC, \
    int M, int N, int K, const float* bias, int bBias, const int* offs
#define G16_PASS A, lda, bA, Bv, ldb, bB, Cv, ldc, bC, pC, M, N, K, bias, bBias, offs

__global__ __launch_bounds__(256) void k_moe1   (G16_ARGS) { gemm16_body<2,1,1,1,0>(G16_PASS); }
__global__ __launch_bounds__(256) void k_moe2   (G16_ARGS) { gemm16_body<7,1,1,2,0>(G16_PASS); }
__global__ __launch_bounds__(256) void k_head_bf(G16_ARGS) { gemm16_body<6,1,0,1,1>(G16_PASS); }
__global__ __launch_bounds__(256) void k_head_f (G16_ARGS) { gemm16_body<6,0,0,1,1>(G16_PASS); }

// ---------------------------------------------------------------------------
__global__ __launch_bounds__(256)
void cvt_split2(const float* __restrict__ s0, ushort_t* __restrict__ dh0,
                ushort_t* __restrict__ dl0,
                const float* __restrict__ s1, ushort_t* __restrict__ dh1,
                ushort_t* __restrict__ dl1, int n4)
{
  const float* s = blockIdx.y ? s1 : s0;
  ushort_t* dh = blockIdx.y ? dh1 : dh0;
  ushort_t* dl = blockIdx.y ? dl1 : dl0;
  int i = blockIdx.x * blockDim.x + threadIdx.x;
  int stride = gridDim.x * blockDim.x;
  for (; i < n4; i += stride) {
    float4 f = ((const float4*)s)[i];
    s4v h, l; ushort_t hh, ll;
    split2(f.x, hh, ll); h[0] = (short)hh; l[0] = (short)ll;
    split2(f.y, hh, ll); h[1] = (short)hh; l[1] = (short)ll;
    split2(f.z, hh, ll); h[2] = (short)hh; l[2] = (short)ll;
    split2(f.w, hh, ll); h[3] = (short)hh; l[3] = (short)ll;
    ((s4v*)dh)[i] = h; ((s4v*)dl)[i] = l;
  }
}

__global__ __launch_bounds__(256)
void cvt_bf16(const float* __restrict__ s, ushort_t* __restrict__ d, int n4)
{
  int i = blockIdx.x * blockDim.x + threadIdx.x;
  int stride = gridDim.x * blockDim.x;
  for (; i < n4; i += stride) {
    float4 f = ((const float4*)s)[i];
    s4v o; o[0] = (short)f2b(f.x); o[1] = (short)f2b(f.y);
    o[2] = (short)f2b(f.z); o[3] = (short)f2b(f.w);
    ((s4v*)d)[i] = o;
  }
}

__global__ __launch_bounds__(256)
void cvt_bf16_2(const float* __restrict__ s0, ushort_t* __restrict__ d0,
                const float* __restrict__ s1, ushort_t* __restrict__ d1, int n4)
{
  const float* s = blockIdx.y ? s1 : s0;
  ushort_t* d = blockIdx.y ? d1 : d0;
  int i = blockIdx.x * blockDim.x + threadIdx.x;
  int stride = gridDim.x * blockDim.x;
  for (; i < n4; i += stride) {
    float4 f = ((const float4*)s)[i];
    s4v o; o[0] = (short)f2b(f.x); o[1] = (short)f2b(f.y);
    o[2] = (short)f2b(f.z); o[3] = (short)f2b(f.w);
    ((s4v*)d)[i] = o;
  }
}

__global__ __launch_bounds__(256)
void embed_kernel(const int* __restrict__ ids, const float* __restrict__ ew,
                  const float* __restrict__ pw, float* __restrict__ x,
                  int* __restrict__ counts)
{
  int srow = blockIdx.x, tid = threadIdx.x;
  if (srow == 0 && tid < 8) counts[tid] = 0;
  int id = ids[srow];
  const float4 e = *(const float4*)(ew + (long long)id * DM + tid * 4);
  const float4 p = *(const float4*)(pw + (long long)srow * DM + tid * 4);
  float4* xr = (float4*)(x + (long long)srow * DM) + tid;
  *xr = make_float4(e.x + p.x, e.y + p.y, e.z + p.z, e.w + p.w);
}

template<int MODE, int NP>
__global__ __launch_bounds__(256)
void ln_fused(float* __restrict__ x, const float* __restrict__ P, long long pC,
              const float* __restrict__ bias_pre,
              const float* __restrict__ g, const float* __restrict__ b,
              ushort_t* __restrict__ outH, ushort_t* __restrict__ outL)
{
  int row = blockIdx.x, tid = threadIdx.x;
  long long xo = (long long)row * DM + tid * 4;
  float4 v = *(const float4*)(x + xo);
  if (NP > 0) {
    float4 bp = *(const float4*)(bias_pre + tid * 4);
    float sx = bp.x, sy = bp.y, sz = bp.z, sw = bp.w;
#pragma unroll
    for (int p = 0; p < NP; ++p) {
      float4 pv = *(const float4*)(P + (long long)p * pC + xo);
      sx += pv.x; sy += pv.y; sz += pv.z; sw += pv.w;
    }
    v.x += sx; v.y += sy; v.z += sz; v.w += sw;
    *(float4*)(x + xo) = v;
  }
  __shared__ float sm1[4], sm2[4];
  float s = v.x + v.y + v.z + v.w;
  for (int o = 32; o > 0; o >>= 1) s += __shfl_down(s, o);
  if ((tid & 63) == 0) sm1[tid >> 6] = s;
  __syncthreads();
  float mean = (sm1[0] + sm1[1] + sm1[2] + sm1[3]) * (1.0f / DM);
  float d0 = v.x - mean, d1 = v.y - mean, d2 = v.z - mean, d3 = v.w - mean;
  float q = d0 * d0 + d1 * d1 + d2 * d2 + d3 * d3;
  for (int o = 32; o > 0; o >>= 1) q += __shfl_down(q, o);
  if ((tid & 63) == 0) sm2[tid >> 6] = q;
  __syncthreads();
  float var = (sm2[0] + sm2[1] + sm2[2] + sm2[3]) * (1.0f / DM);
  float rstd = rsqrtf(var + 1e-5f);
  float4 gv = ((const float4*)g)[tid];
  float4 bv = ((const float4*)b)[tid];
  float o0 = d0 * rstd * gv.x + bv.x, o1 = d1 * rstd * gv.y + bv.y;
  float o2 = d2 * rstd * gv.z + bv.z, o3 = d3 * rstd * gv.w + bv.w;
  long long base = (long long)row * DM + tid * 4;
  if (MODE == 0) {
    ushort_t hh, ll;
    split2(o0, hh, ll); outH[base + 0] = hh; outL[base + 0] = ll;
    split2(o1, hh, ll); outH[base + 1] = hh; outL[base + 1] = ll;
    split2(o2, hh, ll); outH[base + 2] = hh; outL[base + 2] = ll;
    split2(o3, hh, ll); outH[base + 3] = hh; outL[base + 3] = ll;
  } else {
    outH[base + 0] = f2b(o0); outH[base + 1] = f2b(o1);
    outH[base + 2] = f2b(o2); outH[base + 3] = f2b(o3);
  }
}

__global__ __launch_bounds__(256)
void ln_gate_top2(float* __restrict__ x, const float* __restrict__ P,
                  long long pC, const float* __restrict__ bias_pre,
                  const float* __restrict__ g, const float* __restrict__ b,
                  const float* __restrict__ gw, const float* __restrict__ gb,
                  int* __restrict__ topi, float* __restrict__ topw,
                  int* __restrict__ counts, ushort_t* __restrict__ outH)
{
  int row = blockIdx.x, tid = threadIdx.x;
  long long xo = (long long)row * DM + tid * 4;
  float4 v = *(const float4*)(x + xo);
  {
    float4 bp = *(const float4*)(bias_pre + tid * 4);
    float sx = bp.x, sy = bp.y, sz = bp.z, sw = bp.w;
#pragma unroll
    for (int p = 0; p < 4; ++p) {
      float4 pv = *(const float4*)(P + (long long)p * pC + xo);
      sx += pv.x; sy += pv.y; sz += pv.z; sw += pv.w;
    }
    v.x += sx; v.y += sy; v.z += sz; v.w += sw;
    *(float4*)(x + xo) = v;
  }
  __shared__ float sm1[4], sm2[4];
  __shared__ float se[8][4];
  float s = v.x + v.y + v.z + v.w;
  for (int o = 32; o > 0; o >>= 1) s += __shfl_down(s, o);
  if ((tid & 63) == 0) sm1[tid >> 6] = s;
  __syncthreads();
  float mean = (sm1[0] + sm1[1] + sm1[2] + sm1[3]) * (1.0f / DM);
  float d0 = v.x - mean, d1 = v.y - mean, d2 = v.z - mean, d3 = v.w - mean;
  float q = d0 * d0 + d1 * d1 + d2 * d2 + d3 * d3;
  for (int o = 32; o > 0; o >>= 1) q += __shfl_down(q, o);
  if ((tid & 63) == 0) sm2[tid >> 6] = q;
  __syncthreads();
  float var = (sm2[0] + sm2[1] + sm2[2] + sm2[3]) * (1.0f / DM);
  float rstd = rsqrtf(var + 1e-5f);
  float4 gv = ((const float4*)g)[tid];
  float4 bv = ((const float4*)b)[tid];
  float h0 = d0 * rstd * gv.x + bv.x, h1 = d1 * rstd * gv.y + bv.y;
  float h2 = d2 * rstd * gv.z + bv.z, h3 = d3 * rstd * gv.w + bv.w;
  long long base = (long long)row * DM + tid * 4;
  outH[base + 0] = f2b(h0); outH[base + 1] = f2b(h1);
  outH[base + 2] = f2b(h2); outH[base + 3] = f2b(h3);
#pragma unroll
  for (int e = 0; e < 8; ++e) {
    float4 w = ((const float4*)(gw + (long long)e * DM))[tid];
    float p = h0 * w.x + h1 * w.y + h2 * w.z + h3 * w.w;
    for (int o = 32; o > 0; o >>= 1) p += __shfl_down(p, o);
    if ((tid & 63) == 0) se[e][tid >> 6] = p;
  }
  __syncthreads();
  if (tid == 0) {
    float sc[8];
#pragma unroll
    for (int e = 0; e < 8; ++e)
      sc[e] = se[e][0] + se[e][1] + se[e][2] + se[e][3] + gb[e];
    int i1 = 0; float m1 = sc[0];
    for (int e = 1; e < 8; ++e) if (sc[e] > m1) { m1 = sc[e]; i1 = e; }
    int i2 = -1; float m2 = -1e30f;
    for (int e = 0; e < 8; ++e) if (e != i1 && sc[e] > m2) { m2 = sc[e]; i2 = e; }
    float e2 = __expf(m2 - m1);
    float w1 = 1.f / (1.f + e2);
    topi[row * 2] = i1; topi[row * 2 + 1] = i2;
    topw[row * 2] = w1; topw[row * 2 + 1] = 1.f - w1;
    atomicAdd(&counts[i1], 1);
    atomicAdd(&counts[i2], 1);
  }
}

__global__ void moe_prefix(const int* __restrict__ counts, int* __restrict__ offs,
                           int* __restrict__ cursors)
{
  if (threadIdx.x == 0 && blockIdx.x == 0) {
    int a = 0;
    for (int e = 0; e < 8; ++e) { offs[e] = a; a += counts[e]; cursors[e] = 0; }
    offs[8] = a;
  }
}

__global__ __launch_bounds__(256)
void moe_gather(const ushort_t* __restrict__ hH, const int* __restrict__ topi,
                const float* __restrict__ topw, const int* __restrict__ offs,
                int* __restrict__ cursors, int* __restrict__ tokIdx,
                float* __restrict__ tokW, int* __restrict__ slotOf,
                ushort_t* __restrict__ Xg)
{
  int tok = blockIdx.x, tid = threadIdx.x;
  __shared__ int s0s, s1s;
  if (tid == 0) {
    int e0 = topi[tok * 2], e1 = topi[tok * 2 + 1];
    int s0 = offs[e0] + atomicAdd(&cursors[e0], 1);
    int s1 = offs[e1] + atomicAdd(&cursors[e1], 1);
    tokIdx[s0] = tok; tokW[s0] = topw[tok * 2];
    tokIdx[s1] = tok; tokW[s1] = topw[tok * 2 + 1];
    slotOf[tok * 2] = s0; slotOf[tok * 2 + 1] = s1;
    s0s = s0; s1s = s1;
  }
  __syncthreads();
  s4v v = ((const s4v*)(hH + (long long)tok * DM))[tid];
  ((s4v*)(Xg + (long long)s0s * DM))[tid] = v;
  ((s4v*)(Xg + (long long)s1s * DM))[tid] = v;
}

__global__ __launch_bounds__(256)
void moe_ln_final(const float* __restrict__ x, const float* __restrict__ eo,
                  long long pC, const int* __restrict__ slotOf,
                  const int* __restrict__ topi, const float* __restrict__ topw,
                  const float* __restrict__ b2, const float* __restrict__ g,
                  const float* __restrict__ b, ushort_t* __restrict__ outH)
{
  int tok = blockIdx.x, tid = threadIdx.x;
  int s0 = slotOf[tok * 2], s1 = slotOf[tok * 2 + 1];
  int e0 = topi[tok * 2], e1 = topi[tok * 2 + 1];
  float w0 = topw[tok * 2], w1 = topw[tok * 2 + 1];
  float4 a  = ((const float4*)(eo + (long long)s0 * DM))[tid];
  float4 a2 = ((const float4*)(eo + pC + (long long)s0 * DM))[tid];
  float4 bb1= ((const float4*)(eo + (long long)s1 * DM))[tid];
  float4 bb2= ((const float4*)(eo + pC + (long long)s1 * DM))[tid];
  float4 ba = ((const float4*)(b2 + (long long)e0 * DM))[tid];
  float4 bbb= ((const float4*)(b2 + (long long)e1 * DM))[tid];
  float4 v = ((const float4*)(x + (long long)tok * DM))[tid];
  v.x += w0 * (a.x + a2.x + ba.x) + w1 * (bb1.x + bb2.x + bbb.x);
  v.y += w0 * (a.y + a2.y + ba.y) + w1 * (bb1.y + bb2.y + bbb.y);
  v.z += w0 * (a.z + a2.z + ba.z) + w1 * (bb1.z + bb2.z + bbb.z);
  v.w += w0 * (a.w + a2.w + ba.w) + w1 * (bb1.w + bb2.w + bbb.w);
  __shared__ float sm1[4], sm2[4];
  float s = v.x + v.y + v.z + v.w;
  for (int o = 32; o > 0; o >>= 1) s += __shfl_down(s, o);
  if ((tid & 63) == 0) sm1[tid >> 6] = s;
  __syncthreads();
  float mean = (sm1[0] + sm1[1] + sm1[2] + sm1[3]) * (1.0f / DM);
  float d0 = v.x - mean, d1 = v.y - mean, d2 = v.z - mean, d3 = v.w - mean;
  float q = d0 * d0 + d1 * d1 + d2 * d2 + d3 * d3;
  for (int o = 32; o > 0; o >>= 1) q += __shfl_down(q, o);
  if ((tid & 63) == 0) sm2[tid >> 6] = q;
  __syncthreads();
  float var = (sm2[0] + sm2[1] + sm2[2] + sm2[3]) * (1.0f / DM);
  float rstd = rsqrtf(var + 1e-5f);
  float4 gv = ((const float4*)g)[tid];
  float4 bv = ((const float4*)b)[tid];
  long long base = (long long)tok * DM + tid * 4;
  outH[base + 0] = f2b(d0 * rstd * gv.x + bv.x);
  outH[base + 1] = f2b(d1 * rstd * gv.y + bv.y);
  outH[base + 2] = f2b(d2 * rstd * gv.z + bv.z);
  outH[base + 3] = f2b(d3 * rstd * gv.w + bv.w);
}

extern "C" void kernel_launch(void* const* d_in, const int* in_sizes, int n_in,
                              void* d_out, int out_size, void* d_ws, size_t ws_size,
                              hipStream_t stream)
{
  const int* ids = (const int*)d_in[0];
  const float* embed_w = (const float*)d_in[1];
  const float* pos_w   = (const float*)d_in[2];
  const float* ln1_g[2] = {(const float*)d_in[3],  (const float*)d_in[11]};
  const float* ln1_b[2] = {(const float*)d_in[4],  (const float*)d_in[12]};
  const float* in_w[2]  = {(const float*)d_in[5],  (const float*)d_in[13]};
  const float* in_b[2]  = {(const float*)d_in[6],  (const float*)d_in[14]};
  const float* out_w[2] = {(const float*)d_in[7],  (const float*)d_in[15]};
  const float* out_b[2] = {(const float*)d_in[8],  (const float*)d_in[16]};
  const float* ln2_g[2] = {(const float*)d_in[9],  (const float*)d_in[17]};
  const float* ln2_b[2] = {(const float*)d_in[10], (const float*)d_in[18]};
  const float* ffn_w1 = (const float*)d_in[19];
  const float* ffn_b1 = (const float*)d_in[20];
  const float* ffn_w2 = (const float*)d_in[21];
  const float* ffn_b2 = (const float*)d_in[22];
  const float* gate_w = (const float*)d_in[23];
  const float* gate_b = (const float*)d_in[24];
  const float* moe_w1 = (const float*)d_in[25];
  const float* moe_b1 = (const float*)d_in[26];
  const float* moe_w2 = (const float*)d_in[27];
  const float* moe_b2 = (const float*)d_in[28];
  const float* norm_g = (const float*)d_in[29];
  const float* norm_b = (const float*)d_in[30];
  const float* head_w = (const float*)d_in[31];

  char* ob = (char*)d_out;
  size_t off = 0;
  auto alloc = [&](size_t bytes) {
    char* p = ob + off;
    off = (off + bytes + 255) & ~(size_t)255;
    return p;
  };
  float*    x      = (float*)alloc((size_t)SQ * DM * 4);
  ushort_t* hbufH  = (ushort_t*)alloc((size_t)SQ * DM * 2);
  ushort_t* hbufL  = (ushort_t*)alloc((size_t)SQ * DM * 2);
  ushort_t* qkvH   = (ushort_t*)alloc((size_t)SQ * 3 * DM * 2);   // ┐
  ushort_t* qkvL   = (ushort_t*)alloc((size_t)SQ * 3 * DM * 2);   // │ w2b
  ushort_t* VtH    = (ushort_t*)alloc((size_t)NH * HDIM * SQ * 2);// │ 64MiB
  ushort_t* VtL    = (ushort_t*)alloc((size_t)NH * HDIM * SQ * 2);// │
  char*     resv   = (char*)alloc((size_t)32 << 20);              // ┘ filler
  ushort_t* attnH  = (ushort_t*)alloc((size_t)SQ * DM * 2);
  ushort_t* attnL  = (ushort_t*)alloc((size_t)SQ * DM * 2);
  ushort_t* Xg     = (ushort_t*)alloc((size_t)2 * SQ * DM * 2);
  int*      topi   = (int*)alloc(SQ * 2 * 4);
  float*    topw   = (float*)alloc(SQ * 2 * 4);
  int*      tokIdx = (int*)alloc(2 * SQ * 4);
  float*    tokW   = (float*)alloc(2 * SQ * 4);
  int*      slotOf = (int*)alloc(2 * SQ * 4);
  int*      counts = (int*)alloc(256);
  int*      offsb  = (int*)alloc(256);
  int*      cursors= (int*)alloc(256);
  ushort_t* ffnH   = (ushort_t*)alloc((size_t)SQ * FFD * 2);      // ┐ moehid
  ushort_t* ffnL   = (ushort_t*)alloc((size_t)SQ * FFD * 2);      // ┘ 32MiB
  float*    eo     = (float*)alloc((size_t)2 * 2 * SQ * DM * 4);  // 32MiB (also KS partials)
  ushort_t* inwH[2], *inwL[2], *outwH[2], *outwL[2];
  ushort_t* wsplit0 = (ushort_t*)alloc(0);
  inwH[0]  = (ushort_t*)alloc((size_t)3 * DM * DM * 2);
  inwL[0]  = (ushort_t*)alloc((size_t)3 * DM * DM * 2);
  inwH[1]  = (ushort_t*)alloc((size_t)3 * DM * DM * 2);
  inwL[1]  = (ushort_t*)alloc((size_t)3 * DM * DM * 2);
  outwH[0] = (ushort_t*)alloc((size_t)DM * DM * 2);
  outwL[0] = (ushort_t*)alloc((size_t)DM * DM * 2);
  outwH[1] = (ushort_t*)alloc((size_t)DM * DM * 2);
  outwL[1] = (ushort_t*)alloc((size_t)DM * DM * 2);
  ushort_t* f1H = (ushort_t*)alloc((size_t)FFD * DM * 2);
  ushort_t* f1L = (ushort_t*)alloc((size_t)FFD * DM * 2);
  ushort_t* f2H = (ushort_t*)alloc((size_t)DM * FFD * 2);
  ushort_t* f2L = (ushort_t*)alloc((size_t)DM * FFD * 2);
  ushort_t* moe_w1b = wsplit0;            // 64 MiB over weight planes
  ushort_t* moe_w2b = qkvH;               // 64 MiB over qkv+Vt+resv
  ushort_t* moehid  = ffnH;               // 32 MiB over ffn planes
  float*    pp      = eo;                 // KS partial planes
  const long long eoPC = (long long)2 * SQ * DM;
  const long long ppPC = (long long)SQ * DM;
  ushort_t* hfin    = (ushort_t*)d_ws;
  bool wsBig = ws_size >= ((size_t)70 << 20);
  ushort_t* head_wb = (ushort_t*)((char*)d_ws + ((size_t)4 << 20));
  (void)resv;

  embed_kernel<<<SQ, 256, 0, stream>>>(ids, embed_w, pos_w, x, counts);
  cvt_split2<<<dim3(512, 2), 256, 0, stream>>>(
      in_w[0], inwH[0], inwL[0], in_w[1], inwH[1], inwL[1], 3 * DM * DM / 4);
  cvt_split2<<<dim3(512, 2), 256, 0, stream>>>(
      out_w[0], outwH[0], outwL[0], out_w[1], outwH[1], outwL[1], DM * DM / 4);
  cvt_split2<<<dim3(512, 2), 256, 0, stream>>>(
      ffn_w1, f1H, f1L, ffn_w2, f2H, f2L, FFD * DM / 4);
  if (wsBig)
    cvt_bf16<<<1024, 256, 0, stream>>>(head_w, head_wb, NVOC * DM / 4);

  // ---- Layer 0 ----
  ln_fused<0, 0><<<SQ, 256, 0, stream>>>(x, nullptr, 0, nullptr,
                                         ln1_g[0], ln1_b[0], hbufH, hbufL);
  k_qkv<<<dim3(16, 24, 1), 256, 0, stream>>>(
      hbufH, hbufL, DM, 0, inwH[0], inwL[0], DM, 0,
      nullptr, qkvH, qkvL, 3 * DM, 0, 0,
      SQ, 3 * DM, DM, in_b[0], 1.f, VtH, VtL);
  k_attn<<<dim3(SQ / 64, NH), 256, 0, stream>>>(qkvH, qkvL, VtH, VtL,
                                                attnH, attnL);
  k_outp<<<dim3(16, 16, 4), 256, 0, stream>>>(
      attnH, attnL, DM, 0, outwH[0], outwL[0], DM, 0,
      pp, nullptr, nullptr, DM, 0, ppPC,
      SQ, DM, DM / 4, nullptr, 1.f, nullptr, nullptr);
  ln_fused<0, 4><<<SQ, 256, 0, stream>>>(x, pp, ppPC, out_b[0],
                                         ln2_g[0], ln2_b[0], hbufH, hbufL);
  k_ffn1<<<dim3(16, 32, 1), 256, 0, stream>>>(
      hbufH, hbufL, DM, 0, f1H, f1L, DM, 0,
      nullptr, ffnH, ffnL, FFD, 0, 0,
      SQ, FFD, DM, ffn_b1, 1.f, nullptr, nullptr);
  k_ffn2<<<dim3(16, 16, 2), 256, 0, stream>>>(
      ffnH, ffnL, FFD, 0, f2H, f2L, FFD, 0,
      pp, nullptr, nullptr, DM, 0, ppPC,
      SQ, DM, FFD / 2, nullptr, 1.f, nullptr, nullptr);
  // ---- Layer 1 ----
  ln_fused<0, 2><<<SQ, 256, 0, stream>>>(x, pp, ppPC, ffn_b2,
                                         ln1_g[1], ln1_b[1], hbufH, hbufL);
  k_qkv<<<dim3(16, 24, 1), 256, 0, stream>>>(
      hbufH, hbufL, DM, 0, inwH[1], inwL[1], DM, 0,
      nullptr, qkvH, qkvL, 3 * DM, 0, 0,
      SQ, 3 * DM, DM, in_b[1], 1.f, VtH, VtL);
  k_attn<<<dim3(SQ / 64, NH), 256, 0, stream>>>(qkvH, qkvL, VtH, VtL,
                                                attnH, attnL);
  k_outp<<<dim3(16, 16, 4), 256, 0, stream>>>(
      attnH, attnL, DM, 0, outwH[1], outwL[1], DM, 0,
      pp, nullptr, nullptr, DM, 0, ppPC,
      SQ, DM, DM / 4, nullptr, 1.f, nullptr, nullptr);
  cvt_bf16_2<<<dim3(2048, 2), 256, 0, stream>>>(
      moe_w1, moe_w1b, moe_w2, moe_w2b, 8 * FFD * DM / 4);
  ln_gate_top2<<<SQ, 256, 0, stream>>>(x, pp, ppPC, out_b[1],
                                       ln2_g[1], ln2_b[1], gate_w, gate_b,
                                       topi, topw, counts, hbufH);
  moe_prefix<<<1, 64, 0, stream>>>(counts, offsb, cursors);
  moe_gather<<<SQ, 256, 0, stream>>>(hbufH, topi, topw, offsb, cursors,
                                     tokIdx, tokW, slotOf, Xg);
  k_moe1<<<dim3(32, 16, 8), 256, 0, stream>>>(
      Xg, DM, 0, moe_w1b, DM, (long long)FFD * DM,
      moehid, FFD, 0, 0, SQ, FFD, DM, moe_b1, FFD, offsb);
  k_moe2<<<dim3(8, 16, 16), 256, 0, stream>>>(
      moehid, FFD, 0, moe_w2b, FFD, (long long)DM * FFD,
      eo, DM, 0, eoPC, SQ, DM, FFD, nullptr, 0, offsb);
  moe_ln_final<<<SQ, 256, 0, stream>>>(x, eo, eoPC, slotOf, topi, topw,
                                       moe_b2, norm_g, norm_b, hfin);
  if (wsBig)
    k_head_bf<<<dim3(16, 250, 1), 256, 0, stream>>>(
        hfin, DM, 0, head_wb, DM, 0, d_out, NVOC, 0, 0,
        SQ, NVOC, DM, nullptr, 0, nullptr);
  else
    k_head_f<<<dim3(16, 250, 1), 256, 0, stream>>>(
        hfin, DM, 0, head_w, DM, 0, d_out, NVOC, 0, 0,
        SQ, NVOC, DM, nullptr, 0, nullptr);
}